// Round 1
// baseline (29190.671 us; speedup 1.0000x reference)
//
#include <hip/hip_runtime.h>
#include <hip/hip_bf16.h>
#include <math.h>

#define D 768
#define NH 12
#define HD 64
#define NEXP 4
#define FF 3072
#define NBLK 2
#define DEPTH 6
#define NA 64
#define NB 32
#define NC 192
#define BATCH 8
#define TTRAJ 256
#define NTOK 544          // 256 + 64 + 32 + 192
#define MAXTOK 1536       // max tokens in one MoE group (cg: 8*192)

__device__ __forceinline__ float siluf(float v) { return v / (1.f + expf(-v)); }
__device__ __forceinline__ float geluf(float v) {
    float u = 0.7978845608028654f * (v + 0.044715f * v * v * v);
    return 0.5f * v * (1.f + tanhf(u));
}

// ---------------- timestep embedding ----------------
__global__ void timestep_kernel(const int* __restrict__ t, float* __restrict__ temb) {
    int i = blockIdx.x * blockDim.x + threadIdx.x;
    if (i >= BATCH * 128) return;
    int b = i >> 7, j = i & 127;
    float freq = expf(-logf(10000.f) * (float)j / 128.f);
    float ang = (float)t[b] * freq;
    temb[b * 256 + j] = cosf(ang);
    temb[b * 256 + 128 + j] = sinf(ang);
}

__global__ void silu_vec(const float* __restrict__ in, float* __restrict__ out, int n) {
    int i = blockIdx.x * blockDim.x + threadIdx.x;
    if (i < n) out[i] = siluf(in[i]);
}

__global__ void add_ftime(float* __restrict__ traj, const float* __restrict__ wf, int total) {
    int i = blockIdx.x * blockDim.x + threadIdx.x;
    if (i >= total) return;
    int col = i % D;
    int n = (i / D) % TTRAJ;
    traj[i] += wf[(n & 7) * D + col];
}

// ---------------- generic f32 GEMM, C = act(A@B + bias) ----------------
// A row-major [M,lda-stride], B row-major [K,N] (ldb), bias nullable len N.
template<int ACT>
__global__ __launch_bounds__(256) void gemm_act(
    const float* __restrict__ A, int lda,
    const float* __restrict__ B, int ldb,
    const float* __restrict__ bias,
    float* __restrict__ C, int ldc,
    int M, int N, int K)
{
    __shared__ float As[16][65];
    __shared__ float Bs[16][65];
    int tid = threadIdx.x;
    int tx = tid & 15, ty = tid >> 4;
    int row0 = blockIdx.y * 64, col0 = blockIdx.x * 64;
    float acc[4][4] = {};
    for (int k0 = 0; k0 < K; k0 += 16) {
        #pragma unroll
        for (int i = 0; i < 4; ++i) {
            int e = tid + 256 * i; int m = e >> 4; int kk = e & 15;
            int gr = row0 + m, gk = k0 + kk;
            As[kk][m] = (gr < M && gk < K) ? A[(size_t)gr * lda + gk] : 0.f;
        }
        #pragma unroll
        for (int i = 0; i < 4; ++i) {
            int e = tid + 256 * i; int kk = e >> 6; int n = e & 63;
            int gk = k0 + kk, gc = col0 + n;
            Bs[kk][n] = (gk < K && gc < N) ? B[(size_t)gk * ldb + gc] : 0.f;
        }
        __syncthreads();
        #pragma unroll
        for (int kk = 0; kk < 16; ++kk) {
            float a[4], bv[4];
            #pragma unroll
            for (int i = 0; i < 4; ++i) a[i] = As[kk][ty * 4 + i];
            #pragma unroll
            for (int j = 0; j < 4; ++j) bv[j] = Bs[kk][tx * 4 + j];
            #pragma unroll
            for (int i = 0; i < 4; ++i)
                #pragma unroll
                for (int j = 0; j < 4; ++j) acc[i][j] += a[i] * bv[j];
        }
        __syncthreads();
    }
    #pragma unroll
    for (int i = 0; i < 4; ++i) {
        int gr = row0 + ty * 4 + i; if (gr >= M) continue;
        #pragma unroll
        for (int j = 0; j < 4; ++j) {
            int gc = col0 + tx * 4 + j; if (gc >= N) continue;
            float v = acc[i][j] + (bias ? bias[gc] : 0.f);
            if (ACT == 1) v = siluf(v);
            if (ACT == 2) v = geluf(v);
            C[(size_t)gr * ldc + gc] = v;
        }
    }
}

// ---------------- LayerNorm (+ optional adaLN modulate) ----------------
// Y[r] = norm(X[r]) * (1 + mod[b, scale_chunk*D + col]) + mod[b, shift_chunk*D + col]
__global__ __launch_bounds__(256) void ln_kernel(
    const float* __restrict__ X, float* __restrict__ Y, int R, int ntok,
    const float* __restrict__ mod, int modstride, int shift_chunk, int scale_chunk)
{
    int r = blockIdx.x;
    if (r >= R) return;
    const float* xr = X + (size_t)r * D;
    int tid = threadIdx.x;
    int lane = tid & 63, wid = tid >> 6;
    float v0 = xr[tid], v1 = xr[tid + 256], v2 = xr[tid + 512];
    float s = v0 + v1 + v2;
    float s2 = v0 * v0 + v1 * v1 + v2 * v2;
    for (int off = 32; off > 0; off >>= 1) {
        s += __shfl_xor(s, off, 64);
        s2 += __shfl_xor(s2, off, 64);
    }
    __shared__ float shs[4], shs2[4];
    if (lane == 0) { shs[wid] = s; shs2[wid] = s2; }
    __syncthreads();
    float tot = shs[0] + shs[1] + shs[2] + shs[3];
    float tot2 = shs2[0] + shs2[1] + shs2[2] + shs2[3];
    float mu = tot * (1.f / 768.f);
    float var = tot2 * (1.f / 768.f) - mu * mu;
    float rs = rsqrtf(var + 1e-6f);
    int bb = r / ntok;
    float vv[3] = {v0, v1, v2};
    #pragma unroll
    for (int j = 0; j < 3; ++j) {
        int col = tid + j * 256;
        float nrm = (vv[j] - mu) * rs;
        float y = nrm;
        if (mod) {
            float scv = mod[(size_t)bb * modstride + scale_chunk * D + col];
            float shv = mod[(size_t)bb * modstride + shift_chunk * D + col];
            y = nrm * (1.f + scv) + shv;
        }
        Y[(size_t)r * D + col] = y;
    }
}

// ---------------- attention: one wave per (b, h, q-row), exact online softmax ----------------
__global__ __launch_bounds__(64) void attn_kernel(
    const float* __restrict__ Q, const float* __restrict__ K, const float* __restrict__ V,
    float* __restrict__ O, int Nq, int Nkv, int ldq, int ldk, int ldv, int ldo, float scale)
{
    int iq = blockIdx.x, h = blockIdx.y, b = blockIdx.z, d = threadIdx.x;
    float qd = Q[((size_t)b * Nq + iq) * ldq + h * HD + d];
    const float* Kb = K + (size_t)b * Nkv * ldk + h * HD + d;
    const float* Vb = V + (size_t)b * Nkv * ldv + h * HD + d;
    float m = -INFINITY, l = 0.f, acc = 0.f;
    for (int kk = 0; kk < Nkv; ++kk) {
        float sp = qd * Kb[(size_t)kk * ldk];
        for (int off = 32; off > 0; off >>= 1) sp += __shfl_xor(sp, off, 64);
        float sc = sp * scale;
        float mn = fmaxf(m, sc);
        float esc = expf(m - mn);
        float p = expf(sc - mn);
        l = l * esc + p;
        acc = acc * esc + p * Vb[(size_t)kk * ldv];
        m = mn;
    }
    O[((size_t)b * Nq + iq) * ldo + h * HD + d] = acc / l;
}

// ---------------- residual add (optionally gated by adaLN gate chunk) ----------------
__global__ void add_gated(float* __restrict__ dst, const float* __restrict__ src,
                          const float* __restrict__ mod, int modstride, int gchunk,
                          int ntok, int total)
{
    int i = blockIdx.x * blockDim.x + threadIdx.x;
    if (i >= total) return;
    float g = 1.f;
    if (mod) {
        int col = i % D;
        int bb = i / (ntok * D);
        g = mod[(size_t)bb * modstride + gchunk * D + col];
    }
    dst[i] += g * src[i];
}

// ---------------- MoE: router (top-1 switch) ----------------
__global__ __launch_bounds__(64) void router_kernel(
    const float* __restrict__ X, const float* __restrict__ Wr,
    int* __restrict__ idx, float* __restrict__ gval)
{
    int tkn = blockIdx.x; int lane = threadIdx.x;
    const float* xr = X + (size_t)tkn * D;
    float p0 = 0, p1 = 0, p2 = 0, p3 = 0;
    for (int dd = lane; dd < D; dd += 64) {
        float xv = xr[dd];
        const float* w = Wr + dd * 4;
        p0 += xv * w[0]; p1 += xv * w[1]; p2 += xv * w[2]; p3 += xv * w[3];
    }
    for (int off = 32; off > 0; off >>= 1) {
        p0 += __shfl_xor(p0, off, 64); p1 += __shfl_xor(p1, off, 64);
        p2 += __shfl_xor(p2, off, 64); p3 += __shfl_xor(p3, off, 64);
    }
    if (lane == 0) {
        float best = p0; int e = 0;
        if (p1 > best) { best = p1; e = 1; }
        if (p2 > best) { best = p2; e = 2; }
        if (p3 > best) { best = p3; e = 3; }
        float sum = expf(p0 - best) + expf(p1 - best) + expf(p2 - best) + expf(p3 - best);
        idx[tkn] = e;
        gval[tkn] = 1.f / sum;   // softmax prob of the argmax expert
    }
}

__global__ void scatter_kernel(const int* __restrict__ idx, int* __restrict__ cnt,
                               int* __restrict__ list, int ntok)
{
    int i = blockIdx.x * blockDim.x + threadIdx.x;
    if (i >= ntok) return;
    int e = idx[i];
    int pos = atomicAdd(&cnt[e], 1);
    list[e * MAXTOK + pos] = i;
}

// ---------------- MoE: gathered expert GEMM ----------------
// PHASE 1: h[token] = gelu(lnX[token] @ W1[e]),  K=768, N=3072
// PHASE 2: group[token] += gval[token] * (h[token] @ W2[e]), K=3072, N=768
template<int PHASE>
__global__ __launch_bounds__(256) void moe_gemm(
    const float* __restrict__ A, const float* __restrict__ Bbase,
    float* __restrict__ C,
    const int* __restrict__ cnt, const int* __restrict__ list,
    const float* __restrict__ gval,
    int RT, int N, int K)
{
    const int lda = (PHASE == 1) ? 768 : 3072;
    const int ldc = (PHASE == 1) ? 3072 : 768;
    int e = blockIdx.y / RT, rt = blockIdx.y % RT;
    int c = cnt[e];
    int mbase = rt * 64;
    if (mbase >= c) return;
    int mcount = min(64, c - mbase);
    const int* lst = list + e * MAXTOK + mbase;
    const float* B = Bbase + (size_t)e * (768 * 3072);
    __shared__ int toks[64];
    __shared__ float As[16][65];
    __shared__ float Bs[16][65];
    int tid = threadIdx.x, tx = tid & 15, ty = tid >> 4;
    if (tid < 64) toks[tid] = (tid < mcount) ? lst[tid] : lst[0];
    __syncthreads();
    int col0 = blockIdx.x * 64;
    float acc[4][4] = {};
    for (int k0 = 0; k0 < K; k0 += 16) {
        #pragma unroll
        for (int i = 0; i < 4; ++i) {
            int el = tid + 256 * i; int m = el >> 4; int kk = el & 15;
            As[kk][m] = A[(size_t)toks[m] * lda + k0 + kk];
        }
        #pragma unroll
        for (int i = 0; i < 4; ++i) {
            int el = tid + 256 * i; int kk = el >> 6; int n = el & 63;
            Bs[kk][n] = B[(size_t)(k0 + kk) * N + col0 + n];
        }
        __syncthreads();
        #pragma unroll
        for (int kk = 0; kk < 16; ++kk) {
            float a[4], bv[4];
            #pragma unroll
            for (int i = 0; i < 4; ++i) a[i] = As[kk][ty * 4 + i];
            #pragma unroll
            for (int j = 0; j < 4; ++j) bv[j] = Bs[kk][tx * 4 + j];
            #pragma unroll
            for (int i = 0; i < 4; ++i)
                #pragma unroll
                for (int j = 0; j < 4; ++j) acc[i][j] += a[i] * bv[j];
        }
        __syncthreads();
    }
    #pragma unroll
    for (int i = 0; i < 4; ++i) {
        int m = ty * 4 + i; if (m >= mcount) continue;
        int tok = toks[m];
        #pragma unroll
        for (int j = 0; j < 4; ++j) {
            int gc = col0 + tx * 4 + j;
            if (PHASE == 1) C[(size_t)tok * 3072 + gc] = geluf(acc[i][j]);
            else            C[(size_t)tok * 768 + gc] += gval[tok] * acc[i][j];
        }
    }
}

// ---------------- concat [traj | A | B | C] -> x ----------------
__global__ void concat_kernel(const float* __restrict__ traj, const float* __restrict__ a,
                              const float* __restrict__ bg, const float* __restrict__ cg,
                              float* __restrict__ x, int total)
{
    int i = blockIdx.x * blockDim.x + threadIdx.x;
    if (i >= total) return;
    int col = i % D;
    int r = i / D;
    int n = r % NTOK, b = r / NTOK;
    float v;
    if (n < 256)      v = traj[((size_t)b * 256 + n) * D + col];
    else if (n < 320) v = a[((size_t)b * 64 + (n - 256)) * D + col];
    else if (n < 352) v = bg[((size_t)b * 32 + (n - 320)) * D + col];
    else              v = cg[((size_t)b * 192 + (n - 352)) * D + col];
    x[i] = v;
}

// ---------------- output head: traj tokens only, [768] -> [14] ----------------
__global__ __launch_bounds__(64) void head_kernel(
    const float* __restrict__ H, const float* __restrict__ W,
    const float* __restrict__ bias, float* __restrict__ out)
{
    int r = blockIdx.x;           // 0 .. B*256-1
    int b = r >> 8, n = r & 255;
    const float* h = H + ((size_t)(b * NTOK + n)) * D;
    __shared__ float hs[D];
    for (int dd = threadIdx.x; dd < D; dd += 64) hs[dd] = h[dd];
    __syncthreads();
    int t = threadIdx.x;
    if (t < 14) {
        float acc = bias[t];
        for (int dd = 0; dd < D; ++dd) acc += hs[dd] * W[dd * 14 + t];
        out[(size_t)r * 14 + t] = acc;
    }
}

// ---------------- host ----------------
static inline void gemm(int act, const float* A, int lda, const float* B, int ldb,
                        const float* bias, float* C, int ldc, int M, int N, int K,
                        hipStream_t s)
{
    dim3 g((N + 63) / 64, (M + 63) / 64);
    if (act == 0)      gemm_act<0><<<g, 256, 0, s>>>(A, lda, B, ldb, bias, C, ldc, M, N, K);
    else if (act == 1) gemm_act<1><<<g, 256, 0, s>>>(A, lda, B, ldb, bias, C, ldc, M, N, K);
    else               gemm_act<2><<<g, 256, 0, s>>>(A, lda, B, ldb, bias, C, ldc, M, N, K);
}

extern "C" void kernel_launch(void* const* d_in, const int* in_sizes, int n_in,
                              void* d_out, int out_size, void* d_ws, size_t ws_size,
                              hipStream_t stream)
{
    const float* x_traj   = (const float*)d_in[0];
    const int*   t_arr    = (const int*)d_in[1];
    const float* tokA     = (const float*)d_in[2];
    const float* tokB     = (const float*)d_in[3];
    const float* tokC     = (const float*)d_in[4];
    const float* W_traj   = (const float*)d_in[5];
    const float* b_traj   = (const float*)d_in[6];
    const float* W_ftime  = (const float*)d_in[7];
    const float* Wt1      = (const float*)d_in[8];
    const float* bt1      = (const float*)d_in[9];
    const float* Wt2      = (const float*)d_in[10];
    const float* bt2      = (const float*)d_in[11];
    const float* moe_attn = (const float*)d_in[12];
    const float* moe_rout = (const float*)d_in[13];
    const float* moe_W1   = (const float*)d_in[14];
    const float* moe_W2   = (const float*)d_in[15];
    const float* dit_qkv  = (const float*)d_in[16];
    const float* dit_qkvb = (const float*)d_in[17];
    const float* dit_proj = (const float*)d_in[18];
    const float* dit_projb= (const float*)d_in[19];
    const float* dit_mlp1 = (const float*)d_in[20];
    const float* dit_mlp1b= (const float*)d_in[21];
    const float* dit_mlp2 = (const float*)d_in[22];
    const float* dit_mlp2b= (const float*)d_in[23];
    const float* dit_ada  = (const float*)d_in[24];
    const float* dit_adab = (const float*)d_in[25];
    const float* out_adaW = (const float*)d_in[26];
    const float* out_adab = (const float*)d_in[27];
    const float* out_W    = (const float*)d_in[28];
    const float* out_b    = (const float*)d_in[29];
    float* out = (float*)d_out;
    float* ws = (float*)d_ws;

    // workspace layout (floats)
    const size_t o_temb = 0;                       // 2048
    const size_t o_u    = o_temb + 2048;           // 6144
    const size_t o_c    = o_u + 6144;              // 6144
    const size_t o_sc   = o_c + 6144;              // 6144
    const size_t o_mod  = o_sc + 6144;             // 36864 (8x4608)
    const size_t o_cnt  = o_mod + 36864;           // 64 ints
    const size_t o_idx  = o_cnt + 64;              // 1536 ints
    const size_t o_gval = o_idx + 1536;            // 1536
    const size_t o_list = o_gval + 1536;           // 6144 ints
    const size_t o_traj = o_list + 6144;           // 1572864
    const size_t o_a    = o_traj + 1572864;        // 393216
    const size_t o_bg   = o_a + 393216;            // 196608
    const size_t o_cg   = o_bg + 196608;           // 1179648
    const size_t o_x    = o_cg + 1179648;          // 3342336
    const size_t o_S1   = o_x + 3342336;           // 13369344 (qkv / mlp-h / moe-h / cross qkv+o)
    const size_t o_S2   = o_S1 + 13369344;         // 3342336 (ln buf)
    const size_t o_S3   = o_S2 + 3342336;          // 3342336 (attn out)
    // cross-attn scratch carved from S1:
    const size_t o_q = o_S1;
    const size_t o_k = o_S1 + 1179648;
    const size_t o_v = o_S1 + 2359296;
    const size_t o_o = o_S1 + 3538944;

    int* cnt_p  = (int*)(ws + o_cnt);
    int* idx_p  = (int*)(ws + o_idx);
    int* list_p = (int*)(ws + o_list);
    float* gval_p = ws + o_gval;

    // ---- timestep conditioning ----
    timestep_kernel<<<4, 256, 0, stream>>>(t_arr, ws + o_temb);
    gemm(1, ws + o_temb, 256, Wt1, D, bt1, ws + o_u, D, BATCH, D, 256, stream);
    gemm(0, ws + o_u, D, Wt2, D, bt2, ws + o_c, D, BATCH, D, D, stream);
    silu_vec<<<24, 256, 0, stream>>>(ws + o_c, ws + o_sc, BATCH * D);

    // ---- trajectory embedding ----
    gemm(0, x_traj, 7, W_traj, D, b_traj, ws + o_traj, D, BATCH * TTRAJ, D, 7, stream);
    add_ftime<<<(BATCH * TTRAJ * D + 255) / 256, 256, 0, stream>>>(ws + o_traj, W_ftime, BATCH * TTRAJ * D);

    // ---- group buffers (mutable copies) ----
    hipMemcpyAsync(ws + o_a, tokA, (size_t)BATCH * NA * D * 4, hipMemcpyDeviceToDevice, stream);
    hipMemcpyAsync(ws + o_bg, tokB, (size_t)BATCH * NB * D * 4, hipMemcpyDeviceToDevice, stream);
    hipMemcpyAsync(ws + o_cg, tokC, (size_t)BATCH * NC * D * 4, hipMemcpyDeviceToDevice, stream);

    const size_t WSZ = (size_t)D * D;   // 589824 per attn matrix
    for (int i = 0; i < NBLK; ++i) {
        // cross 1: cg += cross(ln(cg), a)
        {
            int Rq = BATCH * NC, Rkv = BATCH * NA;
            const float* Wc = moe_attn + (size_t)(i * 2 + 0) * 4 * WSZ;
            ln_kernel<<<Rq, 256, 0, stream>>>(ws + o_cg, ws + o_S2, Rq, NC, nullptr, 0, 0, 0);
            gemm(0, ws + o_S2, D, Wc + 0 * WSZ, D, nullptr, ws + o_q, D, Rq, D, D, stream);
            gemm(0, ws + o_a, D, Wc + 1 * WSZ, D, nullptr, ws + o_k, D, Rkv, D, D, stream);
            gemm(0, ws + o_a, D, Wc + 2 * WSZ, D, nullptr, ws + o_v, D, Rkv, D, D, stream);
            attn_kernel<<<dim3(NC, NH, BATCH), 64, 0, stream>>>(
                ws + o_q, ws + o_k, ws + o_v, ws + o_S3, NC, NA, D, D, D, D, 0.125f);
            gemm(0, ws + o_S3, D, Wc + 3 * WSZ, D, nullptr, ws + o_o, D, Rq, D, D, stream);
            add_gated<<<(Rq * D + 255) / 256, 256, 0, stream>>>(
                ws + o_cg, ws + o_o, nullptr, 0, 0, NC, Rq * D);
        }
        // cross 2: bg += cross(ln(bg), cg)
        {
            int Rq = BATCH * NB, Rkv = BATCH * NC;
            const float* Wc = moe_attn + (size_t)(i * 2 + 1) * 4 * WSZ;
            ln_kernel<<<Rq, 256, 0, stream>>>(ws + o_bg, ws + o_S2, Rq, NB, nullptr, 0, 0, 0);
            gemm(0, ws + o_S2, D, Wc + 0 * WSZ, D, nullptr, ws + o_q, D, Rq, D, D, stream);
            gemm(0, ws + o_cg, D, Wc + 1 * WSZ, D, nullptr, ws + o_k, D, Rkv, D, D, stream);
            gemm(0, ws + o_cg, D, Wc + 2 * WSZ, D, nullptr, ws + o_v, D, Rkv, D, D, stream);
            attn_kernel<<<dim3(NB, NH, BATCH), 64, 0, stream>>>(
                ws + o_q, ws + o_k, ws + o_v, ws + o_S3, NB, NC, D, D, D, D, 0.125f);
            gemm(0, ws + o_S3, D, Wc + 3 * WSZ, D, nullptr, ws + o_o, D, Rq, D, D, stream);
            add_gated<<<(Rq * D + 255) / 256, 256, 0, stream>>>(
                ws + o_bg, ws + o_o, nullptr, 0, 0, NB, Rq * D);
        }
        // MoE on a, bg, cg (groups 0,1,2)
        const int gn[3] = {BATCH * NA, BATCH * NB, BATCH * NC};
        float* gptr[3] = {ws + o_a, ws + o_bg, ws + o_cg};
        for (int g = 0; g < 3; ++g) {
            int ntok = gn[g];
            const float* Wr = moe_rout + (size_t)(i * 3 + g) * D * NEXP;
            const float* W1 = moe_W1 + (size_t)(i * 3 + g) * NEXP * D * FF;
            const float* W2 = moe_W2 + (size_t)(i * 3 + g) * NEXP * FF * D;
            ln_kernel<<<ntok, 256, 0, stream>>>(gptr[g], ws + o_S2, ntok, 1, nullptr, 0, 0, 0);
            hipMemsetAsync((void*)cnt_p, 0, 4 * sizeof(int), stream);
            router_kernel<<<ntok, 64, 0, stream>>>(ws + o_S2, Wr, idx_p, gval_p);
            scatter_kernel<<<(ntok + 255) / 256, 256, 0, stream>>>(idx_p, cnt_p, list_p, ntok);
            int RT = (ntok + 63) / 64;
            moe_gemm<1><<<dim3(FF / 64, NEXP * RT), 256, 0, stream>>>(
                ws + o_S2, W1, ws + o_S1, cnt_p, list_p, gval_p, RT, FF, D);
            moe_gemm<2><<<dim3(D / 64, NEXP * RT), 256, 0, stream>>>(
                ws + o_S1, W2, gptr[g], cnt_p, list_p, gval_p, RT, D, FF);
        }
    }

    // ---- concat into x ----
    concat_kernel<<<(BATCH * NTOK * D + 255) / 256, 256, 0, stream>>>(
        ws + o_traj, ws + o_a, ws + o_bg, ws + o_cg, ws + o_x, BATCH * NTOK * D);

    const int R = BATCH * NTOK;   // 4352
    for (int i = 0; i < DEPTH; ++i) {
        // mod = silu(c) @ ada + b  -> [8, 4608]; chunks: s1,sc1,g1,s2,sc2,g2
        gemm(0, ws + o_sc, D, dit_ada + (size_t)i * D * 6 * D, 6 * D,
             dit_adab + (size_t)i * 6 * D, ws + o_mod, 6 * D, BATCH, 6 * D, D, stream);
        // h = ln(x)*(1+sc1)+s1
        ln_kernel<<<R, 256, 0, stream>>>(ws + o_x, ws + o_S2, R, NTOK, ws + o_mod, 6 * D, 0, 1);
        // qkv
        gemm(0, ws + o_S2, D, dit_qkv + (size_t)i * D * 3 * D, 3 * D,
             dit_qkvb + (size_t)i * 3 * D, ws + o_S1, 3 * D, R, 3 * D, D, stream);
        attn_kernel<<<dim3(NTOK, NH, BATCH), 64, 0, stream>>>(
            ws + o_S1, ws + o_S1 + D, ws + o_S1 + 2 * D, ws + o_S3,
            NTOK, NTOK, 3 * D, 3 * D, 3 * D, D, 0.125f);
        // proj, then x += g1 * (.)
        gemm(0, ws + o_S3, D, dit_proj + (size_t)i * D * D, D,
             dit_projb + (size_t)i * D, ws + o_S2, D, R, D, D, stream);
        add_gated<<<(R * D + 255) / 256, 256, 0, stream>>>(
            ws + o_x, ws + o_S2, ws + o_mod, 6 * D, 2, NTOK, R * D);
        // h = ln(x)*(1+sc2)+s2
        ln_kernel<<<R, 256, 0, stream>>>(ws + o_x, ws + o_S2, R, NTOK, ws + o_mod, 6 * D, 3, 4);
        // mlp
        gemm(2, ws + o_S2, D, dit_mlp1 + (size_t)i * D * FF, FF,
             dit_mlp1b + (size_t)i * FF, ws + o_S1, FF, R, FF, D, stream);
        gemm(0, ws + o_S1, FF, dit_mlp2 + (size_t)i * FF * D, D,
             dit_mlp2b + (size_t)i * D, ws + o_S3, D, R, D, FF, stream);
        add_gated<<<(R * D + 255) / 256, 256, 0, stream>>>(
            ws + o_x, ws + o_S3, ws + o_mod, 6 * D, 5, NTOK, R * D);
    }

    // ---- output head ----
    gemm(0, ws + o_sc, D, out_adaW, 2 * D, out_adab, ws + o_mod, 2 * D, BATCH, 2 * D, D, stream);
    ln_kernel<<<R, 256, 0, stream>>>(ws + o_x, ws + o_S2, R, NTOK, ws + o_mod, 2 * D, 0, 1);
    head_kernel<<<BATCH * TTRAJ, 64, 0, stream>>>(ws + o_S2, out_W, out_b, out);
}

// Round 2
// 5914.965 us; speedup vs baseline: 4.9351x; 4.9351x over previous
//
#include <hip/hip_runtime.h>
#include <hip/hip_bf16.h>
#include <math.h>

#define D 768
#define NH 12
#define HD 64
#define NEXP 4
#define FF 3072
#define NBLK 2
#define DEPTH 6
#define NA 64
#define NB 32
#define NC 192
#define BATCH 8
#define TTRAJ 256
#define NTOK 544
#define MAXTOK 1536

typedef __attribute__((ext_vector_type(8))) short short8v;   // 8 bf16 (4 VGPRs)
typedef __attribute__((ext_vector_type(4))) float f32x4;

__device__ __forceinline__ float siluf(float v) { return v / (1.f + expf(-v)); }
__device__ __forceinline__ float geluf(float v) {
    float u = 0.7978845608028654f * (v + 0.044715f * v * v * v);
    return 0.5f * v * (1.f + tanhf(u));
}
__device__ __forceinline__ unsigned short f2bf(float f) {
    union { float f; unsigned u; } v; v.f = f;
    unsigned r = v.u + 0x7fffu + ((v.u >> 16) & 1u);
    return (unsigned short)(r >> 16);
}

// ---------------- timestep embedding ----------------
__global__ void timestep_kernel(const int* __restrict__ t, float* __restrict__ temb) {
    int i = blockIdx.x * blockDim.x + threadIdx.x;
    if (i >= BATCH * 128) return;
    int b = i >> 7, j = i & 127;
    float freq = expf(-logf(10000.f) * (float)j / 128.f);
    float ang = (float)t[b] * freq;
    temb[b * 256 + j] = cosf(ang);
    temb[b * 256 + 128 + j] = sinf(ang);
}

__global__ void silu_vec(const float* __restrict__ in, float* __restrict__ out, int n) {
    int i = blockIdx.x * blockDim.x + threadIdx.x;
    if (i < n) out[i] = siluf(in[i]);
}

__global__ void add_ftime(float* __restrict__ traj, const float* __restrict__ wf, int total) {
    int i = blockIdx.x * blockDim.x + threadIdx.x;
    if (i >= total) return;
    int col = i % D;
    int n = (i / D) % TTRAJ;
    traj[i] += wf[(n & 7) * D + col];
}

// ---------------- small f32 GEMM (kept for M=8 conditioning GEMMs, K=7 embed) ----
template<int ACT>
__global__ __launch_bounds__(256) void gemm_act(
    const float* __restrict__ A, int lda,
    const float* __restrict__ B, int ldb,
    const float* __restrict__ bias,
    float* __restrict__ C, int ldc,
    int M, int N, int K)
{
    __shared__ float As[16][65];
    __shared__ float Bs[16][65];
    int tid = threadIdx.x;
    int tx = tid & 15, ty = tid >> 4;
    int row0 = blockIdx.y * 64, col0 = blockIdx.x * 64;
    float acc[4][4] = {};
    for (int k0 = 0; k0 < K; k0 += 16) {
        #pragma unroll
        for (int i = 0; i < 4; ++i) {
            int e = tid + 256 * i; int m = e >> 4; int kk = e & 15;
            int gr = row0 + m, gk = k0 + kk;
            As[kk][m] = (gr < M && gk < K) ? A[(size_t)gr * lda + gk] : 0.f;
        }
        #pragma unroll
        for (int i = 0; i < 4; ++i) {
            int e = tid + 256 * i; int kk = e >> 6; int n = e & 63;
            int gk = k0 + kk, gc = col0 + n;
            Bs[kk][n] = (gk < K && gc < N) ? B[(size_t)gk * ldb + gc] : 0.f;
        }
        __syncthreads();
        #pragma unroll
        for (int kk = 0; kk < 16; ++kk) {
            float a[4], bv[4];
            #pragma unroll
            for (int i = 0; i < 4; ++i) a[i] = As[kk][ty * 4 + i];
            #pragma unroll
            for (int j = 0; j < 4; ++j) bv[j] = Bs[kk][tx * 4 + j];
            #pragma unroll
            for (int i = 0; i < 4; ++i)
                #pragma unroll
                for (int j = 0; j < 4; ++j) acc[i][j] += a[i] * bv[j];
        }
        __syncthreads();
    }
    #pragma unroll
    for (int i = 0; i < 4; ++i) {
        int gr = row0 + ty * 4 + i; if (gr >= M) continue;
        #pragma unroll
        for (int j = 0; j < 4; ++j) {
            int gc = col0 + tx * 4 + j; if (gc >= N) continue;
            float v = acc[i][j] + (bias ? bias[gc] : 0.f);
            if (ACT == 1) v = siluf(v);
            if (ACT == 2) v = geluf(v);
            C[(size_t)gr * ldc + gc] = v;
        }
    }
}

// ---------------- transpose + f32->bf16 convert: in [K][N] f32 -> out [N][K] bf16 ----
// K, N multiples of 64. blockIdx.z batches matrices (stride K*N).
__global__ __launch_bounds__(256) void transpose_cvt(
    const float* __restrict__ in, unsigned short* __restrict__ out, int K, int N)
{
    __shared__ float Ls[64][65];
    const float* src = in + (size_t)blockIdx.z * K * N;
    unsigned short* dst = out + (size_t)blockIdx.z * K * N;
    int k0 = blockIdx.y * 64, n0 = blockIdx.x * 64;
    #pragma unroll
    for (int e = threadIdx.x; e < 4096; e += 256) {
        int r = e >> 6, c = e & 63;
        Ls[r][c] = src[(size_t)(k0 + r) * N + n0 + c];
    }
    __syncthreads();
    #pragma unroll
    for (int e = threadIdx.x; e < 4096; e += 256) {
        int r = e >> 6, c = e & 63;
        dst[(size_t)(n0 + r) * K + k0 + c] = f2bf(Ls[c][r]);
    }
}

// ---------------- bf16 MFMA GEMM: C = act(A @ B + bias) ----------------
// A [M][lda] f32 (converted on the fly), BT [N][K] bf16 (pre-transposed).
// M % 128 == 0, N % 128 == 0, K % 32 == 0.
#define APAD 40   // LDS row stride in bf16 elems (80B, 16B aligned, 2-way banks)
template<int ACT>
__global__ __launch_bounds__(256) void gemm_mfma(
    const float* __restrict__ A, int lda,
    const unsigned short* __restrict__ BT,
    const float* __restrict__ bias,
    float* __restrict__ C, int ldc,
    int N, int K)
{
    __shared__ unsigned short As[128 * APAD];
    __shared__ unsigned short Bs[128 * APAD];
    int tid = threadIdx.x;
    int row0 = blockIdx.y * 128, col0 = blockIdx.x * 128;
    int wid = tid >> 6, lane = tid & 63;
    int wrow = (wid >> 1) * 64, wcol = (wid & 1) * 64;
    int lr = lane & 15, lk = lane >> 4;          // frag row/col and k-slot
    f32x4 acc[4][4] = {};

    int arow = tid >> 1, akc = (tid & 1) * 16;   // A staging: 16 f32 per thread
    int bn = tid >> 1, bkc = (tid & 1) * 16;     // B staging: 2x16B per thread

    for (int k0 = 0; k0 < K; k0 += 32) {
        // stage A (f32 -> bf16)
        {
            const float* ap = A + (size_t)(row0 + arow) * lda + k0 + akc;
            unsigned short tmp[16];
            #pragma unroll
            for (int i = 0; i < 4; ++i) {
                float4 f = *(const float4*)(ap + 4 * i);
                tmp[4 * i + 0] = f2bf(f.x); tmp[4 * i + 1] = f2bf(f.y);
                tmp[4 * i + 2] = f2bf(f.z); tmp[4 * i + 3] = f2bf(f.w);
            }
            unsigned short* d = &As[arow * APAD + akc];
            *(short8v*)d = *(short8v*)tmp;
            *(short8v*)(d + 8) = *(short8v*)(tmp + 8);
        }
        // stage B (already bf16, [N][K])
        {
            const unsigned short* bp = BT + (size_t)(col0 + bn) * K + k0 + bkc;
            unsigned short* d = &Bs[bn * APAD + bkc];
            *(short8v*)d = *(const short8v*)bp;
            *(short8v*)(d + 8) = *(const short8v*)(bp + 8);
        }
        __syncthreads();
        short8v av[4], bv[4];
        #pragma unroll
        for (int mr = 0; mr < 4; ++mr)
            av[mr] = *(const short8v*)&As[(wrow + mr * 16 + lr) * APAD + lk * 8];
        #pragma unroll
        for (int nc = 0; nc < 4; ++nc)
            bv[nc] = *(const short8v*)&Bs[(wcol + nc * 16 + lr) * APAD + lk * 8];
        #pragma unroll
        for (int mr = 0; mr < 4; ++mr)
            #pragma unroll
            for (int nc = 0; nc < 4; ++nc)
                acc[mr][nc] = __builtin_amdgcn_mfma_f32_16x16x32_bf16(
                    av[mr], bv[nc], acc[mr][nc], 0, 0, 0);
        __syncthreads();
    }
    int rbase = (lane >> 4) * 4;
    #pragma unroll
    for (int mr = 0; mr < 4; ++mr) {
        #pragma unroll
        for (int nc = 0; nc < 4; ++nc) {
            int gc = col0 + wcol + nc * 16 + lr;
            float bb = bias ? bias[gc] : 0.f;
            #pragma unroll
            for (int r = 0; r < 4; ++r) {
                int gr = row0 + wrow + mr * 16 + rbase + r;
                float v = acc[mr][nc][r] + bb;
                if (ACT == 2) v = geluf(v);
                C[(size_t)gr * ldc + gc] = v;
            }
        }
    }
}

// ---------------- MoE gathered bf16 MFMA GEMM ----------------
// PHASE 1: h[tok] = gelu(lnX[tok] @ W1[e])  (K=768,  N=3072)
// PHASE 2: grp[tok] += gval[tok]*(h[tok] @ W2[e])  (K=3072, N=768)
template<int PHASE>
__global__ __launch_bounds__(256) void moe_gemm_mfma(
    const float* __restrict__ A,
    const unsigned short* __restrict__ BTbase,   // [E][N][K] bf16
    float* __restrict__ C,
    const int* __restrict__ cnt, const int* __restrict__ list,
    const float* __restrict__ gval, int RT)
{
    const int K = (PHASE == 1) ? 768 : 3072;
    const int N = (PHASE == 1) ? 3072 : 768;
    const int lda = K, ldc = N;
    int e = blockIdx.y / RT, rt = blockIdx.y % RT;
    int c0 = cnt[e];
    int mbase = rt * 128;
    if (mbase >= c0) return;
    int mcount = min(128, c0 - mbase);
    __shared__ int toks[128];
    int tid = threadIdx.x;
    if (tid < 128) toks[tid] = list[e * MAXTOK + mbase + min(tid, mcount - 1)];
    __syncthreads();

    __shared__ unsigned short As[128 * APAD];
    __shared__ unsigned short Bs[128 * APAD];
    const unsigned short* BT = BTbase + (size_t)e * 768 * 3072;
    int col0 = blockIdx.x * 128;
    int wid = tid >> 6, lane = tid & 63;
    int wrow = (wid >> 1) * 64, wcol = (wid & 1) * 64;
    int lr = lane & 15, lk = lane >> 4;
    f32x4 acc[4][4] = {};
    int arow = tid >> 1, akc = (tid & 1) * 16;
    int bn = tid >> 1, bkc = (tid & 1) * 16;

    for (int k0 = 0; k0 < K; k0 += 32) {
        {
            const float* ap = A + (size_t)toks[arow] * lda + k0 + akc;
            unsigned short tmp[16];
            #pragma unroll
            for (int i = 0; i < 4; ++i) {
                float4 f = *(const float4*)(ap + 4 * i);
                tmp[4 * i + 0] = f2bf(f.x); tmp[4 * i + 1] = f2bf(f.y);
                tmp[4 * i + 2] = f2bf(f.z); tmp[4 * i + 3] = f2bf(f.w);
            }
            unsigned short* d = &As[arow * APAD + akc];
            *(short8v*)d = *(short8v*)tmp;
            *(short8v*)(d + 8) = *(short8v*)(tmp + 8);
        }
        {
            const unsigned short* bp = BT + (size_t)(col0 + bn) * K + k0 + bkc;
            unsigned short* d = &Bs[bn * APAD + bkc];
            *(short8v*)d = *(const short8v*)bp;
            *(short8v*)(d + 8) = *(const short8v*)(bp + 8);
        }
        __syncthreads();
        short8v av[4], bv[4];
        #pragma unroll
        for (int mr = 0; mr < 4; ++mr)
            av[mr] = *(const short8v*)&As[(wrow + mr * 16 + lr) * APAD + lk * 8];
        #pragma unroll
        for (int nc = 0; nc < 4; ++nc)
            bv[nc] = *(const short8v*)&Bs[(wcol + nc * 16 + lr) * APAD + lk * 8];
        #pragma unroll
        for (int mr = 0; mr < 4; ++mr)
            #pragma unroll
            for (int nc = 0; nc < 4; ++nc)
                acc[mr][nc] = __builtin_amdgcn_mfma_f32_16x16x32_bf16(
                    av[mr], bv[nc], acc[mr][nc], 0, 0, 0);
        __syncthreads();
    }
    int rbase = (lane >> 4) * 4;
    #pragma unroll
    for (int mr = 0; mr < 4; ++mr) {
        #pragma unroll
        for (int r = 0; r < 4; ++r) {
            int m = wrow + mr * 16 + rbase + r;
            if (m >= mcount) continue;
            int tok = toks[m];
            #pragma unroll
            for (int nc = 0; nc < 4; ++nc) {
                int gc = col0 + wcol + nc * 16 + lr;
                float v = acc[mr][nc][r];
                if (PHASE == 1) C[(size_t)tok * ldc + gc] = geluf(v);
                else            C[(size_t)tok * ldc + gc] += gval[tok] * v;
            }
        }
    }
}

// ---------------- LayerNorm (+ optional adaLN modulate) ----------------
__global__ __launch_bounds__(256) void ln_kernel(
    const float* __restrict__ X, float* __restrict__ Y, int R, int ntok,
    const float* __restrict__ mod, int modstride, int shift_chunk, int scale_chunk)
{
    int r = blockIdx.x;
    if (r >= R) return;
    const float* xr = X + (size_t)r * D;
    int tid = threadIdx.x;
    int lane = tid & 63, wid = tid >> 6;
    float v0 = xr[tid], v1 = xr[tid + 256], v2 = xr[tid + 512];
    float s = v0 + v1 + v2;
    float s2 = v0 * v0 + v1 * v1 + v2 * v2;
    for (int off = 32; off > 0; off >>= 1) {
        s += __shfl_xor(s, off, 64);
        s2 += __shfl_xor(s2, off, 64);
    }
    __shared__ float shs[4], shs2[4];
    if (lane == 0) { shs[wid] = s; shs2[wid] = s2; }
    __syncthreads();
    float tot = shs[0] + shs[1] + shs[2] + shs[3];
    float tot2 = shs2[0] + shs2[1] + shs2[2] + shs2[3];
    float mu = tot * (1.f / 768.f);
    float var = tot2 * (1.f / 768.f) - mu * mu;
    float rs = rsqrtf(var + 1e-6f);
    int bb = r / ntok;
    float vv[3] = {v0, v1, v2};
    #pragma unroll
    for (int j = 0; j < 3; ++j) {
        int col = tid + j * 256;
        float nrm = (vv[j] - mu) * rs;
        float y = nrm;
        if (mod) {
            float scv = mod[(size_t)bb * modstride + scale_chunk * D + col];
            float shv = mod[(size_t)bb * modstride + shift_chunk * D + col];
            y = nrm * (1.f + scv) + shv;
        }
        Y[(size_t)r * D + col] = y;
    }
}

// ---------------- tiled flash attention (f32 exact) ----------------
// 64x64 Q/KV tiles, 256 threads (16x16, 4x4 micro-tile). Q,K stored transposed
// in LDS so S and PV phases both read float4. P overlays the K buffer.
__global__ __launch_bounds__(256) void attn_tiled(
    const float* __restrict__ Q, const float* __restrict__ K, const float* __restrict__ V,
    float* __restrict__ O, int Nq, int Nkv, int ldq, int ldk, int ldv, int ldo, float scale)
{
    __shared__ float Qs[64][68];    // [d][r], pre-scaled
    __shared__ float KPs[64][68];   // K^T [d][c], then P^T [c][r]
    __shared__ float Vs[64][68];    // [c][d]
    int h = blockIdx.y, b = blockIdx.z;
    int q0 = blockIdx.x * 64;
    int tid = threadIdx.x, tx = tid & 15, ty = tid >> 4;
    int sr = tid >> 2, sdc = (tid & 3) * 16;     // staging: row, d-chunk

    {
        int gr = min(q0 + sr, Nq - 1);
        const float* qp = Q + ((size_t)b * Nq + gr) * ldq + h * HD + sdc;
        #pragma unroll
        for (int i = 0; i < 16; i += 4) {
            float4 f = *(const float4*)(qp + i);
            Qs[sdc + i + 0][sr] = f.x * scale; Qs[sdc + i + 1][sr] = f.y * scale;
            Qs[sdc + i + 2][sr] = f.z * scale; Qs[sdc + i + 3][sr] = f.w * scale;
        }
    }
    float m_r[4], l_r[4];
    float o_acc[4][4] = {};
    #pragma unroll
    for (int i = 0; i < 4; ++i) { m_r[i] = -INFINITY; l_r[i] = 0.f; }

    for (int kv0 = 0; kv0 < Nkv; kv0 += 64) {
        __syncthreads();   // prev PV done; Qs ready (first iter)
        {
            int gc = min(kv0 + sr, Nkv - 1);
            const float* kp = K + ((size_t)b * Nkv + gc) * ldk + h * HD + sdc;
            #pragma unroll
            for (int i = 0; i < 16; i += 4) {
                float4 f = *(const float4*)(kp + i);
                KPs[sdc + i + 0][sr] = f.x; KPs[sdc + i + 1][sr] = f.y;
                KPs[sdc + i + 2][sr] = f.z; KPs[sdc + i + 3][sr] = f.w;
            }
            const float* vp = V + ((size_t)b * Nkv + gc) * ldv + h * HD + sdc;
            #pragma unroll
            for (int i = 0; i < 16; i += 4)
                *(float4*)&Vs[sr][sdc + i] = *(const float4*)(vp + i);
        }
        __syncthreads();
        // S = Q K^T (scaled)
        float s[4][4] = {};
        #pragma unroll 4
        for (int d = 0; d < 64; ++d) {
            float4 a = *(const float4*)&Qs[d][ty * 4];
            float4 bv = *(const float4*)&KPs[d][tx * 4];
            float aa[4] = {a.x, a.y, a.z, a.w};
            float bb[4] = {bv.x, bv.y, bv.z, bv.w};
            #pragma unroll
            for (int i = 0; i < 4; ++i)
                #pragma unroll
                for (int j = 0; j < 4; ++j) s[i][j] += aa[i] * bb[j];
        }
        __syncthreads();   // S reads of KPs done before P overwrite
        int cbase = kv0 + tx * 4;
        float p[4][4];
        #pragma unroll
        for (int i = 0; i < 4; ++i) {
            float rmax = -INFINITY;
            #pragma unroll
            for (int j = 0; j < 4; ++j) {
                float sv = (cbase + j < Nkv) ? s[i][j] : -INFINITY;
                s[i][j] = sv;
                rmax = fmaxf(rmax, sv);
            }
            rmax = fmaxf(rmax, __shfl_xor(rmax, 1, 64));
            rmax = fmaxf(rmax, __shfl_xor(rmax, 2, 64));
            rmax = fmaxf(rmax, __shfl_xor(rmax, 4, 64));
            rmax = fmaxf(rmax, __shfl_xor(rmax, 8, 64));
            float mn = fmaxf(m_r[i], rmax);
            float fs = __expf(m_r[i] - mn);
            float rsum = 0.f;
            #pragma unroll
            for (int j = 0; j < 4; ++j) {
                float pv = (cbase + j < Nkv) ? __expf(s[i][j] - mn) : 0.f;
                p[i][j] = pv; rsum += pv;
            }
            rsum += __shfl_xor(rsum, 1, 64);
            rsum += __shfl_xor(rsum, 2, 64);
            rsum += __shfl_xor(rsum, 4, 64);
            rsum += __shfl_xor(rsum, 8, 64);
            l_r[i] = l_r[i] * fs + rsum;
            m_r[i] = mn;
            #pragma unroll
            for (int j = 0; j < 4; ++j) o_acc[i][j] *= fs;
        }
        #pragma unroll
        for (int j = 0; j < 4; ++j) {
            float4 pr = make_float4(p[0][j], p[1][j], p[2][j], p[3][j]);
            *(float4*)&KPs[tx * 4 + j][ty * 4] = pr;
        }
        __syncthreads();
        // O += P V
        #pragma unroll 4
        for (int c = 0; c < 64; ++c) {
            float4 a = *(const float4*)&KPs[c][ty * 4];
            float4 bv = *(const float4*)&Vs[c][tx * 4];
            float aa[4] = {a.x, a.y, a.z, a.w};
            float bb[4] = {bv.x, bv.y, bv.z, bv.w};
            #pragma unroll
            for (int i = 0; i < 4; ++i)
                #pragma unroll
                for (int j = 0; j < 4; ++j) o_acc[i][j] += aa[i] * bb[j];
        }
    }
    #pragma unroll
    for (int i = 0; i < 4; ++i) {
        int gr = q0 + ty * 4 + i;
        if (gr >= Nq) continue;
        float rl = 1.f / l_r[i];
        #pragma unroll
        for (int j = 0; j < 4; ++j)
            O[((size_t)b * Nq + gr) * ldo + h * HD + tx * 4 + j] = o_acc[i][j] * rl;
    }
}

// ---------------- residual add (optionally gated) ----------------
__global__ void add_gated(float* __restrict__ dst, const float* __restrict__ src,
                          const float* __restrict__ mod, int modstride, int gchunk,
                          int ntok, int total)
{
    int i = blockIdx.x * blockDim.x + threadIdx.x;
    if (i >= total) return;
    float g = 1.f;
    if (mod) {
        int col = i % D;
        int bb = i / (ntok * D);
        g = mod[(size_t)bb * modstride + gchunk * D + col];
    }
    dst[i] += g * src[i];
}

// ---------------- MoE router ----------------
__global__ __launch_bounds__(64) void router_kernel(
    const float* __restrict__ X, const float* __restrict__ Wr,
    int* __restrict__ idx, float* __restrict__ gval)
{
    int tkn = blockIdx.x; int lane = threadIdx.x;
    const float* xr = X + (size_t)tkn * D;
    float p0 = 0, p1 = 0, p2 = 0, p3 = 0;
    for (int dd = lane; dd < D; dd += 64) {
        float xv = xr[dd];
        const float* w = Wr + dd * 4;
        p0 += xv * w[0]; p1 += xv * w[1]; p2 += xv * w[2]; p3 += xv * w[3];
    }
    for (int off = 32; off > 0; off >>= 1) {
        p0 += __shfl_xor(p0, off, 64); p1 += __shfl_xor(p1, off, 64);
        p2 += __shfl_xor(p2, off, 64); p3 += __shfl_xor(p3, off, 64);
    }
    if (lane == 0) {
        float best = p0; int e = 0;
        if (p1 > best) { best = p1; e = 1; }
        if (p2 > best) { best = p2; e = 2; }
        if (p3 > best) { best = p3; e = 3; }
        float sum = expf(p0 - best) + expf(p1 - best) + expf(p2 - best) + expf(p3 - best);
        idx[tkn] = e;
        gval[tkn] = 1.f / sum;
    }
}

__global__ void scatter_kernel(const int* __restrict__ idx, int* __restrict__ cnt,
                               int* __restrict__ list, int ntok)
{
    int i = blockIdx.x * blockDim.x + threadIdx.x;
    if (i >= ntok) return;
    int e = idx[i];
    int pos = atomicAdd(&cnt[e], 1);
    list[e * MAXTOK + pos] = i;
}

// ---------------- concat ----------------
__global__ void concat_kernel(const float* __restrict__ traj, const float* __restrict__ a,
                              const float* __restrict__ bg, const float* __restrict__ cg,
                              float* __restrict__ x, int total)
{
    int i = blockIdx.x * blockDim.x + threadIdx.x;
    if (i >= total) return;
    int col = i % D;
    int r = i / D;
    int n = r % NTOK, b = r / NTOK;
    float v;
    if (n < 256)      v = traj[((size_t)b * 256 + n) * D + col];
    else if (n < 320) v = a[((size_t)b * 64 + (n - 256)) * D + col];
    else if (n < 352) v = bg[((size_t)b * 32 + (n - 320)) * D + col];
    else              v = cg[((size_t)b * 192 + (n - 352)) * D + col];
    x[i] = v;
}

// ---------------- output head ----------------
__global__ __launch_bounds__(64) void head_kernel(
    const float* __restrict__ H, const float* __restrict__ W,
    const float* __restrict__ bias, float* __restrict__ out)
{
    int r = blockIdx.x;
    int b = r >> 8, n = r & 255;
    const float* h = H + ((size_t)(b * NTOK + n)) * D;
    __shared__ float hs[D];
    for (int dd = threadIdx.x; dd < D; dd += 64) hs[dd] = h[dd];
    __syncthreads();
    int t = threadIdx.x;
    if (t < 14) {
        float acc = bias[t];
        for (int dd = 0; dd < D; ++dd) acc += hs[dd] * W[dd * 14 + t];
        out[(size_t)r * 14 + t] = acc;
    }
}

// ---------------- host helpers ----------------
static inline void gemm(int act, const float* A, int lda, const float* B, int ldb,
                        const float* bias, float* C, int ldc, int M, int N, int K,
                        hipStream_t s)
{
    dim3 g((N + 63) / 64, (M + 63) / 64);
    if (act == 0)      gemm_act<0><<<g, 256, 0, s>>>(A, lda, B, ldb, bias, C, ldc, M, N, K);
    else if (act == 1) gemm_act<1><<<g, 256, 0, s>>>(A, lda, B, ldb, bias, C, ldc, M, N, K);
    else               gemm_act<2><<<g, 256, 0, s>>>(A, lda, B, ldb, bias, C, ldc, M, N, K);
}
static inline void tcvt(const float* W, unsigned short* WT, int K, int N, int z, hipStream_t s) {
    transpose_cvt<<<dim3(N / 64, K / 64, z), 256, 0, s>>>(W, WT, K, N);
}
static inline void gmfma(int act, const float* A, int lda, const unsigned short* BT,
                         const float* bias, float* C, int ldc, int M, int N, int K,
                         hipStream_t s)
{
    dim3 g(N / 128, M / 128);
    if (act == 2) gemm_mfma<2><<<g, 256, 0, s>>>(A, lda, BT, bias, C, ldc, N, K);
    else          gemm_mfma<0><<<g, 256, 0, s>>>(A, lda, BT, bias, C, ldc, N, K);
}

extern "C" void kernel_launch(void* const* d_in, const int* in_sizes, int n_in,
                              void* d_out, int out_size, void* d_ws, size_t ws_size,
                              hipStream_t stream)
{
    const float* x_traj   = (const float*)d_in[0];
    const int*   t_arr    = (const int*)d_in[1];
    const float* tokA     = (const float*)d_in[2];
    const float* tokB     = (const float*)d_in[3];
    const float* tokC     = (const float*)d_in[4];
    const float* W_traj   = (const float*)d_in[5];
    const float* b_traj   = (const float*)d_in[6];
    const float* W_ftime  = (const float*)d_in[7];
    const float* Wt1      = (const float*)d_in[8];
    const float* bt1      = (const float*)d_in[9];
    const float* Wt2      = (const float*)d_in[10];
    const float* bt2      = (const float*)d_in[11];
    const float* moe_attn = (const float*)d_in[12];
    const float* moe_rout = (const float*)d_in[13];
    const float* moe_W1   = (const float*)d_in[14];
    const float* moe_W2   = (const float*)d_in[15];
    const float* dit_qkv  = (const float*)d_in[16];
    const float* dit_qkvb = (const float*)d_in[17];
    const float* dit_proj = (const float*)d_in[18];
    const float* dit_projb= (const float*)d_in[19];
    const float* dit_mlp1 = (const float*)d_in[20];
    const float* dit_mlp1b= (const float*)d_in[21];
    const float* dit_mlp2 = (const float*)d_in[22];
    const float* dit_mlp2b= (const float*)d_in[23];
    const float* dit_ada  = (const float*)d_in[24];
    const float* dit_adab = (const float*)d_in[25];
    const float* out_adaW = (const float*)d_in[26];
    const float* out_adab = (const float*)d_in[27];
    const float* out_W    = (const float*)d_in[28];
    const float* out_b    = (const float*)d_in[29];
    float* out = (float*)d_out;
    float* ws = (float*)d_ws;

    // workspace layout (float offsets)
    const size_t o_temb = 0;
    const size_t o_u    = o_temb + 2048;
    const size_t o_c    = o_u + 6144;
    const size_t o_sc   = o_c + 6144;
    const size_t o_mod  = o_sc + 6144;
    const size_t o_cnt  = o_mod + 36864;
    const size_t o_idx  = o_cnt + 64;
    const size_t o_gval = o_idx + 1536;
    const size_t o_list = o_gval + 1536;
    const size_t o_traj = o_list + 6144;
    const size_t o_a    = o_traj + 1572864;
    const size_t o_bg   = o_a + 393216;
    const size_t o_cg   = o_bg + 196608;
    const size_t o_x    = o_cg + 1179648;
    const size_t o_S1   = o_x + 3342336;
    const size_t o_S2   = o_S1 + 13369344;
    const size_t o_S3   = o_S2 + 3342336;
    const size_t o_WT   = o_S3 + 3342336;     // 4,718,592 floats = 9.4M bf16
    const size_t o_q = o_S1;
    const size_t o_k = o_S1 + 1179648;
    const size_t o_v = o_S1 + 2359296;
    const size_t o_o = o_S1 + 3538944;

    int* cnt_p  = (int*)(ws + o_cnt);
    int* idx_p  = (int*)(ws + o_idx);
    int* list_p = (int*)(ws + o_list);
    float* gval_p = ws + o_gval;
    unsigned short* wt = (unsigned short*)(ws + o_WT);

    // ---- timestep conditioning ----
    timestep_kernel<<<4, 256, 0, stream>>>(t_arr, ws + o_temb);
    gemm(1, ws + o_temb, 256, Wt1, D, bt1, ws + o_u, D, BATCH, D, 256, stream);
    gemm(0, ws + o_u, D, Wt2, D, bt2, ws + o_c, D, BATCH, D, D, stream);
    silu_vec<<<24, 256, 0, stream>>>(ws + o_c, ws + o_sc, BATCH * D);

    // ---- trajectory embedding ----
    gemm(0, x_traj, 7, W_traj, D, b_traj, ws + o_traj, D, BATCH * TTRAJ, D, 7, stream);
    add_ftime<<<(BATCH * TTRAJ * D + 255) / 256, 256, 0, stream>>>(ws + o_traj, W_ftime, BATCH * TTRAJ * D);

    hipMemcpyAsync(ws + o_a, tokA, (size_t)BATCH * NA * D * 4, hipMemcpyDeviceToDevice, stream);
    hipMemcpyAsync(ws + o_bg, tokB, (size_t)BATCH * NB * D * 4, hipMemcpyDeviceToDevice, stream);
    hipMemcpyAsync(ws + o_cg, tokC, (size_t)BATCH * NC * D * 4, hipMemcpyDeviceToDevice, stream);

    const size_t WSZ = (size_t)D * D;
    for (int i = 0; i < NBLK; ++i) {
        // cross 1: cg += cross(ln(cg), a)
        {
            int Rq = BATCH * NC, Rkv = BATCH * NA;
            const float* Wc = moe_attn + (size_t)(i * 2 + 0) * 4 * WSZ;
            ln_kernel<<<Rq, 256, 0, stream>>>(ws + o_cg, ws + o_S2, Rq, NC, nullptr, 0, 0, 0);
            tcvt(Wc + 0 * WSZ, wt, D, D, 1, stream);
            gmfma(0, ws + o_S2, D, wt, nullptr, ws + o_q, D, Rq, D, D, stream);
            tcvt(Wc + 1 * WSZ, wt, D, D, 1, stream);
            gmfma(0, ws + o_a, D, wt, nullptr, ws + o_k, D, Rkv, D, D, stream);
            tcvt(Wc + 2 * WSZ, wt, D, D, 1, stream);
            gmfma(0, ws + o_a, D, wt, nullptr, ws + o_v, D, Rkv, D, D, stream);
            attn_tiled<<<dim3((NC + 63) / 64, NH, BATCH), 256, 0, stream>>>(
                ws + o_q, ws + o_k, ws + o_v, ws + o_S3, NC, NA, D, D, D, D, 0.125f);
            tcvt(Wc + 3 * WSZ, wt, D, D, 1, stream);
            gmfma(0, ws + o_S3, D, wt, nullptr, ws + o_o, D, Rq, D, D, stream);
            add_gated<<<(Rq * D + 255) / 256, 256, 0, stream>>>(
                ws + o_cg, ws + o_o, nullptr, 0, 0, NC, Rq * D);
        }
        // cross 2: bg += cross(ln(bg), cg)
        {
            int Rq = BATCH * NB, Rkv = BATCH * NC;
            const float* Wc = moe_attn + (size_t)(i * 2 + 1) * 4 * WSZ;
            ln_kernel<<<Rq, 256, 0, stream>>>(ws + o_bg, ws + o_S2, Rq, NB, nullptr, 0, 0, 0);
            tcvt(Wc + 0 * WSZ, wt, D, D, 1, stream);
            gmfma(0, ws + o_S2, D, wt, nullptr, ws + o_q, D, Rq, D, D, stream);
            tcvt(Wc + 1 * WSZ, wt, D, D, 1, stream);
            gmfma(0, ws + o_cg, D, wt, nullptr, ws + o_k, D, Rkv, D, D, stream);
            tcvt(Wc + 2 * WSZ, wt, D, D, 1, stream);
            gmfma(0, ws + o_cg, D, wt, nullptr, ws + o_v, D, Rkv, D, D, stream);
            attn_tiled<<<dim3(1, NH, BATCH), 256, 0, stream>>>(
                ws + o_q, ws + o_k, ws + o_v, ws + o_S3, NB, NC, D, D, D, D, 0.125f);
            tcvt(Wc + 3 * WSZ, wt, D, D, 1, stream);
            gmfma(0, ws + o_S3, D, wt, nullptr, ws + o_o, D, Rq, D, D, stream);
            add_gated<<<(Rq * D + 255) / 256, 256, 0, stream>>>(
                ws + o_bg, ws + o_o, nullptr, 0, 0, NB, Rq * D);
        }
        // MoE on a, bg, cg
        const int gn[3] = {BATCH * NA, BATCH * NB, BATCH * NC};
        float* gptr[3] = {ws + o_a, ws + o_bg, ws + o_cg};
        for (int g = 0; g < 3; ++g) {
            int ntok = gn[g];
            const float* Wr = moe_rout + (size_t)(i * 3 + g) * D * NEXP;
            const float* W1 = moe_W1 + (size_t)(i * 3 + g) * NEXP * D * FF;
            const float* W2 = moe_W2 + (size_t)(i * 3 + g) * NEXP * FF * D;
            ln_kernel<<<ntok, 256, 0, stream>>>(gptr[g], ws + o_S2, ntok, 1, nullptr, 0, 0, 0);
            hipMemsetAsync((void*)cnt_p, 0, 4 * sizeof(int), stream);
            router_kernel<<<ntok, 64, 0, stream>>>(ws + o_S2, Wr, idx_p, gval_p);
            scatter_kernel<<<(ntok + 255) / 256, 256, 0, stream>>>(idx_p, cnt_p, list_p, ntok);
            int RT = (ntok + 127) / 128;
            tcvt(W1, wt, D, FF, NEXP, stream);
            moe_gemm_mfma<1><<<dim3(FF / 128, NEXP * RT), 256, 0, stream>>>(
                ws + o_S2, wt, ws + o_S1, cnt_p, list_p, gval_p, RT);
            tcvt(W2, wt, FF, D, NEXP, stream);
            moe_gemm_mfma<2><<<dim3(D / 128, NEXP * RT), 256, 0, stream>>>(
                ws + o_S1, wt, gptr[g], cnt_p, list_p, gval_p, RT);
        }
    }

    // ---- concat into x ----
    concat_kernel<<<(BATCH * NTOK * D + 255) / 256, 256, 0, stream>>>(
        ws + o_traj, ws + o_a, ws + o_bg, ws + o_cg, ws + o_x, BATCH * NTOK * D);

    const int R = BATCH * NTOK;   // 4352
    for (int i = 0; i < DEPTH; ++i) {
        gemm(0, ws + o_sc, D, dit_ada + (size_t)i * D * 6 * D, 6 * D,
             dit_adab + (size_t)i * 6 * D, ws + o_mod, 6 * D, BATCH, 6 * D, D, stream);
        ln_kernel<<<R, 256, 0, stream>>>(ws + o_x, ws + o_S2, R, NTOK, ws + o_mod, 6 * D, 0, 1);
        tcvt(dit_qkv + (size_t)i * D * 3 * D, wt, D, 3 * D, 1, stream);
        gmfma(0, ws + o_S2, D, wt, dit_qkvb + (size_t)i * 3 * D, ws + o_S1, 3 * D, R, 3 * D, D, stream);
        attn_tiled<<<dim3((NTOK + 63) / 64, NH, BATCH), 256, 0, stream>>>(
            ws + o_S1, ws + o_S1 + D, ws + o_S1 + 2 * D, ws + o_S3,
            NTOK, NTOK, 3 * D, 3 * D, 3 * D, D, 0.125f);
        tcvt(dit_proj + (size_t)i * D * D, wt, D, D, 1, stream);
        gmfma(0, ws + o_S3, D, wt, dit_projb + (size_t)i * D, ws + o_S2, D, R, D, D, stream);
        add_gated<<<(R * D + 255) / 256, 256, 0, stream>>>(
            ws + o_x, ws + o_S2, ws + o_mod, 6 * D, 2, NTOK, R * D);
        ln_kernel<<<R, 256, 0, stream>>>(ws + o_x, ws + o_S2, R, NTOK, ws + o_mod, 6 * D, 3, 4);
        tcvt(dit_mlp1 + (size_t)i * D * FF, wt, D, FF, 1, stream);
        gmfma(2, ws + o_S2, D, wt, dit_mlp1b + (size_t)i * FF, ws + o_S1, FF, R, FF, D, stream);
        tcvt(dit_mlp2 + (size_t)i * FF * D, wt, FF, D, 1, stream);
        gmfma(0, ws + o_S1, FF, wt, dit_mlp2b + (size_t)i * D, ws + o_S3, D, R, D, FF, stream);
        add_gated<<<(R * D + 255) / 256, 256, 0, stream>>>(
            ws + o_x, ws + o_S3, ws + o_mod, 6 * D, 5, NTOK, R * D);
    }

    // ---- output head ----
    gemm(0, ws + o_sc, D, out_adaW, 2 * D, out_adab, ws + o_mod, 2 * D, BATCH, 2 * D, D, stream);
    ln_kernel<<<R, 256, 0, stream>>>(ws + o_x, ws + o_S2, R, NTOK, ws + o_mod, 2 * D, 0, 1);
    head_kernel<<<BATCH * TTRAJ, 64, 0, stream>>>(ws + o_S2, out_W, out_b, out);
}

// Round 3
// 4318.676 us; speedup vs baseline: 6.7592x; 1.3696x over previous
//
#include <hip/hip_runtime.h>
#include <hip/hip_bf16.h>
#include <math.h>

#define D 768
#define NH 12
#define HD 64
#define NEXP 4
#define FF 3072
#define NBLK 2
#define DEPTH 6
#define NA 64
#define NB 32
#define NC 192
#define BATCH 8
#define TTRAJ 256
#define NTOK 544
#define MAXTOK 1536

typedef __attribute__((ext_vector_type(8))) short short8v;
typedef __attribute__((ext_vector_type(4))) float f32x4;

__device__ __forceinline__ float siluf(float v) { return v / (1.f + expf(-v)); }
__device__ __forceinline__ float geluf(float v) {
    float u = 0.7978845608028654f * (v + 0.044715f * v * v * v);
    return 0.5f * v * (1.f + tanhf(u));
}
__device__ __forceinline__ unsigned short f2bf(float f) {
    union { float f; unsigned u; } v; v.f = f;
    unsigned r = v.u + 0x7fffu + ((v.u >> 16) & 1u);
    return (unsigned short)(r >> 16);
}
__device__ __forceinline__ float bf2f(unsigned short u) {
    union { unsigned u; float f; } v; v.u = ((unsigned)u) << 16; return v.f;
}
__device__ __forceinline__ void gl16(const unsigned short* g, unsigned short* l) {
    __builtin_amdgcn_global_load_lds(
        (const __attribute__((address_space(1))) void*)g,
        (__attribute__((address_space(3))) void*)l, 16, 0, 0);
}

// ---------------- timestep embedding ----------------
__global__ void timestep_kernel(const int* __restrict__ t, float* __restrict__ temb) {
    int i = blockIdx.x * blockDim.x + threadIdx.x;
    if (i >= BATCH * 128) return;
    int b = i >> 7, j = i & 127;
    float freq = expf(-logf(10000.f) * (float)j / 128.f);
    float ang = (float)t[b] * freq;
    temb[b * 256 + j] = cosf(ang);
    temb[b * 256 + 128 + j] = sinf(ang);
}

__global__ void silu_vec(const float* __restrict__ in, float* __restrict__ out, int n) {
    int i = blockIdx.x * blockDim.x + threadIdx.x;
    if (i < n) out[i] = siluf(in[i]);
}

__global__ void add_ftime(float* __restrict__ traj, const float* __restrict__ wf, int total) {
    int i = blockIdx.x * blockDim.x + threadIdx.x;
    if (i >= total) return;
    int col = i % D;
    int n = (i / D) % TTRAJ;
    traj[i] += wf[(n & 7) * D + col];
}

__global__ void cvt_bf16(const float* __restrict__ in, unsigned short* __restrict__ out, int n8) {
    int i = blockIdx.x * blockDim.x + threadIdx.x;
    if (i >= n8) return;
    float4 a = *(const float4*)(in + i * 8);
    float4 b = *(const float4*)(in + i * 8 + 4);
    unsigned short t[8] = {f2bf(a.x), f2bf(a.y), f2bf(a.z), f2bf(a.w),
                           f2bf(b.x), f2bf(b.y), f2bf(b.z), f2bf(b.w)};
    *(short8v*)(out + i * 8) = *(short8v*)t;
}

// ---------------- small f32 GEMM (M=8 conditioning, K=7 embed) ----------------
template<int ACT>
__global__ __launch_bounds__(256) void gemm_act(
    const float* __restrict__ A, int lda,
    const float* __restrict__ B, int ldb,
    const float* __restrict__ bias,
    float* __restrict__ C, int ldc,
    int M, int N, int K)
{
    __shared__ float As[16][65];
    __shared__ float Bs[16][65];
    int tid = threadIdx.x;
    int tx = tid & 15, ty = tid >> 4;
    int row0 = blockIdx.y * 64, col0 = blockIdx.x * 64;
    float acc[4][4] = {};
    for (int k0 = 0; k0 < K; k0 += 16) {
        #pragma unroll
        for (int i = 0; i < 4; ++i) {
            int e = tid + 256 * i; int m = e >> 4; int kk = e & 15;
            int gr = row0 + m, gk = k0 + kk;
            As[kk][m] = (gr < M && gk < K) ? A[(size_t)gr * lda + gk] : 0.f;
        }
        #pragma unroll
        for (int i = 0; i < 4; ++i) {
            int e = tid + 256 * i; int kk = e >> 6; int n = e & 63;
            int gk = k0 + kk, gc = col0 + n;
            Bs[kk][n] = (gk < K && gc < N) ? B[(size_t)gk * ldb + gc] : 0.f;
        }
        __syncthreads();
        #pragma unroll
        for (int kk = 0; kk < 16; ++kk) {
            float a[4], bv[4];
            #pragma unroll
            for (int i = 0; i < 4; ++i) a[i] = As[kk][ty * 4 + i];
            #pragma unroll
            for (int j = 0; j < 4; ++j) bv[j] = Bs[kk][tx * 4 + j];
            #pragma unroll
            for (int i = 0; i < 4; ++i)
                #pragma unroll
                for (int j = 0; j < 4; ++j) acc[i][j] += a[i] * bv[j];
        }
        __syncthreads();
    }
    #pragma unroll
    for (int i = 0; i < 4; ++i) {
        int gr = row0 + ty * 4 + i; if (gr >= M) continue;
        #pragma unroll
        for (int j = 0; j < 4; ++j) {
            int gc = col0 + tx * 4 + j; if (gc >= N) continue;
            float v = acc[i][j] + (bias ? bias[gc] : 0.f);
            if (ACT == 1) v = siluf(v);
            if (ACT == 2) v = geluf(v);
            C[(size_t)gr * ldc + gc] = v;
        }
    }
}

// ---------------- weight transpose + cvt: [K][N] f32 -> [N][K] bf16 ----------------
__global__ __launch_bounds__(256) void transpose_cvt(
    const float* __restrict__ in, unsigned short* __restrict__ out, int K, int N)
{
    __shared__ float Ls[64][65];
    const float* src = in + (size_t)blockIdx.z * K * N;
    unsigned short* dst = out + (size_t)blockIdx.z * K * N;
    int k0 = blockIdx.y * 64, n0 = blockIdx.x * 64;
    for (int e = threadIdx.x; e < 4096; e += 256) {
        int r = e >> 6, c = e & 63;
        Ls[r][c] = src[(size_t)(k0 + r) * N + n0 + c];
    }
    __syncthreads();
    for (int e = threadIdx.x; e < 4096; e += 256) {
        int r = e >> 6, c = e & 63;
        dst[(size_t)(n0 + r) * K + k0 + c] = f2bf(Ls[c][r]);
    }
}

// ---------------- MFMA GEMM, global_load_lds staging, both-sides XOR swizzle ----
// A [M][K] bf16, BT [N][K] bf16. M,N multiples of 128, K multiple of 32.
// OUT: 0 = f32 C; 1 = bf16 C (qscale_cols leading cols ×0.125); 2 = f32 residual
//      C += g * (acc+bias) with g = mod[b*modstride + gchunk*768 + col] (or 1).
template<int ACT, int OUT>
__global__ __launch_bounds__(256) void gemm_lds(
    const unsigned short* __restrict__ A,
    const unsigned short* __restrict__ BT,
    const float* __restrict__ bias,
    float* __restrict__ Cf, unsigned short* __restrict__ Cb, int ldc,
    int K, int qscale_cols,
    const float* __restrict__ mod, int modstride, int gchunk, int ntok)
{
    __shared__ unsigned short As[128 * 32];
    __shared__ unsigned short Bs[128 * 32];
    int tid = threadIdx.x, w = tid >> 6, lane = tid & 63;
    int row0 = blockIdx.y * 128, col0 = blockIdx.x * 128;
    int wrow = (w >> 1) * 64, wcol = (w & 1) * 64;
    int lr = lane & 15, g = lane >> 4;
    f32x4 acc[4][4] = {};

    // staging geometry (two 16B issues per thread per buffer)
    int r_s[2], ks_s[2], ld_s[2];
    #pragma unroll
    for (int i = 0; i < 2; ++i) {
        int off = tid * 16 + i * 4096;          // byte offset in LDS
        int row = off >> 6;
        int slot = (off >> 4) & 3;
        r_s[i] = row;
        ks_s[i] = (slot ^ ((row >> 1) & 3)) * 8;  // source k-chunk (elems)
        ld_s[i] = off >> 1;                        // LDS elem offset (linear)
    }

    for (int k0 = 0; k0 < K; k0 += 32) {
        #pragma unroll
        for (int i = 0; i < 2; ++i)
            gl16(A + (size_t)(row0 + r_s[i]) * K + k0 + ks_s[i], (unsigned short*)As + ld_s[i]);
        #pragma unroll
        for (int i = 0; i < 2; ++i)
            gl16(BT + (size_t)(col0 + r_s[i]) * K + k0 + ks_s[i], (unsigned short*)Bs + ld_s[i]);
        __syncthreads();
        short8v av[4], bv[4];
        #pragma unroll
        for (int mr = 0; mr < 4; ++mr) {
            int row = wrow + mr * 16 + lr;
            av[mr] = *(const short8v*)&As[row * 32 + (g ^ ((row >> 1) & 3)) * 8];
        }
        #pragma unroll
        for (int nc = 0; nc < 4; ++nc) {
            int row = wcol + nc * 16 + lr;
            bv[nc] = *(const short8v*)&Bs[row * 32 + (g ^ ((row >> 1) & 3)) * 8];
        }
        #pragma unroll
        for (int mr = 0; mr < 4; ++mr)
            #pragma unroll
            for (int nc = 0; nc < 4; ++nc)
                acc[mr][nc] = __builtin_amdgcn_mfma_f32_16x16x32_bf16(
                    av[mr], bv[nc], acc[mr][nc], 0, 0, 0);
        __syncthreads();
    }
    int rbase = g * 4;
    #pragma unroll
    for (int mr = 0; mr < 4; ++mr) {
        #pragma unroll
        for (int nc = 0; nc < 4; ++nc) {
            int gc = col0 + wcol + nc * 16 + lr;
            float bb = bias ? bias[gc] : 0.f;
            #pragma unroll
            for (int r = 0; r < 4; ++r) {
                int gr = row0 + wrow + mr * 16 + rbase + r;
                float v = acc[mr][nc][r] + bb;
                if (ACT == 2) v = geluf(v);
                if (OUT == 0) {
                    Cf[(size_t)gr * ldc + gc] = v;
                } else if (OUT == 1) {
                    if (gc < qscale_cols) v *= 0.125f;
                    Cb[(size_t)gr * ldc + gc] = f2bf(v);
                } else {
                    float gg = 1.f;
                    if (mod) gg = mod[(size_t)(gr / ntok) * modstride + gchunk * D + gc];
                    Cf[(size_t)gr * ldc + gc] += gg * v;
                }
            }
        }
    }
}

// ---------------- MoE gathered MFMA GEMM ----------------
template<int PHASE>
__global__ __launch_bounds__(256) void moe_lds(
    const unsigned short* __restrict__ A,      // phase1: lnb [ntok][768]; phase2: h [ntok][3072]
    const unsigned short* __restrict__ BTbase, // [E][N][K]
    float* __restrict__ Cf, unsigned short* __restrict__ Cb,
    const int* __restrict__ cnt, const int* __restrict__ list,
    const float* __restrict__ gval, int RT)
{
    const int K = (PHASE == 1) ? 768 : 3072;
    const int N = (PHASE == 1) ? 3072 : 768;
    int e = blockIdx.y / RT, rt = blockIdx.y % RT;
    int c0 = cnt[e];
    int mbase = rt * 128;
    if (mbase >= c0) return;
    int mcount = min(128, c0 - mbase);
    __shared__ int toks[128];
    int tid = threadIdx.x, w = tid >> 6, lane = tid & 63;
    if (tid < 128) toks[tid] = list[e * MAXTOK + mbase + min(tid, mcount - 1)];
    __syncthreads();

    __shared__ unsigned short As[128 * 32];
    __shared__ unsigned short Bs[128 * 32];
    const unsigned short* BT = BTbase + (size_t)e * 768 * 3072;
    int col0 = blockIdx.x * 128;
    int wrow = (w >> 1) * 64, wcol = (w & 1) * 64;
    int lr = lane & 15, g = lane >> 4;
    f32x4 acc[4][4] = {};

    int r_s[2], ks_s[2], ld_s[2], tok_s[2];
    #pragma unroll
    for (int i = 0; i < 2; ++i) {
        int off = tid * 16 + i * 4096;
        int row = off >> 6;
        int slot = (off >> 4) & 3;
        r_s[i] = row;
        ks_s[i] = (slot ^ ((row >> 1) & 3)) * 8;
        ld_s[i] = off >> 1;
        tok_s[i] = toks[row];
    }

    for (int k0 = 0; k0 < K; k0 += 32) {
        #pragma unroll
        for (int i = 0; i < 2; ++i)
            gl16(A + (size_t)tok_s[i] * K + k0 + ks_s[i], (unsigned short*)As + ld_s[i]);
        #pragma unroll
        for (int i = 0; i < 2; ++i)
            gl16(BT + (size_t)(col0 + r_s[i]) * K + k0 + ks_s[i], (unsigned short*)Bs + ld_s[i]);
        __syncthreads();
        short8v av[4], bv[4];
        #pragma unroll
        for (int mr = 0; mr < 4; ++mr) {
            int row = wrow + mr * 16 + lr;
            av[mr] = *(const short8v*)&As[row * 32 + (g ^ ((row >> 1) & 3)) * 8];
        }
        #pragma unroll
        for (int nc = 0; nc < 4; ++nc) {
            int row = wcol + nc * 16 + lr;
            bv[nc] = *(const short8v*)&Bs[row * 32 + (g ^ ((row >> 1) & 3)) * 8];
        }
        #pragma unroll
        for (int mr = 0; mr < 4; ++mr)
            #pragma unroll
            for (int nc = 0; nc < 4; ++nc)
                acc[mr][nc] = __builtin_amdgcn_mfma_f32_16x16x32_bf16(
                    av[mr], bv[nc], acc[mr][nc], 0, 0, 0);
        __syncthreads();
    }
    int rbase = g * 4;
    #pragma unroll
    for (int mr = 0; mr < 4; ++mr) {
        #pragma unroll
        for (int r = 0; r < 4; ++r) {
            int m = wrow + mr * 16 + rbase + r;
            if (m >= mcount) continue;
            int tok = toks[m];
            #pragma unroll
            for (int nc = 0; nc < 4; ++nc) {
                int gc = col0 + wcol + nc * 16 + lr;
                float v = acc[mr][nc][r];
                if (PHASE == 1) Cb[(size_t)tok * 3072 + gc] = f2bf(geluf(v));
                else            Cf[(size_t)tok * 768 + gc] += gval[tok] * v;
            }
        }
    }
}

// ---------------- LayerNorm -> bf16 (+ optional adaLN modulate) ----------------
__global__ __launch_bounds__(256) void ln_kernel(
    const float* __restrict__ X, unsigned short* __restrict__ Y, int R, int ntok,
    const float* __restrict__ mod, int modstride, int shift_chunk, int scale_chunk)
{
    int r = blockIdx.x;
    if (r >= R) return;
    const float* xr = X + (size_t)r * D;
    int tid = threadIdx.x;
    int lane = tid & 63, wid = tid >> 6;
    float v0 = xr[tid], v1 = xr[tid + 256], v2 = xr[tid + 512];
    float s = v0 + v1 + v2;
    float s2 = v0 * v0 + v1 * v1 + v2 * v2;
    for (int off = 32; off > 0; off >>= 1) {
        s += __shfl_xor(s, off, 64);
        s2 += __shfl_xor(s2, off, 64);
    }
    __shared__ float shs[4], shs2[4];
    if (lane == 0) { shs[wid] = s; shs2[wid] = s2; }
    __syncthreads();
    float tot = shs[0] + shs[1] + shs[2] + shs[3];
    float tot2 = shs2[0] + shs2[1] + shs2[2] + shs2[3];
    float mu = tot * (1.f / 768.f);
    float var = tot2 * (1.f / 768.f) - mu * mu;
    float rs = rsqrtf(var + 1e-6f);
    int bb = r / ntok;
    float vv[3] = {v0, v1, v2};
    #pragma unroll
    for (int j = 0; j < 3; ++j) {
        int col = tid + j * 256;
        float nrm = (vv[j] - mu) * rs;
        float y = nrm;
        if (mod) {
            float scv = mod[(size_t)bb * modstride + scale_chunk * D + col];
            float shv = mod[(size_t)bb * modstride + shift_chunk * D + col];
            y = nrm * (1.f + scv) + shv;
        }
        Y[(size_t)r * D + col] = f2bf(y);
    }
}

// ---------------- V transpose: bf16 [row][col-panel] -> VT [b][h][64][nkvpad] ----
__global__ __launch_bounds__(256) void vt_kernel(
    const unsigned short* __restrict__ V, int ldv, int voff,
    unsigned short* __restrict__ VT, int Nkv, int nkvpad)
{
    __shared__ unsigned short Ls[64][72];
    int h = blockIdx.y, b = blockIdx.z, kv0 = blockIdx.x * 64;
    int tid = threadIdx.x;
    int srow = tid >> 2, sc = (tid & 3) * 16;
    int kv = kv0 + srow;
    if (kv < Nkv) {
        const unsigned short* vp = V + (size_t)(b * Nkv + kv) * ldv + voff + h * 64 + sc;
        #pragma unroll
        for (int j = 0; j < 16; ++j) Ls[srow][sc + j] = vp[j];
    } else {
        #pragma unroll
        for (int j = 0; j < 16; ++j) Ls[srow][sc + j] = 0;
    }
    __syncthreads();
    int d = tid >> 2, c0 = (tid & 3) * 16;
    unsigned short tmp[16];
    #pragma unroll
    for (int j = 0; j < 16; ++j) tmp[j] = Ls[c0 + j][d];
    unsigned short* op = VT + ((size_t)(b * NH + h) * 64 + d) * nkvpad + kv0 + c0;
    *(short8v*)op = *(short8v*)tmp;
    *(short8v*)(op + 8) = *(short8v*)(tmp + 8);
}

// ---------------- MFMA flash attention (bf16 in, f32 accum, bf16 out) ----------
// 64 q rows/block, 4 waves (wave w: rows w*16..+16). KV tiles of 64.
__global__ __launch_bounds__(256) void attn_mfma(
    const unsigned short* __restrict__ Qp, int ldq, int qoff,
    const unsigned short* __restrict__ Kp, int ldk, int koff,
    const unsigned short* __restrict__ VT, int nkvpad,
    unsigned short* __restrict__ O, int ldo,
    int Nq, int Nkv)
{
    __shared__ unsigned short Qs[64 * 64];
    __shared__ unsigned short Ks[64 * 64];
    __shared__ unsigned short Vs[64 * 64];
    __shared__ unsigned short Ps[64 * 64];
    int h = blockIdx.y, b = blockIdx.z, q0 = blockIdx.x * 64;
    int tid = threadIdx.x, w = tid >> 6, lane = tid & 63;
    int wrow = w * 16;
    int lr = lane & 15, g = lane >> 4;
    int srow = tid >> 2, sc = (tid & 3) * 16;

    // stage Q (swizzled: 8 slots/row, slot ^= row&7)
    {
        int gr = min(q0 + srow, Nq - 1);
        const unsigned short* qp = Qp + (size_t)(b * Nq + gr) * ldq + qoff + h * 64 + sc;
        short8v v0 = *(const short8v*)qp, v1 = *(const short8v*)(qp + 8);
        int s0 = sc >> 3;
        *(short8v*)&Qs[srow * 64 + (s0 ^ (srow & 7)) * 8] = v0;
        *(short8v*)&Qs[srow * 64 + ((s0 + 1) ^ (srow & 7)) * 8] = v1;
    }
    float m_r[4] = {-1e30f, -1e30f, -1e30f, -1e30f};
    float l_r[4] = {};
    f32x4 acc0 = {}, acc1 = {}, acc2 = {}, acc3 = {};
    const unsigned short* vtb = VT + (size_t)(b * NH + h) * 64 * nkvpad;

    for (int kv0 = 0; kv0 < Nkv; kv0 += 64) {
        // stage K, V
        {
            int gc = min(kv0 + srow, Nkv - 1);
            const unsigned short* kp = Kp + (size_t)(b * Nkv + gc) * ldk + koff + h * 64 + sc;
            short8v v0 = *(const short8v*)kp, v1 = *(const short8v*)(kp + 8);
            int s0 = sc >> 3;
            *(short8v*)&Ks[srow * 64 + (s0 ^ (srow & 7)) * 8] = v0;
            *(short8v*)&Ks[srow * 64 + ((s0 + 1) ^ (srow & 7)) * 8] = v1;
            const unsigned short* vp = vtb + (size_t)srow * nkvpad + kv0 + sc;
            short8v u0 = *(const short8v*)vp, u1 = *(const short8v*)(vp + 8);
            *(short8v*)&Vs[srow * 64 + (s0 ^ (srow & 7)) * 8] = u0;
            *(short8v*)&Vs[srow * 64 + ((s0 + 1) ^ (srow & 7)) * 8] = u1;
        }
        __syncthreads();
        // S = Q K^T
        short8v aq0, aq1;
        {
            int row = wrow + lr;
            aq0 = *(const short8v*)&Qs[row * 64 + ((0 * 4 + g) ^ (row & 7)) * 8];
            aq1 = *(const short8v*)&Qs[row * 64 + ((1 * 4 + g) ^ (row & 7)) * 8];
        }
        f32x4 sf[4];
        #pragma unroll
        for (int nc = 0; nc < 4; ++nc) {
            int row = nc * 16 + lr;
            short8v bk0 = *(const short8v*)&Ks[row * 64 + ((0 * 4 + g) ^ (row & 7)) * 8];
            short8v bk1 = *(const short8v*)&Ks[row * 64 + ((1 * 4 + g) ^ (row & 7)) * 8];
            f32x4 z = {};
            z = __builtin_amdgcn_mfma_f32_16x16x32_bf16(aq0, bk0, z, 0, 0, 0);
            sf[nc] = __builtin_amdgcn_mfma_f32_16x16x32_bf16(aq1, bk1, z, 0, 0, 0);
        }
        __syncthreads();   // QK reads done; Ps can be overwritten
        // online softmax; write P tile (bf16) to LDS
        bool val0 = (kv0 + 0 * 16 + lr) < Nkv;
        bool val1 = (kv0 + 1 * 16 + lr) < Nkv;
        bool val2 = (kv0 + 2 * 16 + lr) < Nkv;
        bool val3 = (kv0 + 3 * 16 + lr) < Nkv;
        float fs[4];
        #pragma unroll
        for (int r = 0; r < 4; ++r) {
            float s0 = val0 ? sf[0][r] : -1e30f;
            float s1 = val1 ? sf[1][r] : -1e30f;
            float s2 = val2 ? sf[2][r] : -1e30f;
            float s3 = val3 ? sf[3][r] : -1e30f;
            float mx = fmaxf(fmaxf(s0, s1), fmaxf(s2, s3));
            mx = fmaxf(mx, __shfl_xor(mx, 1, 64));
            mx = fmaxf(mx, __shfl_xor(mx, 2, 64));
            mx = fmaxf(mx, __shfl_xor(mx, 4, 64));
            mx = fmaxf(mx, __shfl_xor(mx, 8, 64));
            float mn = fmaxf(m_r[r], mx);
            fs[r] = __expf(m_r[r] - mn);
            m_r[r] = mn;
            float p0 = __expf(s0 - mn), p1 = __expf(s1 - mn);
            float p2 = __expf(s2 - mn), p3 = __expf(s3 - mn);
            float rsum = p0 + p1 + p2 + p3;
            rsum += __shfl_xor(rsum, 1, 64);
            rsum += __shfl_xor(rsum, 2, 64);
            rsum += __shfl_xor(rsum, 4, 64);
            rsum += __shfl_xor(rsum, 8, 64);
            l_r[r] = l_r[r] * fs[r] + rsum;
            int ql = wrow + g * 4 + r;
            int base = ql * 64;
            int x7 = ql & 7;
            Ps[base + (((0 * 16 + lr) >> 3) ^ x7) * 8 + (lr & 7)] = f2bf(p0);
            Ps[base + (((1 * 16 + lr) >> 3) ^ x7) * 8 + (lr & 7)] = f2bf(p1);
            Ps[base + (((2 * 16 + lr) >> 3) ^ x7) * 8 + (lr & 7)] = f2bf(p2);
            Ps[base + (((3 * 16 + lr) >> 3) ^ x7) * 8 + (lr & 7)] = f2bf(p3);
            acc0[r] *= fs[r]; acc1[r] *= fs[r]; acc2[r] *= fs[r]; acc3[r] *= fs[r];
        }
        __syncthreads();   // P tile visible
        // O += P V  (A = P rows, B = Vs rows = V^T)
        short8v ap0, ap1;
        {
            int row = wrow + lr;
            ap0 = *(const short8v*)&Ps[row * 64 + ((0 * 4 + g) ^ (row & 7)) * 8];
            ap1 = *(const short8v*)&Ps[row * 64 + ((1 * 4 + g) ^ (row & 7)) * 8];
        }
        {
            int row = 0 * 16 + lr;
            short8v b0 = *(const short8v*)&Vs[row * 64 + ((0 * 4 + g) ^ (row & 7)) * 8];
            short8v b1 = *(const short8v*)&Vs[row * 64 + ((1 * 4 + g) ^ (row & 7)) * 8];
            acc0 = __builtin_amdgcn_mfma_f32_16x16x32_bf16(ap0, b0, acc0, 0, 0, 0);
            acc0 = __builtin_amdgcn_mfma_f32_16x16x32_bf16(ap1, b1, acc0, 0, 0, 0);
        }
        {
            int row = 1 * 16 + lr;
            short8v b0 = *(const short8v*)&Vs[row * 64 + ((0 * 4 + g) ^ (row & 7)) * 8];
            short8v b1 = *(const short8v*)&Vs[row * 64 + ((1 * 4 + g) ^ (row & 7)) * 8];
            acc1 = __builtin_amdgcn_mfma_f32_16x16x32_bf16(ap0, b0, acc1, 0, 0, 0);
            acc1 = __builtin_amdgcn_mfma_f32_16x16x32_bf16(ap1, b1, acc1, 0, 0, 0);
        }
        {
            int row = 2 * 16 + lr;
            short8v b0 = *(const short8v*)&Vs[row * 64 + ((0 * 4 + g) ^ (row & 7)) * 8];
            short8v b1 = *(const short8v*)&Vs[row * 64 + ((1 * 4 + g) ^ (row & 7)) * 8];
            acc2 = __builtin_amdgcn_mfma_f32_16x16x32_bf16(ap0, b0, acc2, 0, 0, 0);
            acc2 = __builtin_amdgcn_mfma_f32_16x16x32_bf16(ap1, b1, acc2, 0, 0, 0);
        }
        {
            int row = 3 * 16 + lr;
            short8v b0 = *(const short8v*)&Vs[row * 64 + ((0 * 4 + g) ^ (row & 7)) * 8];
            short8v b1 = *(const short8v*)&Vs[row * 64 + ((1 * 4 + g) ^ (row & 7)) * 8];
            acc3 = __builtin_amdgcn_mfma_f32_16x16x32_bf16(ap0, b0, acc3, 0, 0, 0);
            acc3 = __builtin_amdgcn_mfma_f32_16x16x32_bf16(ap1, b1, acc3, 0, 0, 0);
        }
        __syncthreads();   // PV reads done; next staging may overwrite
    }
    #pragma unroll
    for (int r = 0; r < 4; ++r) {
        int ql = wrow + g * 4 + r;
        if (q0 + ql >= Nq) continue;
        float rl = 1.f / l_r[r];
        unsigned short* op = O + (size_t)(b * Nq + q0 + ql) * ldo + h * 64 + lr;
        op[0]  = f2bf(acc0[r] * rl);
        op[16] = f2bf(acc1[r] * rl);
        op[32] = f2bf(acc2[r] * rl);
        op[48] = f2bf(acc3[r] * rl);
    }
}

// ---------------- MoE router (bf16 ln input) ----------------
__global__ __launch_bounds__(64) void router_kernel(
    const unsigned short* __restrict__ X, const float* __restrict__ Wr,
    int* __restrict__ idx, float* __restrict__ gval)
{
    int tkn = blockIdx.x; int lane = threadIdx.x;
    const unsigned short* xr = X + (size_t)tkn * D;
    float p0 = 0, p1 = 0, p2 = 0, p3 = 0;
    for (int dd = lane; dd < D; dd += 64) {
        float xv = bf2f(xr[dd]);
        const float* wq = Wr + dd * 4;
        p0 += xv * wq[0]; p1 += xv * wq[1]; p2 += xv * wq[2]; p3 += xv * wq[3];
    }
    for (int off = 32; off > 0; off >>= 1) {
        p0 += __shfl_xor(p0, off, 64); p1 += __shfl_xor(p1, off, 64);
        p2 += __shfl_xor(p2, off, 64); p3 += __shfl_xor(p3, off, 64);
    }
    if (lane == 0) {
        float best = p0; int e = 0;
        if (p1 > best) { best = p1; e = 1; }
        if (p2 > best) { best = p2; e = 2; }
        if (p3 > best) { best = p3; e = 3; }
        float sum = expf(p0 - best) + expf(p1 - best) + expf(p2 - best) + expf(p3 - best);
        idx[tkn] = e;
        gval[tkn] = 1.f / sum;
    }
}

__global__ void scatter_kernel(const int* __restrict__ idx, int* __restrict__ cnt,
                               int* __restrict__ list, int ntok)
{
    int i = blockIdx.x * blockDim.x + threadIdx.x;
    if (i >= ntok) return;
    int e = idx[i];
    int pos = atomicAdd(&cnt[e], 1);
    list[e * MAXTOK + pos] = i;
}

// ---------------- concat ----------------
__global__ void concat_kernel(const float* __restrict__ traj, const float* __restrict__ a,
                              const float* __restrict__ bg, const float* __restrict__ cg,
                              float* __restrict__ x, int total)
{
    int i = blockIdx.x * blockDim.x + threadIdx.x;
    if (i >= total) return;
    int col = i % D;
    int r = i / D;
    int n = r % NTOK, b = r / NTOK;
    float v;
    if (n < 256)      v = traj[((size_t)b * 256 + n) * D + col];
    else if (n < 320) v = a[((size_t)b * 64 + (n - 256)) * D + col];
    else if (n < 352) v = bg[((size_t)b * 32 + (n - 320)) * D + col];
    else              v = cg[((size_t)b * 192 + (n - 352)) * D + col];
    x[i] = v;
}

// ---------------- output head ----------------
__global__ void head_prep(const float* __restrict__ W, unsigned short* __restrict__ WT14) {
    int i = blockIdx.x * blockDim.x + threadIdx.x;
    if (i >= 14 * 768) return;
    int o = i / 768, d = i % 768;
    WT14[i] = f2bf(W[d * 14 + o]);
}

__global__ __launch_bounds__(64) void head_kernel(
    const unsigned short* __restrict__ lnb, const unsigned short* __restrict__ WT14,
    const float* __restrict__ bias, float* __restrict__ out)
{
    int r = blockIdx.x;
    int b = r >> 8, n = r & 255;
    const unsigned short* hrow = lnb + (size_t)(b * NTOK + n) * D;
    int l = threadIdx.x;
    if (l >= 56) return;
    int o = l >> 2, p = l & 3;
    const unsigned short* hp = hrow + p * 192;
    const unsigned short* wp = WT14 + o * 768 + p * 192;
    float acc = 0.f;
    for (int i = 0; i < 192; i += 8) {
        short8v hv = *(const short8v*)(hp + i);
        short8v wv = *(const short8v*)(wp + i);
        #pragma unroll
        for (int j = 0; j < 8; ++j)
            acc += bf2f((unsigned short)hv[j]) * bf2f((unsigned short)wv[j]);
    }
    acc += __shfl_xor(acc, 1, 64);
    acc += __shfl_xor(acc, 2, 64);
    if (p == 0) out[(size_t)r * 14 + o] = acc + bias[o];
}

// ---------------- host helpers ----------------
static inline void gemm(int act, const float* A, int lda, const float* B, int ldb,
                        const float* bias, float* C, int ldc, int M, int N, int K,
                        hipStream_t s)
{
    dim3 g((N + 63) / 64, (M + 63) / 64);
    if (act == 0)      gemm_act<0><<<g, 256, 0, s>>>(A, lda, B, ldb, bias, C, ldc, M, N, K);
    else if (act == 1) gemm_act<1><<<g, 256, 0, s>>>(A, lda, B, ldb, bias, C, ldc, M, N, K);
    else               gemm_act<2><<<g, 256, 0, s>>>(A, lda, B, ldb, bias, C, ldc, M, N, K);
}
static inline void tcvt(const float* W, unsigned short* WT, int K, int N, int z, hipStream_t s) {
    transpose_cvt<<<dim3(N / 64, K / 64, z), 256, 0, s>>>(W, WT, K, N);
}
// bf16 out (optional gelu, optional qscale)
static inline void g_bf(int act, const unsigned short* A, const unsigned short* BT,
                        const float* bias, unsigned short* C, int ldc,
                        int M, int N, int K, int qcols, hipStream_t s)
{
    dim3 g(N / 128, M / 128);
    if (act == 2) gemm_lds<2, 1><<<g, 256, 0, s>>>(A, BT, bias, nullptr, C, ldc, K, qcols, nullptr, 0, 0, 1);
    else          gemm_lds<0, 1><<<g, 256, 0, s>>>(A, BT, bias, nullptr, C, ldc, K, qcols, nullptr, 0, 0, 1);
}
// f32 residual out
static inline void g_res(const unsigned short* A, const unsigned short* BT,
                         const float* bias, float* C, int ldc, int M, int N, int K,
                         const float* mod, int modstride, int gchunk, int ntok, hipStream_t s)
{
    dim3 g(N / 128, M / 128);
    gemm_lds<0, 2><<<g, 256, 0, s>>>(A, BT, bias, C, nullptr, ldc, K, 0, mod, modstride, gchunk, ntok);
}

extern "C" void kernel_launch(void* const* d_in, const int* in_sizes, int n_in,
                              void* d_out, int out_size, void* d_ws, size_t ws_size,
                              hipStream_t stream)
{
    const float* x_traj   = (const float*)d_in[0];
    const int*   t_arr    = (const int*)d_in[1];
    const float* tokA     = (const float*)d_in[2];
    const float* tokB     = (const float*)d_in[3];
    const float* tokC     = (const float*)d_in[4];
    const float* W_traj   = (const float*)d_in[5];
    const float* b_traj   = (const float*)d_in[6];
    const float* W_ftime  = (const float*)d_in[7];
    const float* Wt1      = (const float*)d_in[8];
    const float* bt1      = (const float*)d_in[9];
    const float* Wt2      = (const float*)d_in[10];
    const float* bt2      = (const float*)d_in[11];
    const float* moe_attn = (const float*)d_in[12];
    const float* moe_rout = (const float*)d_in[13];
    const float* moe_W1   = (const float*)d_in[14];
    const float* moe_W2   = (const float*)d_in[15];
    const float* dit_qkv  = (const float*)d_in[16];
    const float* dit_qkvb = (const float*)d_in[17];
    const float* dit_proj = (const float*)d_in[18];
    const float* dit_projb= (const float*)d_in[19];
    const float* dit_mlp1 = (const float*)d_in[20];
    const float* dit_mlp1b= (const float*)d_in[21];
    const float* dit_mlp2 = (const float*)d_in[22];
    const float* dit_mlp2b= (const float*)d_in[23];
    const float* dit_ada  = (const float*)d_in[24];
    const float* dit_adab = (const float*)d_in[25];
    const float* out_adaW = (const float*)d_in[26];
    const float* out_adab = (const float*)d_in[27];
    const float* out_W    = (const float*)d_in[28];
    const float* out_b    = (const float*)d_in[29];
    float* out = (float*)d_out;
    float* ws = (float*)d_ws;

    // workspace layout (float offsets)
    const size_t o_temb = 0;                 // 2048
    const size_t o_u    = 2048;              // 6144
    const size_t o_c    = 8192;              // 6144
    const size_t o_sc   = 14336;             // 6144
    const size_t o_mod  = 20480;             // 36864
    const size_t o_cnt  = 57344;             // 64
    const size_t o_idx  = 57408;             // 1536
    const size_t o_gval = 58944;             // 1536
    const size_t o_list = 60480;             // 6144
    const size_t o_traj = 66624;             // 1572864
    const size_t o_a    = 1639488;           // 393216
    const size_t o_bg   = 2032704;           // 196608
    const size_t o_cg   = 2229312;           // 1179648
    const size_t o_x    = 3408960;           // 3342336
    const size_t o_lnb  = 6751296;           // 1671168 (bf16 4352x768)
    const size_t o_qkvb = 8422464;           // 5013504 (bf16 4352x2304)
    const size_t o_attnO= 13435968;          // 1671168 (bf16 4352x768)
    const size_t o_h    = 15107136;          // 6684672 (bf16 4352x3072)
    const size_t o_vt   = 21791808;          // 1769472 (bf16 8x12x64x576)
    const size_t o_kvbf = 23561280;          // 589824 (bf16 1536x768)
    const size_t o_wt   = 24151104;          // 4718592 (bf16 up to 4x768x3072)
    const size_t o_wt14 = 28869696;          // 5376

    int* cnt_p  = (int*)(ws + o_cnt);
    int* idx_p  = (int*)(ws + o_idx);
    int* list_p = (int*)(ws + o_list);
    float* gval_p = ws + o_gval;
    unsigned short* lnb  = (unsigned short*)(ws + o_lnb);
    unsigned short* qkvb = (unsigned short*)(ws + o_qkvb);
    unsigned short* attO = (unsigned short*)(ws + o_attnO);
    unsigned short* hbuf = (unsigned short*)(ws + o_h);
    unsigned short* vtb  = (unsigned short*)(ws + o_vt);
    unsigned short* kvbf = (unsigned short*)(ws + o_kvbf);
    unsigned short* wt   = (unsigned short*)(ws + o_wt);
    unsigned short* wt14 = (unsigned short*)(ws + o_wt14);
    // cross-attn q/k/v bf16 carved from qkvb region
    unsigned short* c_q = qkvb;
    unsigned short* c_k = qkvb + 1179648;
    unsigned short* c_v = qkvb + 2359296;

    // ---- timestep conditioning ----
    timestep_kernel<<<4, 256, 0, stream>>>(t_arr, ws + o_temb);
    gemm(1, ws + o_temb, 256, Wt1, D, bt1, ws + o_u, D, BATCH, D, 256, stream);
    gemm(0, ws + o_u, D, Wt2, D, bt2, ws + o_c, D, BATCH, D, D, stream);
    silu_vec<<<24, 256, 0, stream>>>(ws + o_c, ws + o_sc, BATCH * D);

    // ---- trajectory embedding ----
    gemm(0, x_traj, 7, W_traj, D, b_traj, ws + o_traj, D, BATCH * TTRAJ, D, 7, stream);
    add_ftime<<<(BATCH * TTRAJ * D + 255) / 256, 256, 0, stream>>>(ws + o_traj, W_ftime, BATCH * TTRAJ * D);

    hipMemcpyAsync(ws + o_a, tokA, (size_t)BATCH * NA * D * 4, hipMemcpyDeviceToDevice, stream);
    hipMemcpyAsync(ws + o_bg, tokB, (size_t)BATCH * NB * D * 4, hipMemcpyDeviceToDevice, stream);
    hipMemcpyAsync(ws + o_cg, tokC, (size_t)BATCH * NC * D * 4, hipMemcpyDeviceToDevice, stream);
    head_prep<<<42, 256, 0, stream>>>(out_W, wt14);

    const size_t WSZ = (size_t)D * D;
    for (int i = 0; i < NBLK; ++i) {
        // cross 1: cg += cross(ln(cg), a)   Rq=1536, Rkv=512
        {
            const float* Wc = moe_attn + (size_t)(i * 2 + 0) * 4 * WSZ;
            ln_kernel<<<BATCH * NC, 256, 0, stream>>>(ws + o_cg, lnb, BATCH * NC, 1, nullptr, 0, 0, 0);
            tcvt(Wc + 0 * WSZ, wt, D, D, 1, stream);
            g_bf(0, lnb, wt, nullptr, c_q, D, BATCH * NC, D, D, 768, stream);
            cvt_bf16<<<(BATCH * NA * D / 8 + 255) / 256, 256, 0, stream>>>(ws + o_a, kvbf, BATCH * NA * D / 8);
            tcvt(Wc + 1 * WSZ, wt, D, D, 1, stream);
            g_bf(0, kvbf, wt, nullptr, c_k, D, BATCH * NA, D, D, 0, stream);
            tcvt(Wc + 2 * WSZ, wt, D, D, 1, stream);
            g_bf(0, kvbf, wt, nullptr, c_v, D, BATCH * NA, D, D, 0, stream);
            vt_kernel<<<dim3(1, NH, BATCH), 256, 0, stream>>>(c_v, D, 0, vtb, NA, 64);
            attn_mfma<<<dim3(3, NH, BATCH), 256, 0, stream>>>(
                c_q, D, 0, c_k, D, 0, vtb, 64, attO, D, NC, NA);
            tcvt(Wc + 3 * WSZ, wt, D, D, 1, stream);
            g_res(attO, wt, nullptr, ws + o_cg, D, BATCH * NC, D, D, nullptr, 0, 0, 1, stream);
        }
        // cross 2: bg += cross(ln(bg), cg)  Rq=256, Rkv=1536
        {
            const float* Wc = moe_attn + (size_t)(i * 2 + 1) * 4 * WSZ;
            ln_kernel<<<BATCH * NB, 256, 0, stream>>>(ws + o_bg, lnb, BATCH * NB, 1, nullptr, 0, 0, 0);
            tcvt(Wc + 0 * WSZ, wt, D, D, 1, stream);
            g_bf(0, lnb, wt, nullptr, c_q, D, BATCH * NB, D, D, 768, stream);
            cvt_bf16<<<(BATCH * NC * D / 8 + 255) / 256, 256, 0, stream>>>(ws + o_cg, kvbf, BATCH * NC * D / 8);
            tcvt(Wc + 1 * WSZ, wt, D, D, 1, stream);
            g_bf(0, kvbf, wt, nullptr, c_k, D, BATCH * NC, D, D, 0, stream);
            tcvt(Wc + 2 * WSZ, wt, D, D, 1, stream);
            g_bf(0, kvbf, wt, nullptr, c_v, D, BATCH * NC, D, D, 0, stream);
            vt_kernel<<<dim3(3, NH, BATCH), 256, 0, stream>>>(c_v, D, 0, vtb, NC, 192);
            attn_mfma<<<dim3(1, NH, BATCH), 256, 0, stream>>>(
                c_q, D, 0, c_k, D, 0, vtb, 192, attO, D, NB, NC);
            tcvt(Wc + 3 * WSZ, wt, D, D, 1, stream);
            g_res(attO, wt, nullptr, ws + o_bg, D, BATCH * NB, D, D, nullptr, 0, 0, 1, stream);
        }
        // MoE on a, bg, cg
        const int gn[3] = {BATCH * NA, BATCH * NB, BATCH * NC};
        float* gptr[3] = {ws + o_a, ws + o_bg, ws + o_cg};
        for (int g = 0; g < 3; ++g) {
            int ntok = gn[g];
            const float* Wr = moe_rout + (size_t)(i * 3 + g) * D * NEXP;
            const float* W1 = moe_W1 + (size_t)(i * 3 + g) * NEXP * D * FF;
            const float* W2 = moe_W2 + (size_t)(i * 3 + g) * NEXP * FF * D;
            ln_kernel<<<ntok, 256, 0, stream>>>(gptr[g], lnb, ntok, 1, nullptr, 0, 0, 0);
            hipMemsetAsync((void*)cnt_p, 0, 4 * sizeof(int), stream);
            router_kernel<<<ntok, 64, 0, stream>>>(lnb, Wr, idx_p, gval_p);
            scatter_kernel<<<(ntok + 255) / 256, 256, 0, stream>>>(idx_p, cnt_p, list_p, ntok);
            int RT = (ntok + 127) / 128;
            tcvt(W1, wt, D, FF, NEXP, stream);
            moe_lds<1><<<dim3(FF / 128, NEXP * RT), 256, 0, stream>>>(
                lnb, wt, nullptr, hbuf, cnt_p, list_p, gval_p, RT);
            tcvt(W2, wt, FF, D, NEXP, stream);
            moe_lds<2><<<dim3(D / 128, NEXP * RT), 256, 0, stream>>>(
                hbuf, wt, gptr[g], nullptr, cnt_p, list_p, gval_p, RT);
        }
    }

    // ---- concat into x ----
    concat_kernel<<<(BATCH * NTOK * D + 255) / 256, 256, 0, stream>>>(
        ws + o_traj, ws + o_a, ws + o_bg, ws + o_cg, ws + o_x, BATCH * NTOK * D);

    const int R = BATCH * NTOK;   // 4352 = 34*128
    for (int i = 0; i < DEPTH; ++i) {
        gemm(0, ws + o_sc, D, dit_ada + (size_t)i * D * 6 * D, 6 * D,
             dit_adab + (size_t)i * 6 * D, ws + o_mod, 6 * D, BATCH, 6 * D, D, stream);
        ln_kernel<<<R, 256, 0, stream>>>(ws + o_x, lnb, R, NTOK, ws + o_mod, 6 * D, 0, 1);
        tcvt(dit_qkv + (size_t)i * D * 3 * D, wt, D, 3 * D, 1, stream);
        g_bf(0, lnb, wt, dit_qkvb + (size_t)i * 3 * D, qkvb, 3 * D, R, 3 * D, D, 768, stream);
        vt_kernel<<<dim3(9, NH, BATCH), 256, 0, stream>>>(qkvb, 3 * D, 2 * D, vtb, NTOK, 576);
        attn_mfma<<<dim3(9, NH, BATCH), 256, 0, stream>>>(
            qkvb, 3 * D, 0, qkvb, 3 * D, D, vtb, 576, attO, D, NTOK, NTOK);
        tcvt(dit_proj + (size_t)i * D * D, wt, D, D, 1, stream);
        g_res(attO, wt, dit_projb + (size_t)i * D, ws + o_x, D, R, D, D,
              ws + o_mod, 6 * D, 2, NTOK, stream);
        ln_kernel<<<R, 256, 0, stream>>>(ws + o_x, lnb, R, NTOK, ws + o_mod, 6 * D, 3, 4);
        tcvt(dit_mlp1 + (size_t)i * D * FF, wt, D, FF, 1, stream);
        g_bf(2, lnb, wt, dit_mlp1b + (size_t)i * FF, hbuf, FF, R, FF, D, 0, stream);
        tcvt(dit_mlp2 + (size_t)i * FF * D, wt, FF, D, 1, stream);
        g_res(hbuf, wt, dit_mlp2b + (size_t)i * D, ws + o_x, D, R, D, FF,
              ws + o_mod, 6 * D, 5, NTOK, stream);
    }

    // ---- output head ----
    gemm(0, ws + o_sc, D, out_adaW, 2 * D, out_adab, ws + o_mod, 2 * D, BATCH, 2 * D, D, stream);
    ln_kernel<<<R, 256, 0, stream>>>(ws + o_x, lnb, R, NTOK, ws + o_mod, 2 * D, 0, 1);
    head_kernel<<<BATCH * TTRAJ, 64, 0, stream>>>(lnb, wt14, out_b, out);
}

// Round 4
// 4154.287 us; speedup vs baseline: 7.0266x; 1.0396x over previous
//
#include <hip/hip_runtime.h>
#include <hip/hip_bf16.h>
#include <math.h>

#define D 768
#define NH 12
#define HD 64
#define NEXP 4
#define FF 3072
#define NBLK 2
#define DEPTH 6
#define NA 64
#define NB 32
#define NC 192
#define BATCH 8
#define TTRAJ 256
#define NTOK 544
#define MAXTOK 1536

typedef __attribute__((ext_vector_type(8))) short short8v;
typedef __attribute__((ext_vector_type(4))) float f32x4;

__device__ __forceinline__ float siluf(float v) { return v / (1.f + expf(-v)); }
__device__ __forceinline__ float geluf(float v) {
    float u = 0.7978845608028654f * (v + 0.044715f * v * v * v);
    return 0.5f * v * (1.f + tanhf(u));
}
__device__ __forceinline__ unsigned short f2bf(float f) {
    union { float f; unsigned u; } v; v.f = f;
    unsigned r = v.u + 0x7fffu + ((v.u >> 16) & 1u);
    return (unsigned short)(r >> 16);
}
__device__ __forceinline__ float bf2f(unsigned short u) {
    union { unsigned u; float f; } v; v.u = ((unsigned)u) << 16; return v.f;
}
__device__ __forceinline__ void gl16(const unsigned short* g, unsigned short* l) {
    __builtin_amdgcn_global_load_lds(
        (const __attribute__((address_space(1))) void*)g,
        (__attribute__((address_space(3))) void*)l, 16, 0, 0);
}

// ---------------- timestep embedding ----------------
__global__ void timestep_kernel(const int* __restrict__ t, float* __restrict__ temb) {
    int i = blockIdx.x * blockDim.x + threadIdx.x;
    if (i >= BATCH * 128) return;
    int b = i >> 7, j = i & 127;
    float freq = expf(-logf(10000.f) * (float)j / 128.f);
    float ang = (float)t[b] * freq;
    temb[b * 256 + j] = cosf(ang);
    temb[b * 256 + 128 + j] = sinf(ang);
}

__global__ void add_ftime(float* __restrict__ traj, const float* __restrict__ wf, int total) {
    int i = blockIdx.x * blockDim.x + threadIdx.x;
    if (i >= total) return;
    int col = i % D;
    int n = (i / D) % TTRAJ;
    traj[i] += wf[(n & 7) * D + col];
}

__global__ void cvt_bf16(const float* __restrict__ in, unsigned short* __restrict__ out, int n8) {
    int i = blockIdx.x * blockDim.x + threadIdx.x;
    if (i >= n8) return;
    float4 a = *(const float4*)(in + i * 8);
    float4 b = *(const float4*)(in + i * 8 + 4);
    unsigned short t[8] = {f2bf(a.x), f2bf(a.y), f2bf(a.z), f2bf(a.w),
                           f2bf(b.x), f2bf(b.y), f2bf(b.z), f2bf(b.w)};
    *(short8v*)(out + i * 8) = *(short8v*)t;
}

// ---------------- skinny GEMM for M=8: C[z][8][N] = act(A[8][K] @ B[z] + bias[z]) ----
// Each thread: 4 contiguous output columns x 8 rows. A cached in LDS.
template<int ACT>
__global__ __launch_bounds__(256) void skinny8(
    const float* __restrict__ A,          // [8][K]
    const float* __restrict__ Bbase,      // [z][K][N]
    const float* __restrict__ biasbase,   // [z][N] (nullable)
    float* __restrict__ Cbase,            // [z][8][N]
    int N, int K)
{
    extern __shared__ float As[];
    const float* B = Bbase + (size_t)blockIdx.z * K * N;
    const float* bias = biasbase ? biasbase + (size_t)blockIdx.z * N : nullptr;
    float* C = Cbase + (size_t)blockIdx.z * 8 * N;
    int tid = threadIdx.x;
    for (int i = tid; i < 8 * K; i += 256) As[i] = A[i];
    __syncthreads();
    int n0 = blockIdx.x * 1024 + tid * 4;
    if (n0 >= N) return;
    f32x4 acc[8] = {};
    for (int k = 0; k < K; k += 2) {
        float4 b0 = *(const float4*)(B + (size_t)k * N + n0);
        float4 b1 = *(const float4*)(B + (size_t)(k + 1) * N + n0);
        #pragma unroll
        for (int r = 0; r < 8; ++r) {
            float a0 = As[r * K + k], a1 = As[r * K + k + 1];
            acc[r][0] += a0 * b0.x + a1 * b1.x;
            acc[r][1] += a0 * b0.y + a1 * b1.y;
            acc[r][2] += a0 * b0.z + a1 * b1.z;
            acc[r][3] += a0 * b0.w + a1 * b1.w;
        }
    }
    float4 bb = make_float4(0.f, 0.f, 0.f, 0.f);
    if (bias) bb = *(const float4*)(bias + n0);
    #pragma unroll
    for (int r = 0; r < 8; ++r) {
        float4 v;
        v.x = acc[r][0] + bb.x; v.y = acc[r][1] + bb.y;
        v.z = acc[r][2] + bb.z; v.w = acc[r][3] + bb.w;
        if (ACT == 1) { v.x = siluf(v.x); v.y = siluf(v.y); v.z = siluf(v.z); v.w = siluf(v.w); }
        *(float4*)(C + (size_t)r * N + n0) = v;
    }
}

// ---------------- small f32 GEMM (traj embed, K=7) ----------------
template<int ACT>
__global__ __launch_bounds__(256) void gemm_act(
    const float* __restrict__ A, int lda,
    const float* __restrict__ B, int ldb,
    const float* __restrict__ bias,
    float* __restrict__ C, int ldc,
    int M, int N, int K)
{
    __shared__ float As[16][65];
    __shared__ float Bs[16][65];
    int tid = threadIdx.x;
    int tx = tid & 15, ty = tid >> 4;
    int row0 = blockIdx.y * 64, col0 = blockIdx.x * 64;
    float acc[4][4] = {};
    for (int k0 = 0; k0 < K; k0 += 16) {
        #pragma unroll
        for (int i = 0; i < 4; ++i) {
            int e = tid + 256 * i; int m = e >> 4; int kk = e & 15;
            int gr = row0 + m, gk = k0 + kk;
            As[kk][m] = (gr < M && gk < K) ? A[(size_t)gr * lda + gk] : 0.f;
        }
        #pragma unroll
        for (int i = 0; i < 4; ++i) {
            int e = tid + 256 * i; int kk = e >> 6; int n = e & 63;
            int gk = k0 + kk, gc = col0 + n;
            Bs[kk][n] = (gk < K && gc < N) ? B[(size_t)gk * ldb + gc] : 0.f;
        }
        __syncthreads();
        #pragma unroll
        for (int kk = 0; kk < 16; ++kk) {
            float a[4], bv[4];
            #pragma unroll
            for (int i = 0; i < 4; ++i) a[i] = As[kk][ty * 4 + i];
            #pragma unroll
            for (int j = 0; j < 4; ++j) bv[j] = Bs[kk][tx * 4 + j];
            #pragma unroll
            for (int i = 0; i < 4; ++i)
                #pragma unroll
                for (int j = 0; j < 4; ++j) acc[i][j] += a[i] * bv[j];
        }
        __syncthreads();
    }
    #pragma unroll
    for (int i = 0; i < 4; ++i) {
        int gr = row0 + ty * 4 + i; if (gr >= M) continue;
        #pragma unroll
        for (int j = 0; j < 4; ++j) {
            int gc = col0 + tx * 4 + j; if (gc >= N) continue;
            float v = acc[i][j] + (bias ? bias[gc] : 0.f);
            if (ACT == 1) v = siluf(v);
            if (ACT == 2) v = geluf(v);
            C[(size_t)gr * ldc + gc] = v;
        }
    }
}

// ---------------- weight transpose + cvt: [K][N] f32 -> [N][K] bf16 ----------------
// 64x64 tiles; 16B vector loads, 2x16B vector stores per thread.
__global__ __launch_bounds__(256) void transpose_cvt(
    const float* __restrict__ in, unsigned short* __restrict__ out, int K, int N)
{
    __shared__ unsigned short Ls[64][72];
    const float* src = in + (size_t)blockIdx.z * K * N;
    unsigned short* dst = out + (size_t)blockIdx.z * K * N;
    int k0 = blockIdx.y * 64, n0 = blockIdx.x * 64;
    int tid = threadIdx.x;
    int r = tid >> 2, c0 = (tid & 3) * 16;
    {
        const float* sp = src + (size_t)(k0 + r) * N + n0 + c0;
        #pragma unroll
        for (int j = 0; j < 16; j += 4) {
            float4 f = *(const float4*)(sp + j);
            Ls[c0 + j + 0][r] = f2bf(f.x);
            Ls[c0 + j + 1][r] = f2bf(f.y);
            Ls[c0 + j + 2][r] = f2bf(f.z);
            Ls[c0 + j + 3][r] = f2bf(f.w);
        }
    }
    __syncthreads();
    {
        unsigned short tmp[16];
        #pragma unroll
        for (int j = 0; j < 16; ++j) tmp[j] = Ls[r][c0 + j];
        unsigned short* dp = dst + (size_t)(n0 + r) * K + k0 + c0;
        *(short8v*)dp = *(short8v*)tmp;
        *(short8v*)(dp + 8) = *(short8v*)(tmp + 8);
    }
}

// ---------------- MFMA GEMM, global_load_lds staging, both-sides XOR swizzle ----
template<int ACT, int OUT>
__global__ __launch_bounds__(256) void gemm_lds(
    const unsigned short* __restrict__ A,
    const unsigned short* __restrict__ BT,
    const float* __restrict__ bias,
    float* __restrict__ Cf, unsigned short* __restrict__ Cb, int ldc,
    int K, int qscale_cols,
    const float* __restrict__ mod, int modstride, int gchunk, int ntok)
{
    __shared__ unsigned short As[128 * 32];
    __shared__ unsigned short Bs[128 * 32];
    int tid = threadIdx.x, w = tid >> 6, lane = tid & 63;
    int row0 = blockIdx.y * 128, col0 = blockIdx.x * 128;
    int wrow = (w >> 1) * 64, wcol = (w & 1) * 64;
    int lr = lane & 15, g = lane >> 4;
    f32x4 acc[4][4] = {};

    int r_s[2], ks_s[2], ld_s[2];
    #pragma unroll
    for (int i = 0; i < 2; ++i) {
        int off = tid * 16 + i * 4096;
        int row = off >> 6;
        int slot = (off >> 4) & 3;
        r_s[i] = row;
        ks_s[i] = (slot ^ ((row >> 1) & 3)) * 8;
        ld_s[i] = off >> 1;
    }

    for (int k0 = 0; k0 < K; k0 += 32) {
        #pragma unroll
        for (int i = 0; i < 2; ++i)
            gl16(A + (size_t)(row0 + r_s[i]) * K + k0 + ks_s[i], (unsigned short*)As + ld_s[i]);
        #pragma unroll
        for (int i = 0; i < 2; ++i)
            gl16(BT + (size_t)(col0 + r_s[i]) * K + k0 + ks_s[i], (unsigned short*)Bs + ld_s[i]);
        __syncthreads();
        short8v av[4], bv[4];
        #pragma unroll
        for (int mr = 0; mr < 4; ++mr) {
            int row = wrow + mr * 16 + lr;
            av[mr] = *(const short8v*)&As[row * 32 + (g ^ ((row >> 1) & 3)) * 8];
        }
        #pragma unroll
        for (int nc = 0; nc < 4; ++nc) {
            int row = wcol + nc * 16 + lr;
            bv[nc] = *(const short8v*)&Bs[row * 32 + (g ^ ((row >> 1) & 3)) * 8];
        }
        #pragma unroll
        for (int mr = 0; mr < 4; ++mr)
            #pragma unroll
            for (int nc = 0; nc < 4; ++nc)
                acc[mr][nc] = __builtin_amdgcn_mfma_f32_16x16x32_bf16(
                    av[mr], bv[nc], acc[mr][nc], 0, 0, 0);
        __syncthreads();
    }
    int rbase = g * 4;
    #pragma unroll
    for (int mr = 0; mr < 4; ++mr) {
        #pragma unroll
        for (int nc = 0; nc < 4; ++nc) {
            int gc = col0 + wcol + nc * 16 + lr;
            float bb = bias ? bias[gc] : 0.f;
            #pragma unroll
            for (int r = 0; r < 4; ++r) {
                int gr = row0 + wrow + mr * 16 + rbase + r;
                float v = acc[mr][nc][r] + bb;
                if (ACT == 2) v = geluf(v);
                if (OUT == 0) {
                    Cf[(size_t)gr * ldc + gc] = v;
                } else if (OUT == 1) {
                    if (gc < qscale_cols) v *= 0.125f;
                    Cb[(size_t)gr * ldc + gc] = f2bf(v);
                } else {
                    float gg = 1.f;
                    if (mod) gg = mod[(size_t)(gr / ntok) * modstride + gchunk * D + gc];
                    Cf[(size_t)gr * ldc + gc] += gg * v;
                }
            }
        }
    }
}

// ---------------- MoE gathered MFMA GEMM ----------------
template<int PHASE>
__global__ __launch_bounds__(256) void moe_lds(
    const unsigned short* __restrict__ A,
    const unsigned short* __restrict__ BTbase,
    float* __restrict__ Cf, unsigned short* __restrict__ Cb,
    const int* __restrict__ cnt, const int* __restrict__ list,
    const float* __restrict__ gval, int RT)
{
    const int K = (PHASE == 1) ? 768 : 3072;
    const int N = (PHASE == 1) ? 3072 : 768;
    int e = blockIdx.y / RT, rt = blockIdx.y % RT;
    int c0 = cnt[e];
    int mbase = rt * 128;
    if (mbase >= c0) return;
    int mcount = min(128, c0 - mbase);
    __shared__ int toks[128];
    int tid = threadIdx.x, w = tid >> 6, lane = tid & 63;
    if (tid < 128) toks[tid] = list[e * MAXTOK + mbase + min(tid, mcount - 1)];
    __syncthreads();

    __shared__ unsigned short As[128 * 32];
    __shared__ unsigned short Bs[128 * 32];
    const unsigned short* BT = BTbase + (size_t)e * 768 * 3072;
    int col0 = blockIdx.x * 128;
    int wrow = (w >> 1) * 64, wcol = (w & 1) * 64;
    int lr = lane & 15, g = lane >> 4;
    f32x4 acc[4][4] = {};

    int r_s[2], ks_s[2], ld_s[2], tok_s[2];
    #pragma unroll
    for (int i = 0; i < 2; ++i) {
        int off = tid * 16 + i * 4096;
        int row = off >> 6;
        int slot = (off >> 4) & 3;
        r_s[i] = row;
        ks_s[i] = (slot ^ ((row >> 1) & 3)) * 8;
        ld_s[i] = off >> 1;
        tok_s[i] = toks[row];
    }

    for (int k0 = 0; k0 < K; k0 += 32) {
        #pragma unroll
        for (int i = 0; i < 2; ++i)
            gl16(A + (size_t)tok_s[i] * K + k0 + ks_s[i], (unsigned short*)As + ld_s[i]);
        #pragma unroll
        for (int i = 0; i < 2; ++i)
            gl16(BT + (size_t)(col0 + r_s[i]) * K + k0 + ks_s[i], (unsigned short*)Bs + ld_s[i]);
        __syncthreads();
        short8v av[4], bv[4];
        #pragma unroll
        for (int mr = 0; mr < 4; ++mr) {
            int row = wrow + mr * 16 + lr;
            av[mr] = *(const short8v*)&As[row * 32 + (g ^ ((row >> 1) & 3)) * 8];
        }
        #pragma unroll
        for (int nc = 0; nc < 4; ++nc) {
            int row = wcol + nc * 16 + lr;
            bv[nc] = *(const short8v*)&Bs[row * 32 + (g ^ ((row >> 1) & 3)) * 8];
        }
        #pragma unroll
        for (int mr = 0; mr < 4; ++mr)
            #pragma unroll
            for (int nc = 0; nc < 4; ++nc)
                acc[mr][nc] = __builtin_amdgcn_mfma_f32_16x16x32_bf16(
                    av[mr], bv[nc], acc[mr][nc], 0, 0, 0);
        __syncthreads();
    }
    int rbase = g * 4;
    #pragma unroll
    for (int mr = 0; mr < 4; ++mr) {
        #pragma unroll
        for (int r = 0; r < 4; ++r) {
            int m = wrow + mr * 16 + rbase + r;
            if (m >= mcount) continue;
            int tok = toks[m];
            #pragma unroll
            for (int nc = 0; nc < 4; ++nc) {
                int gc = col0 + wcol + nc * 16 + lr;
                float v = acc[mr][nc][r];
                if (PHASE == 1) Cb[(size_t)tok * 3072 + gc] = f2bf(geluf(v));
                else            Cf[(size_t)tok * 768 + gc] += gval[tok] * v;
            }
        }
    }
}

// ---------------- LayerNorm -> bf16 (+ optional adaLN modulate) ----------------
__global__ __launch_bounds__(256) void ln_kernel(
    const float* __restrict__ X, unsigned short* __restrict__ Y, int R, int ntok,
    const float* __restrict__ mod, int modstride, int shift_chunk, int scale_chunk)
{
    int r = blockIdx.x;
    if (r >= R) return;
    const float* xr = X + (size_t)r * D;
    int tid = threadIdx.x;
    int lane = tid & 63, wid = tid >> 6;
    float v0 = xr[tid], v1 = xr[tid + 256], v2 = xr[tid + 512];
    float s = v0 + v1 + v2;
    float s2 = v0 * v0 + v1 * v1 + v2 * v2;
    for (int off = 32; off > 0; off >>= 1) {
        s += __shfl_xor(s, off, 64);
        s2 += __shfl_xor(s2, off, 64);
    }
    __shared__ float shs[4], shs2[4];
    if (lane == 0) { shs[wid] = s; shs2[wid] = s2; }
    __syncthreads();
    float tot = shs[0] + shs[1] + shs[2] + shs[3];
    float tot2 = shs2[0] + shs2[1] + shs2[2] + shs2[3];
    float mu = tot * (1.f / 768.f);
    float var = tot2 * (1.f / 768.f) - mu * mu;
    float rs = rsqrtf(var + 1e-6f);
    int bb = r / ntok;
    float vv[3] = {v0, v1, v2};
    #pragma unroll
    for (int j = 0; j < 3; ++j) {
        int col = tid + j * 256;
        float nrm = (vv[j] - mu) * rs;
        float y = nrm;
        if (mod) {
            float scv = mod[(size_t)bb * modstride + scale_chunk * D + col];
            float shv = mod[(size_t)bb * modstride + shift_chunk * D + col];
            y = nrm * (1.f + scv) + shv;
        }
        Y[(size_t)r * D + col] = f2bf(y);
    }
}

// ---------------- V transpose ----------------
__global__ __launch_bounds__(256) void vt_kernel(
    const unsigned short* __restrict__ V, int ldv, int voff,
    unsigned short* __restrict__ VT, int Nkv, int nkvpad)
{
    __shared__ unsigned short Ls[64][72];
    int h = blockIdx.y, b = blockIdx.z, kv0 = blockIdx.x * 64;
    int tid = threadIdx.x;
    int srow = tid >> 2, sc = (tid & 3) * 16;
    int kv = kv0 + srow;
    if (kv < Nkv) {
        const unsigned short* vp = V + (size_t)(b * Nkv + kv) * ldv + voff + h * 64 + sc;
        #pragma unroll
        for (int j = 0; j < 16; ++j) Ls[srow][sc + j] = vp[j];
    } else {
        #pragma unroll
        for (int j = 0; j < 16; ++j) Ls[srow][sc + j] = 0;
    }
    __syncthreads();
    int d = tid >> 2, c0 = (tid & 3) * 16;
    unsigned short tmp[16];
    #pragma unroll
    for (int j = 0; j < 16; ++j) tmp[j] = Ls[c0 + j][d];
    unsigned short* op = VT + ((size_t)(b * NH + h) * 64 + d) * nkvpad + kv0 + c0;
    *(short8v*)op = *(short8v*)tmp;
    *(short8v*)(op + 8) = *(short8v*)(tmp + 8);
}

// ---------------- MFMA flash attention ----------------
__global__ __launch_bounds__(256) void attn_mfma(
    const unsigned short* __restrict__ Qp, int ldq, int qoff,
    const unsigned short* __restrict__ Kp, int ldk, int koff,
    const unsigned short* __restrict__ VT, int nkvpad,
    unsigned short* __restrict__ O, int ldo,
    int Nq, int Nkv)
{
    __shared__ unsigned short Qs[64 * 64];
    __shared__ unsigned short Ks[64 * 64];
    __shared__ unsigned short Vs[64 * 64];
    __shared__ unsigned short Ps[64 * 64];
    int h = blockIdx.y, b = blockIdx.z, q0 = blockIdx.x * 64;
    int tid = threadIdx.x, w = tid >> 6, lane = tid & 63;
    int wrow = w * 16;
    int lr = lane & 15, g = lane >> 4;
    int srow = tid >> 2, sc = (tid & 3) * 16;

    {
        int gr = min(q0 + srow, Nq - 1);
        const unsigned short* qp = Qp + (size_t)(b * Nq + gr) * ldq + qoff + h * 64 + sc;
        short8v v0 = *(const short8v*)qp, v1 = *(const short8v*)(qp + 8);
        int s0 = sc >> 3;
        *(short8v*)&Qs[srow * 64 + (s0 ^ (srow & 7)) * 8] = v0;
        *(short8v*)&Qs[srow * 64 + ((s0 + 1) ^ (srow & 7)) * 8] = v1;
    }
    float m_r[4] = {-1e30f, -1e30f, -1e30f, -1e30f};
    float l_r[4] = {};
    f32x4 acc0 = {}, acc1 = {}, acc2 = {}, acc3 = {};
    const unsigned short* vtb = VT + (size_t)(b * NH + h) * 64 * nkvpad;

    for (int kv0 = 0; kv0 < Nkv; kv0 += 64) {
        {
            int gc = min(kv0 + srow, Nkv - 1);
            const unsigned short* kp = Kp + (size_t)(b * Nkv + gc) * ldk + koff + h * 64 + sc;
            short8v v0 = *(const short8v*)kp, v1 = *(const short8v*)(kp + 8);
            int s0 = sc >> 3;
            *(short8v*)&Ks[srow * 64 + (s0 ^ (srow & 7)) * 8] = v0;
            *(short8v*)&Ks[srow * 64 + ((s0 + 1) ^ (srow & 7)) * 8] = v1;
            const unsigned short* vp = vtb + (size_t)srow * nkvpad + kv0 + sc;
            short8v u0 = *(const short8v*)vp, u1 = *(const short8v*)(vp + 8);
            *(short8v*)&Vs[srow * 64 + (s0 ^ (srow & 7)) * 8] = u0;
            *(short8v*)&Vs[srow * 64 + ((s0 + 1) ^ (srow & 7)) * 8] = u1;
        }
        __syncthreads();
        short8v aq0, aq1;
        {
            int row = wrow + lr;
            aq0 = *(const short8v*)&Qs[row * 64 + ((0 * 4 + g) ^ (row & 7)) * 8];
            aq1 = *(const short8v*)&Qs[row * 64 + ((1 * 4 + g) ^ (row & 7)) * 8];
        }
        f32x4 sf[4];
        #pragma unroll
        for (int nc = 0; nc < 4; ++nc) {
            int row = nc * 16 + lr;
            short8v bk0 = *(const short8v*)&Ks[row * 64 + ((0 * 4 + g) ^ (row & 7)) * 8];
            short8v bk1 = *(const short8v*)&Ks[row * 64 + ((1 * 4 + g) ^ (row & 7)) * 8];
            f32x4 z = {};
            z = __builtin_amdgcn_mfma_f32_16x16x32_bf16(aq0, bk0, z, 0, 0, 0);
            sf[nc] = __builtin_amdgcn_mfma_f32_16x16x32_bf16(aq1, bk1, z, 0, 0, 0);
        }
        __syncthreads();
        bool val0 = (kv0 + 0 * 16 + lr) < Nkv;
        bool val1 = (kv0 + 1 * 16 + lr) < Nkv;
        bool val2 = (kv0 + 2 * 16 + lr) < Nkv;
        bool val3 = (kv0 + 3 * 16 + lr) < Nkv;
        float fs[4];
        #pragma unroll
        for (int r = 0; r < 4; ++r) {
            float s0 = val0 ? sf[0][r] : -1e30f;
            float s1 = val1 ? sf[1][r] : -1e30f;
            float s2 = val2 ? sf[2][r] : -1e30f;
            float s3 = val3 ? sf[3][r] : -1e30f;
            float mx = fmaxf(fmaxf(s0, s1), fmaxf(s2, s3));
            mx = fmaxf(mx, __shfl_xor(mx, 1, 64));
            mx = fmaxf(mx, __shfl_xor(mx, 2, 64));
            mx = fmaxf(mx, __shfl_xor(mx, 4, 64));
            mx = fmaxf(mx, __shfl_xor(mx, 8, 64));
            float mn = fmaxf(m_r[r], mx);
            fs[r] = __expf(m_r[r] - mn);
            m_r[r] = mn;
            float p0 = __expf(s0 - mn), p1 = __expf(s1 - mn);
            float p2 = __expf(s2 - mn), p3 = __expf(s3 - mn);
            float rsum = p0 + p1 + p2 + p3;
            rsum += __shfl_xor(rsum, 1, 64);
            rsum += __shfl_xor(rsum, 2, 64);
            rsum += __shfl_xor(rsum, 4, 64);
            rsum += __shfl_xor(rsum, 8, 64);
            l_r[r] = l_r[r] * fs[r] + rsum;
            int ql = wrow + g * 4 + r;
            int base = ql * 64;
            int x7 = ql & 7;
            Ps[base + (((0 * 16 + lr) >> 3) ^ x7) * 8 + (lr & 7)] = f2bf(p0);
            Ps[base + (((1 * 16 + lr) >> 3) ^ x7) * 8 + (lr & 7)] = f2bf(p1);
            Ps[base + (((2 * 16 + lr) >> 3) ^ x7) * 8 + (lr & 7)] = f2bf(p2);
            Ps[base + (((3 * 16 + lr) >> 3) ^ x7) * 8 + (lr & 7)] = f2bf(p3);
            acc0[r] *= fs[r]; acc1[r] *= fs[r]; acc2[r] *= fs[r]; acc3[r] *= fs[r];
        }
        __syncthreads();
        short8v ap0, ap1;
        {
            int row = wrow + lr;
            ap0 = *(const short8v*)&Ps[row * 64 + ((0 * 4 + g) ^ (row & 7)) * 8];
            ap1 = *(const short8v*)&Ps[row * 64 + ((1 * 4 + g) ^ (row & 7)) * 8];
        }
        {
            int row = 0 * 16 + lr;
            short8v b0 = *(const short8v*)&Vs[row * 64 + ((0 * 4 + g) ^ (row & 7)) * 8];
            short8v b1 = *(const short8v*)&Vs[row * 64 + ((1 * 4 + g) ^ (row & 7)) * 8];
            acc0 = __builtin_amdgcn_mfma_f32_16x16x32_bf16(ap0, b0, acc0, 0, 0, 0);
            acc0 = __builtin_amdgcn_mfma_f32_16x16x32_bf16(ap1, b1, acc0, 0, 0, 0);
        }
        {
            int row = 1 * 16 + lr;
            short8v b0 = *(const short8v*)&Vs[row * 64 + ((0 * 4 + g) ^ (row & 7)) * 8];
            short8v b1 = *(const short8v*)&Vs[row * 64 + ((1 * 4 + g) ^ (row & 7)) * 8];
            acc1 = __builtin_amdgcn_mfma_f32_16x16x32_bf16(ap0, b0, acc1, 0, 0, 0);
            acc1 = __builtin_amdgcn_mfma_f32_16x16x32_bf16(ap1, b1, acc1, 0, 0, 0);
        }
        {
            int row = 2 * 16 + lr;
            short8v b0 = *(const short8v*)&Vs[row * 64 + ((0 * 4 + g) ^ (row & 7)) * 8];
            short8v b1 = *(const short8v*)&Vs[row * 64 + ((1 * 4 + g) ^ (row & 7)) * 8];
            acc2 = __builtin_amdgcn_mfma_f32_16x16x32_bf16(ap0, b0, acc2, 0, 0, 0);
            acc2 = __builtin_amdgcn_mfma_f32_16x16x32_bf16(ap1, b1, acc2, 0, 0, 0);
        }
        {
            int row = 3 * 16 + lr;
            short8v b0 = *(const short8v*)&Vs[row * 64 + ((0 * 4 + g) ^ (row & 7)) * 8];
            short8v b1 = *(const short8v*)&Vs[row * 64 + ((1 * 4 + g) ^ (row & 7)) * 8];
            acc3 = __builtin_amdgcn_mfma_f32_16x16x32_bf16(ap0, b0, acc3, 0, 0, 0);
            acc3 = __builtin_amdgcn_mfma_f32_16x16x32_bf16(ap1, b1, acc3, 0, 0, 0);
        }
        __syncthreads();
    }
    #pragma unroll
    for (int r = 0; r < 4; ++r) {
        int ql = wrow + g * 4 + r;
        if (q0 + ql >= Nq) continue;
        float rl = 1.f / l_r[r];
        unsigned short* op = O + (size_t)(b * Nq + q0 + ql) * ldo + h * 64 + lr;
        op[0]  = f2bf(acc0[r] * rl);
        op[16] = f2bf(acc1[r] * rl);
        op[32] = f2bf(acc2[r] * rl);
        op[48] = f2bf(acc3[r] * rl);
    }
}

// ---------------- MoE router ----------------
__global__ __launch_bounds__(64) void router_kernel(
    const unsigned short* __restrict__ X, const float* __restrict__ Wr,
    int* __restrict__ idx, float* __restrict__ gval)
{
    int tkn = blockIdx.x; int lane = threadIdx.x;
    const unsigned short* xr = X + (size_t)tkn * D;
    float p0 = 0, p1 = 0, p2 = 0, p3 = 0;
    for (int dd = lane; dd < D; dd += 64) {
        float xv = bf2f(xr[dd]);
        const float* wq = Wr + dd * 4;
        p0 += xv * wq[0]; p1 += xv * wq[1]; p2 += xv * wq[2]; p3 += xv * wq[3];
    }
    for (int off = 32; off > 0; off >>= 1) {
        p0 += __shfl_xor(p0, off, 64); p1 += __shfl_xor(p1, off, 64);
        p2 += __shfl_xor(p2, off, 64); p3 += __shfl_xor(p3, off, 64);
    }
    if (lane == 0) {
        float best = p0; int e = 0;
        if (p1 > best) { best = p1; e = 1; }
        if (p2 > best) { best = p2; e = 2; }
        if (p3 > best) { best = p3; e = 3; }
        float sum = expf(p0 - best) + expf(p1 - best) + expf(p2 - best) + expf(p3 - best);
        idx[tkn] = e;
        gval[tkn] = 1.f / sum;
    }
}

__global__ void scatter_kernel(const int* __restrict__ idx, int* __restrict__ cnt,
                               int* __restrict__ list, int ntok)
{
    int i = blockIdx.x * blockDim.x + threadIdx.x;
    if (i >= ntok) return;
    int e = idx[i];
    int pos = atomicAdd(&cnt[e], 1);
    list[e * MAXTOK + pos] = i;
}

// ---------------- concat ----------------
__global__ void concat_kernel(const float* __restrict__ traj, const float* __restrict__ a,
                              const float* __restrict__ bg, const float* __restrict__ cg,
                              float* __restrict__ x, int total)
{
    int i = blockIdx.x * blockDim.x + threadIdx.x;
    if (i >= total) return;
    int col = i % D;
    int r = i / D;
    int n = r % NTOK, b = r / NTOK;
    float v;
    if (n < 256)      v = traj[((size_t)b * 256 + n) * D + col];
    else if (n < 320) v = a[((size_t)b * 64 + (n - 256)) * D + col];
    else if (n < 352) v = bg[((size_t)b * 32 + (n - 320)) * D + col];
    else              v = cg[((size_t)b * 192 + (n - 352)) * D + col];
    x[i] = v;
}

// ---------------- output head ----------------
__global__ void head_prep(const float* __restrict__ W, unsigned short* __restrict__ WT14) {
    int i = blockIdx.x * blockDim.x + threadIdx.x;
    if (i >= 14 * 768) return;
    int o = i / 768, d = i % 768;
    WT14[i] = f2bf(W[d * 14 + o]);
}

__global__ __launch_bounds__(64) void head_kernel(
    const unsigned short* __restrict__ lnb, const unsigned short* __restrict__ WT14,
    const float* __restrict__ bias, float* __restrict__ out)
{
    int r = blockIdx.x;
    int b = r >> 8, n = r & 255;
    const unsigned short* hrow = lnb + (size_t)(b * NTOK + n) * D;
    int l = threadIdx.x;
    if (l >= 56) return;
    int o = l >> 2, p = l & 3;
    const unsigned short* hp = hrow + p * 192;
    const unsigned short* wp = WT14 + o * 768 + p * 192;
    float acc = 0.f;
    for (int i = 0; i < 192; i += 8) {
        short8v hv = *(const short8v*)(hp + i);
        short8v wv = *(const short8v*)(wp + i);
        #pragma unroll
        for (int j = 0; j < 8; ++j)
            acc += bf2f((unsigned short)hv[j]) * bf2f((unsigned short)wv[j]);
    }
    acc += __shfl_xor(acc, 1, 64);
    acc += __shfl_xor(acc, 2, 64);
    if (p == 0) out[(size_t)r * 14 + o] = acc + bias[o];
}

// ---------------- host helpers ----------------
static inline void tcvt(const float* W, unsigned short* WT, int K, int N, int z, hipStream_t s) {
    transpose_cvt<<<dim3(N / 64, K / 64, z), 256, 0, s>>>(W, WT, K, N);
}
static inline void g_bf(int act, const unsigned short* A, const unsigned short* BT,
                        const float* bias, unsigned short* C, int ldc,
                        int M, int N, int K, int qcols, hipStream_t s)
{
    dim3 g(N / 128, M / 128);
    if (act == 2) gemm_lds<2, 1><<<g, 256, 0, s>>>(A, BT, bias, nullptr, C, ldc, K, qcols, nullptr, 0, 0, 1);
    else          gemm_lds<0, 1><<<g, 256, 0, s>>>(A, BT, bias, nullptr, C, ldc, K, qcols, nullptr, 0, 0, 1);
}
static inline void g_res(const unsigned short* A, const unsigned short* BT,
                         const float* bias, float* C, int ldc, int M, int N, int K,
                         const float* mod, int modstride, int gchunk, int ntok, hipStream_t s)
{
    dim3 g(N / 128, M / 128);
    gemm_lds<0, 2><<<g, 256, 0, s>>>(A, BT, bias, C, nullptr, ldc, K, 0, mod, modstride, gchunk, ntok);
}

extern "C" void kernel_launch(void* const* d_in, const int* in_sizes, int n_in,
                              void* d_out, int out_size, void* d_ws, size_t ws_size,
                              hipStream_t stream)
{
    const float* x_traj   = (const float*)d_in[0];
    const int*   t_arr    = (const int*)d_in[1];
    const float* tokA     = (const float*)d_in[2];
    const float* tokB     = (const float*)d_in[3];
    const float* tokC     = (const float*)d_in[4];
    const float* W_traj   = (const float*)d_in[5];
    const float* b_traj   = (const float*)d_in[6];
    const float* W_ftime  = (const float*)d_in[7];
    const float* Wt1      = (const float*)d_in[8];
    const float* bt1      = (const float*)d_in[9];
    const float* Wt2      = (const float*)d_in[10];
    const float* bt2      = (const float*)d_in[11];
    const float* moe_attn = (const float*)d_in[12];
    const float* moe_rout = (const float*)d_in[13];
    const float* moe_W1   = (const float*)d_in[14];
    const float* moe_W2   = (const float*)d_in[15];
    const float* dit_qkv  = (const float*)d_in[16];
    const float* dit_qkvb = (const float*)d_in[17];
    const float* dit_proj = (const float*)d_in[18];
    const float* dit_projb= (const float*)d_in[19];
    const float* dit_mlp1 = (const float*)d_in[20];
    const float* dit_mlp1b= (const float*)d_in[21];
    const float* dit_mlp2 = (const float*)d_in[22];
    const float* dit_mlp2b= (const float*)d_in[23];
    const float* dit_ada  = (const float*)d_in[24];
    const float* dit_adab = (const float*)d_in[25];
    const float* out_adaW = (const float*)d_in[26];
    const float* out_adab = (const float*)d_in[27];
    const float* out_W    = (const float*)d_in[28];
    const float* out_b    = (const float*)d_in[29];
    float* out = (float*)d_out;
    float* ws = (float*)d_ws;

    // workspace layout (float offsets) — mods overlay the traj region (dead after concat)
    const size_t o_temb = 0;                 // 2048
    const size_t o_u    = 2048;              // 6144
    const size_t o_sc   = 8192;              // 6144
    const size_t o_cnt  = 14336;             // 64
    const size_t o_idx  = 14400;             // 1536
    const size_t o_gval = 15936;             // 1536
    const size_t o_list = 17472;             // 6144
    const size_t o_traj = 66624;             // 1572864 (traj; later mod[6][8][4608]+mod2[8][1536])
    const size_t o_a    = 1639488;           // 393216
    const size_t o_bg   = 2032704;           // 196608
    const size_t o_cg   = 2229312;           // 1179648
    const size_t o_x    = 3408960;           // 3342336
    const size_t o_lnb  = 6751296;           // 1671168
    const size_t o_qkvb = 8422464;           // 5013504
    const size_t o_attnO= 13435968;          // 1671168
    const size_t o_h    = 15107136;          // 6684672
    const size_t o_vt   = 21791808;          // 1769472
    const size_t o_kvbf = 23561280;          // 589824
    const size_t o_wt   = 24151104;          // 4718592
    const size_t o_wt14 = 28869696;          // 5376

    const size_t o_mod  = o_traj;            // [6][8][4608] = 221184
    const size_t o_mod2 = o_traj + 221184;   // [8][1536]

    int* cnt_p  = (int*)(ws + o_cnt);
    int* idx_p  = (int*)(ws + o_idx);
    int* list_p = (int*)(ws + o_list);
    float* gval_p = ws + o_gval;
    unsigned short* lnb  = (unsigned short*)(ws + o_lnb);
    unsigned short* qkvb = (unsigned short*)(ws + o_qkvb);
    unsigned short* attO = (unsigned short*)(ws + o_attnO);
    unsigned short* hbuf = (unsigned short*)(ws + o_h);
    unsigned short* vtb  = (unsigned short*)(ws + o_vt);
    unsigned short* kvbf = (unsigned short*)(ws + o_kvbf);
    unsigned short* wt   = (unsigned short*)(ws + o_wt);
    unsigned short* wt14 = (unsigned short*)(ws + o_wt14);
    unsigned short* c_q = qkvb;
    unsigned short* c_k = qkvb + 1179648;
    unsigned short* c_v = qkvb + 2359296;

    // ---- trajectory embedding (traj region live until concat) ----
    gemm_act<0><<<dim3(12, 32), 256, 0, stream>>>(x_traj, 7, W_traj, D, b_traj,
                                                  ws + o_traj, D, BATCH * TTRAJ, D, 7);
    add_ftime<<<(BATCH * TTRAJ * D + 255) / 256, 256, 0, stream>>>(ws + o_traj, W_ftime, BATCH * TTRAJ * D);

    hipMemcpyAsync(ws + o_a, tokA, (size_t)BATCH * NA * D * 4, hipMemcpyDeviceToDevice, stream);
    hipMemcpyAsync(ws + o_bg, tokB, (size_t)BATCH * NB * D * 4, hipMemcpyDeviceToDevice, stream);
    hipMemcpyAsync(ws + o_cg, tokC, (size_t)BATCH * NC * D * 4, hipMemcpyDeviceToDevice, stream);
    head_prep<<<42, 256, 0, stream>>>(out_W, wt14);
    timestep_kernel<<<4, 256, 0, stream>>>(t_arr, ws + o_temb);
    skinny8<1><<<dim3(1, 1, 1), 256, 8 * 256 * 4, stream>>>(ws + o_temb, Wt1, bt1, ws + o_u, D, 256);
    skinny8<1><<<dim3(1, 1, 1), 256, 8 * 768 * 4, stream>>>(ws + o_u, Wt2, bt2, ws + o_sc, D, D);

    const size_t WSZ = (size_t)D * D;
    for (int i = 0; i < NBLK; ++i) {
        // cross 1: cg += cross(ln(cg), a)
        {
            const float* Wc = moe_attn + (size_t)(i * 2 + 0) * 4 * WSZ;
            tcvt(Wc, wt, D, D, 4, stream);
            ln_kernel<<<BATCH * NC, 256, 0, stream>>>(ws + o_cg, lnb, BATCH * NC, 1, nullptr, 0, 0, 0);
            g_bf(0, lnb, wt, nullptr, c_q, D, BATCH * NC, D, D, 768, stream);
            cvt_bf16<<<(BATCH * NA * D / 8 + 255) / 256, 256, 0, stream>>>(ws + o_a, kvbf, BATCH * NA * D / 8);
            g_bf(0, kvbf, wt + 1 * WSZ, nullptr, c_k, D, BATCH * NA, D, D, 0, stream);
            g_bf(0, kvbf, wt + 2 * WSZ, nullptr, c_v, D, BATCH * NA, D, D, 0, stream);
            vt_kernel<<<dim3(1, NH, BATCH), 256, 0, stream>>>(c_v, D, 0, vtb, NA, 64);
            attn_mfma<<<dim3(3, NH, BATCH), 256, 0, stream>>>(
                c_q, D, 0, c_k, D, 0, vtb, 64, attO, D, NC, NA);
            g_res(attO, wt + 3 * WSZ, nullptr, ws + o_cg, D, BATCH * NC, D, D, nullptr, 0, 0, 1, stream);
        }
        // cross 2: bg += cross(ln(bg), cg)
        {
            const float* Wc = moe_attn + (size_t)(i * 2 + 1) * 4 * WSZ;
            tcvt(Wc, wt, D, D, 4, stream);
            ln_kernel<<<BATCH * NB, 256, 0, stream>>>(ws + o_bg, lnb, BATCH * NB, 1, nullptr, 0, 0, 0);
            g_bf(0, lnb, wt, nullptr, c_q, D, BATCH * NB, D, D, 768, stream);
            cvt_bf16<<<(BATCH * NC * D / 8 + 255) / 256, 256, 0, stream>>>(ws + o_cg, kvbf, BATCH * NC * D / 8);
            g_bf(0, kvbf, wt + 1 * WSZ, nullptr, c_k, D, BATCH * NC, D, D, 0, stream);
            g_bf(0, kvbf, wt + 2 * WSZ, nullptr, c_v, D, BATCH * NC, D, D, 0, stream);
            vt_kernel<<<dim3(3, NH, BATCH), 256, 0, stream>>>(c_v, D, 0, vtb, NC, 192);
            attn_mfma<<<dim3(1, NH, BATCH), 256, 0, stream>>>(
                c_q, D, 0, c_k, D, 0, vtb, 192, attO, D, NB, NC);
            g_res(attO, wt + 3 * WSZ, nullptr, ws + o_bg, D, BATCH * NB, D, D, nullptr, 0, 0, 1, stream);
        }
        // MoE on a, bg, cg
        const int gn[3] = {BATCH * NA, BATCH * NB, BATCH * NC};
        float* gptr[3] = {ws + o_a, ws + o_bg, ws + o_cg};
        for (int g = 0; g < 3; ++g) {
            int ntok = gn[g];
            const float* Wr = moe_rout + (size_t)(i * 3 + g) * D * NEXP;
            const float* W1 = moe_W1 + (size_t)(i * 3 + g) * NEXP * D * FF;
            const float* W2 = moe_W2 + (size_t)(i * 3 + g) * NEXP * FF * D;
            ln_kernel<<<ntok, 256, 0, stream>>>(gptr[g], lnb, ntok, 1, nullptr, 0, 0, 0);
            hipMemsetAsync((void*)cnt_p, 0, 4 * sizeof(int), stream);
            router_kernel<<<ntok, 64, 0, stream>>>(lnb, Wr, idx_p, gval_p);
            scatter_kernel<<<(ntok + 255) / 256, 256, 0, stream>>>(idx_p, cnt_p, list_p, ntok);
            int RT = (ntok + 127) / 128;
            tcvt(W1, wt, D, FF, NEXP, stream);
            moe_lds<1><<<dim3(FF / 128, NEXP * RT), 256, 0, stream>>>(
                lnb, wt, nullptr, hbuf, cnt_p, list_p, gval_p, RT);
            tcvt(W2, wt, FF, D, NEXP, stream);
            moe_lds<2><<<dim3(D / 128, NEXP * RT), 256, 0, stream>>>(
                hbuf, wt, gptr[g], nullptr, cnt_p, list_p, gval_p, RT);
        }
    }

    // ---- concat into x (traj region dead afterwards) ----
    concat_kernel<<<(BATCH * NTOK * D + 255) / 256, 256, 0, stream>>>(
        ws + o_traj, ws + o_a, ws + o_bg, ws + o_cg, ws + o_x, BATCH * NTOK * D);

    // ---- adaLN modulations for all layers + output head (overlay traj region) ----
    skinny8<0><<<dim3(5, 1, 6), 256, 8 * 768 * 4, stream>>>(
        ws + o_sc, dit_ada, dit_adab, ws + o_mod, 6 * D, D);
    skinny8<0><<<dim3(2, 1, 1), 256, 8 * 768 * 4, stream>>>(
        ws + o_sc, out_adaW, out_adab, ws + o_mod2, 2 * D, D);

    const int R = BATCH * NTOK;   // 4352 = 34*128
    for (int i = 0; i < DEPTH; ++i) {
        const float* mod_l = ws + o_mod + (size_t)i * 8 * 6 * D;
        ln_kernel<<<R, 256, 0, stream>>>(ws + o_x, lnb, R, NTOK, mod_l, 6 * D, 0, 1);
        tcvt(dit_qkv + (size_t)i * D * 3 * D, wt, D, 3 * D, 1, stream);
        g_bf(0, lnb, wt, dit_qkvb + (size_t)i * 3 * D, qkvb, 3 * D, R, 3 * D, D, 768, stream);
        vt_kernel<<<dim3(9, NH, BATCH), 256, 0, stream>>>(qkvb, 3 * D, 2 * D, vtb, NTOK, 576);
        attn_mfma<<<dim3(9, NH, BATCH), 256, 0, stream>>>(
            qkvb, 3 * D, 0, qkvb, 3 * D, D, vtb, 576, attO, D, NTOK, NTOK);
        tcvt(dit_proj + (size_t)i * D * D, wt, D, D, 1, stream);
        g_res(attO, wt, dit_projb + (size_t)i * D, ws + o_x, D, R, D, D,
              mod_l, 6 * D, 2, NTOK, stream);
        ln_kernel<<<R, 256, 0, stream>>>(ws + o_x, lnb, R, NTOK, mod_l, 6 * D, 3, 4);
        tcvt(dit_mlp1 + (size_t)i * D * FF, wt, D, FF, 1, stream);
        g_bf(2, lnb, wt, dit_mlp1b + (size_t)i * FF, hbuf, FF, R, FF, D, 0, stream);
        tcvt(dit_mlp2 + (size_t)i * FF * D, wt, FF, D, 1, stream);
        g_res(hbuf, wt, dit_mlp2b + (size_t)i * D, ws + o_x, D, R, D, FF,
              mod_l, 6 * D, 5, NTOK, stream);
    }

    // ---- output head ----
    ln_kernel<<<R, 256, 0, stream>>>(ws + o_x, lnb, R, NTOK, ws + o_mod2, 2 * D, 0, 1);
    head_kernel<<<BATCH * TTRAJ, 64, 0, stream>>>(lnb, wt14, out_b, out);
}

// Round 6
// 3578.777 us; speedup vs baseline: 8.1566x; 1.1608x over previous
//
#include <hip/hip_runtime.h>
#include <hip/hip_bf16.h>
#include <math.h>

#define D 768
#define NH 12
#define HD 64
#define NEXP 4
#define FF 3072
#define NBLK 2
#define DEPTH 6
#define NA 64
#define NB 32
#define NC 192
#define BATCH 8
#define TTRAJ 256
#define NTOK 544
#define MAXTOK 1536

typedef __attribute__((ext_vector_type(8))) short short8v;
typedef __attribute__((ext_vector_type(4))) float f32x4;

__device__ __forceinline__ float siluf(float v) { return v / (1.f + expf(-v)); }
__device__ __forceinline__ float geluf(float v) {
    float u = 0.7978845608028654f * (v + 0.044715f * v * v * v);
    return 0.5f * v * (1.f + tanhf(u));
}
__device__ __forceinline__ unsigned short f2bf(float f) {
    union { float f; unsigned u; } v; v.f = f;
    unsigned r = v.u + 0x7fffu + ((v.u >> 16) & 1u);
    return (unsigned short)(r >> 16);
}
__device__ __forceinline__ float bf2f(unsigned short u) {
    union { unsigned u; float f; } v; v.u = ((unsigned)u) << 16; return v.f;
}
__device__ __forceinline__ void gl16(const unsigned short* g, unsigned short* l) {
    __builtin_amdgcn_global_load_lds(
        (const __attribute__((address_space(1))) void*)g,
        (__attribute__((address_space(3))) void*)l, 16, 0, 0);
}

// ---------------- timestep embedding -> bf16 [128][256] (rows 8..127 zero) ----
__global__ void timestep_kernel(const int* __restrict__ t, unsigned short* __restrict__ tembP) {
    int i = blockIdx.x * blockDim.x + threadIdx.x;
    if (i >= 128 * 256) return;
    int b = i >> 8, j = i & 255;
    float v = 0.f;
    if (b < BATCH) {
        int jj = (j & 127);
        float freq = expf(-logf(10000.f) * (float)jj / 128.f);
        float ang = (float)t[b] * freq;
        v = (j < 128) ? cosf(ang) : sinf(ang);
    }
    tembP[i] = f2bf(v);
}

__global__ void add_ftime(float* __restrict__ traj, const float* __restrict__ wf, int total) {
    int i = blockIdx.x * blockDim.x + threadIdx.x;
    if (i >= total) return;
    int col = i % D;
    int n = (i / D) % TTRAJ;
    traj[i] += wf[(n & 7) * D + col];
}

__global__ void cvt_bf16(const float* __restrict__ in, unsigned short* __restrict__ out, int n8) {
    int i = blockIdx.x * blockDim.x + threadIdx.x;
    if (i >= n8) return;
    float4 a = *(const float4*)(in + i * 8);
    float4 b = *(const float4*)(in + i * 8 + 4);
    unsigned short t[8] = {f2bf(a.x), f2bf(a.y), f2bf(a.z), f2bf(a.w),
                           f2bf(b.x), f2bf(b.y), f2bf(b.z), f2bf(b.w)};
    *(short8v*)(out + i * 8) = *(short8v*)t;
}

// ---------------- small f32 GEMM (traj embed, K=7) ----------------
template<int ACT>
__global__ __launch_bounds__(256) void gemm_act(
    const float* __restrict__ A, int lda,
    const float* __restrict__ B, int ldb,
    const float* __restrict__ bias,
    float* __restrict__ C, int ldc,
    int M, int N, int K)
{
    __shared__ float As[16][65];
    __shared__ float Bs[16][65];
    int tid = threadIdx.x;
    int tx = tid & 15, ty = tid >> 4;
    int row0 = blockIdx.y * 64, col0 = blockIdx.x * 64;
    float acc[4][4] = {};
    for (int k0 = 0; k0 < K; k0 += 16) {
        #pragma unroll
        for (int i = 0; i < 4; ++i) {
            int e = tid + 256 * i; int m = e >> 4; int kk = e & 15;
            int gr = row0 + m, gk = k0 + kk;
            As[kk][m] = (gr < M && gk < K) ? A[(size_t)gr * lda + gk] : 0.f;
        }
        #pragma unroll
        for (int i = 0; i < 4; ++i) {
            int e = tid + 256 * i; int kk = e >> 6; int n = e & 63;
            int gk = k0 + kk, gc = col0 + n;
            Bs[kk][n] = (gk < K && gc < N) ? B[(size_t)gk * ldb + gc] : 0.f;
        }
        __syncthreads();
        #pragma unroll
        for (int kk = 0; kk < 16; ++kk) {
            float a[4], bv[4];
            #pragma unroll
            for (int i = 0; i < 4; ++i) a[i] = As[kk][ty * 4 + i];
            #pragma unroll
            for (int j = 0; j < 4; ++j) bv[j] = Bs[kk][tx * 4 + j];
            #pragma unroll
            for (int i = 0; i < 4; ++i)
                #pragma unroll
                for (int j = 0; j < 4; ++j) acc[i][j] += a[i] * bv[j];
        }
        __syncthreads();
    }
    #pragma unroll
    for (int i = 0; i < 4; ++i) {
        int gr = row0 + ty * 4 + i; if (gr >= M) continue;
        #pragma unroll
        for (int j = 0; j < 4; ++j) {
            int gc = col0 + tx * 4 + j; if (gc >= N) continue;
            float v = acc[i][j] + (bias ? bias[gc] : 0.f);
            if (ACT == 1) v = siluf(v);
            if (ACT == 2) v = geluf(v);
            C[(size_t)gr * ldc + gc] = v;
        }
    }
}

// ---------------- weight transpose + cvt: [K][N] f32 -> [N][K] bf16 ----------------
__global__ __launch_bounds__(256) void transpose_cvt(
    const float* __restrict__ in, unsigned short* __restrict__ out, int K, int N)
{
    __shared__ unsigned short Ls[64][72];
    const float* src = in + (size_t)blockIdx.z * K * N;
    unsigned short* dst = out + (size_t)blockIdx.z * K * N;
    int k0 = blockIdx.y * 64, n0 = blockIdx.x * 64;
    int tid = threadIdx.x;
    int r = tid >> 2, c0 = (tid & 3) * 16;
    {
        const float* sp = src + (size_t)(k0 + r) * N + n0 + c0;
        #pragma unroll
        for (int j = 0; j < 16; j += 4) {
            float4 f = *(const float4*)(sp + j);
            Ls[c0 + j + 0][r] = f2bf(f.x);
            Ls[c0 + j + 1][r] = f2bf(f.y);
            Ls[c0 + j + 2][r] = f2bf(f.z);
            Ls[c0 + j + 3][r] = f2bf(f.w);
        }
    }
    __syncthreads();
    {
        unsigned short tmp[16];
        #pragma unroll
        for (int j = 0; j < 16; ++j) tmp[j] = Ls[r][c0 + j];
        unsigned short* dp = dst + (size_t)(n0 + r) * K + k0 + c0;
        *(short8v*)dp = *(short8v*)tmp;
        *(short8v*)(dp + 8) = *(short8v*)(tmp + 8);
    }
}

// ---------------- MFMA GEMM, global_load_lds staging, both-sides XOR swizzle ----
// ACT: 0 none, 1 silu, 2 gelu. OUT: 0 f32, 1 bf16 (+qscale), 2 f32 gated residual.
// mrows: rows actually written (M may be padded to 128).
template<int ACT, int OUT>
__global__ __launch_bounds__(256) void gemm_lds(
    const unsigned short* __restrict__ A,
    const unsigned short* __restrict__ BT,
    const float* __restrict__ bias,
    float* __restrict__ Cf, unsigned short* __restrict__ Cb, int ldc,
    int K, int qscale_cols,
    const float* __restrict__ mod, int modstride, int gchunk, int ntok, int mrows)
{
    __shared__ unsigned short As[128 * 32];
    __shared__ unsigned short Bs[128 * 32];
    int tid = threadIdx.x, w = tid >> 6, lane = tid & 63;
    int row0 = blockIdx.y * 128, col0 = blockIdx.x * 128;
    int wrow = (w >> 1) * 64, wcol = (w & 1) * 64;
    int lr = lane & 15, g = lane >> 4;
    f32x4 acc[4][4] = {};

    int r_s[2], ks_s[2], ld_s[2];
    #pragma unroll
    for (int i = 0; i < 2; ++i) {
        int off = tid * 16 + i * 4096;
        int row = off >> 6;
        int slot = (off >> 4) & 3;
        r_s[i] = row;
        ks_s[i] = (slot ^ ((row >> 1) & 3)) * 8;
        ld_s[i] = off >> 1;
    }

    for (int k0 = 0; k0 < K; k0 += 32) {
        #pragma unroll
        for (int i = 0; i < 2; ++i)
            gl16(A + (size_t)(row0 + r_s[i]) * K + k0 + ks_s[i], (unsigned short*)As + ld_s[i]);
        #pragma unroll
        for (int i = 0; i < 2; ++i)
            gl16(BT + (size_t)(col0 + r_s[i]) * K + k0 + ks_s[i], (unsigned short*)Bs + ld_s[i]);
        __syncthreads();
        short8v av[4], bv[4];
        #pragma unroll
        for (int mr = 0; mr < 4; ++mr) {
            int row = wrow + mr * 16 + lr;
            av[mr] = *(const short8v*)&As[row * 32 + (g ^ ((row >> 1) & 3)) * 8];
        }
        #pragma unroll
        for (int nc = 0; nc < 4; ++nc) {
            int row = wcol + nc * 16 + lr;
            bv[nc] = *(const short8v*)&Bs[row * 32 + (g ^ ((row >> 1) & 3)) * 8];
        }
        #pragma unroll
        for (int mr = 0; mr < 4; ++mr)
            #pragma unroll
            for (int nc = 0; nc < 4; ++nc)
                acc[mr][nc] = __builtin_amdgcn_mfma_f32_16x16x32_bf16(
                    av[mr], bv[nc], acc[mr][nc], 0, 0, 0);
        __syncthreads();
    }
    int rbase = g * 4;
    #pragma unroll
    for (int mr = 0; mr < 4; ++mr) {
        #pragma unroll
        for (int nc = 0; nc < 4; ++nc) {
            int gc = col0 + wcol + nc * 16 + lr;
            float bb = bias ? bias[gc] : 0.f;
            #pragma unroll
            for (int r = 0; r < 4; ++r) {
                int gr = row0 + wrow + mr * 16 + rbase + r;
                if (gr >= mrows) continue;
                float v = acc[mr][nc][r] + bb;
                if (ACT == 1) v = siluf(v);
                if (ACT == 2) v = geluf(v);
                if (OUT == 0) {
                    Cf[(size_t)gr * ldc + gc] = v;
                } else if (OUT == 1) {
                    if (gc < qscale_cols) v *= 0.125f;
                    Cb[(size_t)gr * ldc + gc] = f2bf(v);
                } else {
                    float gg = 1.f;
                    if (mod) gg = mod[(size_t)(gr / ntok) * modstride + gchunk * D + gc];
                    Cf[(size_t)gr * ldc + gc] += gg * v;
                }
            }
        }
    }
}

// ---------------- MoE gathered MFMA GEMM ----------------
template<int PHASE>
__global__ __launch_bounds__(256) void moe_lds(
    const unsigned short* __restrict__ A,
    const unsigned short* __restrict__ BTbase,
    float* __restrict__ Cf, unsigned short* __restrict__ Cb,
    const int* __restrict__ cnt, const int* __restrict__ list,
    const float* __restrict__ gval, int RT)
{
    const int K = (PHASE == 1) ? 768 : 3072;
    const int N = (PHASE == 1) ? 3072 : 768;
    int e = blockIdx.y / RT, rt = blockIdx.y % RT;
    int c0 = cnt[e];
    int mbase = rt * 128;
    if (mbase >= c0) return;
    int mcount = min(128, c0 - mbase);
    __shared__ int toks[128];
    int tid = threadIdx.x, w = tid >> 6, lane = tid & 63;
    if (tid < 128) toks[tid] = list[e * MAXTOK + mbase + min(tid, mcount - 1)];
    __syncthreads();

    __shared__ unsigned short As[128 * 32];
    __shared__ unsigned short Bs[128 * 32];
    const unsigned short* BT = BTbase + (size_t)e * 768 * 3072;
    int col0 = blockIdx.x * 128;
    int wrow = (w >> 1) * 64, wcol = (w & 1) * 64;
    int lr = lane & 15, g = lane >> 4;
    f32x4 acc[4][4] = {};

    int r_s[2], ks_s[2], ld_s[2], tok_s[2];
    #pragma unroll
    for (int i = 0; i < 2; ++i) {
        int off = tid * 16 + i * 4096;
        int row = off >> 6;
        int slot = (off >> 4) & 3;
        r_s[i] = row;
        ks_s[i] = (slot ^ ((row >> 1) & 3)) * 8;
        ld_s[i] = off >> 1;
        tok_s[i] = toks[row];
    }

    for (int k0 = 0; k0 < K; k0 += 32) {
        #pragma unroll
        for (int i = 0; i < 2; ++i)
            gl16(A + (size_t)tok_s[i] * K + k0 + ks_s[i], (unsigned short*)As + ld_s[i]);
        #pragma unroll
        for (int i = 0; i < 2; ++i)
            gl16(BT + (size_t)(col0 + r_s[i]) * K + k0 + ks_s[i], (unsigned short*)Bs + ld_s[i]);
        __syncthreads();
        short8v av[4], bv[4];
        #pragma unroll
        for (int mr = 0; mr < 4; ++mr) {
            int row = wrow + mr * 16 + lr;
            av[mr] = *(const short8v*)&As[row * 32 + (g ^ ((row >> 1) & 3)) * 8];
        }
        #pragma unroll
        for (int nc = 0; nc < 4; ++nc) {
            int row = wcol + nc * 16 + lr;
            bv[nc] = *(const short8v*)&Bs[row * 32 + (g ^ ((row >> 1) & 3)) * 8];
        }
        #pragma unroll
        for (int mr = 0; mr < 4; ++mr)
            #pragma unroll
            for (int nc = 0; nc < 4; ++nc)
                acc[mr][nc] = __builtin_amdgcn_mfma_f32_16x16x32_bf16(
                    av[mr], bv[nc], acc[mr][nc], 0, 0, 0);
        __syncthreads();
    }
    int rbase = g * 4;
    #pragma unroll
    for (int mr = 0; mr < 4; ++mr) {
        #pragma unroll
        for (int r = 0; r < 4; ++r) {
            int m = wrow + mr * 16 + rbase + r;
            if (m >= mcount) continue;
            int tok = toks[m];
            #pragma unroll
            for (int nc = 0; nc < 4; ++nc) {
                int gc = col0 + wcol + nc * 16 + lr;
                float v = acc[mr][nc][r];
                if (PHASE == 1) Cb[(size_t)tok * 3072 + gc] = f2bf(geluf(v));
                else            Cf[(size_t)tok * 768 + gc] += gval[tok] * v;
            }
        }
    }
}

// ---------------- LayerNorm -> bf16 (+ optional adaLN modulate) ----------------
__global__ __launch_bounds__(256) void ln_kernel(
    const float* __restrict__ X, unsigned short* __restrict__ Y, int R, int ntok,
    const float* __restrict__ mod, int modstride, int shift_chunk, int scale_chunk)
{
    int r = blockIdx.x;
    if (r >= R) return;
    const float* xr = X + (size_t)r * D;
    int tid = threadIdx.x;
    int lane = tid & 63, wid = tid >> 6;
    float v0 = xr[tid], v1 = xr[tid + 256], v2 = xr[tid + 512];
    float s = v0 + v1 + v2;
    float s2 = v0 * v0 + v1 * v1 + v2 * v2;
    for (int off = 32; off > 0; off >>= 1) {
        s += __shfl_xor(s, off, 64);
        s2 += __shfl_xor(s2, off, 64);
    }
    __shared__ float shs[4], shs2[4];
    if (lane == 0) { shs[wid] = s; shs2[wid] = s2; }
    __syncthreads();
    float tot = shs[0] + shs[1] + shs[2] + shs[3];
    float tot2 = shs2[0] + shs2[1] + shs2[2] + shs2[3];
    float mu = tot * (1.f / 768.f);
    float var = tot2 * (1.f / 768.f) - mu * mu;
    float rs = rsqrtf(var + 1e-6f);
    int bb = r / ntok;
    float vv[3] = {v0, v1, v2};
    #pragma unroll
    for (int j = 0; j < 3; ++j) {
        int col = tid + j * 256;
        float nrm = (vv[j] - mu) * rs;
        float y = nrm;
        if (mod) {
            float scv = mod[(size_t)bb * modstride + scale_chunk * D + col];
            float shv = mod[(size_t)bb * modstride + shift_chunk * D + col];
            y = nrm * (1.f + scv) + shv;
        }
        Y[(size_t)r * D + col] = f2bf(y);
    }
}

// ---------------- V transpose ----------------
__global__ __launch_bounds__(256) void vt_kernel(
    const unsigned short* __restrict__ V, int ldv, int voff,
    unsigned short* __restrict__ VT, int Nkv, int nkvpad)
{
    __shared__ unsigned short Ls[64][72];
    int h = blockIdx.y, b = blockIdx.z, kv0 = blockIdx.x * 64;
    int tid = threadIdx.x;
    int srow = tid >> 2, sc = (tid & 3) * 16;
    int kv = kv0 + srow;
    if (kv < Nkv) {
        const unsigned short* vp = V + (size_t)(b * Nkv + kv) * ldv + voff + h * 64 + sc;
        #pragma unroll
        for (int j = 0; j < 16; ++j) Ls[srow][sc + j] = vp[j];
    } else {
        #pragma unroll
        for (int j = 0; j < 16; ++j) Ls[srow][sc + j] = 0;
    }
    __syncthreads();
    int d = tid >> 2, c0 = (tid & 3) * 16;
    unsigned short tmp[16];
    #pragma unroll
    for (int j = 0; j < 16; ++j) tmp[j] = Ls[c0 + j][d];
    unsigned short* op = VT + ((size_t)(b * NH + h) * 64 + d) * nkvpad + kv0 + c0;
    *(short8v*)op = *(short8v*)tmp;
    *(short8v*)(op + 8) = *(short8v*)(tmp + 8);
}

// ---------------- MFMA flash attention ----------------
__global__ __launch_bounds__(256) void attn_mfma(
    const unsigned short* __restrict__ Qp, int ldq, int qoff,
    const unsigned short* __restrict__ Kp, int ldk, int koff,
    const unsigned short* __restrict__ VT, int nkvpad,
    unsigned short* __restrict__ O, int ldo,
    int Nq, int Nkv)
{
    __shared__ unsigned short Qs[64 * 64];
    __shared__ unsigned short Ks[64 * 64];
    __shared__ unsigned short Vs[64 * 64];
    __shared__ unsigned short Ps[64 * 64];
    int h = blockIdx.y, b = blockIdx.z, q0 = blockIdx.x * 64;
    int tid = threadIdx.x, w = tid >> 6, lane = tid & 63;
    int wrow = w * 16;
    int lr = lane & 15, g = lane >> 4;
    int srow = tid >> 2, sc = (tid & 3) * 16;

    {
        int gr = min(q0 + srow, Nq - 1);
        const unsigned short* qp = Qp + (size_t)(b * Nq + gr) * ldq + qoff + h * 64 + sc;
        short8v v0 = *(const short8v*)qp, v1 = *(const short8v*)(qp + 8);
        int s0 = sc >> 3;
        *(short8v*)&Qs[srow * 64 + (s0 ^ (srow & 7)) * 8] = v0;
        *(short8v*)&Qs[srow * 64 + ((s0 + 1) ^ (srow & 7)) * 8] = v1;
    }
    float m_r[4] = {-1e30f, -1e30f, -1e30f, -1e30f};
    float l_r[4] = {};
    f32x4 acc0 = {}, acc1 = {}, acc2 = {}, acc3 = {};
    const unsigned short* vtb = VT + (size_t)(b * NH + h) * 64 * nkvpad;

    for (int kv0 = 0; kv0 < Nkv; kv0 += 64) {
        {
            int gc = min(kv0 + srow, Nkv - 1);
            const unsigned short* kp = Kp + (size_t)(b * Nkv + gc) * ldk + koff + h * 64 + sc;
            short8v v0 = *(const short8v*)kp, v1 = *(const short8v*)(kp + 8);
            int s0 = sc >> 3;
            *(short8v*)&Ks[srow * 64 + (s0 ^ (srow & 7)) * 8] = v0;
            *(short8v*)&Ks[srow * 64 + ((s0 + 1) ^ (srow & 7)) * 8] = v1;
            const unsigned short* vp = vtb + (size_t)srow * nkvpad + kv0 + sc;
            short8v u0 = *(const short8v*)vp, u1 = *(const short8v*)(vp + 8);
            *(short8v*)&Vs[srow * 64 + (s0 ^ (srow & 7)) * 8] = u0;
            *(short8v*)&Vs[srow * 64 + ((s0 + 1) ^ (srow & 7)) * 8] = u1;
        }
        __syncthreads();
        short8v aq0, aq1;
        {
            int row = wrow + lr;
            aq0 = *(const short8v*)&Qs[row * 64 + ((0 * 4 + g) ^ (row & 7)) * 8];
            aq1 = *(const short8v*)&Qs[row * 64 + ((1 * 4 + g) ^ (row & 7)) * 8];
        }
        f32x4 sf[4];
        #pragma unroll
        for (int nc = 0; nc < 4; ++nc) {
            int row = nc * 16 + lr;
            short8v bk0 = *(const short8v*)&Ks[row * 64 + ((0 * 4 + g) ^ (row & 7)) * 8];
            short8v bk1 = *(const short8v*)&Ks[row * 64 + ((1 * 4 + g) ^ (row & 7)) * 8];
            f32x4 z = {};
            z = __builtin_amdgcn_mfma_f32_16x16x32_bf16(aq0, bk0, z, 0, 0, 0);
            sf[nc] = __builtin_amdgcn_mfma_f32_16x16x32_bf16(aq1, bk1, z, 0, 0, 0);
        }
        __syncthreads();
        bool val0 = (kv0 + 0 * 16 + lr) < Nkv;
        bool val1 = (kv0 + 1 * 16 + lr) < Nkv;
        bool val2 = (kv0 + 2 * 16 + lr) < Nkv;
        bool val3 = (kv0 + 3 * 16 + lr) < Nkv;
        float fs[4];
        #pragma unroll
        for (int r = 0; r < 4; ++r) {
            float s0 = val0 ? sf[0][r] : -1e30f;
            float s1 = val1 ? sf[1][r] : -1e30f;
            float s2 = val2 ? sf[2][r] : -1e30f;
            float s3 = val3 ? sf[3][r] : -1e30f;
            float mx = fmaxf(fmaxf(s0, s1), fmaxf(s2, s3));
            mx = fmaxf(mx, __shfl_xor(mx, 1, 64));
            mx = fmaxf(mx, __shfl_xor(mx, 2, 64));
            mx = fmaxf(mx, __shfl_xor(mx, 4, 64));
            mx = fmaxf(mx, __shfl_xor(mx, 8, 64));
            float mn = fmaxf(m_r[r], mx);
            fs[r] = __expf(m_r[r] - mn);
            m_r[r] = mn;
            float p0 = __expf(s0 - mn), p1 = __expf(s1 - mn);
            float p2 = __expf(s2 - mn), p3 = __expf(s3 - mn);
            float rsum = p0 + p1 + p2 + p3;
            rsum += __shfl_xor(rsum, 1, 64);
            rsum += __shfl_xor(rsum, 2, 64);
            rsum += __shfl_xor(rsum, 4, 64);
            rsum += __shfl_xor(rsum, 8, 64);
            l_r[r] = l_r[r] * fs[r] + rsum;
            int ql = wrow + g * 4 + r;
            int base = ql * 64;
            int x7 = ql & 7;
            Ps[base + (((0 * 16 + lr) >> 3) ^ x7) * 8 + (lr & 7)] = f2bf(p0);
            Ps[base + (((1 * 16 + lr) >> 3) ^ x7) * 8 + (lr & 7)] = f2bf(p1);
            Ps[base + (((2 * 16 + lr) >> 3) ^ x7) * 8 + (lr & 7)] = f2bf(p2);
            Ps[base + (((3 * 16 + lr) >> 3) ^ x7) * 8 + (lr & 7)] = f2bf(p3);
            acc0[r] *= fs[r]; acc1[r] *= fs[r]; acc2[r] *= fs[r]; acc3[r] *= fs[r];
        }
        __syncthreads();
        short8v ap0, ap1;
        {
            int row = wrow + lr;
            ap0 = *(const short8v*)&Ps[row * 64 + ((0 * 4 + g) ^ (row & 7)) * 8];
            ap1 = *(const short8v*)&Ps[row * 64 + ((1 * 4 + g) ^ (row & 7)) * 8];
        }
        {
            int row = 0 * 16 + lr;
            short8v b0 = *(const short8v*)&Vs[row * 64 + ((0 * 4 + g) ^ (row & 7)) * 8];
            short8v b1 = *(const short8v*)&Vs[row * 64 + ((1 * 4 + g) ^ (row & 7)) * 8];
            acc0 = __builtin_amdgcn_mfma_f32_16x16x32_bf16(ap0, b0, acc0, 0, 0, 0);
            acc0 = __builtin_amdgcn_mfma_f32_16x16x32_bf16(ap1, b1, acc0, 0, 0, 0);
        }
        {
            int row = 1 * 16 + lr;
            short8v b0 = *(const short8v*)&Vs[row * 64 + ((0 * 4 + g) ^ (row & 7)) * 8];
            short8v b1 = *(const short8v*)&Vs[row * 64 + ((1 * 4 + g) ^ (row & 7)) * 8];
            acc1 = __builtin_amdgcn_mfma_f32_16x16x32_bf16(ap0, b0, acc1, 0, 0, 0);
            acc1 = __builtin_amdgcn_mfma_f32_16x16x32_bf16(ap1, b1, acc1, 0, 0, 0);
        }
        {
            int row = 2 * 16 + lr;
            short8v b0 = *(const short8v*)&Vs[row * 64 + ((0 * 4 + g) ^ (row & 7)) * 8];
            short8v b1 = *(const short8v*)&Vs[row * 64 + ((1 * 4 + g) ^ (row & 7)) * 8];
            acc2 = __builtin_amdgcn_mfma_f32_16x16x32_bf16(ap0, b0, acc2, 0, 0, 0);
            acc2 = __builtin_amdgcn_mfma_f32_16x16x32_bf16(ap1, b1, acc2, 0, 0, 0);
        }
        {
            int row = 3 * 16 + lr;
            short8v b0 = *(const short8v*)&Vs[row * 64 + ((0 * 4 + g) ^ (row & 7)) * 8];
            short8v b1 = *(const short8v*)&Vs[row * 64 + ((1 * 4 + g) ^ (row & 7)) * 8];
            acc3 = __builtin_amdgcn_mfma_f32_16x16x32_bf16(ap0, b0, acc3, 0, 0, 0);
            acc3 = __builtin_amdgcn_mfma_f32_16x16x32_bf16(ap1, b1, acc3, 0, 0, 0);
        }
        __syncthreads();
    }
    #pragma unroll
    for (int r = 0; r < 4; ++r) {
        int ql = wrow + g * 4 + r;
        if (q0 + ql >= Nq) continue;
        float rl = 1.f / l_r[r];
        unsigned short* op = O + (size_t)(b * Nq + q0 + ql) * ldo + h * 64 + lr;
        op[0]  = f2bf(acc0[r] * rl);
        op[16] = f2bf(acc1[r] * rl);
        op[32] = f2bf(acc2[r] * rl);
        op[48] = f2bf(acc3[r] * rl);
    }
}

// ---------------- MoE router ----------------
__global__ __launch_bounds__(64) void router_kernel(
    const unsigned short* __restrict__ X, const float* __restrict__ Wr,
    int* __restrict__ idx, float* __restrict__ gval)
{
    int tkn = blockIdx.x; int lane = threadIdx.x;
    const unsigned short* xr = X + (size_t)tkn * D;
    float p0 = 0, p1 = 0, p2 = 0, p3 = 0;
    for (int dd = lane; dd < D; dd += 64) {
        float xv = bf2f(xr[dd]);
        const float* wq = Wr + dd * 4;
        p0 += xv * wq[0]; p1 += xv * wq[1]; p2 += xv * wq[2]; p3 += xv * wq[3];
    }
    for (int off = 32; off > 0; off >>= 1) {
        p0 += __shfl_xor(p0, off, 64); p1 += __shfl_xor(p1, off, 64);
        p2 += __shfl_xor(p2, off, 64); p3 += __shfl_xor(p3, off, 64);
    }
    if (lane == 0) {
        float best = p0; int e = 0;
        if (p1 > best) { best = p1; e = 1; }
        if (p2 > best) { best = p2; e = 2; }
        if (p3 > best) { best = p3; e = 3; }
        float sum = expf(p0 - best) + expf(p1 - best) + expf(p2 - best) + expf(p3 - best);
        idx[tkn] = e;
        gval[tkn] = 1.f / sum;
    }
}

__global__ void scatter_kernel(const int* __restrict__ idx, int* __restrict__ cnt,
                               int* __restrict__ list, int ntok)
{
    int i = blockIdx.x * blockDim.x + threadIdx.x;
    if (i >= ntok) return;
    int e = idx[i];
    int pos = atomicAdd(&cnt[e], 1);
    list[e * MAXTOK + pos] = i;
}

// ---------------- concat ----------------
__global__ void concat_kernel(const float* __restrict__ traj, const float* __restrict__ a,
                              const float* __restrict__ bg, const float* __restrict__ cg,
                              float* __restrict__ x, int total)
{
    int i = blockIdx.x * blockDim.x + threadIdx.x;
    if (i >= total) return;
    int col = i % D;
    int r = i / D;
    int n = r % NTOK, b = r / NTOK;
    float v;
    if (n < 256)      v = traj[((size_t)b * 256 + n) * D + col];
    else if (n < 320) v = a[((size_t)b * 64 + (n - 256)) * D + col];
    else if (n < 352) v = bg[((size_t)b * 32 + (n - 320)) * D + col];
    else              v = cg[((size_t)b * 192 + (n - 352)) * D + col];
    x[i] = v;
}

// ---------------- output head ----------------
__global__ void head_prep(const float* __restrict__ W, unsigned short* __restrict__ WT14) {
    int i = blockIdx.x * blockDim.x + threadIdx.x;
    if (i >= 14 * 768) return;
    int o = i / 768, d = i % 768;
    WT14[i] = f2bf(W[d * 14 + o]);
}

__global__ __launch_bounds__(64) void head_kernel(
    const unsigned short* __restrict__ lnb, const unsigned short* __restrict__ WT14,
    const float* __restrict__ bias, float* __restrict__ out)
{
    int r = blockIdx.x;
    int b = r >> 8, n = r & 255;
    const unsigned short* hrow = lnb + (size_t)(b * NTOK + n) * D;
    int l = threadIdx.x;
    if (l >= 56) return;
    int o = l >> 2, p = l & 3;
    const unsigned short* hp = hrow + p * 192;
    const unsigned short* wp = WT14 + o * 768 + p * 192;
    float acc = 0.f;
    for (int i = 0; i < 192; i += 8) {
        short8v hv = *(const short8v*)(hp + i);
        short8v wv = *(const short8v*)(wp + i);
        #pragma unroll
        for (int j = 0; j < 8; ++j)
            acc += bf2f((unsigned short)hv[j]) * bf2f((unsigned short)wv[j]);
    }
    acc += __shfl_xor(acc, 1, 64);
    acc += __shfl_xor(acc, 2, 64);
    if (p == 0) out[(size_t)r * 14 + o] = acc + bias[o];
}

// ---------------- host helpers ----------------
static inline void tcvt(const float* W, unsigned short* WT, int K, int N, int z, hipStream_t s) {
    transpose_cvt<<<dim3(N / 64, K / 64, z), 256, 0, s>>>(W, WT, K, N);
}
static inline void g_bf(int act, const unsigned short* A, const unsigned short* BT,
                        const float* bias, unsigned short* C, int ldc,
                        int M, int N, int K, int qcols, hipStream_t s)
{
    dim3 g(N / 128, M / 128);
    if (act == 2) gemm_lds<2, 1><<<g, 256, 0, s>>>(A, BT, bias, nullptr, C, ldc, K, qcols, nullptr, 0, 0, 1, 1 << 30);
    else          gemm_lds<0, 1><<<g, 256, 0, s>>>(A, BT, bias, nullptr, C, ldc, K, qcols, nullptr, 0, 0, 1, 1 << 30);
}
static inline void g_res(const unsigned short* A, const unsigned short* BT,
                         const float* bias, float* C, int ldc, int M, int N, int K,
                         const float* mod, int modstride, int gchunk, int ntok, hipStream_t s)
{
    dim3 g(N / 128, M / 128);
    gemm_lds<0, 2><<<g, 256, 0, s>>>(A, BT, bias, C, nullptr, ldc, K, 0, mod, modstride, gchunk, ntok, 1 << 30);
}

extern "C" void kernel_launch(void* const* d_in, const int* in_sizes, int n_in,
                              void* d_out, int out_size, void* d_ws, size_t ws_size,
                              hipStream_t stream)
{
    const float* x_traj   = (const float*)d_in[0];
    const int*   t_arr    = (const int*)d_in[1];
    const float* tokA     = (const float*)d_in[2];
    const float* tokB     = (const float*)d_in[3];
    const float* tokC     = (const float*)d_in[4];
    const float* W_traj   = (const float*)d_in[5];
    const float* b_traj   = (const float*)d_in[6];
    const float* W_ftime  = (const float*)d_in[7];
    const float* Wt1      = (const float*)d_in[8];
    const float* bt1      = (const float*)d_in[9];
    const float* Wt2      = (const float*)d_in[10];
    const float* bt2      = (const float*)d_in[11];
    const float* moe_attn = (const float*)d_in[12];
    const float* moe_rout = (const float*)d_in[13];
    const float* moe_W1   = (const float*)d_in[14];
    const float* moe_W2   = (const float*)d_in[15];
    const float* dit_qkv  = (const float*)d_in[16];
    const float* dit_qkvb = (const float*)d_in[17];
    const float* dit_proj = (const float*)d_in[18];
    const float* dit_projb= (const float*)d_in[19];
    const float* dit_mlp1 = (const float*)d_in[20];
    const float* dit_mlp1b= (const float*)d_in[21];
    const float* dit_mlp2 = (const float*)d_in[22];
    const float* dit_mlp2b= (const float*)d_in[23];
    const float* dit_ada  = (const float*)d_in[24];
    const float* dit_adab = (const float*)d_in[25];
    const float* out_adaW = (const float*)d_in[26];
    const float* out_adab = (const float*)d_in[27];
    const float* out_W    = (const float*)d_in[28];
    const float* out_b    = (const float*)d_in[29];
    float* out = (float*)d_out;
    float* ws = (float*)d_ws;

    // workspace layout (float offsets)
    const size_t o_cnt  = 14336;             // 64
    const size_t o_idx  = 14400;             // 1536
    const size_t o_gval = 15936;             // 1536
    const size_t o_list = 17472;             // 6144
    const size_t o_traj = 66624;             // 1572864 (traj; later mod buffers)
    const size_t o_a    = 1639488;           // 393216
    const size_t o_bg   = 2032704;           // 196608
    const size_t o_cg   = 2229312;           // 1179648
    const size_t o_x    = 3408960;           // 3342336
    const size_t o_lnb  = 6751296;           // 1671168
    const size_t o_qkvb = 8422464;           // 5013504
    const size_t o_attnO= 13435968;          // 1671168
    const size_t o_h    = 15107136;          // 6684672
    const size_t o_vt   = 21791808;          // 1769472
    const size_t o_kvbf = 23561280;          // 589824
    const size_t o_wt   = 24151104;          // 4718592
    const size_t o_wt14 = 28869696;          // 5376 floats (14*768 bf16 = 10752 bf16) — FULL size
    const size_t o_tembP= 28875072;          // bf16 [128][256] = 16384 floats
    const size_t o_ub   = 28891456;          // bf16 [128][768] = 49152 floats
    const size_t o_scb  = 28940608;          // bf16 [128][768] = 49152 floats (ends 28989760)

    const size_t o_mod  = o_traj;            // f32 [6][8][4608]
    const size_t o_mod2 = o_traj + 221184;   // f32 [8][1536]

    int* cnt_p  = (int*)(ws + o_cnt);
    int* idx_p  = (int*)(ws + o_idx);
    int* list_p = (int*)(ws + o_list);
    float* gval_p = ws + o_gval;
    unsigned short* lnb  = (unsigned short*)(ws + o_lnb);
    unsigned short* qkvb = (unsigned short*)(ws + o_qkvb);
    unsigned short* attO = (unsigned short*)(ws + o_attnO);
    unsigned short* hbuf = (unsigned short*)(ws + o_h);
    unsigned short* vtb  = (unsigned short*)(ws + o_vt);
    unsigned short* kvbf = (unsigned short*)(ws + o_kvbf);
    unsigned short* wt   = (unsigned short*)(ws + o_wt);
    unsigned short* wt14 = (unsigned short*)(ws + o_wt14);
    unsigned short* tembP= (unsigned short*)(ws + o_tembP);
    unsigned short* ub   = (unsigned short*)(ws + o_ub);
    unsigned short* scb  = (unsigned short*)(ws + o_scb);
    unsigned short* c_q = qkvb;
    unsigned short* c_k = qkvb + 1179648;
    unsigned short* c_v = qkvb + 2359296;

    // ---- trajectory embedding ----
    gemm_act<0><<<dim3(12, 32), 256, 0, stream>>>(x_traj, 7, W_traj, D, b_traj,
                                                  ws + o_traj, D, BATCH * TTRAJ, D, 7);
    add_ftime<<<(BATCH * TTRAJ * D + 255) / 256, 256, 0, stream>>>(ws + o_traj, W_ftime, BATCH * TTRAJ * D);

    hipMemcpyAsync(ws + o_a, tokA, (size_t)BATCH * NA * D * 4, hipMemcpyDeviceToDevice, stream);
    hipMemcpyAsync(ws + o_bg, tokB, (size_t)BATCH * NB * D * 4, hipMemcpyDeviceToDevice, stream);
    hipMemcpyAsync(ws + o_cg, tokC, (size_t)BATCH * NC * D * 4, hipMemcpyDeviceToDevice, stream);
    head_prep<<<42, 256, 0, stream>>>(out_W, wt14);

    // ---- conditioning chain on MFMA (M padded to 128) ----
    timestep_kernel<<<128, 256, 0, stream>>>(t_arr, tembP);
    tcvt(Wt1, wt, 256, D, 1, stream);       // [768][256] bf16
    gemm_lds<1, 1><<<dim3(6, 1), 256, 0, stream>>>(
        tembP, wt, bt1, nullptr, ub, D, 256, 0, nullptr, 0, 0, 1, 128);
    tcvt(Wt2, wt, D, D, 1, stream);
    gemm_lds<1, 1><<<dim3(6, 1), 256, 0, stream>>>(
        ub, wt, bt2, nullptr, scb, D, D, 0, nullptr, 0, 0, 1, 128);   // scb = silu(c)

    const size_t WSZ = (size_t)D * D;
    for (int i = 0; i < NBLK; ++i) {
        // cross 1: cg += cross(ln(cg), a)
        {
            const float* Wc = moe_attn + (size_t)(i * 2 + 0) * 4 * WSZ;
            tcvt(Wc, wt, D, D, 4, stream);
            ln_kernel<<<BATCH * NC, 256, 0, stream>>>(ws + o_cg, lnb, BATCH * NC, 1, nullptr, 0, 0, 0);
            g_bf(0, lnb, wt, nullptr, c_q, D, BATCH * NC, D, D, 768, stream);
            cvt_bf16<<<(BATCH * NA * D / 8 + 255) / 256, 256, 0, stream>>>(ws + o_a, kvbf, BATCH * NA * D / 8);
            g_bf(0, kvbf, wt + 1 * WSZ, nullptr, c_k, D, BATCH * NA, D, D, 0, stream);
            g_bf(0, kvbf, wt + 2 * WSZ, nullptr, c_v, D, BATCH * NA, D, D, 0, stream);
            vt_kernel<<<dim3(1, NH, BATCH), 256, 0, stream>>>(c_v, D, 0, vtb, NA, 64);
            attn_mfma<<<dim3(3, NH, BATCH), 256, 0, stream>>>(
                c_q, D, 0, c_k, D, 0, vtb, 64, attO, D, NC, NA);
            g_res(attO, wt + 3 * WSZ, nullptr, ws + o_cg, D, BATCH * NC, D, D, nullptr, 0, 0, 1, stream);
        }
        // cross 2: bg += cross(ln(bg), cg)
        {
            const float* Wc = moe_attn + (size_t)(i * 2 + 1) * 4 * WSZ;
            tcvt(Wc, wt, D, D, 4, stream);
            ln_kernel<<<BATCH * NB, 256, 0, stream>>>(ws + o_bg, lnb, BATCH * NB, 1, nullptr, 0, 0, 0);
            g_bf(0, lnb, wt, nullptr, c_q, D, BATCH * NB, D, D, 768, stream);
            cvt_bf16<<<(BATCH * NC * D / 8 + 255) / 256, 256, 0, stream>>>(ws + o_cg, kvbf, BATCH * NC * D / 8);
            g_bf(0, kvbf, wt + 1 * WSZ, nullptr, c_k, D, BATCH * NC, D, D, 0, stream);
            g_bf(0, kvbf, wt + 2 * WSZ, nullptr, c_v, D, BATCH * NC, D, D, 0, stream);
            vt_kernel<<<dim3(3, NH, BATCH), 256, 0, stream>>>(c_v, D, 0, vtb, NC, 192);
            attn_mfma<<<dim3(1, NH, BATCH), 256, 0, stream>>>(
                c_q, D, 0, c_k, D, 0, vtb, 192, attO, D, NB, NC);
            g_res(attO, wt + 3 * WSZ, nullptr, ws + o_bg, D, BATCH * NB, D, D, nullptr, 0, 0, 1, stream);
        }
        // MoE on a, bg, cg
        const int gn[3] = {BATCH * NA, BATCH * NB, BATCH * NC};
        float* gptr[3] = {ws + o_a, ws + o_bg, ws + o_cg};
        for (int g = 0; g < 3; ++g) {
            int ntok = gn[g];
            const float* Wr = moe_rout + (size_t)(i * 3 + g) * D * NEXP;
            const float* W1 = moe_W1 + (size_t)(i * 3 + g) * NEXP * D * FF;
            const float* W2 = moe_W2 + (size_t)(i * 3 + g) * NEXP * FF * D;
            ln_kernel<<<ntok, 256, 0, stream>>>(gptr[g], lnb, ntok, 1, nullptr, 0, 0, 0);
            hipMemsetAsync((void*)cnt_p, 0, 4 * sizeof(int), stream);
            router_kernel<<<ntok, 64, 0, stream>>>(lnb, Wr, idx_p, gval_p);
            scatter_kernel<<<(ntok + 255) / 256, 256, 0, stream>>>(idx_p, cnt_p, list_p, ntok);
            int RT = (ntok + 127) / 128;
            tcvt(W1, wt, D, FF, NEXP, stream);
            moe_lds<1><<<dim3(FF / 128, NEXP * RT), 256, 0, stream>>>(
                lnb, wt, nullptr, hbuf, cnt_p, list_p, gval_p, RT);
            tcvt(W2, wt, FF, D, NEXP, stream);
            moe_lds<2><<<dim3(D / 128, NEXP * RT), 256, 0, stream>>>(
                hbuf, wt, gptr[g], nullptr, cnt_p, list_p, gval_p, RT);
        }
    }

    // ---- concat into x (traj region dead afterwards) ----
    concat_kernel<<<(BATCH * NTOK * D + 255) / 256, 256, 0, stream>>>(
        ws + o_traj, ws + o_a, ws + o_bg, ws + o_cg, ws + o_x, BATCH * NTOK * D);

    // ---- adaLN modulations via MFMA (mrows=8 clip) ----
    for (int i = 0; i < DEPTH; ++i) {
        tcvt(dit_ada + (size_t)i * D * 6 * D, wt, D, 6 * D, 1, stream);
        gemm_lds<0, 0><<<dim3(36, 1), 256, 0, stream>>>(
            scb, wt, dit_adab + (size_t)i * 6 * D, ws + o_mod + (size_t)i * 8 * 6 * D,
            nullptr, 6 * D, D, 0, nullptr, 0, 0, 1, 8);
    }
    tcvt(out_adaW, wt, D, 2 * D, 1, stream);
    gemm_lds<0, 0><<<dim3(12, 1), 256, 0, stream>>>(
        scb, wt, out_adab, ws + o_mod2, nullptr, 2 * D, D, 0, nullptr, 0, 0, 1, 8);

    const int R = BATCH * NTOK;   // 4352 = 34*128
    for (int i = 0; i < DEPTH; ++i) {
        const float* mod_l = ws + o_mod + (size_t)i * 8 * 6 * D;
        ln_kernel<<<R, 256, 0, stream>>>(ws + o_x, lnb, R, NTOK, mod_l, 6 * D, 0, 1);
        tcvt(dit_qkv + (size_t)i * D * 3 * D, wt, D, 3 * D, 1, stream);
        g_bf(0, lnb, wt, dit_qkvb + (size_t)i * 3 * D, qkvb, 3 * D, R, 3 * D, D, 768, stream);
        vt_kernel<<<dim3(9, NH, BATCH), 256, 0, stream>>>(qkvb, 3 * D, 2 * D, vtb, NTOK, 576);
        attn_mfma<<<dim3(9, NH, BATCH), 256, 0, stream>>>(
            qkvb, 3 * D, 0, qkvb, 3 * D, D, vtb, 576, attO, D, NTOK, NTOK);
        tcvt(dit_proj + (size_t)i * D * D, wt, D, D, 1, stream);
        g_res(attO, wt, dit_projb + (size_t)i * D, ws + o_x, D, R, D, D,
              mod_l, 6 * D, 2, NTOK, stream);
        ln_kernel<<<R, 256, 0, stream>>>(ws + o_x, lnb, R, NTOK, mod_l, 6 * D, 3, 4);
        tcvt(dit_mlp1 + (size_t)i * D * FF, wt, D, FF, 1, stream);
        g_bf(2, lnb, wt, dit_mlp1b + (size_t)i * FF, hbuf, FF, R, FF, D, 0, stream);
        tcvt(dit_mlp2 + (size_t)i * FF * D, wt, FF, D, 1, stream);
        g_res(hbuf, wt, dit_mlp2b + (size_t)i * D, ws + o_x, D, R, D, FF,
              mod_l, 6 * D, 5, NTOK, stream);
    }

    // ---- output head ----
    ln_kernel<<<R, 256, 0, stream>>>(ws + o_x, lnb, R, NTOK, ws + o_mod2, 2 * D, 0, 1);
    head_kernel<<<BATCH * TTRAJ, 64, 0, stream>>>(lnb, wt14, out_b, out);
}

// Round 7
// 3442.422 us; speedup vs baseline: 8.4797x; 1.0396x over previous
//
#include <hip/hip_runtime.h>
#include <hip/hip_bf16.h>
#include <math.h>

#define D 768
#define NH 12
#define HD 64
#define NEXP 4
#define FF 3072
#define NBLK 2
#define DEPTH 6
#define NA 64
#define NB 32
#define NC 192
#define BATCH 8
#define TTRAJ 256
#define NTOK 544
#define MAXTOK 1536

typedef __attribute__((ext_vector_type(8))) short short8v;
typedef __attribute__((ext_vector_type(4))) float f32x4;

__device__ __forceinline__ float siluf(float v) { return v / (1.f + expf(-v)); }
__device__ __forceinline__ float geluf(float v) {
    float u = 0.7978845608028654f * (v + 0.044715f * v * v * v);
    return 0.5f * v * (1.f + tanhf(u));
}
__device__ __forceinline__ unsigned short f2bf(float f) {
    union { float f; unsigned u; } v; v.f = f;
    unsigned r = v.u + 0x7fffu + ((v.u >> 16) & 1u);
    return (unsigned short)(r >> 16);
}
__device__ __forceinline__ float bf2f(unsigned short u) {
    union { unsigned u; float f; } v; v.u = ((unsigned)u) << 16; return v.f;
}
__device__ __forceinline__ void gl16(const unsigned short* g, unsigned short* l) {
    __builtin_amdgcn_global_load_lds(
        (const __attribute__((address_space(1))) void*)g,
        (__attribute__((address_space(3))) void*)l, 16, 0, 0);
}

// ---------------- timestep embedding -> bf16 [128][256] (rows 8..127 zero) ----
__global__ void timestep_kernel(const int* __restrict__ t, unsigned short* __restrict__ tembP) {
    int i = blockIdx.x * blockDim.x + threadIdx.x;
    if (i >= 128 * 256) return;
    int b = i >> 8, j = i & 255;
    float v = 0.f;
    if (b < BATCH) {
        int jj = (j & 127);
        float freq = expf(-logf(10000.f) * (float)jj / 128.f);
        float ang = (float)t[b] * freq;
        v = (j < 128) ? cosf(ang) : sinf(ang);
    }
    tembP[i] = f2bf(v);
}

__global__ void add_ftime(float* __restrict__ traj, const float* __restrict__ wf, int total) {
    int i = blockIdx.x * blockDim.x + threadIdx.x;
    if (i >= total) return;
    int col = i % D;
    int n = (i / D) % TTRAJ;
    traj[i] += wf[(n & 7) * D + col];
}

__global__ void cvt_bf16(const float* __restrict__ in, unsigned short* __restrict__ out, int n8) {
    int i = blockIdx.x * blockDim.x + threadIdx.x;
    if (i >= n8) return;
    float4 a = *(const float4*)(in + i * 8);
    float4 b = *(const float4*)(in + i * 8 + 4);
    unsigned short t[8] = {f2bf(a.x), f2bf(a.y), f2bf(a.z), f2bf(a.w),
                           f2bf(b.x), f2bf(b.y), f2bf(b.z), f2bf(b.w)};
    *(short8v*)(out + i * 8) = *(short8v*)t;
}

// ---------------- small f32 GEMM (traj embed, K=7) ----------------
template<int ACT>
__global__ __launch_bounds__(256) void gemm_act(
    const float* __restrict__ A, int lda,
    const float* __restrict__ B, int ldb,
    const float* __restrict__ bias,
    float* __restrict__ C, int ldc,
    int M, int N, int K)
{
    __shared__ float As[16][65];
    __shared__ float Bs[16][65];
    int tid = threadIdx.x;
    int tx = tid & 15, ty = tid >> 4;
    int row0 = blockIdx.y * 64, col0 = blockIdx.x * 64;
    float acc[4][4] = {};
    for (int k0 = 0; k0 < K; k0 += 16) {
        #pragma unroll
        for (int i = 0; i < 4; ++i) {
            int e = tid + 256 * i; int m = e >> 4; int kk = e & 15;
            int gr = row0 + m, gk = k0 + kk;
            As[kk][m] = (gr < M && gk < K) ? A[(size_t)gr * lda + gk] : 0.f;
        }
        #pragma unroll
        for (int i = 0; i < 4; ++i) {
            int e = tid + 256 * i; int kk = e >> 6; int n = e & 63;
            int gk = k0 + kk, gc = col0 + n;
            Bs[kk][n] = (gk < K && gc < N) ? B[(size_t)gk * ldb + gc] : 0.f;
        }
        __syncthreads();
        #pragma unroll
        for (int kk = 0; kk < 16; ++kk) {
            float a[4], bv[4];
            #pragma unroll
            for (int i = 0; i < 4; ++i) a[i] = As[kk][ty * 4 + i];
            #pragma unroll
            for (int j = 0; j < 4; ++j) bv[j] = Bs[kk][tx * 4 + j];
            #pragma unroll
            for (int i = 0; i < 4; ++i)
                #pragma unroll
                for (int j = 0; j < 4; ++j) acc[i][j] += a[i] * bv[j];
        }
        __syncthreads();
    }
    #pragma unroll
    for (int i = 0; i < 4; ++i) {
        int gr = row0 + ty * 4 + i; if (gr >= M) continue;
        #pragma unroll
        for (int j = 0; j < 4; ++j) {
            int gc = col0 + tx * 4 + j; if (gc >= N) continue;
            float v = acc[i][j] + (bias ? bias[gc] : 0.f);
            if (ACT == 1) v = siluf(v);
            if (ACT == 2) v = geluf(v);
            C[(size_t)gr * ldc + gc] = v;
        }
    }
}

// ---------------- weight transpose + cvt: [K][N] f32 -> [N][K] bf16 ----------------
__global__ __launch_bounds__(256) void transpose_cvt(
    const float* __restrict__ in, unsigned short* __restrict__ out, int K, int N)
{
    __shared__ unsigned short Ls[64][72];
    const float* src = in + (size_t)blockIdx.z * K * N;
    unsigned short* dst = out + (size_t)blockIdx.z * K * N;
    int k0 = blockIdx.y * 64, n0 = blockIdx.x * 64;
    int tid = threadIdx.x;
    int r = tid >> 2, c0 = (tid & 3) * 16;
    {
        const float* sp = src + (size_t)(k0 + r) * N + n0 + c0;
        #pragma unroll
        for (int j = 0; j < 16; j += 4) {
            float4 f = *(const float4*)(sp + j);
            Ls[c0 + j + 0][r] = f2bf(f.x);
            Ls[c0 + j + 1][r] = f2bf(f.y);
            Ls[c0 + j + 2][r] = f2bf(f.z);
            Ls[c0 + j + 3][r] = f2bf(f.w);
        }
    }
    __syncthreads();
    {
        unsigned short tmp[16];
        #pragma unroll
        for (int j = 0; j < 16; ++j) tmp[j] = Ls[r][c0 + j];
        unsigned short* dp = dst + (size_t)(n0 + r) * K + k0 + c0;
        *(short8v*)dp = *(short8v*)tmp;
        *(short8v*)(dp + 8) = *(short8v*)(tmp + 8);
    }
}

// ---------------- MFMA GEMM, BK=64, global_load_lds, 8-slot XOR swizzle ----
// ACT: 0 none, 1 silu, 2 gelu. OUT: 0 f32, 1 bf16 (+qscale), 2 f32 gated residual.
template<int ACT, int OUT>
__global__ __launch_bounds__(256) void gemm_lds(
    const unsigned short* __restrict__ A,
    const unsigned short* __restrict__ BT,
    const float* __restrict__ bias,
    float* __restrict__ Cf, unsigned short* __restrict__ Cb, int ldc,
    int K, int qscale_cols,
    const float* __restrict__ mod, int modstride, int gchunk, int ntok, int mrows)
{
    __shared__ unsigned short As[128 * 64];
    __shared__ unsigned short Bs[128 * 64];
    int tid = threadIdx.x, w = tid >> 6, lane = tid & 63;
    int row0 = blockIdx.y * 128, col0 = blockIdx.x * 128;
    int wrow = (w >> 1) * 64, wcol = (w & 1) * 64;
    int lr = lane & 15, g = lane >> 4;
    f32x4 acc[4][4] = {};

    int r_s[4], ks_s[4], ld_s[4];
    #pragma unroll
    for (int i = 0; i < 4; ++i) {
        int off = tid * 16 + i * 4096;          // bytes; 16 KB total per buffer
        int row = off >> 7;                     // 128 B per row
        int slot = (off >> 4) & 7;
        r_s[i] = row;
        ks_s[i] = (slot ^ (row & 7)) * 8;
        ld_s[i] = off >> 1;
    }

    for (int k0 = 0; k0 < K; k0 += 64) {
        #pragma unroll
        for (int i = 0; i < 4; ++i)
            gl16(A + (size_t)(row0 + r_s[i]) * K + k0 + ks_s[i], (unsigned short*)As + ld_s[i]);
        #pragma unroll
        for (int i = 0; i < 4; ++i)
            gl16(BT + (size_t)(col0 + r_s[i]) * K + k0 + ks_s[i], (unsigned short*)Bs + ld_s[i]);
        __syncthreads();
        short8v av[4][2], bv[4][2];
        #pragma unroll
        for (int mr = 0; mr < 4; ++mr) {
            int row = wrow + mr * 16 + lr;
            av[mr][0] = *(const short8v*)&As[row * 64 + ((g) ^ (row & 7)) * 8];
            av[mr][1] = *(const short8v*)&As[row * 64 + ((4 + g) ^ (row & 7)) * 8];
        }
        #pragma unroll
        for (int nc = 0; nc < 4; ++nc) {
            int row = wcol + nc * 16 + lr;
            bv[nc][0] = *(const short8v*)&Bs[row * 64 + ((g) ^ (row & 7)) * 8];
            bv[nc][1] = *(const short8v*)&Bs[row * 64 + ((4 + g) ^ (row & 7)) * 8];
        }
        #pragma unroll
        for (int mr = 0; mr < 4; ++mr)
            #pragma unroll
            for (int nc = 0; nc < 4; ++nc) {
                acc[mr][nc] = __builtin_amdgcn_mfma_f32_16x16x32_bf16(
                    av[mr][0], bv[nc][0], acc[mr][nc], 0, 0, 0);
                acc[mr][nc] = __builtin_amdgcn_mfma_f32_16x16x32_bf16(
                    av[mr][1], bv[nc][1], acc[mr][nc], 0, 0, 0);
            }
        __syncthreads();
    }
    int rbase = g * 4;
    #pragma unroll
    for (int mr = 0; mr < 4; ++mr) {
        #pragma unroll
        for (int nc = 0; nc < 4; ++nc) {
            int gc = col0 + wcol + nc * 16 + lr;
            float bb = bias ? bias[gc] : 0.f;
            #pragma unroll
            for (int r = 0; r < 4; ++r) {
                int gr = row0 + wrow + mr * 16 + rbase + r;
                if (gr >= mrows) continue;
                float v = acc[mr][nc][r] + bb;
                if (ACT == 1) v = siluf(v);
                if (ACT == 2) v = geluf(v);
                if (OUT == 0) {
                    Cf[(size_t)gr * ldc + gc] = v;
                } else if (OUT == 1) {
                    if (gc < qscale_cols) v *= 0.125f;
                    Cb[(size_t)gr * ldc + gc] = f2bf(v);
                } else {
                    float gg = 1.f;
                    if (mod) gg = mod[(size_t)(gr / ntok) * modstride + gchunk * D + gc];
                    Cf[(size_t)gr * ldc + gc] += gg * v;
                }
            }
        }
    }
}

// ---------------- MoE gathered MFMA GEMM (BK=64) ----------------
template<int PHASE>
__global__ __launch_bounds__(256) void moe_lds(
    const unsigned short* __restrict__ A,
    const unsigned short* __restrict__ BTbase,
    float* __restrict__ Cf, unsigned short* __restrict__ Cb,
    const int* __restrict__ cnt, const int* __restrict__ list,
    const float* __restrict__ gval, int RT)
{
    const int K = (PHASE == 1) ? 768 : 3072;
    const int N = (PHASE == 1) ? 3072 : 768;
    int e = blockIdx.y / RT, rt = blockIdx.y % RT;
    int c0 = cnt[e];
    int mbase = rt * 128;
    if (mbase >= c0) return;
    int mcount = min(128, c0 - mbase);
    __shared__ int toks[128];
    int tid = threadIdx.x, w = tid >> 6, lane = tid & 63;
    if (tid < 128) toks[tid] = list[e * MAXTOK + mbase + min(tid, mcount - 1)];
    __syncthreads();

    __shared__ unsigned short As[128 * 64];
    __shared__ unsigned short Bs[128 * 64];
    const unsigned short* BT = BTbase + (size_t)e * 768 * 3072;
    int col0 = blockIdx.x * 128;
    int wrow = (w >> 1) * 64, wcol = (w & 1) * 64;
    int lr = lane & 15, g = lane >> 4;
    f32x4 acc[4][4] = {};

    int r_s[4], ks_s[4], ld_s[4], tok_s[4];
    #pragma unroll
    for (int i = 0; i < 4; ++i) {
        int off = tid * 16 + i * 4096;
        int row = off >> 7;
        int slot = (off >> 4) & 7;
        r_s[i] = row;
        ks_s[i] = (slot ^ (row & 7)) * 8;
        ld_s[i] = off >> 1;
        tok_s[i] = toks[row];
    }

    for (int k0 = 0; k0 < K; k0 += 64) {
        #pragma unroll
        for (int i = 0; i < 4; ++i)
            gl16(A + (size_t)tok_s[i] * K + k0 + ks_s[i], (unsigned short*)As + ld_s[i]);
        #pragma unroll
        for (int i = 0; i < 4; ++i)
            gl16(BT + (size_t)(col0 + r_s[i]) * K + k0 + ks_s[i], (unsigned short*)Bs + ld_s[i]);
        __syncthreads();
        short8v av[4][2], bv[4][2];
        #pragma unroll
        for (int mr = 0; mr < 4; ++mr) {
            int row = wrow + mr * 16 + lr;
            av[mr][0] = *(const short8v*)&As[row * 64 + ((g) ^ (row & 7)) * 8];
            av[mr][1] = *(const short8v*)&As[row * 64 + ((4 + g) ^ (row & 7)) * 8];
        }
        #pragma unroll
        for (int nc = 0; nc < 4; ++nc) {
            int row = wcol + nc * 16 + lr;
            bv[nc][0] = *(const short8v*)&Bs[row * 64 + ((g) ^ (row & 7)) * 8];
            bv[nc][1] = *(const short8v*)&Bs[row * 64 + ((4 + g) ^ (row & 7)) * 8];
        }
        #pragma unroll
        for (int mr = 0; mr < 4; ++mr)
            #pragma unroll
            for (int nc = 0; nc < 4; ++nc) {
                acc[mr][nc] = __builtin_amdgcn_mfma_f32_16x16x32_bf16(
                    av[mr][0], bv[nc][0], acc[mr][nc], 0, 0, 0);
                acc[mr][nc] = __builtin_amdgcn_mfma_f32_16x16x32_bf16(
                    av[mr][1], bv[nc][1], acc[mr][nc], 0, 0, 0);
            }
        __syncthreads();
    }
    int rbase = g * 4;
    #pragma unroll
    for (int mr = 0; mr < 4; ++mr) {
        #pragma unroll
        for (int r = 0; r < 4; ++r) {
            int m = wrow + mr * 16 + rbase + r;
            if (m >= mcount) continue;
            int tok = toks[m];
            #pragma unroll
            for (int nc = 0; nc < 4; ++nc) {
                int gc = col0 + wcol + nc * 16 + lr;
                float v = acc[mr][nc][r];
                if (PHASE == 1) Cb[(size_t)tok * 3072 + gc] = f2bf(geluf(v));
                else            Cf[(size_t)tok * 768 + gc] += gval[tok] * v;
            }
        }
    }
}

// ---------------- LayerNorm -> bf16 (+ optional adaLN modulate) ----------------
__global__ __launch_bounds__(256) void ln_kernel(
    const float* __restrict__ X, unsigned short* __restrict__ Y, int R, int ntok,
    const float* __restrict__ mod, int modstride, int shift_chunk, int scale_chunk)
{
    int r = blockIdx.x;
    if (r >= R) return;
    const float* xr = X + (size_t)r * D;
    int tid = threadIdx.x;
    int lane = tid & 63, wid = tid >> 6;
    float v0 = xr[tid], v1 = xr[tid + 256], v2 = xr[tid + 512];
    float s = v0 + v1 + v2;
    float s2 = v0 * v0 + v1 * v1 + v2 * v2;
    for (int off = 32; off > 0; off >>= 1) {
        s += __shfl_xor(s, off, 64);
        s2 += __shfl_xor(s2, off, 64);
    }
    __shared__ float shs[4], shs2[4];
    if (lane == 0) { shs[wid] = s; shs2[wid] = s2; }
    __syncthreads();
    float tot = shs[0] + shs[1] + shs[2] + shs[3];
    float tot2 = shs2[0] + shs2[1] + shs2[2] + shs2[3];
    float mu = tot * (1.f / 768.f);
    float var = tot2 * (1.f / 768.f) - mu * mu;
    float rs = rsqrtf(var + 1e-6f);
    int bb = r / ntok;
    float vv[3] = {v0, v1, v2};
    #pragma unroll
    for (int j = 0; j < 3; ++j) {
        int col = tid + j * 256;
        float nrm = (vv[j] - mu) * rs;
        float y = nrm;
        if (mod) {
            float scv = mod[(size_t)bb * modstride + scale_chunk * D + col];
            float shv = mod[(size_t)bb * modstride + shift_chunk * D + col];
            y = nrm * (1.f + scv) + shv;
        }
        Y[(size_t)r * D + col] = f2bf(y);
    }
}

// ---------------- V transpose ----------------
__global__ __launch_bounds__(256) void vt_kernel(
    const unsigned short* __restrict__ V, int ldv, int voff,
    unsigned short* __restrict__ VT, int Nkv, int nkvpad)
{
    __shared__ unsigned short Ls[64][72];
    int h = blockIdx.y, b = blockIdx.z, kv0 = blockIdx.x * 64;
    int tid = threadIdx.x;
    int srow = tid >> 2, sc = (tid & 3) * 16;
    int kv = kv0 + srow;
    if (kv < Nkv) {
        const unsigned short* vp = V + (size_t)(b * Nkv + kv) * ldv + voff + h * 64 + sc;
        #pragma unroll
        for (int j = 0; j < 16; ++j) Ls[srow][sc + j] = vp[j];
    } else {
        #pragma unroll
        for (int j = 0; j < 16; ++j) Ls[srow][sc + j] = 0;
    }
    __syncthreads();
    int d = tid >> 2, c0 = (tid & 3) * 16;
    unsigned short tmp[16];
    #pragma unroll
    for (int j = 0; j < 16; ++j) tmp[j] = Ls[c0 + j][d];
    unsigned short* op = VT + ((size_t)(b * NH + h) * 64 + d) * nkvpad + kv0 + c0;
    *(short8v*)op = *(short8v*)tmp;
    *(short8v*)(op + 8) = *(short8v*)(tmp + 8);
}

// ---------------- MFMA flash attention: 128 q-rows, 8 waves, 512 threads ----
__global__ __launch_bounds__(512) void attn_mfma(
    const unsigned short* __restrict__ Qp, int ldq, int qoff,
    const unsigned short* __restrict__ Kp, int ldk, int koff,
    const unsigned short* __restrict__ VT, int nkvpad,
    unsigned short* __restrict__ O, int ldo,
    int Nq, int Nkv)
{
    __shared__ unsigned short Qs[128 * 64];
    __shared__ unsigned short Ks[64 * 64];
    __shared__ unsigned short Vs[64 * 64];
    __shared__ unsigned short Ps[128 * 64];
    int h = blockIdx.y, b = blockIdx.z, q0 = blockIdx.x * 128;
    int tid = threadIdx.x, w = tid >> 6, lane = tid & 63;
    int wrow = w * 16;
    int lr = lane & 15, g = lane >> 4;

    {   // Q staging: 512 threads x (2x16B) = 128 rows x 64 elems
        int srow = tid >> 2, sc = (tid & 3) * 16;
        int gr = min(q0 + srow, Nq - 1);
        const unsigned short* qp = Qp + (size_t)(b * Nq + gr) * ldq + qoff + h * 64 + sc;
        short8v v0 = *(const short8v*)qp, v1 = *(const short8v*)(qp + 8);
        int s0 = sc >> 3;
        *(short8v*)&Qs[srow * 64 + (s0 ^ (srow & 7)) * 8] = v0;
        *(short8v*)&Qs[srow * 64 + ((s0 + 1) ^ (srow & 7)) * 8] = v1;
    }
    float m_r[4] = {-1e30f, -1e30f, -1e30f, -1e30f};
    float l_r[4] = {};
    f32x4 acc0 = {}, acc1 = {}, acc2 = {}, acc3 = {};
    const unsigned short* vtb = VT + (size_t)(b * NH + h) * 64 * nkvpad;

    for (int kv0 = 0; kv0 < Nkv; kv0 += 64) {
        {   // K staged by threads 0..255, V^T by 256..511
            int t2 = tid & 255;
            int srow = t2 >> 2, sc = (t2 & 3) * 16;
            int s0 = sc >> 3;
            if (tid < 256) {
                int gc = min(kv0 + srow, Nkv - 1);
                const unsigned short* kp = Kp + (size_t)(b * Nkv + gc) * ldk + koff + h * 64 + sc;
                short8v v0 = *(const short8v*)kp, v1 = *(const short8v*)(kp + 8);
                *(short8v*)&Ks[srow * 64 + (s0 ^ (srow & 7)) * 8] = v0;
                *(short8v*)&Ks[srow * 64 + ((s0 + 1) ^ (srow & 7)) * 8] = v1;
            } else {
                const unsigned short* vp = vtb + (size_t)srow * nkvpad + kv0 + sc;
                short8v u0 = *(const short8v*)vp, u1 = *(const short8v*)(vp + 8);
                *(short8v*)&Vs[srow * 64 + (s0 ^ (srow & 7)) * 8] = u0;
                *(short8v*)&Vs[srow * 64 + ((s0 + 1) ^ (srow & 7)) * 8] = u1;
            }
        }
        __syncthreads();
        short8v aq0, aq1;
        {
            int row = wrow + lr;
            aq0 = *(const short8v*)&Qs[row * 64 + ((0 + g) ^ (row & 7)) * 8];
            aq1 = *(const short8v*)&Qs[row * 64 + ((4 + g) ^ (row & 7)) * 8];
        }
        f32x4 sf[4];
        #pragma unroll
        for (int nc = 0; nc < 4; ++nc) {
            int row = nc * 16 + lr;
            short8v bk0 = *(const short8v*)&Ks[row * 64 + ((0 + g) ^ (row & 7)) * 8];
            short8v bk1 = *(const short8v*)&Ks[row * 64 + ((4 + g) ^ (row & 7)) * 8];
            f32x4 z = {};
            z = __builtin_amdgcn_mfma_f32_16x16x32_bf16(aq0, bk0, z, 0, 0, 0);
            sf[nc] = __builtin_amdgcn_mfma_f32_16x16x32_bf16(aq1, bk1, z, 0, 0, 0);
        }
        bool val0 = (kv0 + 0 * 16 + lr) < Nkv;
        bool val1 = (kv0 + 1 * 16 + lr) < Nkv;
        bool val2 = (kv0 + 2 * 16 + lr) < Nkv;
        bool val3 = (kv0 + 3 * 16 + lr) < Nkv;
        float fs[4];
        #pragma unroll
        for (int r = 0; r < 4; ++r) {
            float s0 = val0 ? sf[0][r] : -1e30f;
            float s1 = val1 ? sf[1][r] : -1e30f;
            float s2 = val2 ? sf[2][r] : -1e30f;
            float s3 = val3 ? sf[3][r] : -1e30f;
            float mx = fmaxf(fmaxf(s0, s1), fmaxf(s2, s3));
            mx = fmaxf(mx, __shfl_xor(mx, 1, 64));
            mx = fmaxf(mx, __shfl_xor(mx, 2, 64));
            mx = fmaxf(mx, __shfl_xor(mx, 4, 64));
            mx = fmaxf(mx, __shfl_xor(mx, 8, 64));
            float mn = fmaxf(m_r[r], mx);
            fs[r] = __expf(m_r[r] - mn);
            m_r[r] = mn;
            float p0 = __expf(s0 - mn), p1 = __expf(s1 - mn);
            float p2 = __expf(s2 - mn), p3 = __expf(s3 - mn);
            float rsum = p0 + p1 + p2 + p3;
            rsum += __shfl_xor(rsum, 1, 64);
            rsum += __shfl_xor(rsum, 2, 64);
            rsum += __shfl_xor(rsum, 4, 64);
            rsum += __shfl_xor(rsum, 8, 64);
            l_r[r] = l_r[r] * fs[r] + rsum;
            int ql = wrow + g * 4 + r;
            int base = ql * 64;
            int x7 = ql & 7;
            Ps[base + (((0 * 16 + lr) >> 3) ^ x7) * 8 + (lr & 7)] = f2bf(p0);
            Ps[base + (((1 * 16 + lr) >> 3) ^ x7) * 8 + (lr & 7)] = f2bf(p1);
            Ps[base + (((2 * 16 + lr) >> 3) ^ x7) * 8 + (lr & 7)] = f2bf(p2);
            Ps[base + (((3 * 16 + lr) >> 3) ^ x7) * 8 + (lr & 7)] = f2bf(p3);
            acc0[r] *= fs[r]; acc1[r] *= fs[r]; acc2[r] *= fs[r]; acc3[r] *= fs[r];
        }
        __syncthreads();   // P visible (wave-local but conservative), Vs stable
        short8v ap0, ap1;
        {
            int row = wrow + lr;
            ap0 = *(const short8v*)&Ps[row * 64 + ((0 + g) ^ (row & 7)) * 8];
            ap1 = *(const short8v*)&Ps[row * 64 + ((4 + g) ^ (row & 7)) * 8];
        }
        {
            int row = 0 * 16 + lr;
            short8v b0 = *(const short8v*)&Vs[row * 64 + ((0 + g) ^ (row & 7)) * 8];
            short8v b1 = *(const short8v*)&Vs[row * 64 + ((4 + g) ^ (row & 7)) * 8];
            acc0 = __builtin_amdgcn_mfma_f32_16x16x32_bf16(ap0, b0, acc0, 0, 0, 0);
            acc0 = __builtin_amdgcn_mfma_f32_16x16x32_bf16(ap1, b1, acc0, 0, 0, 0);
        }
        {
            int row = 1 * 16 + lr;
            short8v b0 = *(const short8v*)&Vs[row * 64 + ((0 + g) ^ (row & 7)) * 8];
            short8v b1 = *(const short8v*)&Vs[row * 64 + ((4 + g) ^ (row & 7)) * 8];
            acc1 = __builtin_amdgcn_mfma_f32_16x16x32_bf16(ap0, b0, acc1, 0, 0, 0);
            acc1 = __builtin_amdgcn_mfma_f32_16x16x32_bf16(ap1, b1, acc1, 0, 0, 0);
        }
        {
            int row = 2 * 16 + lr;
            short8v b0 = *(const short8v*)&Vs[row * 64 + ((0 + g) ^ (row & 7)) * 8];
            short8v b1 = *(const short8v*)&Vs[row * 64 + ((4 + g) ^ (row & 7)) * 8];
            acc2 = __builtin_amdgcn_mfma_f32_16x16x32_bf16(ap0, b0, acc2, 0, 0, 0);
            acc2 = __builtin_amdgcn_mfma_f32_16x16x32_bf16(ap1, b1, acc2, 0, 0, 0);
        }
        {
            int row = 3 * 16 + lr;
            short8v b0 = *(const short8v*)&Vs[row * 64 + ((0 + g) ^ (row & 7)) * 8];
            short8v b1 = *(const short8v*)&Vs[row * 64 + ((4 + g) ^ (row & 7)) * 8];
            acc3 = __builtin_amdgcn_mfma_f32_16x16x32_bf16(ap0, b0, acc3, 0, 0, 0);
            acc3 = __builtin_amdgcn_mfma_f32_16x16x32_bf16(ap1, b1, acc3, 0, 0, 0);
        }
        __syncthreads();   // all reads of Ks/Vs done before next staging
    }
    #pragma unroll
    for (int r = 0; r < 4; ++r) {
        int ql = wrow + g * 4 + r;
        if (q0 + ql >= Nq) continue;
        float rl = 1.f / l_r[r];
        unsigned short* op = O + (size_t)(b * Nq + q0 + ql) * ldo + h * 64 + lr;
        op[0]  = f2bf(acc0[r] * rl);
        op[16] = f2bf(acc1[r] * rl);
        op[32] = f2bf(acc2[r] * rl);
        op[48] = f2bf(acc3[r] * rl);
    }
}

// ---------------- MoE router ----------------
__global__ __launch_bounds__(64) void router_kernel(
    const unsigned short* __restrict__ X, const float* __restrict__ Wr,
    int* __restrict__ idx, float* __restrict__ gval)
{
    int tkn = blockIdx.x; int lane = threadIdx.x;
    const unsigned short* xr = X + (size_t)tkn * D;
    float p0 = 0, p1 = 0, p2 = 0, p3 = 0;
    for (int dd = lane; dd < D; dd += 64) {
        float xv = bf2f(xr[dd]);
        const float* wq = Wr + dd * 4;
        p0 += xv * wq[0]; p1 += xv * wq[1]; p2 += xv * wq[2]; p3 += xv * wq[3];
    }
    for (int off = 32; off > 0; off >>= 1) {
        p0 += __shfl_xor(p0, off, 64); p1 += __shfl_xor(p1, off, 64);
        p2 += __shfl_xor(p2, off, 64); p3 += __shfl_xor(p3, off, 64);
    }
    if (lane == 0) {
        float best = p0; int e = 0;
        if (p1 > best) { best = p1; e = 1; }
        if (p2 > best) { best = p2; e = 2; }
        if (p3 > best) { best = p3; e = 3; }
        float sum = expf(p0 - best) + expf(p1 - best) + expf(p2 - best) + expf(p3 - best);
        idx[tkn] = e;
        gval[tkn] = 1.f / sum;
    }
}

// single block: zero counters + scatter (replaces memset + multi-block scatter)
__global__ __launch_bounds__(256) void scatter_kernel(
    const int* __restrict__ idx, int* __restrict__ cnt,
    int* __restrict__ list, int ntok)
{
    __shared__ int lcnt[4];
    int tid = threadIdx.x;
    if (tid < 4) lcnt[tid] = 0;
    __syncthreads();
    for (int i = tid; i < ntok; i += 256) {
        int e = idx[i];
        int pos = atomicAdd(&lcnt[e], 1);
        list[e * MAXTOK + pos] = i;
    }
    __syncthreads();
    if (tid < 4) cnt[tid] = lcnt[tid];
}

// ---------------- concat ----------------
__global__ void concat_kernel(const float* __restrict__ traj, const float* __restrict__ a,
                              const float* __restrict__ bg, const float* __restrict__ cg,
                              float* __restrict__ x, int total)
{
    int i = blockIdx.x * blockDim.x + threadIdx.x;
    if (i >= total) return;
    int col = i % D;
    int r = i / D;
    int n = r % NTOK, b = r / NTOK;
    float v;
    if (n < 256)      v = traj[((size_t)b * 256 + n) * D + col];
    else if (n < 320) v = a[((size_t)b * 64 + (n - 256)) * D + col];
    else if (n < 352) v = bg[((size_t)b * 32 + (n - 320)) * D + col];
    else              v = cg[((size_t)b * 192 + (n - 352)) * D + col];
    x[i] = v;
}

// ---------------- output head ----------------
__global__ void head_prep(const float* __restrict__ W, unsigned short* __restrict__ WT14) {
    int i = blockIdx.x * blockDim.x + threadIdx.x;
    if (i >= 14 * 768) return;
    int o = i / 768, d = i % 768;
    WT14[i] = f2bf(W[d * 14 + o]);
}

__global__ __launch_bounds__(64) void head_kernel(
    const unsigned short* __restrict__ lnb, const unsigned short* __restrict__ WT14,
    const float* __restrict__ bias, float* __restrict__ out)
{
    int r = blockIdx.x;
    int b = r >> 8, n = r & 255;
    const unsigned short* hrow = lnb + (size_t)(b * NTOK + n) * D;
    int l = threadIdx.x;
    if (l >= 56) return;
    int o = l >> 2, p = l & 3;
    const unsigned short* hp = hrow + p * 192;
    const unsigned short* wp = WT14 + o * 768 + p * 192;
    float acc = 0.f;
    for (int i = 0; i < 192; i += 8) {
        short8v hv = *(const short8v*)(hp + i);
        short8v wv = *(const short8v*)(wp + i);
        #pragma unroll
        for (int j = 0; j < 8; ++j)
            acc += bf2f((unsigned short)hv[j]) * bf2f((unsigned short)wv[j]);
    }
    acc += __shfl_xor(acc, 1, 64);
    acc += __shfl_xor(acc, 2, 64);
    if (p == 0) out[(size_t)r * 14 + o] = acc + bias[o];
}

// ---------------- host helpers ----------------
static inline void tcvt(const float* W, unsigned short* WT, int K, int N, int z, hipStream_t s) {
    transpose_cvt<<<dim3(N / 64, K / 64, z), 256, 0, s>>>(W, WT, K, N);
}
static inline void g_bf(int act, const unsigned short* A, const unsigned short* BT,
                        const float* bias, unsigned short* C, int ldc,
                        int M, int N, int K, int qcols, hipStream_t s)
{
    dim3 g(N / 128, M / 128);
    if (act == 2) gemm_lds<2, 1><<<g, 256, 0, s>>>(A, BT, bias, nullptr, C, ldc, K, qcols, nullptr, 0, 0, 1, 1 << 30);
    else          gemm_lds<0, 1><<<g, 256, 0, s>>>(A, BT, bias, nullptr, C, ldc, K, qcols, nullptr, 0, 0, 1, 1 << 30);
}
static inline void g_res(const unsigned short* A, const unsigned short* BT,
                         const float* bias, float* C, int ldc, int M, int N, int K,
                         const float* mod, int modstride, int gchunk, int ntok, hipStream_t s)
{
    dim3 g(N / 128, M / 128);
    gemm_lds<0, 2><<<g, 256, 0, s>>>(A, BT, bias, C, nullptr, ldc, K, 0, mod, modstride, gchunk, ntok, 1 << 30);
}

extern "C" void kernel_launch(void* const* d_in, const int* in_sizes, int n_in,
                              void* d_out, int out_size, void* d_ws, size_t ws_size,
                              hipStream_t stream)
{
    const float* x_traj   = (const float*)d_in[0];
    const int*   t_arr    = (const int*)d_in[1];
    const float* tokA     = (const float*)d_in[2];
    const float* tokB     = (const float*)d_in[3];
    const float* tokC     = (const float*)d_in[4];
    const float* W_traj   = (const float*)d_in[5];
    const float* b_traj   = (const float*)d_in[6];
    const float* W_ftime  = (const float*)d_in[7];
    const float* Wt1      = (const float*)d_in[8];
    const float* bt1      = (const float*)d_in[9];
    const float* Wt2      = (const float*)d_in[10];
    const float* bt2      = (const float*)d_in[11];
    const float* moe_attn = (const float*)d_in[12];
    const float* moe_rout = (const float*)d_in[13];
    const float* moe_W1   = (const float*)d_in[14];
    const float* moe_W2   = (const float*)d_in[15];
    const float* dit_qkv  = (const float*)d_in[16];
    const float* dit_qkvb = (const float*)d_in[17];
    const float* dit_proj = (const float*)d_in[18];
    const float* dit_projb= (const float*)d_in[19];
    const float* dit_mlp1 = (const float*)d_in[20];
    const float* dit_mlp1b= (const float*)d_in[21];
    const float* dit_mlp2 = (const float*)d_in[22];
    const float* dit_mlp2b= (const float*)d_in[23];
    const float* dit_ada  = (const float*)d_in[24];
    const float* dit_adab = (const float*)d_in[25];
    const float* out_adaW = (const float*)d_in[26];
    const float* out_adab = (const float*)d_in[27];
    const float* out_W    = (const float*)d_in[28];
    const float* out_b    = (const float*)d_in[29];
    float* out = (float*)d_out;
    float* ws = (float*)d_ws;

    // base workspace layout (float offsets)
    const size_t o_cnt  = 14336;
    const size_t o_idx  = 14400;
    const size_t o_gval = 15936;
    const size_t o_list = 17472;
    const size_t o_traj = 66624;             // traj; later mod buffers
    const size_t o_a    = 1639488;
    const size_t o_bg   = 2032704;
    const size_t o_cg   = 2229312;
    const size_t o_x    = 3408960;
    const size_t o_lnb  = 6751296;
    const size_t o_qkvb = 8422464;
    const size_t o_attnO= 13435968;
    const size_t o_h    = 15107136;
    const size_t o_vt   = 21791808;
    const size_t o_kvbf = 23561280;
    const size_t o_wt   = 24151104;          // scratch for fallback tcvt
    const size_t o_wt14 = 28869696;          // 5376 floats
    const size_t o_tembP= 28875072;
    const size_t o_ub   = 28891456;
    const size_t o_scb  = 28940608;          // ends 28989760
    const size_t o_mod  = o_traj;
    const size_t o_mod2 = o_traj + 221184;

    // optional big-weight region (all weights pre-converted, batched)
    const size_t o_wqkv  = 29000000;  // 5,308,416
    const size_t o_wproj = 34308416;  // 1,769,472
    const size_t o_wmlp1 = 36077888;  // 7,077,888
    const size_t o_wmlp2 = 43155776;  // 7,077,888
    const size_t o_wada  = 50233664;  // 10,616,832
    const size_t o_wada2 = 60850496;  // 589,824
    const size_t o_wcross= 61440320;  // 4,718,592
    const size_t o_wmoe1 = 66158912;  // 28,311,552
    const size_t o_wmoe2 = 94470464;  // 28,311,552 -> ends 122,782,016 floats
    const bool bigw = ws_size >= (size_t)123000000 * 4;

    int* cnt_p  = (int*)(ws + o_cnt);
    int* idx_p  = (int*)(ws + o_idx);
    int* list_p = (int*)(ws + o_list);
    float* gval_p = ws + o_gval;
    unsigned short* lnb  = (unsigned short*)(ws + o_lnb);
    unsigned short* qkvb = (unsigned short*)(ws + o_qkvb);
    unsigned short* attO = (unsigned short*)(ws + o_attnO);
    unsigned short* hbuf = (unsigned short*)(ws + o_h);
    unsigned short* vtb  = (unsigned short*)(ws + o_vt);
    unsigned short* kvbf = (unsigned short*)(ws + o_kvbf);
    unsigned short* wt   = (unsigned short*)(ws + o_wt);
    unsigned short* wt14 = (unsigned short*)(ws + o_wt14);
    unsigned short* tembP= (unsigned short*)(ws + o_tembP);
    unsigned short* ub   = (unsigned short*)(ws + o_ub);
    unsigned short* scb  = (unsigned short*)(ws + o_scb);
    unsigned short* wqkvS = (unsigned short*)(ws + o_wqkv);
    unsigned short* wprojS= (unsigned short*)(ws + o_wproj);
    unsigned short* wmlp1S= (unsigned short*)(ws + o_wmlp1);
    unsigned short* wmlp2S= (unsigned short*)(ws + o_wmlp2);
    unsigned short* wadaS = (unsigned short*)(ws + o_wada);
    unsigned short* wada2S= (unsigned short*)(ws + o_wada2);
    unsigned short* wcrossS=(unsigned short*)(ws + o_wcross);
    unsigned short* wmoe1S= (unsigned short*)(ws + o_wmoe1);
    unsigned short* wmoe2S= (unsigned short*)(ws + o_wmoe2);
    unsigned short* c_q = qkvb;
    unsigned short* c_k = qkvb + 1179648;
    unsigned short* c_v = qkvb + 2359296;

    const size_t WSZ = (size_t)D * D;          // 589824 (shorts per 768x768)

    // ---- trajectory embedding ----
    gemm_act<0><<<dim3(12, 32), 256, 0, stream>>>(x_traj, 7, W_traj, D, b_traj,
                                                  ws + o_traj, D, BATCH * TTRAJ, D, 7);
    add_ftime<<<(BATCH * TTRAJ * D + 255) / 256, 256, 0, stream>>>(ws + o_traj, W_ftime, BATCH * TTRAJ * D);

    hipMemcpyAsync(ws + o_a, tokA, (size_t)BATCH * NA * D * 4, hipMemcpyDeviceToDevice, stream);
    hipMemcpyAsync(ws + o_bg, tokB, (size_t)BATCH * NB * D * 4, hipMemcpyDeviceToDevice, stream);
    hipMemcpyAsync(ws + o_cg, tokC, (size_t)BATCH * NC * D * 4, hipMemcpyDeviceToDevice, stream);
    head_prep<<<42, 256, 0, stream>>>(out_W, wt14);

    // ---- all weight conversions up front (batched) when workspace allows ----
    if (bigw) {
        tcvt(dit_qkv,  wqkvS,  D, 3 * D, DEPTH, stream);
        tcvt(dit_proj, wprojS, D, D, DEPTH, stream);
        tcvt(dit_mlp1, wmlp1S, D, FF, DEPTH, stream);
        tcvt(dit_mlp2, wmlp2S, FF, D, DEPTH, stream);
        tcvt(dit_ada,  wadaS,  D, 6 * D, DEPTH, stream);
        tcvt(out_adaW, wada2S, D, 2 * D, 1, stream);
        tcvt(moe_attn, wcrossS, D, D, NBLK * 2 * 4, stream);
        tcvt(moe_W1,   wmoe1S, D, FF, NBLK * 3 * NEXP, stream);
        tcvt(moe_W2,   wmoe2S, FF, D, NBLK * 3 * NEXP, stream);
    }

    // ---- conditioning chain on MFMA (M padded to 128) ----
    timestep_kernel<<<128, 256, 0, stream>>>(t_arr, tembP);
    tcvt(Wt1, wt, 256, D, 1, stream);
    gemm_lds<1, 1><<<dim3(6, 1), 256, 0, stream>>>(
        tembP, wt, bt1, nullptr, ub, D, 256, 0, nullptr, 0, 0, 1, 128);
    tcvt(Wt2, wt, D, D, 1, stream);
    gemm_lds<1, 1><<<dim3(6, 1), 256, 0, stream>>>(
        ub, wt, bt2, nullptr, scb, D, D, 0, nullptr, 0, 0, 1, 128);   // scb = silu(c)

    for (int i = 0; i < NBLK; ++i) {
        // cross 1: cg += cross(ln(cg), a)
        {
            const unsigned short* Wc;
            if (bigw) Wc = wcrossS + (size_t)(i * 2 + 0) * 4 * WSZ;
            else { tcvt(moe_attn + (size_t)(i * 2 + 0) * 4 * WSZ, wt, D, D, 4, stream); Wc = wt; }
            ln_kernel<<<BATCH * NC, 256, 0, stream>>>(ws + o_cg, lnb, BATCH * NC, 1, nullptr, 0, 0, 0);
            g_bf(0, lnb, Wc, nullptr, c_q, D, BATCH * NC, D, D, 768, stream);
            cvt_bf16<<<(BATCH * NA * D / 8 + 255) / 256, 256, 0, stream>>>(ws + o_a, kvbf, BATCH * NA * D / 8);
            g_bf(0, kvbf, Wc + 1 * WSZ, nullptr, c_k, D, BATCH * NA, D, D, 0, stream);
            g_bf(0, kvbf, Wc + 2 * WSZ, nullptr, c_v, D, BATCH * NA, D, D, 0, stream);
            vt_kernel<<<dim3(1, NH, BATCH), 256, 0, stream>>>(c_v, D, 0, vtb, NA, 64);
            attn_mfma<<<dim3((NC + 127) / 128, NH, BATCH), 512, 0, stream>>>(
                c_q, D, 0, c_k, D, 0, vtb, 64, attO, D, NC, NA);
            g_res(attO, Wc + 3 * WSZ, nullptr, ws + o_cg, D, BATCH * NC, D, D, nullptr, 0, 0, 1, stream);
        }
        // cross 2: bg += cross(ln(bg), cg)
        {
            const unsigned short* Wc;
            if (bigw) Wc = wcrossS + (size_t)(i * 2 + 1) * 4 * WSZ;
            else { tcvt(moe_attn + (size_t)(i * 2 + 1) * 4 * WSZ, wt, D, D, 4, stream); Wc = wt; }
            ln_kernel<<<BATCH * NB, 256, 0, stream>>>(ws + o_bg, lnb, BATCH * NB, 1, nullptr, 0, 0, 0);
            g_bf(0, lnb, Wc, nullptr, c_q, D, BATCH * NB, D, D, 768, stream);
            cvt_bf16<<<(BATCH * NC * D / 8 + 255) / 256, 256, 0, stream>>>(ws + o_cg, kvbf, BATCH * NC * D / 8);
            g_bf(0, kvbf, Wc + 1 * WSZ, nullptr, c_k, D, BATCH * NC, D, D, 0, stream);
            g_bf(0, kvbf, Wc + 2 * WSZ, nullptr, c_v, D, BATCH * NC, D, D, 0, stream);
            vt_kernel<<<dim3(3, NH, BATCH), 256, 0, stream>>>(c_v, D, 0, vtb, NC, 192);
            attn_mfma<<<dim3(1, NH, BATCH), 512, 0, stream>>>(
                c_q, D, 0, c_k, D, 0, vtb, 192, attO, D, NB, NC);
            g_res(attO, Wc + 3 * WSZ, nullptr, ws + o_bg, D, BATCH * NB, D, D, nullptr, 0, 0, 1, stream);
        }
        // MoE on a, bg, cg
        const int gn[3] = {BATCH * NA, BATCH * NB, BATCH * NC};
        float* gptr[3] = {ws + o_a, ws + o_bg, ws + o_cg};
        for (int g = 0; g < 3; ++g) {
            int ntok = gn[g];
            const float* Wr = moe_rout + (size_t)(i * 3 + g) * D * NEXP;
            ln_kernel<<<ntok, 256, 0, stream>>>(gptr[g], lnb, ntok, 1, nullptr, 0, 0, 0);
            router_kernel<<<ntok, 64, 0, stream>>>(lnb, Wr, idx_p, gval_p);
            scatter_kernel<<<1, 256, 0, stream>>>(idx_p, cnt_p, list_p, ntok);
            int RT = (ntok + 127) / 128;
            const unsigned short* W1b;
            const unsigned short* W2b;
            if (bigw) {
                W1b = wmoe1S + (size_t)(i * 3 + g) * NEXP * D * FF;
                W2b = wmoe2S + (size_t)(i * 3 + g) * NEXP * D * FF;
            } else {
                tcvt(moe_W1 + (size_t)(i * 3 + g) * NEXP * D * FF, wt, D, FF, NEXP, stream);
                W1b = wt;
            }
            moe_lds<1><<<dim3(FF / 128, NEXP * RT), 256, 0, stream>>>(
                lnb, W1b, nullptr, hbuf, cnt_p, list_p, gval_p, RT);
            if (!bigw) {
                tcvt(moe_W2 + (size_t)(i * 3 + g) * NEXP * FF * D, wt, FF, D, NEXP, stream);
                W2b = wt;
            }
            moe_lds<2><<<dim3(D / 128, NEXP * RT), 256, 0, stream>>>(
                hbuf, W2b, gptr[g], nullptr, cnt_p, list_p, gval_p, RT);
        }
    }

    // ---- concat into x (traj region dead afterwards) ----
    concat_kernel<<<(BATCH * NTOK * D + 255) / 256, 256, 0, stream>>>(
        ws + o_traj, ws + o_a, ws + o_bg, ws + o_cg, ws + o_x, BATCH * NTOK * D);

    // ---- adaLN modulations via MFMA (mrows=8 clip) ----
    for (int i = 0; i < DEPTH; ++i) {
        const unsigned short* Wa;
        if (bigw) Wa = wadaS + (size_t)i * D * 6 * D;
        else { tcvt(dit_ada + (size_t)i * D * 6 * D, wt, D, 6 * D, 1, stream); Wa = wt; }
        gemm_lds<0, 0><<<dim3(36, 1), 256, 0, stream>>>(
            scb, Wa, dit_adab + (size_t)i * 6 * D, ws + o_mod + (size_t)i * 8 * 6 * D,
            nullptr, 6 * D, D, 0, nullptr, 0, 0, 1, 8);
    }
    {
        const unsigned short* Wa2;
        if (bigw) Wa2 = wada2S;
        else { tcvt(out_adaW, wt, D, 2 * D, 1, stream); Wa2 = wt; }
        gemm_lds<0, 0><<<dim3(12, 1), 256, 0, stream>>>(
            scb, Wa2, out_adab, ws + o_mod2, nullptr, 2 * D, D, 0, nullptr, 0, 0, 1, 8);
    }

    const int R = BATCH * NTOK;   // 4352 = 34*128
    for (int i = 0; i < DEPTH; ++i) {
        const float* mod_l = ws + o_mod + (size_t)i * 8 * 6 * D;
        const unsigned short *Wq, *Wp, *Wm1, *Wm2;
        if (bigw) {
            Wq  = wqkvS  + (size_t)i * D * 3 * D;
            Wp  = wprojS + (size_t)i * D * D;
            Wm1 = wmlp1S + (size_t)i * D * FF;
            Wm2 = wmlp2S + (size_t)i * D * FF;
        }
        ln_kernel<<<R, 256, 0, stream>>>(ws + o_x, lnb, R, NTOK, mod_l, 6 * D, 0, 1);
        if (!bigw) { tcvt(dit_qkv + (size_t)i * D * 3 * D, wt, D, 3 * D, 1, stream); Wq = wt; }
        g_bf(0, lnb, Wq, dit_qkvb + (size_t)i * 3 * D, qkvb, 3 * D, R, 3 * D, D, 768, stream);
        vt_kernel<<<dim3(9, NH, BATCH), 256, 0, stream>>>(qkvb, 3 * D, 2 * D, vtb, NTOK, 576);
        attn_mfma<<<dim3((NTOK + 127) / 128, NH, BATCH), 512, 0, stream>>>(
            qkvb, 3 * D, 0, qkvb, 3 * D, D, vtb, 576, attO, D, NTOK, NTOK);
        if (!bigw) { tcvt(dit_proj + (size_t)i * D * D, wt, D, D, 1, stream); Wp = wt; }
        g_res(attO, Wp, dit_projb + (size_t)i * D, ws + o_x, D, R, D, D,
              mod_l, 6 * D, 2, NTOK, stream);
        ln_kernel<<<R, 256, 0, stream>>>(ws + o_x, lnb, R, NTOK, mod_l, 6 * D, 3, 4);
        if (!bigw) { tcvt(dit_mlp1 + (size_t)i * D * FF, wt, D, FF, 1, stream); Wm1 = wt; }
        g_bf(2, lnb, Wm1, dit_mlp1b + (size_t)i * FF, hbuf, FF, R, FF, D, 0, stream);
        if (!bigw) { tcvt(dit_mlp2 + (size_t)i * FF * D, wt, FF, D, 1, stream); Wm2 = wt; }
        g_res(hbuf, Wm2, dit_mlp2b + (size_t)i * D, ws + o_x, D, R, D, FF,
              mod_l, 6 * D, 5, NTOK, stream);
    }

    // ---- output head ----
    ln_kernel<<<R, 256, 0, stream>>>(ws + o_x, lnb, R, NTOK, ws + o_mod2, 2 * D, 0, 1);
    head_kernel<<<BATCH * TTRAJ, 64, 0, stream>>>(lnb, wt14, out_b, out);
}

// Round 9
// 2714.648 us; speedup vs baseline: 10.7530x; 1.2681x over previous
//
#include <hip/hip_runtime.h>
#include <hip/hip_bf16.h>
#include <math.h>

#define D 768
#define NH 12
#define HD 64
#define NEXP 4
#define FF 3072
#define NBLK 2
#define DEPTH 6
#define NA 64
#define NB 32
#define NC 192
#define BATCH 8
#define TTRAJ 256
#define NTOK 544
#define MAXTOK 1536
#define MOER 2304   // 512 + 256 + 1536 tokens per MoE pass (a|bg|cg contiguous)

typedef __attribute__((ext_vector_type(8))) short short8v;
typedef __attribute__((ext_vector_type(4))) float f32x4;

__device__ __forceinline__ float siluf(float v) { return v / (1.f + expf(-v)); }
__device__ __forceinline__ float geluf(float v) {
    float u = 0.7978845608028654f * (v + 0.044715f * v * v * v);
    return 0.5f * v * (1.f + tanhf(u));
}
__device__ __forceinline__ unsigned short f2bf(float f) {
    union { float f; unsigned u; } v; v.f = f;
    unsigned r = v.u + 0x7fffu + ((v.u >> 16) & 1u);
    return (unsigned short)(r >> 16);
}
__device__ __forceinline__ float bf2f(unsigned short u) {
    union { unsigned u; float f; } v; v.u = ((unsigned)u) << 16; return v.f;
}
__device__ __forceinline__ void gl16(const unsigned short* g, unsigned short* l) {
    __builtin_amdgcn_global_load_lds(
        (const __attribute__((address_space(1))) void*)g,
        (__attribute__((address_space(3))) void*)l, 16, 0, 0);
}

// ---------------- timestep embedding -> bf16 [128][256] (rows 8..127 zero) ----
__global__ void timestep_kernel(const int* __restrict__ t, unsigned short* __restrict__ tembP) {
    int i = blockIdx.x * blockDim.x + threadIdx.x;
    if (i >= 128 * 256) return;
    int b = i >> 8, j = i & 255;
    float v = 0.f;
    if (b < BATCH) {
        int jj = (j & 127);
        float freq = expf(-logf(10000.f) * (float)jj / 128.f);
        float ang = (float)t[b] * freq;
        v = (j < 128) ? cosf(ang) : sinf(ang);
    }
    tembP[i] = f2bf(v);
}

__global__ void add_ftime(float* __restrict__ traj, const float* __restrict__ wf, int total) {
    int i = blockIdx.x * blockDim.x + threadIdx.x;
    if (i >= total) return;
    int col = i % D;
    int n = (i / D) % TTRAJ;
    traj[i] += wf[(n & 7) * D + col];
}

__global__ void cvt_bf16(const float* __restrict__ in, unsigned short* __restrict__ out, int n8) {
    int i = blockIdx.x * blockDim.x + threadIdx.x;
    if (i >= n8) return;
    float4 a = *(const float4*)(in + i * 8);
    float4 b = *(const float4*)(in + i * 8 + 4);
    unsigned short t[8] = {f2bf(a.x), f2bf(a.y), f2bf(a.z), f2bf(a.w),
                           f2bf(b.x), f2bf(b.y), f2bf(b.z), f2bf(b.w)};
    *(short8v*)(out + i * 8) = *(short8v*)t;
}

// ---------------- small f32 GEMM (traj embed, K=7) ----------------
template<int ACT>
__global__ __launch_bounds__(256) void gemm_act(
    const float* __restrict__ A, int lda,
    const float* __restrict__ B, int ldb,
    const float* __restrict__ bias,
    float* __restrict__ C, int ldc,
    int M, int N, int K)
{
    __shared__ float As[16][65];
    __shared__ float Bs[16][65];
    int tid = threadIdx.x;
    int tx = tid & 15, ty = tid >> 4;
    int row0 = blockIdx.y * 64, col0 = blockIdx.x * 64;
    float acc[4][4] = {};
    for (int k0 = 0; k0 < K; k0 += 16) {
        #pragma unroll
        for (int i = 0; i < 4; ++i) {
            int e = tid + 256 * i; int m = e >> 4; int kk = e & 15;
            int gr = row0 + m, gk = k0 + kk;
            As[kk][m] = (gr < M && gk < K) ? A[(size_t)gr * lda + gk] : 0.f;
        }
        #pragma unroll
        for (int i = 0; i < 4; ++i) {
            int e = tid + 256 * i; int kk = e >> 6; int n = e & 63;
            int gk = k0 + kk, gc = col0 + n;
            Bs[kk][n] = (gk < K && gc < N) ? B[(size_t)gk * ldb + gc] : 0.f;
        }
        __syncthreads();
        #pragma unroll
        for (int kk = 0; kk < 16; ++kk) {
            float a[4], bv[4];
            #pragma unroll
            for (int i = 0; i < 4; ++i) a[i] = As[kk][ty * 4 + i];
            #pragma unroll
            for (int j = 0; j < 4; ++j) bv[j] = Bs[kk][tx * 4 + j];
            #pragma unroll
            for (int i = 0; i < 4; ++i)
                #pragma unroll
                for (int j = 0; j < 4; ++j) acc[i][j] += a[i] * bv[j];
        }
        __syncthreads();
    }
    #pragma unroll
    for (int i = 0; i < 4; ++i) {
        int gr = row0 + ty * 4 + i; if (gr >= M) continue;
        #pragma unroll
        for (int j = 0; j < 4; ++j) {
            int gc = col0 + tx * 4 + j; if (gc >= N) continue;
            float v = acc[i][j] + (bias ? bias[gc] : 0.f);
            if (ACT == 1) v = siluf(v);
            if (ACT == 2) v = geluf(v);
            C[(size_t)gr * ldc + gc] = v;
        }
    }
}

// ---------------- weight transpose + cvt: [K][N] f32 -> [N][K] bf16 ----------------
__global__ __launch_bounds__(256) void transpose_cvt(
    const float* __restrict__ in, unsigned short* __restrict__ out, int K, int N)
{
    __shared__ unsigned short Ls[64][72];
    const float* src = in + (size_t)blockIdx.z * K * N;
    unsigned short* dst = out + (size_t)blockIdx.z * K * N;
    int k0 = blockIdx.y * 64, n0 = blockIdx.x * 64;
    int tid = threadIdx.x;
    int r = tid >> 2, c0 = (tid & 3) * 16;
    {
        const float* sp = src + (size_t)(k0 + r) * N + n0 + c0;
        #pragma unroll
        for (int j = 0; j < 16; j += 4) {
            float4 f = *(const float4*)(sp + j);
            Ls[c0 + j + 0][r] = f2bf(f.x);
            Ls[c0 + j + 1][r] = f2bf(f.y);
            Ls[c0 + j + 2][r] = f2bf(f.z);
            Ls[c0 + j + 3][r] = f2bf(f.w);
        }
    }
    __syncthreads();
    {
        unsigned short tmp[16];
        #pragma unroll
        for (int j = 0; j < 16; ++j) tmp[j] = Ls[r][c0 + j];
        unsigned short* dp = dst + (size_t)(n0 + r) * K + k0 + c0;
        *(short8v*)dp = *(short8v*)tmp;
        *(short8v*)(dp + 8) = *(short8v*)(tmp + 8);
    }
}

// ---------------- MFMA GEMM: BK=32, double-buffered LDS, one barrier/K-step ----
// TN = 128 or 64 (block N-tile). Tile M=128. 4 waves.
// ACT: 0 none, 1 silu, 2 gelu. OUT: 0 f32, 1 bf16 (+qscale), 2 f32 gated residual.
template<int ACT, int OUT, int TN>
__global__ __launch_bounds__(256) void gemm_lds(
    const unsigned short* __restrict__ A,
    const unsigned short* __restrict__ BT,
    const float* __restrict__ bias,
    float* __restrict__ Cf, unsigned short* __restrict__ Cb, int ldc,
    int K, int qscale_cols,
    const float* __restrict__ mod, int modstride, int gchunk, int ntok, int mrows)
{
    constexpr int NCF = TN / 32;       // B frags per wave
    constexpr int NBS = TN / 64;       // B stage issues per thread
    __shared__ unsigned short As[2][128 * 32];
    __shared__ unsigned short Bs[2][TN * 32];
    int tid = threadIdx.x, w = tid >> 6, lane = tid & 63;
    int row0 = blockIdx.y * 128, col0 = blockIdx.x * TN;
    int wrow = (w >> 1) * 64, wcol = (w & 1) * (TN / 2);
    int lr = lane & 15, g = lane >> 4;
    f32x4 acc[4][NCF] = {};

    int ra[2], ka[2], la[2];
    #pragma unroll
    for (int i = 0; i < 2; ++i) {
        int off = tid * 16 + i * 4096;
        int row = off >> 6;
        int slot = (off >> 4) & 3;
        ra[i] = row;
        ka[i] = (slot ^ ((row >> 1) & 3)) * 8;
        la[i] = off >> 1;
    }
    int nt = K >> 5, cur = 0;
    // prologue: stage tile 0
    #pragma unroll
    for (int i = 0; i < 2; ++i)
        gl16(A + (size_t)(row0 + ra[i]) * K + ka[i], &As[0][la[i]]);
    #pragma unroll
    for (int i = 0; i < NBS; ++i)
        gl16(BT + (size_t)(col0 + ra[i]) * K + ka[i], &Bs[0][la[i]]);

    for (int t = 0; t < nt; ++t) {
        __syncthreads();                       // stage into buf[cur] landed
        if (t + 1 < nt) {                      // issue next tile BEFORE compute
            int k0 = (t + 1) << 5;
            #pragma unroll
            for (int i = 0; i < 2; ++i)
                gl16(A + (size_t)(row0 + ra[i]) * K + k0 + ka[i], &As[cur ^ 1][la[i]]);
            #pragma unroll
            for (int i = 0; i < NBS; ++i)
                gl16(BT + (size_t)(col0 + ra[i]) * K + k0 + ka[i], &Bs[cur ^ 1][la[i]]);
        }
        short8v av[4], bv[NCF];
        #pragma unroll
        for (int mr = 0; mr < 4; ++mr) {
            int row = wrow + mr * 16 + lr;
            av[mr] = *(const short8v*)&As[cur][row * 32 + (g ^ ((row >> 1) & 3)) * 8];
        }
        #pragma unroll
        for (int nc = 0; nc < NCF; ++nc) {
            int row = wcol + nc * 16 + lr;
            bv[nc] = *(const short8v*)&Bs[cur][row * 32 + (g ^ ((row >> 1) & 3)) * 8];
        }
        #pragma unroll
        for (int mr = 0; mr < 4; ++mr)
            #pragma unroll
            for (int nc = 0; nc < NCF; ++nc)
                acc[mr][nc] = __builtin_amdgcn_mfma_f32_16x16x32_bf16(
                    av[mr], bv[nc], acc[mr][nc], 0, 0, 0);
        cur ^= 1;
    }
    int rbase = g * 4;
    #pragma unroll
    for (int mr = 0; mr < 4; ++mr) {
        #pragma unroll
        for (int nc = 0; nc < NCF; ++nc) {
            int gc = col0 + wcol + nc * 16 + lr;
            float bb = bias ? bias[gc] : 0.f;
            #pragma unroll
            for (int r = 0; r < 4; ++r) {
                int gr = row0 + wrow + mr * 16 + rbase + r;
                if (gr >= mrows) continue;
                float v = acc[mr][nc][r] + bb;
                if (ACT == 1) v = siluf(v);
                if (ACT == 2) v = geluf(v);
                if (OUT == 0) {
                    Cf[(size_t)gr * ldc + gc] = v;
                } else if (OUT == 1) {
                    if (gc < qscale_cols) v *= 0.125f;
                    Cb[(size_t)gr * ldc + gc] = f2bf(v);
                } else {
                    float gg = 1.f;
                    if (mod) gg = mod[(size_t)(gr / ntok) * modstride + gchunk * D + gc];
                    Cf[(size_t)gr * ldc + gc] += gg * v;
                }
            }
        }
    }
}

// ---------------- MoE gathered MFMA GEMM (dbuf, all groups batched) ----------
template<int PHASE>
__global__ __launch_bounds__(256) void moe_lds(
    const unsigned short* __restrict__ A,
    const unsigned short* __restrict__ BTconv,
    float* __restrict__ Cf, unsigned short* __restrict__ Cb,
    const int* __restrict__ cnt, const int* __restrict__ list,
    const float* __restrict__ gval, int RT, int egbase)
{
    constexpr int K  = (PHASE == 1) ? 768 : 3072;
    constexpr int TN = (PHASE == 1) ? 128 : 64;
    constexpr int NCF = TN / 32;
    constexpr int NBS = TN / 64;
    int egl = blockIdx.y / RT, rt = blockIdx.y % RT;
    int eg = egbase + egl;
    int c0 = cnt[eg];
    int mbase = rt * 128;
    if (mbase >= c0) return;
    int mcount = min(128, c0 - mbase);
    __shared__ int toks[128];
    int tid = threadIdx.x, w = tid >> 6, lane = tid & 63;
    if (tid < 128) toks[tid] = list[eg * MAXTOK + mbase + min(tid, mcount - 1)];
    __syncthreads();

    __shared__ unsigned short As[2][128 * 32];
    __shared__ unsigned short Bs[2][TN * 32];
    const unsigned short* BT = BTconv + (size_t)egl * (768 * 3072);
    int col0 = blockIdx.x * TN;
    int wrow = (w >> 1) * 64, wcol = (w & 1) * (TN / 2);
    int lr = lane & 15, g = lane >> 4;
    f32x4 acc[4][NCF] = {};

    int ra[2], ka[2], la[2], tok_s[2];
    #pragma unroll
    for (int i = 0; i < 2; ++i) {
        int off = tid * 16 + i * 4096;
        int row = off >> 6;
        int slot = (off >> 4) & 3;
        ra[i] = row;
        ka[i] = (slot ^ ((row >> 1) & 3)) * 8;
        la[i] = off >> 1;
        tok_s[i] = toks[row];
    }
    int nt = K >> 5, cur = 0;
    #pragma unroll
    for (int i = 0; i < 2; ++i)
        gl16(A + (size_t)tok_s[i] * K + ka[i], &As[0][la[i]]);
    #pragma unroll
    for (int i = 0; i < NBS; ++i)
        gl16(BT + (size_t)(col0 + ra[i]) * K + ka[i], &Bs[0][la[i]]);

    for (int t = 0; t < nt; ++t) {
        __syncthreads();
        if (t + 1 < nt) {
            int k0 = (t + 1) << 5;
            #pragma unroll
            for (int i = 0; i < 2; ++i)
                gl16(A + (size_t)tok_s[i] * K + k0 + ka[i], &As[cur ^ 1][la[i]]);
            #pragma unroll
            for (int i = 0; i < NBS; ++i)
                gl16(BT + (size_t)(col0 + ra[i]) * K + k0 + ka[i], &Bs[cur ^ 1][la[i]]);
        }
        short8v av[4], bv[NCF];
        #pragma unroll
        for (int mr = 0; mr < 4; ++mr) {
            int row = wrow + mr * 16 + lr;
            av[mr] = *(const short8v*)&As[cur][row * 32 + (g ^ ((row >> 1) & 3)) * 8];
        }
        #pragma unroll
        for (int nc = 0; nc < NCF; ++nc) {
            int row = wcol + nc * 16 + lr;
            bv[nc] = *(const short8v*)&Bs[cur][row * 32 + (g ^ ((row >> 1) & 3)) * 8];
        }
        #pragma unroll
        for (int mr = 0; mr < 4; ++mr)
            #pragma unroll
            for (int nc = 0; nc < NCF; ++nc)
                acc[mr][nc] = __builtin_amdgcn_mfma_f32_16x16x32_bf16(
                    av[mr], bv[nc], acc[mr][nc], 0, 0, 0);
        cur ^= 1;
    }
    int rbase = g * 4;
    #pragma unroll
    for (int mr = 0; mr < 4; ++mr) {
        #pragma unroll
        for (int r = 0; r < 4; ++r) {
            int m = wrow + mr * 16 + rbase + r;
            if (m >= mcount) continue;
            int tok = toks[m];
            #pragma unroll
            for (int nc = 0; nc < NCF; ++nc) {
                int gc = col0 + wcol + nc * 16 + lr;
                float v = acc[mr][nc][r];
                if (PHASE == 1) Cb[(size_t)tok * 3072 + gc] = f2bf(geluf(v));
                else            Cf[(size_t)tok * 768 + gc] += gval[tok] * v;
            }
        }
    }
}

// ---------------- LayerNorm -> bf16 (+ optional adaLN modulate) ----------------
__global__ __launch_bounds__(256) void ln_kernel(
    const float* __restrict__ X, unsigned short* __restrict__ Y, int R, int ntok,
    const float* __restrict__ mod, int modstride, int shift_chunk, int scale_chunk)
{
    int r = blockIdx.x;
    if (r >= R) return;
    const float* xr = X + (size_t)r * D;
    int tid = threadIdx.x;
    int lane = tid & 63, wid = tid >> 6;
    float v0 = xr[tid], v1 = xr[tid + 256], v2 = xr[tid + 512];
    float s = v0 + v1 + v2;
    float s2 = v0 * v0 + v1 * v1 + v2 * v2;
    for (int off = 32; off > 0; off >>= 1) {
        s += __shfl_xor(s, off, 64);
        s2 += __shfl_xor(s2, off, 64);
    }
    __shared__ float shs[4], shs2[4];
    if (lane == 0) { shs[wid] = s; shs2[wid] = s2; }
    __syncthreads();
    float tot = shs[0] + shs[1] + shs[2] + shs[3];
    float tot2 = shs2[0] + shs2[1] + shs2[2] + shs2[3];
    float mu = tot * (1.f / 768.f);
    float var = tot2 * (1.f / 768.f) - mu * mu;
    float rs = rsqrtf(var + 1e-6f);
    int bb = r / ntok;
    float vv[3] = {v0, v1, v2};
    #pragma unroll
    for (int j = 0; j < 3; ++j) {
        int col = tid + j * 256;
        float nrm = (vv[j] - mu) * rs;
        float y = nrm;
        if (mod) {
            float scv = mod[(size_t)bb * modstride + scale_chunk * D + col];
            float shv = mod[(size_t)bb * modstride + shift_chunk * D + col];
            y = nrm * (1.f + scv) + shv;
        }
        Y[(size_t)r * D + col] = f2bf(y);
    }
}

// ---------------- V transpose ----------------
__global__ __launch_bounds__(256) void vt_kernel(
    const unsigned short* __restrict__ V, int ldv, int voff,
    unsigned short* __restrict__ VT, int Nkv, int nkvpad)
{
    __shared__ unsigned short Ls[64][72];
    int h = blockIdx.y, b = blockIdx.z, kv0 = blockIdx.x * 64;
    int tid = threadIdx.x;
    int srow = tid >> 2, sc = (tid & 3) * 16;
    int kv = kv0 + srow;
    if (kv < Nkv) {
        const unsigned short* vp = V + (size_t)(b * Nkv + kv) * ldv + voff + h * 64 + sc;
        #pragma unroll
        for (int j = 0; j < 16; ++j) Ls[srow][sc + j] = vp[j];
    } else {
        #pragma unroll
        for (int j = 0; j < 16; ++j) Ls[srow][sc + j] = 0;
    }
    __syncthreads();
    int d = tid >> 2, c0 = (tid & 3) * 16;
    unsigned short tmp[16];
    #pragma unroll
    for (int j = 0; j < 16; ++j) tmp[j] = Ls[c0 + j][d];
    unsigned short* op = VT + ((size_t)(b * NH + h) * 64 + d) * nkvpad + kv0 + c0;
    *(short8v*)op = *(short8v*)tmp;
    *(short8v*)(op + 8) = *(short8v*)(tmp + 8);
}

// ---------------- MFMA flash attention: 128 q-rows, 8 waves, 512 threads ----
__global__ __launch_bounds__(512) void attn_mfma(
    const unsigned short* __restrict__ Qp, int ldq, int qoff,
    const unsigned short* __restrict__ Kp, int ldk, int koff,
    const unsigned short* __restrict__ VT, int nkvpad,
    unsigned short* __restrict__ O, int ldo,
    int Nq, int Nkv)
{
    __shared__ unsigned short Qs[128 * 64];
    __shared__ unsigned short Ks[64 * 64];
    __shared__ unsigned short Vs[64 * 64];
    __shared__ unsigned short Ps[128 * 64];
    int h = blockIdx.y, b = blockIdx.z, q0 = blockIdx.x * 128;
    int tid = threadIdx.x, w = tid >> 6, lane = tid & 63;
    int wrow = w * 16;
    int lr = lane & 15, g = lane >> 4;

    {
        int srow = tid >> 2, sc = (tid & 3) * 16;
        int gr = min(q0 + srow, Nq - 1);
        const unsigned short* qp = Qp + (size_t)(b * Nq + gr) * ldq + qoff + h * 64 + sc;
        short8v v0 = *(const short8v*)qp, v1 = *(const short8v*)(qp + 8);
        int s0 = sc >> 3;
        *(short8v*)&Qs[srow * 64 + (s0 ^ (srow & 7)) * 8] = v0;
        *(short8v*)&Qs[srow * 64 + ((s0 + 1) ^ (srow & 7)) * 8] = v1;
    }
    float m_r[4] = {-1e30f, -1e30f, -1e30f, -1e30f};
    float l_r[4] = {};
    f32x4 acc0 = {}, acc1 = {}, acc2 = {}, acc3 = {};
    const unsigned short* vtb = VT + (size_t)(b * NH + h) * 64 * nkvpad;

    for (int kv0 = 0; kv0 < Nkv; kv0 += 64) {
        {
            int t2 = tid & 255;
            int srow = t2 >> 2, sc = (t2 & 3) * 16;
            int s0 = sc >> 3;
            if (tid < 256) {
                int gc = min(kv0 + srow, Nkv - 1);
                const unsigned short* kp = Kp + (size_t)(b * Nkv + gc) * ldk + koff + h * 64 + sc;
                short8v v0 = *(const short8v*)kp, v1 = *(const short8v*)(kp + 8);
                *(short8v*)&Ks[srow * 64 + (s0 ^ (srow & 7)) * 8] = v0;
                *(short8v*)&Ks[srow * 64 + ((s0 + 1) ^ (srow & 7)) * 8] = v1;
            } else {
                const unsigned short* vp = vtb + (size_t)srow * nkvpad + kv0 + sc;
                short8v u0 = *(const short8v*)vp, u1 = *(const short8v*)(vp + 8);
                *(short8v*)&Vs[srow * 64 + (s0 ^ (srow & 7)) * 8] = u0;
                *(short8v*)&Vs[srow * 64 + ((s0 + 1) ^ (srow & 7)) * 8] = u1;
            }
        }
        __syncthreads();
        short8v aq0, aq1;
        {
            int row = wrow + lr;
            aq0 = *(const short8v*)&Qs[row * 64 + ((0 + g) ^ (row & 7)) * 8];
            aq1 = *(const short8v*)&Qs[row * 64 + ((4 + g) ^ (row & 7)) * 8];
        }
        f32x4 sf[4];
        #pragma unroll
        for (int nc = 0; nc < 4; ++nc) {
            int row = nc * 16 + lr;
            short8v bk0 = *(const short8v*)&Ks[row * 64 + ((0 + g) ^ (row & 7)) * 8];
            short8v bk1 = *(const short8v*)&Ks[row * 64 + ((4 + g) ^ (row & 7)) * 8];
            f32x4 z = {};
            z = __builtin_amdgcn_mfma_f32_16x16x32_bf16(aq0, bk0, z, 0, 0, 0);
            sf[nc] = __builtin_amdgcn_mfma_f32_16x16x32_bf16(aq1, bk1, z, 0, 0, 0);
        }
        bool val0 = (kv0 + 0 * 16 + lr) < Nkv;
        bool val1 = (kv0 + 1 * 16 + lr) < Nkv;
        bool val2 = (kv0 + 2 * 16 + lr) < Nkv;
        bool val3 = (kv0 + 3 * 16 + lr) < Nkv;
        float fs[4];
        #pragma unroll
        for (int r = 0; r < 4; ++r) {
            float s0 = val0 ? sf[0][r] : -1e30f;
            float s1 = val1 ? sf[1][r] : -1e30f;
            float s2 = val2 ? sf[2][r] : -1e30f;
            float s3 = val3 ? sf[3][r] : -1e30f;
            float mx = fmaxf(fmaxf(s0, s1), fmaxf(s2, s3));
            mx = fmaxf(mx, __shfl_xor(mx, 1, 64));
            mx = fmaxf(mx, __shfl_xor(mx, 2, 64));
            mx = fmaxf(mx, __shfl_xor(mx, 4, 64));
            mx = fmaxf(mx, __shfl_xor(mx, 8, 64));
            float mn = fmaxf(m_r[r], mx);
            fs[r] = __expf(m_r[r] - mn);
            m_r[r] = mn;
            float p0 = __expf(s0 - mn), p1 = __expf(s1 - mn);
            float p2 = __expf(s2 - mn), p3 = __expf(s3 - mn);
            float rsum = p0 + p1 + p2 + p3;
            rsum += __shfl_xor(rsum, 1, 64);
            rsum += __shfl_xor(rsum, 2, 64);
            rsum += __shfl_xor(rsum, 4, 64);
            rsum += __shfl_xor(rsum, 8, 64);
            l_r[r] = l_r[r] * fs[r] + rsum;
            int ql = wrow + g * 4 + r;
            int base = ql * 64;
            int x7 = ql & 7;
            Ps[base + (((0 * 16 + lr) >> 3) ^ x7) * 8 + (lr & 7)] = f2bf(p0);
            Ps[base + (((1 * 16 + lr) >> 3) ^ x7) * 8 + (lr & 7)] = f2bf(p1);
            Ps[base + (((2 * 16 + lr) >> 3) ^ x7) * 8 + (lr & 7)] = f2bf(p2);
            Ps[base + (((3 * 16 + lr) >> 3) ^ x7) * 8 + (lr & 7)] = f2bf(p3);
            acc0[r] *= fs[r]; acc1[r] *= fs[r]; acc2[r] *= fs[r]; acc3[r] *= fs[r];
        }
        __syncthreads();
        short8v ap0, ap1;
        {
            int row = wrow + lr;
            ap0 = *(const short8v*)&Ps[row * 64 + ((0 + g) ^ (row & 7)) * 8];
            ap1 = *(const short8v*)&Ps[row * 64 + ((4 + g) ^ (row & 7)) * 8];
        }
        {
            int row = 0 * 16 + lr;
            short8v b0 = *(const short8v*)&Vs[row * 64 + ((0 + g) ^ (row & 7)) * 8];
            short8v b1 = *(const short8v*)&Vs[row * 64 + ((4 + g) ^ (row & 7)) * 8];
            acc0 = __builtin_amdgcn_mfma_f32_16x16x32_bf16(ap0, b0, acc0, 0, 0, 0);
            acc0 = __builtin_amdgcn_mfma_f32_16x16x32_bf16(ap1, b1, acc0, 0, 0, 0);
        }
        {
            int row = 1 * 16 + lr;
            short8v b0 = *(const short8v*)&Vs[row * 64 + ((0 + g) ^ (row & 7)) * 8];
            short8v b1 = *(const short8v*)&Vs[row * 64 + ((4 + g) ^ (row & 7)) * 8];
            acc1 = __builtin_amdgcn_mfma_f32_16x16x32_bf16(ap0, b0, acc1, 0, 0, 0);
            acc1 = __builtin_amdgcn_mfma_f32_16x16x32_bf16(ap1, b1, acc1, 0, 0, 0);
        }
        {
            int row = 2 * 16 + lr;
            short8v b0 = *(const short8v*)&Vs[row * 64 + ((0 + g) ^ (row & 7)) * 8];
            short8v b1 = *(const short8v*)&Vs[row * 64 + ((4 + g) ^ (row & 7)) * 8];
            acc2 = __builtin_amdgcn_mfma_f32_16x16x32_bf16(ap0, b0, acc2, 0, 0, 0);
            acc2 = __builtin_amdgcn_mfma_f32_16x16x32_bf16(ap1, b1, acc2, 0, 0, 0);
        }
        {
            int row = 3 * 16 + lr;
            short8v b0 = *(const short8v*)&Vs[row * 64 + ((0 + g) ^ (row & 7)) * 8];
            short8v b1 = *(const short8v*)&Vs[row * 64 + ((4 + g) ^ (row & 7)) * 8];
            acc3 = __builtin_amdgcn_mfma_f32_16x16x32_bf16(ap0, b0, acc3, 0, 0, 0);
            acc3 = __builtin_amdgcn_mfma_f32_16x16x32_bf16(ap1, b1, acc3, 0, 0, 0);
        }
        __syncthreads();
    }
    #pragma unroll
    for (int r = 0; r < 4; ++r) {
        int ql = wrow + g * 4 + r;
        if (q0 + ql >= Nq) continue;
        float rl = 1.f / l_r[r];
        unsigned short* op = O + (size_t)(b * Nq + q0 + ql) * ldo + h * 64 + lr;
        op[0]  = f2bf(acc0[r] * rl);
        op[16] = f2bf(acc1[r] * rl);
        op[32] = f2bf(acc2[r] * rl);
        op[48] = f2bf(acc3[r] * rl);
    }
}

// ---------------- MoE router (group-aware, all 2304 tokens) ----------------
__global__ __launch_bounds__(64) void router_kernel(
    const unsigned short* __restrict__ X, const float* __restrict__ WrBase,
    int* __restrict__ idx, float* __restrict__ gval)
{
    int tkn = blockIdx.x; int lane = threadIdx.x;
    int grp = (tkn >= 768) ? 2 : (tkn >= 512 ? 1 : 0);
    const float* Wr = WrBase + (size_t)grp * D * NEXP;
    const unsigned short* xr = X + (size_t)tkn * D;
    float p0 = 0, p1 = 0, p2 = 0, p3 = 0;
    for (int dd = lane; dd < D; dd += 64) {
        float xv = bf2f(xr[dd]);
        const float* wq = Wr + dd * 4;
        p0 += xv * wq[0]; p1 += xv * wq[1]; p2 += xv * wq[2]; p3 += xv * wq[3];
    }
    for (int off = 32; off > 0; off >>= 1) {
        p0 += __shfl_xor(p0, off, 64); p1 += __shfl_xor(p1, off, 64);
        p2 += __shfl_xor(p2, off, 64); p3 += __shfl_xor(p3, off, 64);
    }
    if (lane == 0) {
        float best = p0; int e = 0;
        if (p1 > best) { best = p1; e = 1; }
        if (p2 > best) { best = p2; e = 2; }
        if (p3 > best) { best = p3; e = 3; }
        float sum = expf(p0 - best) + expf(p1 - best) + expf(p2 - best) + expf(p3 - best);
        idx[tkn] = grp * 4 + e;
        gval[tkn] = 1.f / sum;
    }
}

// single block: zero 12 counters + scatter to 12 lists
__global__ __launch_bounds__(256) void scatter_kernel(
    const int* __restrict__ idx, int* __restrict__ cnt,
    int* __restrict__ list, int ntok)
{
    __shared__ int lcnt[12];
    int tid = threadIdx.x;
    if (tid < 12) lcnt[tid] = 0;
    __syncthreads();
    for (int i = tid; i < ntok; i += 256) {
        int e = idx[i];
        int pos = atomicAdd(&lcnt[e], 1);
        list[e * MAXTOK + pos] = i;
    }
    __syncthreads();
    if (tid < 12) cnt[tid] = lcnt[tid];
}

// ---------------- concat ----------------
__global__ void concat_kernel(const float* __restrict__ traj, const float* __restrict__ a,
                              const float* __restrict__ bg, const float* __restrict__ cg,
                              float* __restrict__ x, int total)
{
    int i = blockIdx.x * blockDim.x + threadIdx.x;
    if (i >= total) return;
    int col = i % D;
    int r = i / D;
    int n = r % NTOK, b = r / NTOK;
    float v;
    if (n < 256)      v = traj[((size_t)b * 256 + n) * D + col];
    else if (n < 320) v = a[((size_t)b * 64 + (n - 256)) * D + col];
    else if (n < 352) v = bg[((size_t)b * 32 + (n - 320)) * D + col];
    else              v = cg[((size_t)b * 192 + (n - 352)) * D + col];
    x[i] = v;
}

// ---------------- output head ----------------
__global__ void head_prep(const float* __restrict__ W, unsigned short* __restrict__ WT14) {
    int i = blockIdx.x * blockDim.x + threadIdx.x;
    if (i >= 14 * 768) return;
    int o = i / 768, d = i % 768;
    WT14[i] = f2bf(W[d * 14 + o]);
}

__global__ __launch_bounds__(64) void head_kernel(
    const unsigned short* __restrict__ lnb, const unsigned short* __restrict__ WT14,
    const float* __restrict__ bias, float* __restrict__ out)
{
    int r = blockIdx.x;
    int b = r >> 8, n = r & 255;
    const unsigned short* hrow = lnb + (size_t)(b * NTOK + n) * D;
    int l = threadIdx.x;
    if (l >= 56) return;
    int o = l >> 2, p = l & 3;
    const unsigned short* hp = hrow + p * 192;
    const unsigned short* wp = WT14 + o * 768 + p * 192;
    float acc = 0.f;
    for (int i = 0; i < 192; i += 8) {
        short8v hv = *(const short8v*)(hp + i);
        short8v wv = *(const short8v*)(wp + i);
        #pragma unroll
        for (int j = 0; j < 8; ++j)
            acc += bf2f((unsigned short)hv[j]) * bf2f((unsigned short)wv[j]);
    }
    acc += __shfl_xor(acc, 1, 64);
    acc += __shfl_xor(acc, 2, 64);
    if (p == 0) out[(size_t)r * 14 + o] = acc + bias[o];
}

// ---------------- host helpers ----------------
static inline void tcvt(const float* W, unsigned short* WT, int K, int N, int z, hipStream_t s) {
    transpose_cvt<<<dim3(N / 64, K / 64, z), 256, 0, s>>>(W, WT, K, N);
}
static inline void g_bf(int act, const unsigned short* A, const unsigned short* BT,
                        const float* bias, unsigned short* C, int ldc,
                        int M, int N, int K, int qcols, hipStream_t s)
{
    if (N != 768) {
        dim3 g(N / 128, M / 128);
        if (act == 2) gemm_lds<2, 1, 128><<<g, 256, 0, s>>>(A, BT, bias, nullptr, C, ldc, K, qcols, nullptr, 0, 0, 1, 1 << 30);
        else          gemm_lds<0, 1, 128><<<g, 256, 0, s>>>(A, BT, bias, nullptr, C, ldc, K, qcols, nullptr, 0, 0, 1, 1 << 30);
    } else {
        dim3 g(N / 64, M / 128);
        if (act == 2) gemm_lds<2, 1, 64><<<g, 256, 0, s>>>(A, BT, bias, nullptr, C, ldc, K, qcols, nullptr, 0, 0, 1, 1 << 30);
        else          gemm_lds<0, 1, 64><<<g, 256, 0, s>>>(A, BT, bias, nullptr, C, ldc, K, qcols, nullptr, 0, 0, 1, 1 << 30);
    }
}
static inline void g_res(const unsigned short* A, const unsigned short* BT,
                         const float* bias, float* C, int ldc, int M, int N, int K,
                         const float* mod, int modstride, int gchunk, int ntok, hipStream_t s)
{
    dim3 g(N / 64, M / 128);
    gemm_lds<0, 2, 64><<<g, 256, 0, s>>>(A, BT, bias, C, nullptr, ldc, K, 0, mod, modstride, gchunk, ntok, 1 << 30);
}

extern "C" void kernel_launch(void* const* d_in, const int* in_sizes, int n_in,
                              void* d_out, int out_size, void* d_ws, size_t ws_size,
                              hipStream_t stream)
{
    const float* x_traj   = (const float*)d_in[0];
    const int*   t_arr    = (const int*)d_in[1];
    const float* tokA     = (const float*)d_in[2];
    const float* tokB     = (const float*)d_in[3];
    const float* tokC     = (const float*)d_in[4];
    const float* W_traj   = (const float*)d_in[5];
    const float* b_traj   = (const float*)d_in[6];
    const float* W_ftime  = (const float*)d_in[7];
    const float* Wt1      = (const float*)d_in[8];
    const float* bt1      = (const float*)d_in[9];
    const float* Wt2      = (const float*)d_in[10];
    const float* bt2      = (const float*)d_in[11];
    const float* moe_attn = (const float*)d_in[12];
    const float* moe_rout = (const float*)d_in[13];
    const float* moe_W1   = (const float*)d_in[14];
    const float* moe_W2   = (const float*)d_in[15];
    const float* dit_qkv  = (const float*)d_in[16];
    const float* dit_qkvb = (const float*)d_in[17];
    const float* dit_proj = (const float*)d_in[18];
    const float* dit_projb= (const float*)d_in[19];
    const float* dit_mlp1 = (const float*)d_in[20];
    const float* dit_mlp1b= (const float*)d_in[21];
    const float* dit_mlp2 = (const float*)d_in[22];
    const float* dit_mlp2b= (const float*)d_in[23];
    const float* dit_ada  = (const float*)d_in[24];
    const float* dit_adab = (const float*)d_in[25];
    const float* out_adaW = (const float*)d_in[26];
    const float* out_adab = (const float*)d_in[27];
    const float* out_W    = (const float*)d_in[28];
    const float* out_b    = (const float*)d_in[29];
    float* out = (float*)d_out;
    float* ws = (float*)d_ws;

    // base workspace layout (float offsets)
    const size_t o_cnt  = 14336;             // 12 ints
    const size_t o_idx  = 14400;             // 2304 ints
    const size_t o_gval = 16704;             // 2304 floats
    const size_t o_list = 19008;             // 12*1536 = 18432 ints (ends 37440)
    const size_t o_traj = 66624;             // traj; later mod buffers
    const size_t o_a    = 1639488;           // a|bg|cg contiguous = 2304 rows
    const size_t o_bg   = 2032704;
    const size_t o_cg   = 2229312;
    const size_t o_x    = 3408960;
    const size_t o_lnb  = 6751296;
    const size_t o_qkvb = 8422464;
    const size_t o_attnO= 13435968;
    const size_t o_h    = 15107136;
    const size_t o_vt   = 21791808;
    const size_t o_kvbf = 23561280;
    const size_t o_wt   = 24151104;          // fallback tcvt scratch (4.7M floats)
    const size_t o_wt14 = 28869696;          // 5376 floats
    const size_t o_tembP= 28875072;
    const size_t o_ub   = 28891456;
    const size_t o_scb  = 28940608;          // ends 28989760
    const size_t o_mod  = o_traj;
    const size_t o_mod2 = o_traj + 221184;

    // big-weight region (all weights pre-converted, batched)
    const size_t o_wqkv  = 29000000;
    const size_t o_wproj = 34308416;
    const size_t o_wmlp1 = 36077888;
    const size_t o_wmlp2 = 43155776;
    const size_t o_wada  = 50233664;
    const size_t o_wada2 = 60850496;
    const size_t o_wcross= 61440320;
    const size_t o_wmoe1 = 66158912;
    const size_t o_wmoe2 = 94470464;         // ends 122,782,016 floats
    const bool bigw = ws_size >= (size_t)123000000 * 4;

    int* cnt_p  = (int*)(ws + o_cnt);
    int* idx_p  = (int*)(ws + o_idx);
    int* list_p = (int*)(ws + o_list);
    float* gval_p = ws + o_gval;
    unsigned short* lnb  = (unsigned short*)(ws + o_lnb);
    unsigned short* qkvb = (unsigned short*)(ws + o_qkvb);
    unsigned short* attO = (unsigned short*)(ws + o_attnO);
    unsigned short* hbuf = (unsigned short*)(ws + o_h);
    unsigned short* vtb  = (unsigned short*)(ws + o_vt);
    unsigned short* kvbf = (unsigned short*)(ws + o_kvbf);
    unsigned short* wt   = (unsigned short*)(ws + o_wt);
    unsigned short* wt14 = (unsigned short*)(ws + o_wt14);
    unsigned short* tembP= (unsigned short*)(ws + o_tembP);
    unsigned short* ub   = (unsigned short*)(ws + o_ub);
    unsigned short* scb  = (unsigned short*)(ws + o_scb);
    unsigned short* wqkvS = (unsigned short*)(ws + o_wqkv);
    unsigned short* wprojS= (unsigned short*)(ws + o_wproj);
    unsigned short* wmlp1S= (unsigned short*)(ws + o_wmlp1);
    unsigned short* wmlp2S= (unsigned short*)(ws + o_wmlp2);
    unsigned short* wadaS = (unsigned short*)(ws + o_wada);
    unsigned short* wada2S= (unsigned short*)(ws + o_wada2);
    unsigned short* wcrossS=(unsigned short*)(ws + o_wcross);
    unsigned short* wmoe1S= (unsigned short*)(ws + o_wmoe1);
    unsigned short* wmoe2S= (unsigned short*)(ws + o_wmoe2);
    unsigned short* c_q  = qkvb;                    // [Rq][768]
    unsigned short* c_kv = qkvb + 1179648;          // [Rkv][1536]  (K | V)

    const size_t WSZ = (size_t)D * D;

    // ---- trajectory embedding ----
    gemm_act<0><<<dim3(12, 32), 256, 0, stream>>>(x_traj, 7, W_traj, D, b_traj,
                                                  ws + o_traj, D, BATCH * TTRAJ, D, 7);
    add_ftime<<<(BATCH * TTRAJ * D + 255) / 256, 256, 0, stream>>>(ws + o_traj, W_ftime, BATCH * TTRAJ * D);

    hipError_t e1 = hipMemcpyAsync(ws + o_a, tokA, (size_t)BATCH * NA * D * 4, hipMemcpyDeviceToDevice, stream); (void)e1;
    hipError_t e2 = hipMemcpyAsync(ws + o_bg, tokB, (size_t)BATCH * NB * D * 4, hipMemcpyDeviceToDevice, stream); (void)e2;
    hipError_t e3 = hipMemcpyAsync(ws + o_cg, tokC, (size_t)BATCH * NC * D * 4, hipMemcpyDeviceToDevice, stream); (void)e3;
    head_prep<<<42, 256, 0, stream>>>(out_W, wt14);

    // ---- all weight conversions up front (batched) ----
    if (bigw) {
        tcvt(dit_qkv,  wqkvS,  D, 3 * D, DEPTH, stream);
        tcvt(dit_proj, wprojS, D, D, DEPTH, stream);
        tcvt(dit_mlp1, wmlp1S, D, FF, DEPTH, stream);
        tcvt(dit_mlp2, wmlp2S, FF, D, DEPTH, stream);
        tcvt(dit_ada,  wadaS,  D, 6 * D, DEPTH, stream);
        tcvt(out_adaW, wada2S, D, 2 * D, 1, stream);
        tcvt(moe_attn, wcrossS, D, D, NBLK * 2 * 4, stream);
        tcvt(moe_W1,   wmoe1S, D, FF, NBLK * 3 * NEXP, stream);
        tcvt(moe_W2,   wmoe2S, FF, D, NBLK * 3 * NEXP, stream);
    }

    // ---- conditioning chain on MFMA (M padded to 128) ----
    timestep_kernel<<<128, 256, 0, stream>>>(t_arr, tembP);
    tcvt(Wt1, wt, 256, D, 1, stream);
    gemm_lds<1, 1, 64><<<dim3(12, 1), 256, 0, stream>>>(
        tembP, wt, bt1, nullptr, ub, D, 256, 0, nullptr, 0, 0, 1, 128);
    tcvt(Wt2, wt, D, D, 1, stream);
    gemm_lds<1, 1, 64><<<dim3(12, 1), 256, 0, stream>>>(
        ub, wt, bt2, nullptr, scb, D, D, 0, nullptr, 0, 0, 1, 128);   // scb = silu(c)

    for (int i = 0; i < NBLK; ++i) {
        // cross 1: cg += cross(ln(cg), a)
        {
            const unsigned short* Wc;
            if (bigw) Wc = wcrossS + (size_t)(i * 2 + 0) * 4 * WSZ;
            else { tcvt(moe_attn + (size_t)(i * 2 + 0) * 4 * WSZ, wt, D, D, 4, stream); Wc = wt; }
            ln_kernel<<<BATCH * NC, 256, 0, stream>>>(ws + o_cg, lnb, BATCH * NC, 1, nullptr, 0, 0, 0);
            g_bf(0, lnb, Wc, nullptr, c_q, D, BATCH * NC, D, D, 768, stream);
            cvt_bf16<<<(BATCH * NA * D / 8 + 255) / 256, 256, 0, stream>>>(ws + o_a, kvbf, BATCH * NA * D / 8);
            g_bf(0, kvbf, Wc + 1 * WSZ, nullptr, c_kv, 2 * D, BATCH * NA, 2 * D, D, 0, stream);
            vt_kernel<<<dim3(1, NH, BATCH), 256, 0, stream>>>(c_kv, 2 * D, D, vtb, NA, 64);
            attn_mfma<<<dim3((NC + 127) / 128, NH, BATCH), 512, 0, stream>>>(
                c_q, D, 0, c_kv, 2 * D, 0, vtb, 64, attO, D, NC, NA);
            g_res(attO, Wc + 3 * WSZ, nullptr, ws + o_cg, D, BATCH * NC, D, D, nullptr, 0, 0, 1, stream);
        }
        // cross 2: bg += cross(ln(bg), cg)
        {
            const unsigned short* Wc;
            if (bigw) Wc = wcrossS + (size_t)(i * 2 + 1) * 4 * WSZ;
            else { tcvt(moe_attn + (size_t)(i * 2 + 1) * 4 * WSZ, wt, D, D, 4, stream); Wc = wt; }
            ln_kernel<<<BATCH * NB, 256, 0, stream>>>(ws + o_bg, lnb, BATCH * NB, 1, nullptr, 0, 0, 0);
            g_bf(0, lnb, Wc, nullptr, c_q, D, BATCH * NB, D, D, 768, stream);
            cvt_bf16<<<(BATCH * NC * D / 8 + 255) / 256, 256, 0, stream>>>(ws + o_cg, kvbf, BATCH * NC * D / 8);
            g_bf(0, kvbf, Wc + 1 * WSZ, nullptr, c_kv, 2 * D, BATCH * NC, 2 * D, D, 0, stream);
            vt_kernel<<<dim3(3, NH, BATCH), 256, 0, stream>>>(c_kv, 2 * D, D, vtb, NC, 192);
            attn_mfma<<<dim3(1, NH, BATCH), 512, 0, stream>>>(
                c_q, D, 0, c_kv, 2 * D, 0, vtb, 192, attO, D, NB, NC);
            g_res(attO, Wc + 3 * WSZ, nullptr, ws + o_bg, D, BATCH * NB, D, D, nullptr, 0, 0, 1, stream);
        }
        // ---- MoE: all 3 groups batched (a|bg|cg contiguous = 2304 rows) ----
        ln_kernel<<<MOER, 256, 0, stream>>>(ws + o_a, lnb, MOER, 1, nullptr, 0, 0, 0);
        router_kernel<<<MOER, 64, 0, stream>>>(lnb, moe_rout + (size_t)(i * 3) * D * NEXP, idx_p, gval_p);
        scatter_kernel<<<1, 256, 0, stream>>>(idx_p, cnt_p, list_p, MOER);
        const int RT = 12;
        if (bigw) {
            moe_lds<1><<<dim3(24, 12 * RT), 256, 0, stream>>>(
                lnb, wmoe1S + (size_t)(i * 3) * NEXP * D * FF, nullptr, hbuf,
                cnt_p, list_p, gval_p, RT, 0);
            moe_lds<2><<<dim3(12, 12 * RT), 256, 0, stream>>>(
                hbuf, wmoe2S + (size_t)(i * 3) * NEXP * D * FF, ws + o_a, nullptr,
                cnt_p, list_p, gval_p, RT, 0);
        } else {
            for (int g = 0; g < 3; ++g) {
                tcvt(moe_W1 + (size_t)(i * 3 + g) * NEXP * D * FF, wt, D, FF, NEXP, stream);
                moe_lds<1><<<dim3(24, 4 * RT), 256, 0, stream>>>(
                    lnb, wt, nullptr, hbuf, cnt_p, list_p, gval_p, RT, g * 4);
                tcvt(moe_W2 + (size_t)(i * 3 + g) * NEXP * FF * D, wt, FF, D, NEXP, stream);
                moe_lds<2><<<dim3(12, 4 * RT), 256, 0, stream>>>(
                    hbuf, wt, ws + o_a, nullptr, cnt_p, list_p, gval_p, RT, g * 4);
            }
        }
    }

    // ---- concat into x (traj region dead afterwards) ----
    concat_kernel<<<(BATCH * NTOK * D + 255) / 256, 256, 0, stream>>>(
        ws + o_traj, ws + o_a, ws + o_bg, ws + o_cg, ws + o_x, BATCH * NTOK * D);

    // ---- adaLN modulations via MFMA (mrows=8 clip) ----
    for (int i = 0; i < DEPTH; ++i) {
        const unsigned short* Wa;
        if (bigw) Wa = wadaS + (size_t)i * D * 6 * D;
        else { tcvt(dit_ada + (size_t)i * D * 6 * D, wt, D, 6 * D, 1, stream); Wa = wt; }
        gemm_lds<0, 0, 128><<<dim3(36, 1), 256, 0, stream>>>(
            scb, Wa, dit_adab + (size_t)i * 6 * D, ws + o_mod + (size_t)i * 8 * 6 * D,
            nullptr, 6 * D, D, 0, nullptr, 0, 0, 1, 8);
    }
    {
        const unsigned short* Wa2;
        if (bigw) Wa2 = wada2S;
        else { tcvt(out_adaW, wt, D, 2 * D, 1, stream); Wa2 = wt; }
        gemm_lds<0, 0, 128><<<dim3(12, 1), 256, 0, stream>>>(
            scb, Wa2, out_adab, ws + o_mod2, nullptr, 2 * D, D, 0, nullptr, 0, 0, 1, 8);
    }

    const int R = BATCH * NTOK;   // 4352 = 34*128
    for (int i = 0; i < DEPTH; ++i) {
        const float* mod_l = ws + o_mod + (size_t)i * 8 * 6 * D;
        const unsigned short *Wq = nullptr, *Wp = nullptr, *Wm1 = nullptr, *Wm2 = nullptr;
        if (bigw) {
            Wq  = wqkvS  + (size_t)i * D * 3 * D;
            Wp  = wprojS + (size_t)i * D * D;
            Wm1 = wmlp1S + (size_t)i * D * FF;
            Wm2 = wmlp2S + (size_t)i * D * FF;
        }
        ln_kernel<<<R, 256, 0, stream>>>(ws + o_x, lnb, R, NTOK, mod_l, 6 * D, 0, 1);
        if (!bigw) { tcvt(dit_qkv + (size_t)i * D * 3 * D, wt, D, 3 * D, 1, stream); Wq = wt; }
        g_bf(0, lnb, Wq, dit_qkvb + (size_t)i * 3 * D, qkvb, 3 * D, R, 3 * D, D, 768, stream);
        vt_kernel<<<dim3(9, NH, BATCH), 256, 0, stream>>>(qkvb, 3 * D, 2 * D, vtb, NTOK, 576);
        attn_mfma<<<dim3((NTOK + 127) / 128, NH, BATCH), 512, 0, stream>>>(
            qkvb, 3 * D, 0, qkvb, 3 * D, D, vtb, 576, attO, D, NTOK, NTOK);
        if (!bigw) { tcvt(dit_proj + (size_t)i * D * D, wt, D, D, 1, stream); Wp = wt; }
        g_res(attO, Wp, dit_projb + (size_t)i * D, ws + o_x, D, R, D, D,
              mod_l, 6 * D, 2, NTOK, stream);
        ln_kernel<<<R, 256, 0, stream>>>(ws + o_x, lnb, R, NTOK, mod_l, 6 * D, 3, 4);
        if (!bigw) { tcvt(dit_mlp1 + (size_t)i * D * FF, wt, D, FF, 1, stream); Wm1 = wt; }
        g_bf(2, lnb, Wm1, dit_mlp1b + (size_t)i * FF, hbuf, FF, R, FF, D, 0, stream);
        if (!bigw) { tcvt(dit_mlp2 + (size_t)i * FF * D, wt, FF, D, 1, stream); Wm2 = wt; }
        g_res(hbuf, Wm2, dit_mlp2b + (size_t)i * D, ws + o_x, D, R, D, FF,
              mod_l, 6 * D, 5, NTOK, stream);
    }

    // ---- output head ----
    ln_kernel<<<R, 256, 0, stream>>>(ws + o_x, lnb, R, NTOK, ws + o_mod2, 2 * D, 0, 1);
    head_kernel<<<BATCH * TTRAJ, 64, 0, stream>>>(lnb, wt14, out_b, out);
}

// Round 10
// 2577.826 us; speedup vs baseline: 11.3238x; 1.0531x over previous
//
#include <hip/hip_runtime.h>
#include <hip/hip_bf16.h>
#include <math.h>

#define D 768
#define NH 12
#define HD 64
#define NEXP 4
#define FF 3072
#define NBLK 2
#define DEPTH 6
#define NA 64
#define NB 32
#define NC 192
#define BATCH 8
#define TTRAJ 256
#define NTOK 544
#define MAXTOK 1536
#define MOER 2304   // 512 + 256 + 1536 tokens per MoE pass (a|bg|cg contiguous)

typedef __attribute__((ext_vector_type(8))) short short8v;
typedef __attribute__((ext_vector_type(4))) float f32x4;

__device__ __forceinline__ float siluf(float v) { return v / (1.f + expf(-v)); }
__device__ __forceinline__ float geluf(float v) {
    float u = 0.7978845608028654f * (v + 0.044715f * v * v * v);
    return 0.5f * v * (1.f + tanhf(u));
}
__device__ __forceinline__ unsigned short f2bf(float f) {
    union { float f; unsigned u; } v; v.f = f;
    unsigned r = v.u + 0x7fffu + ((v.u >> 16) & 1u);
    return (unsigned short)(r >> 16);
}
__device__ __forceinline__ float bf2f(unsigned short u) {
    union { unsigned u; float f; } v; v.u = ((unsigned)u) << 16; return v.f;
}
__device__ __forceinline__ void gl16(const unsigned short* g, unsigned short* l) {
    __builtin_amdgcn_global_load_lds(
        (const __attribute__((address_space(1))) void*)g,
        (__attribute__((address_space(3))) void*)l, 16, 0, 0);
}

// ---------------- timestep embedding -> bf16 [128][256] (rows 8..127 zero) ----
__global__ void timestep_kernel(const int* __restrict__ t, unsigned short* __restrict__ tembP) {
    int i = blockIdx.x * blockDim.x + threadIdx.x;
    if (i >= 128 * 256) return;
    int b = i >> 8, j = i & 255;
    float v = 0.f;
    if (b < BATCH) {
        int jj = (j & 127);
        float freq = expf(-logf(10000.f) * (float)jj / 128.f);
        float ang = (float)t[b] * freq;
        v = (j < 128) ? cosf(ang) : sinf(ang);
    }
    tembP[i] = f2bf(v);
}

__global__ void add_ftime(float* __restrict__ traj, const float* __restrict__ wf, int total) {
    int i = blockIdx.x * blockDim.x + threadIdx.x;
    if (i >= total) return;
    int col = i % D;
    int n = (i / D) % TTRAJ;
    traj[i] += wf[(n & 7) * D + col];
}

__global__ void cvt_bf16(const float* __restrict__ in, unsigned short* __restrict__ out, int n8) {
    int i = blockIdx.x * blockDim.x + threadIdx.x;
    if (i >= n8) return;
    float4 a = *(const float4*)(in + i * 8);
    float4 b = *(const float4*)(in + i * 8 + 4);
    unsigned short t[8] = {f2bf(a.x), f2bf(a.y), f2bf(a.z), f2bf(a.w),
                           f2bf(b.x), f2bf(b.y), f2bf(b.z), f2bf(b.w)};
    *(short8v*)(out + i * 8) = *(short8v*)t;
}

// ---------------- small f32 GEMM (traj embed, K=7) ----------------
template<int ACT>
__global__ __launch_bounds__(256) void gemm_act(
    const float* __restrict__ A, int lda,
    const float* __restrict__ B, int ldb,
    const float* __restrict__ bias,
    float* __restrict__ C, int ldc,
    int M, int N, int K)
{
    __shared__ float As[16][65];
    __shared__ float Bs[16][65];
    int tid = threadIdx.x;
    int tx = tid & 15, ty = tid >> 4;
    int row0 = blockIdx.y * 64, col0 = blockIdx.x * 64;
    float acc[4][4] = {};
    for (int k0 = 0; k0 < K; k0 += 16) {
        #pragma unroll
        for (int i = 0; i < 4; ++i) {
            int e = tid + 256 * i; int m = e >> 4; int kk = e & 15;
            int gr = row0 + m, gk = k0 + kk;
            As[kk][m] = (gr < M && gk < K) ? A[(size_t)gr * lda + gk] : 0.f;
        }
        #pragma unroll
        for (int i = 0; i < 4; ++i) {
            int e = tid + 256 * i; int kk = e >> 6; int n = e & 63;
            int gk = k0 + kk, gc = col0 + n;
            Bs[kk][n] = (gk < K && gc < N) ? B[(size_t)gk * ldb + gc] : 0.f;
        }
        __syncthreads();
        #pragma unroll
        for (int kk = 0; kk < 16; ++kk) {
            float a[4], bv[4];
            #pragma unroll
            for (int i = 0; i < 4; ++i) a[i] = As[kk][ty * 4 + i];
            #pragma unroll
            for (int j = 0; j < 4; ++j) bv[j] = Bs[kk][tx * 4 + j];
            #pragma unroll
            for (int i = 0; i < 4; ++i)
                #pragma unroll
                for (int j = 0; j < 4; ++j) acc[i][j] += a[i] * bv[j];
        }
        __syncthreads();
    }
    #pragma unroll
    for (int i = 0; i < 4; ++i) {
        int gr = row0 + ty * 4 + i; if (gr >= M) continue;
        #pragma unroll
        for (int j = 0; j < 4; ++j) {
            int gc = col0 + tx * 4 + j; if (gc >= N) continue;
            float v = acc[i][j] + (bias ? bias[gc] : 0.f);
            if (ACT == 1) v = siluf(v);
            if (ACT == 2) v = geluf(v);
            C[(size_t)gr * ldc + gc] = v;
        }
    }
}

// ---------------- weight transpose + cvt: [K][N] f32 -> [N][K] bf16 ----------------
__global__ __launch_bounds__(256) void transpose_cvt(
    const float* __restrict__ in, unsigned short* __restrict__ out, int K, int N)
{
    __shared__ unsigned short Ls[64][72];
    const float* src = in + (size_t)blockIdx.z * K * N;
    unsigned short* dst = out + (size_t)blockIdx.z * K * N;
    int k0 = blockIdx.y * 64, n0 = blockIdx.x * 64;
    int tid = threadIdx.x;
    int r = tid >> 2, c0 = (tid & 3) * 16;
    {
        const float* sp = src + (size_t)(k0 + r) * N + n0 + c0;
        #pragma unroll
        for (int j = 0; j < 16; j += 4) {
            float4 f = *(const float4*)(sp + j);
            Ls[c0 + j + 0][r] = f2bf(f.x);
            Ls[c0 + j + 1][r] = f2bf(f.y);
            Ls[c0 + j + 2][r] = f2bf(f.z);
            Ls[c0 + j + 3][r] = f2bf(f.w);
        }
    }
    __syncthreads();
    {
        unsigned short tmp[16];
        #pragma unroll
        for (int j = 0; j < 16; ++j) tmp[j] = Ls[r][c0 + j];
        unsigned short* dp = dst + (size_t)(n0 + r) * K + k0 + c0;
        *(short8v*)dp = *(short8v*)tmp;
        *(short8v*)(dp + 8) = *(short8v*)(tmp + 8);
    }
}

// ---------------- MFMA GEMM: BK=32, double-buffered LDS, one barrier/K-step ----
// TN = 128 or 64. Tile M=128, 4 waves. z-strides allow batching (blockIdx.z).
// ACT: 0 none, 1 silu, 2 gelu. OUT: 0 f32, 1 bf16 (+qscale), 2 f32 gated residual.
template<int ACT, int OUT, int TN>
__global__ __launch_bounds__(256) void gemm_lds(
    const unsigned short* __restrict__ A,
    const unsigned short* __restrict__ BT,
    const float* __restrict__ bias,
    float* __restrict__ Cf, unsigned short* __restrict__ Cb, int ldc,
    int K, int qscale_cols,
    const float* __restrict__ mod, int modstride, int gchunk, int ntok, int mrows,
    size_t bt_zs = 0, size_t bias_zs = 0, size_t c_zs = 0)
{
    constexpr int NCF = TN / 32;
    constexpr int NBS = TN / 64;
    if (bt_zs) BT += (size_t)blockIdx.z * bt_zs;
    if (bias && bias_zs) bias += (size_t)blockIdx.z * bias_zs;
    if (c_zs) { if (Cf) Cf += (size_t)blockIdx.z * c_zs; if (Cb) Cb += (size_t)blockIdx.z * c_zs; }
    __shared__ unsigned short As[2][128 * 32];
    __shared__ unsigned short Bs[2][TN * 32];
    int tid = threadIdx.x, w = tid >> 6, lane = tid & 63;
    int row0 = blockIdx.y * 128, col0 = blockIdx.x * TN;
    int wrow = (w >> 1) * 64, wcol = (w & 1) * (TN / 2);
    int lr = lane & 15, g = lane >> 4;
    f32x4 acc[4][NCF] = {};

    int ra[2], ka[2], la[2];
    #pragma unroll
    for (int i = 0; i < 2; ++i) {
        int off = tid * 16 + i * 4096;
        int row = off >> 6;
        int slot = (off >> 4) & 3;
        ra[i] = row;
        ka[i] = (slot ^ ((row >> 1) & 3)) * 8;
        la[i] = off >> 1;
    }
    int nt = K >> 5, cur = 0;
    #pragma unroll
    for (int i = 0; i < 2; ++i)
        gl16(A + (size_t)(row0 + ra[i]) * K + ka[i], &As[0][la[i]]);
    #pragma unroll
    for (int i = 0; i < NBS; ++i)
        gl16(BT + (size_t)(col0 + ra[i]) * K + ka[i], &Bs[0][la[i]]);

    for (int t = 0; t < nt; ++t) {
        __syncthreads();
        if (t + 1 < nt) {
            int k0 = (t + 1) << 5;
            #pragma unroll
            for (int i = 0; i < 2; ++i)
                gl16(A + (size_t)(row0 + ra[i]) * K + k0 + ka[i], &As[cur ^ 1][la[i]]);
            #pragma unroll
            for (int i = 0; i < NBS; ++i)
                gl16(BT + (size_t)(col0 + ra[i]) * K + k0 + ka[i], &Bs[cur ^ 1][la[i]]);
        }
        short8v av[4], bv[NCF];
        #pragma unroll
        for (int mr = 0; mr < 4; ++mr) {
            int row = wrow + mr * 16 + lr;
            av[mr] = *(const short8v*)&As[cur][row * 32 + (g ^ ((row >> 1) & 3)) * 8];
        }
        #pragma unroll
        for (int nc = 0; nc < NCF; ++nc) {
            int row = wcol + nc * 16 + lr;
            bv[nc] = *(const short8v*)&Bs[cur][row * 32 + (g ^ ((row >> 1) & 3)) * 8];
        }
        #pragma unroll
        for (int mr = 0; mr < 4; ++mr)
            #pragma unroll
            for (int nc = 0; nc < NCF; ++nc)
                acc[mr][nc] = __builtin_amdgcn_mfma_f32_16x16x32_bf16(
                    av[mr], bv[nc], acc[mr][nc], 0, 0, 0);
        cur ^= 1;
    }
    int rbase = g * 4;
    #pragma unroll
    for (int mr = 0; mr < 4; ++mr) {
        #pragma unroll
        for (int nc = 0; nc < NCF; ++nc) {
            int gc = col0 + wcol + nc * 16 + lr;
            float bb = bias ? bias[gc] : 0.f;
            #pragma unroll
            for (int r = 0; r < 4; ++r) {
                int gr = row0 + wrow + mr * 16 + rbase + r;
                if (gr >= mrows) continue;
                float v = acc[mr][nc][r] + bb;
                if (ACT == 1) v = siluf(v);
                if (ACT == 2) v = geluf(v);
                if (OUT == 0) {
                    Cf[(size_t)gr * ldc + gc] = v;
                } else if (OUT == 1) {
                    if (gc < qscale_cols) v *= 0.125f;
                    Cb[(size_t)gr * ldc + gc] = f2bf(v);
                } else {
                    float gg = 1.f;
                    if (mod) gg = mod[(size_t)(gr / ntok) * modstride + gchunk * D + gc];
                    Cf[(size_t)gr * ldc + gc] += gg * v;
                }
            }
        }
    }
}

// ---------------- MoE gathered MFMA GEMM (dbuf, all groups batched) ----------
template<int PHASE>
__global__ __launch_bounds__(256) void moe_lds(
    const unsigned short* __restrict__ A,
    const unsigned short* __restrict__ BTconv,
    float* __restrict__ Cf, unsigned short* __restrict__ Cb,
    const int* __restrict__ cnt, const int* __restrict__ list,
    const float* __restrict__ gval, int RT, int egbase)
{
    constexpr int K  = (PHASE == 1) ? 768 : 3072;
    constexpr int TN = (PHASE == 1) ? 128 : 64;
    constexpr int NCF = TN / 32;
    constexpr int NBS = TN / 64;
    int egl = blockIdx.y / RT, rt = blockIdx.y % RT;
    int eg = egbase + egl;
    int c0 = cnt[eg];
    int mbase = rt * 128;
    if (mbase >= c0) return;
    int mcount = min(128, c0 - mbase);
    __shared__ int toks[128];
    int tid = threadIdx.x, w = tid >> 6, lane = tid & 63;
    if (tid < 128) toks[tid] = list[eg * MAXTOK + mbase + min(tid, mcount - 1)];
    __syncthreads();

    __shared__ unsigned short As[2][128 * 32];
    __shared__ unsigned short Bs[2][TN * 32];
    const unsigned short* BT = BTconv + (size_t)egl * (768 * 3072);
    int col0 = blockIdx.x * TN;
    int wrow = (w >> 1) * 64, wcol = (w & 1) * (TN / 2);
    int lr = lane & 15, g = lane >> 4;
    f32x4 acc[4][NCF] = {};

    int ra[2], ka[2], la[2], tok_s[2];
    #pragma unroll
    for (int i = 0; i < 2; ++i) {
        int off = tid * 16 + i * 4096;
        int row = off >> 6;
        int slot = (off >> 4) & 3;
        ra[i] = row;
        ka[i] = (slot ^ ((row >> 1) & 3)) * 8;
        la[i] = off >> 1;
        tok_s[i] = toks[row];
    }
    int nt = K >> 5, cur = 0;
    #pragma unroll
    for (int i = 0; i < 2; ++i)
        gl16(A + (size_t)tok_s[i] * K + ka[i], &As[0][la[i]]);
    #pragma unroll
    for (int i = 0; i < NBS; ++i)
        gl16(BT + (size_t)(col0 + ra[i]) * K + ka[i], &Bs[0][la[i]]);

    for (int t = 0; t < nt; ++t) {
        __syncthreads();
        if (t + 1 < nt) {
            int k0 = (t + 1) << 5;
            #pragma unroll
            for (int i = 0; i < 2; ++i)
                gl16(A + (size_t)tok_s[i] * K + k0 + ka[i], &As[cur ^ 1][la[i]]);
            #pragma unroll
            for (int i = 0; i < NBS; ++i)
                gl16(BT + (size_t)(col0 + ra[i]) * K + k0 + ka[i], &Bs[cur ^ 1][la[i]]);
        }
        short8v av[4], bv[NCF];
        #pragma unroll
        for (int mr = 0; mr < 4; ++mr) {
            int row = wrow + mr * 16 + lr;
            av[mr] = *(const short8v*)&As[cur][row * 32 + (g ^ ((row >> 1) & 3)) * 8];
        }
        #pragma unroll
        for (int nc = 0; nc < NCF; ++nc) {
            int row = wcol + nc * 16 + lr;
            bv[nc] = *(const short8v*)&Bs[cur][row * 32 + (g ^ ((row >> 1) & 3)) * 8];
        }
        #pragma unroll
        for (int mr = 0; mr < 4; ++mr)
            #pragma unroll
            for (int nc = 0; nc < NCF; ++nc)
                acc[mr][nc] = __builtin_amdgcn_mfma_f32_16x16x32_bf16(
                    av[mr], bv[nc], acc[mr][nc], 0, 0, 0);
        cur ^= 1;
    }
    int rbase = g * 4;
    #pragma unroll
    for (int mr = 0; mr < 4; ++mr) {
        #pragma unroll
        for (int r = 0; r < 4; ++r) {
            int m = wrow + mr * 16 + rbase + r;
            if (m >= mcount) continue;
            int tok = toks[m];
            #pragma unroll
            for (int nc = 0; nc < NCF; ++nc) {
                int gc = col0 + wcol + nc * 16 + lr;
                float v = acc[mr][nc][r];
                if (PHASE == 1) Cb[(size_t)tok * 3072 + gc] = f2bf(geluf(v));
                else            Cf[(size_t)tok * 768 + gc] += gval[tok] * v;
            }
        }
    }
}

// ---------------- LayerNorm -> bf16 (+ optional adaLN modulate) ----------------
__global__ __launch_bounds__(256) void ln_kernel(
    const float* __restrict__ X, unsigned short* __restrict__ Y, int R, int ntok,
    const float* __restrict__ mod, int modstride, int shift_chunk, int scale_chunk)
{
    int r = blockIdx.x;
    if (r >= R) return;
    const float* xr = X + (size_t)r * D;
    int tid = threadIdx.x;
    int lane = tid & 63, wid = tid >> 6;
    float v0 = xr[tid], v1 = xr[tid + 256], v2 = xr[tid + 512];
    float s = v0 + v1 + v2;
    float s2 = v0 * v0 + v1 * v1 + v2 * v2;
    for (int off = 32; off > 0; off >>= 1) {
        s += __shfl_xor(s, off, 64);
        s2 += __shfl_xor(s2, off, 64);
    }
    __shared__ float shs[4], shs2[4];
    if (lane == 0) { shs[wid] = s; shs2[wid] = s2; }
    __syncthreads();
    float tot = shs[0] + shs[1] + shs[2] + shs[3];
    float tot2 = shs2[0] + shs2[1] + shs2[2] + shs2[3];
    float mu = tot * (1.f / 768.f);
    float var = tot2 * (1.f / 768.f) - mu * mu;
    float rs = rsqrtf(var + 1e-6f);
    int bb = r / ntok;
    float vv[3] = {v0, v1, v2};
    #pragma unroll
    for (int j = 0; j < 3; ++j) {
        int col = tid + j * 256;
        float nrm = (vv[j] - mu) * rs;
        float y = nrm;
        if (mod) {
            float scv = mod[(size_t)bb * modstride + scale_chunk * D + col];
            float shv = mod[(size_t)bb * modstride + shift_chunk * D + col];
            y = nrm * (1.f + scv) + shv;
        }
        Y[(size_t)r * D + col] = f2bf(y);
    }
}

// ---------------- MFMA flash attention: 128 q-rows, 8 waves, 512 threads ----
// V transposed in-kernel during staging (no separate vt pass).
__global__ __launch_bounds__(512) void attn_mfma(
    const unsigned short* __restrict__ Qp, int ldq, int qoff,
    const unsigned short* __restrict__ Kp, int ldk, int koff,
    const unsigned short* __restrict__ Vp, int ldv, int voff,
    unsigned short* __restrict__ O, int ldo,
    int Nq, int Nkv)
{
    __shared__ unsigned short Qs[128 * 64];
    __shared__ unsigned short Ks[64 * 64];
    __shared__ unsigned short Vs[64 * 64];   // V^T: [d][kv], swizzled
    __shared__ unsigned short Ps[128 * 64];
    int h = blockIdx.y, b = blockIdx.z, q0 = blockIdx.x * 128;
    int tid = threadIdx.x, w = tid >> 6, lane = tid & 63;
    int wrow = w * 16;
    int lr = lane & 15, g = lane >> 4;

    {
        int srow = tid >> 2, sc = (tid & 3) * 16;
        int gr = min(q0 + srow, Nq - 1);
        const unsigned short* qp = Qp + (size_t)(b * Nq + gr) * ldq + qoff + h * 64 + sc;
        short8v v0 = *(const short8v*)qp, v1 = *(const short8v*)(qp + 8);
        int s0 = sc >> 3;
        *(short8v*)&Qs[srow * 64 + (s0 ^ (srow & 7)) * 8] = v0;
        *(short8v*)&Qs[srow * 64 + ((s0 + 1) ^ (srow & 7)) * 8] = v1;
    }
    float m_r[4] = {-1e30f, -1e30f, -1e30f, -1e30f};
    float l_r[4] = {};
    f32x4 acc0 = {}, acc1 = {}, acc2 = {}, acc3 = {};

    for (int kv0 = 0; kv0 < Nkv; kv0 += 64) {
        {
            int t2 = tid & 255;
            int srow = t2 >> 2, sc = (t2 & 3) * 16;
            int gc = min(kv0 + srow, Nkv - 1);
            if (tid < 256) {
                const unsigned short* kp = Kp + (size_t)(b * Nkv + gc) * ldk + koff + h * 64 + sc;
                short8v v0 = *(const short8v*)kp, v1 = *(const short8v*)(kp + 8);
                int s0 = sc >> 3;
                *(short8v*)&Ks[srow * 64 + (s0 ^ (srow & 7)) * 8] = v0;
                *(short8v*)&Ks[srow * 64 + ((s0 + 1) ^ (srow & 7)) * 8] = v1;
            } else {
                // V rows -> transposed LDS: Vs[d][kv] with slot swizzle
                const unsigned short* vp = Vp + (size_t)(b * Nkv + gc) * ldv + voff + h * 64 + sc;
                #pragma unroll
                for (int j = 0; j < 16; ++j) {
                    int d = sc + j;
                    Vs[d * 64 + (((srow >> 3) ^ (d & 7)) * 8) + (srow & 7)] = vp[j];
                }
            }
        }
        __syncthreads();
        short8v aq0, aq1;
        {
            int row = wrow + lr;
            aq0 = *(const short8v*)&Qs[row * 64 + ((0 + g) ^ (row & 7)) * 8];
            aq1 = *(const short8v*)&Qs[row * 64 + ((4 + g) ^ (row & 7)) * 8];
        }
        f32x4 sf[4];
        #pragma unroll
        for (int nc = 0; nc < 4; ++nc) {
            int row = nc * 16 + lr;
            short8v bk0 = *(const short8v*)&Ks[row * 64 + ((0 + g) ^ (row & 7)) * 8];
            short8v bk1 = *(const short8v*)&Ks[row * 64 + ((4 + g) ^ (row & 7)) * 8];
            f32x4 z = {};
            z = __builtin_amdgcn_mfma_f32_16x16x32_bf16(aq0, bk0, z, 0, 0, 0);
            sf[nc] = __builtin_amdgcn_mfma_f32_16x16x32_bf16(aq1, bk1, z, 0, 0, 0);
        }
        bool val0 = (kv0 + 0 * 16 + lr) < Nkv;
        bool val1 = (kv0 + 1 * 16 + lr) < Nkv;
        bool val2 = (kv0 + 2 * 16 + lr) < Nkv;
        bool val3 = (kv0 + 3 * 16 + lr) < Nkv;
        float fs[4];
        #pragma unroll
        for (int r = 0; r < 4; ++r) {
            float s0 = val0 ? sf[0][r] : -1e30f;
            float s1 = val1 ? sf[1][r] : -1e30f;
            float s2 = val2 ? sf[2][r] : -1e30f;
            float s3 = val3 ? sf[3][r] : -1e30f;
            float mx = fmaxf(fmaxf(s0, s1), fmaxf(s2, s3));
            mx = fmaxf(mx, __shfl_xor(mx, 1, 64));
            mx = fmaxf(mx, __shfl_xor(mx, 2, 64));
            mx = fmaxf(mx, __shfl_xor(mx, 4, 64));
            mx = fmaxf(mx, __shfl_xor(mx, 8, 64));
            float mn = fmaxf(m_r[r], mx);
            fs[r] = __expf(m_r[r] - mn);
            m_r[r] = mn;
            float p0 = __expf(s0 - mn), p1 = __expf(s1 - mn);
            float p2 = __expf(s2 - mn), p3 = __expf(s3 - mn);
            float rsum = p0 + p1 + p2 + p3;
            rsum += __shfl_xor(rsum, 1, 64);
            rsum += __shfl_xor(rsum, 2, 64);
            rsum += __shfl_xor(rsum, 4, 64);
            rsum += __shfl_xor(rsum, 8, 64);
            l_r[r] = l_r[r] * fs[r] + rsum;
            int ql = wrow + g * 4 + r;
            int base = ql * 64;
            int x7 = ql & 7;
            Ps[base + (((0 * 16 + lr) >> 3) ^ x7) * 8 + (lr & 7)] = f2bf(p0);
            Ps[base + (((1 * 16 + lr) >> 3) ^ x7) * 8 + (lr & 7)] = f2bf(p1);
            Ps[base + (((2 * 16 + lr) >> 3) ^ x7) * 8 + (lr & 7)] = f2bf(p2);
            Ps[base + (((3 * 16 + lr) >> 3) ^ x7) * 8 + (lr & 7)] = f2bf(p3);
            acc0[r] *= fs[r]; acc1[r] *= fs[r]; acc2[r] *= fs[r]; acc3[r] *= fs[r];
        }
        __syncthreads();
        short8v ap0, ap1;
        {
            int row = wrow + lr;
            ap0 = *(const short8v*)&Ps[row * 64 + ((0 + g) ^ (row & 7)) * 8];
            ap1 = *(const short8v*)&Ps[row * 64 + ((4 + g) ^ (row & 7)) * 8];
        }
        {
            int row = 0 * 16 + lr;
            short8v b0 = *(const short8v*)&Vs[row * 64 + ((0 + g) ^ (row & 7)) * 8];
            short8v b1 = *(const short8v*)&Vs[row * 64 + ((4 + g) ^ (row & 7)) * 8];
            acc0 = __builtin_amdgcn_mfma_f32_16x16x32_bf16(ap0, b0, acc0, 0, 0, 0);
            acc0 = __builtin_amdgcn_mfma_f32_16x16x32_bf16(ap1, b1, acc0, 0, 0, 0);
        }
        {
            int row = 1 * 16 + lr;
            short8v b0 = *(const short8v*)&Vs[row * 64 + ((0 + g) ^ (row & 7)) * 8];
            short8v b1 = *(const short8v*)&Vs[row * 64 + ((4 + g) ^ (row & 7)) * 8];
            acc1 = __builtin_amdgcn_mfma_f32_16x16x32_bf16(ap0, b0, acc1, 0, 0, 0);
            acc1 = __builtin_amdgcn_mfma_f32_16x16x32_bf16(ap1, b1, acc1, 0, 0, 0);
        }
        {
            int row = 2 * 16 + lr;
            short8v b0 = *(const short8v*)&Vs[row * 64 + ((0 + g) ^ (row & 7)) * 8];
            short8v b1 = *(const short8v*)&Vs[row * 64 + ((4 + g) ^ (row & 7)) * 8];
            acc2 = __builtin_amdgcn_mfma_f32_16x16x32_bf16(ap0, b0, acc2, 0, 0, 0);
            acc2 = __builtin_amdgcn_mfma_f32_16x16x32_bf16(ap1, b1, acc2, 0, 0, 0);
        }
        {
            int row = 3 * 16 + lr;
            short8v b0 = *(const short8v*)&Vs[row * 64 + ((0 + g) ^ (row & 7)) * 8];
            short8v b1 = *(const short8v*)&Vs[row * 64 + ((4 + g) ^ (row & 7)) * 8];
            acc3 = __builtin_amdgcn_mfma_f32_16x16x32_bf16(ap0, b0, acc3, 0, 0, 0);
            acc3 = __builtin_amdgcn_mfma_f32_16x16x32_bf16(ap1, b1, acc3, 0, 0, 0);
        }
        __syncthreads();
    }
    #pragma unroll
    for (int r = 0; r < 4; ++r) {
        int ql = wrow + g * 4 + r;
        if (q0 + ql >= Nq) continue;
        float rl = 1.f / l_r[r];
        unsigned short* op = O + (size_t)(b * Nq + q0 + ql) * ldo + h * 64 + lr;
        op[0]  = f2bf(acc0[r] * rl);
        op[16] = f2bf(acc1[r] * rl);
        op[32] = f2bf(acc2[r] * rl);
        op[48] = f2bf(acc3[r] * rl);
    }
}

// ---------------- MoE router (group-aware, all 2304 tokens) ----------------
__global__ __launch_bounds__(64) void router_kernel(
    const unsigned short* __restrict__ X, const float* __restrict__ WrBase,
    int* __restrict__ idx, float* __restrict__ gval)
{
    int tkn = blockIdx.x; int lane = threadIdx.x;
    int grp = (tkn >= 768) ? 2 : (tkn >= 512 ? 1 : 0);
    const float* Wr = WrBase + (size_t)grp * D * NEXP;
    const unsigned short* xr = X + (size_t)tkn * D;
    float p0 = 0, p1 = 0, p2 = 0, p3 = 0;
    for (int dd = lane; dd < D; dd += 64) {
        float xv = bf2f(xr[dd]);
        const float* wq = Wr + dd * 4;
        p0 += xv * wq[0]; p1 += xv * wq[1]; p2 += xv * wq[2]; p3 += xv * wq[3];
    }
    for (int off = 32; off > 0; off >>= 1) {
        p0 += __shfl_xor(p0, off, 64); p1 += __shfl_xor(p1, off, 64);
        p2 += __shfl_xor(p2, off, 64); p3 += __shfl_xor(p3, off, 64);
    }
    if (lane == 0) {
        float best = p0; int e = 0;
        if (p1 > best) { best = p1; e = 1; }
        if (p2 > best) { best = p2; e = 2; }
        if (p3 > best) { best = p3; e = 3; }
        float sum = expf(p0 - best) + expf(p1 - best) + expf(p2 - best) + expf(p3 - best);
        idx[tkn] = grp * 4 + e;
        gval[tkn] = 1.f / sum;
    }
}

// single block: zero 12 counters + scatter to 12 lists
__global__ __launch_bounds__(256) void scatter_kernel(
    const int* __restrict__ idx, int* __restrict__ cnt,
    int* __restrict__ list, int ntok)
{
    __shared__ int lcnt[12];
    int tid = threadIdx.x;
    if (tid < 12) lcnt[tid] = 0;
    __syncthreads();
    for (int i = tid; i < ntok; i += 256) {
        int e = idx[i];
        int pos = atomicAdd(&lcnt[e], 1);
        list[e * MAXTOK + pos] = i;
    }
    __syncthreads();
    if (tid < 12) cnt[tid] = lcnt[tid];
}

// ---------------- concat ----------------
__global__ void concat_kernel(const float* __restrict__ traj, const float* __restrict__ a,
                              const float* __restrict__ bg, const float* __restrict__ cg,
                              float* __restrict__ x, int total)
{
    int i = blockIdx.x * blockDim.x + threadIdx.x;
    if (i >= total) return;
    int col = i % D;
    int r = i / D;
    int n = r % NTOK, b = r / NTOK;
    float v;
    if (n < 256)      v = traj[((size_t)b * 256 + n) * D + col];
    else if (n < 320) v = a[((size_t)b * 64 + (n - 256)) * D + col];
    else if (n < 352) v = bg[((size_t)b * 32 + (n - 320)) * D + col];
    else              v = cg[((size_t)b * 192 + (n - 352)) * D + col];
    x[i] = v;
}

// ---------------- output head ----------------
__global__ void head_prep(const float* __restrict__ W, unsigned short* __restrict__ WT14) {
    int i = blockIdx.x * blockDim.x + threadIdx.x;
    if (i >= 14 * 768) return;
    int o = i / 768, d = i % 768;
    WT14[i] = f2bf(W[d * 14 + o]);
}

__global__ __launch_bounds__(64) void head_kernel(
    const unsigned short* __restrict__ lnb, const unsigned short* __restrict__ WT14,
    const float* __restrict__ bias, float* __restrict__ out)
{
    int r = blockIdx.x;
    int b = r >> 8, n = r & 255;
    const unsigned short* hrow = lnb + (size_t)(b * NTOK + n) * D;
    int l = threadIdx.x;
    if (l >= 56) return;
    int o = l >> 2, p = l & 3;
    const unsigned short* hp = hrow + p * 192;
    const unsigned short* wp = WT14 + o * 768 + p * 192;
    float acc = 0.f;
    for (int i = 0; i < 192; i += 8) {
        short8v hv = *(const short8v*)(hp + i);
        short8v wv = *(const short8v*)(wp + i);
        #pragma unroll
        for (int j = 0; j < 8; ++j)
            acc += bf2f((unsigned short)hv[j]) * bf2f((unsigned short)wv[j]);
    }
    acc += __shfl_xor(acc, 1, 64);
    acc += __shfl_xor(acc, 2, 64);
    if (p == 0) out[(size_t)r * 14 + o] = acc + bias[o];
}

// ---------------- host helpers ----------------
static inline void tcvt(const float* W, unsigned short* WT, int K, int N, int z, hipStream_t s) {
    transpose_cvt<<<dim3(N / 64, K / 64, z), 256, 0, s>>>(W, WT, K, N);
}
static inline void g_bf(int act, const unsigned short* A, const unsigned short* BT,
                        const float* bias, unsigned short* C, int ldc,
                        int M, int N, int K, int qcols, hipStream_t s)
{
    if (N != 768) {
        dim3 g(N / 128, M / 128);
        if (act == 2) gemm_lds<2, 1, 128><<<g, 256, 0, s>>>(A, BT, bias, nullptr, C, ldc, K, qcols, nullptr, 0, 0, 1, 1 << 30);
        else          gemm_lds<0, 1, 128><<<g, 256, 0, s>>>(A, BT, bias, nullptr, C, ldc, K, qcols, nullptr, 0, 0, 1, 1 << 30);
    } else {
        dim3 g(N / 64, M / 128);
        if (act == 2) gemm_lds<2, 1, 64><<<g, 256, 0, s>>>(A, BT, bias, nullptr, C, ldc, K, qcols, nullptr, 0, 0, 1, 1 << 30);
        else          gemm_lds<0, 1, 64><<<g, 256, 0, s>>>(A, BT, bias, nullptr, C, ldc, K, qcols, nullptr, 0, 0, 1, 1 << 30);
    }
}
static inline void g_res(const unsigned short* A, const unsigned short* BT,
                         const float* bias, float* C, int ldc, int M, int N, int K,
                         const float* mod, int modstride, int gchunk, int ntok, hipStream_t s)
{
    dim3 g(N / 64, M / 128);
    gemm_lds<0, 2, 64><<<g, 256, 0, s>>>(A, BT, bias, C, nullptr, ldc, K, 0, mod, modstride, gchunk, ntok, 1 << 30);
}

extern "C" void kernel_launch(void* const* d_in, const int* in_sizes, int n_in,
                              void* d_out, int out_size, void* d_ws, size_t ws_size,
                              hipStream_t stream)
{
    const float* x_traj   = (const float*)d_in[0];
    const int*   t_arr    = (const int*)d_in[1];
    const float* tokA     = (const float*)d_in[2];
    const float* tokB     = (const float*)d_in[3];
    const float* tokC     = (const float*)d_in[4];
    const float* W_traj   = (const float*)d_in[5];
    const float* b_traj   = (const float*)d_in[6];
    const float* W_ftime  = (const float*)d_in[7];
    const float* Wt1      = (const float*)d_in[8];
    const float* bt1      = (const float*)d_in[9];
    const float* Wt2      = (const float*)d_in[10];
    const float* bt2      = (const float*)d_in[11];
    const float* moe_attn = (const float*)d_in[12];
    const float* moe_rout = (const float*)d_in[13];
    const float* moe_W1   = (const float*)d_in[14];
    const float* moe_W2   = (const float*)d_in[15];
    const float* dit_qkv  = (const float*)d_in[16];
    const float* dit_qkvb = (const float*)d_in[17];
    const float* dit_proj = (const float*)d_in[18];
    const float* dit_projb= (const float*)d_in[19];
    const float* dit_mlp1 = (const float*)d_in[20];
    const float* dit_mlp1b= (const float*)d_in[21];
    const float* dit_mlp2 = (const float*)d_in[22];
    const float* dit_mlp2b= (const float*)d_in[23];
    const float* dit_ada  = (const float*)d_in[24];
    const float* dit_adab = (const float*)d_in[25];
    const float* out_adaW = (const float*)d_in[26];
    const float* out_adab = (const float*)d_in[27];
    const float* out_W    = (const float*)d_in[28];
    const float* out_b    = (const float*)d_in[29];
    float* out = (float*)d_out;
    float* ws = (float*)d_ws;

    // base workspace layout (float offsets)
    const size_t o_cnt  = 14336;
    const size_t o_idx  = 14400;
    const size_t o_gval = 16704;
    const size_t o_list = 19008;
    const size_t o_traj = 66624;
    const size_t o_a    = 1639488;
    const size_t o_bg   = 2032704;
    const size_t o_cg   = 2229312;
    const size_t o_x    = 3408960;
    const size_t o_lnb  = 6751296;
    const size_t o_qkvb = 8422464;
    const size_t o_attnO= 13435968;
    const size_t o_h    = 15107136;
    const size_t o_kvbf = 23561280;
    const size_t o_wt   = 24151104;
    const size_t o_wt14 = 28869696;
    const size_t o_tembP= 28875072;
    const size_t o_ub   = 28891456;
    const size_t o_scb  = 28940608;
    const size_t o_mod  = o_traj;
    const size_t o_mod2 = o_traj + 221184;

    // big-weight region
    const size_t o_wqkv  = 29000000;
    const size_t o_wproj = 34308416;
    const size_t o_wmlp1 = 36077888;
    const size_t o_wmlp2 = 43155776;
    const size_t o_wada  = 50233664;
    const size_t o_wada2 = 60850496;
    const size_t o_wcross= 61440320;
    const size_t o_wmoe1 = 66158912;
    const size_t o_wmoe2 = 94470464;
    const bool bigw = ws_size >= (size_t)123000000 * 4;

    int* cnt_p  = (int*)(ws + o_cnt);
    int* idx_p  = (int*)(ws + o_idx);
    int* list_p = (int*)(ws + o_list);
    float* gval_p = ws + o_gval;
    unsigned short* lnb  = (unsigned short*)(ws + o_lnb);
    unsigned short* qkvb = (unsigned short*)(ws + o_qkvb);
    unsigned short* attO = (unsigned short*)(ws + o_attnO);
    unsigned short* hbuf = (unsigned short*)(ws + o_h);
    unsigned short* kvbf = (unsigned short*)(ws + o_kvbf);
    unsigned short* wt   = (unsigned short*)(ws + o_wt);
    unsigned short* wt14 = (unsigned short*)(ws + o_wt14);
    unsigned short* tembP= (unsigned short*)(ws + o_tembP);
    unsigned short* ub   = (unsigned short*)(ws + o_ub);
    unsigned short* scb  = (unsigned short*)(ws + o_scb);
    unsigned short* wqkvS = (unsigned short*)(ws + o_wqkv);
    unsigned short* wprojS= (unsigned short*)(ws + o_wproj);
    unsigned short* wmlp1S= (unsigned short*)(ws + o_wmlp1);
    unsigned short* wmlp2S= (unsigned short*)(ws + o_wmlp2);
    unsigned short* wadaS = (unsigned short*)(ws + o_wada);
    unsigned short* wada2S= (unsigned short*)(ws + o_wada2);
    unsigned short* wcrossS=(unsigned short*)(ws + o_wcross);
    unsigned short* wmoe1S= (unsigned short*)(ws + o_wmoe1);
    unsigned short* wmoe2S= (unsigned short*)(ws + o_wmoe2);
    unsigned short* c_q  = qkvb;
    unsigned short* c_kv = qkvb + 1179648;

    const size_t WSZ = (size_t)D * D;

    // ---- trajectory embedding ----
    gemm_act<0><<<dim3(12, 32), 256, 0, stream>>>(x_traj, 7, W_traj, D, b_traj,
                                                  ws + o_traj, D, BATCH * TTRAJ, D, 7);
    add_ftime<<<(BATCH * TTRAJ * D + 255) / 256, 256, 0, stream>>>(ws + o_traj, W_ftime, BATCH * TTRAJ * D);

    hipError_t e1 = hipMemcpyAsync(ws + o_a, tokA, (size_t)BATCH * NA * D * 4, hipMemcpyDeviceToDevice, stream); (void)e1;
    hipError_t e2 = hipMemcpyAsync(ws + o_bg, tokB, (size_t)BATCH * NB * D * 4, hipMemcpyDeviceToDevice, stream); (void)e2;
    hipError_t e3 = hipMemcpyAsync(ws + o_cg, tokC, (size_t)BATCH * NC * D * 4, hipMemcpyDeviceToDevice, stream); (void)e3;
    head_prep<<<42, 256, 0, stream>>>(out_W, wt14);

    // ---- all weight conversions up front (batched) ----
    if (bigw) {
        tcvt(dit_qkv,  wqkvS,  D, 3 * D, DEPTH, stream);
        tcvt(dit_proj, wprojS, D, D, DEPTH, stream);
        tcvt(dit_mlp1, wmlp1S, D, FF, DEPTH, stream);
        tcvt(dit_mlp2, wmlp2S, FF, D, DEPTH, stream);
        tcvt(dit_ada,  wadaS,  D, 6 * D, DEPTH, stream);
        tcvt(out_adaW, wada2S, D, 2 * D, 1, stream);
        tcvt(moe_attn, wcrossS, D, D, NBLK * 2 * 4, stream);
        tcvt(moe_W1,   wmoe1S, D, FF, NBLK * 3 * NEXP, stream);
        tcvt(moe_W2,   wmoe2S, FF, D, NBLK * 3 * NEXP, stream);
    }

    // ---- conditioning chain on MFMA (M padded to 128) ----
    timestep_kernel<<<128, 256, 0, stream>>>(t_arr, tembP);
    tcvt(Wt1, wt, 256, D, 1, stream);
    gemm_lds<1, 1, 64><<<dim3(12, 1), 256, 0, stream>>>(
        tembP, wt, bt1, nullptr, ub, D, 256, 0, nullptr, 0, 0, 1, 128);
    tcvt(Wt2, wt, D, D, 1, stream);
    gemm_lds<1, 1, 64><<<dim3(12, 1), 256, 0, stream>>>(
        ub, wt, bt2, nullptr, scb, D, D, 0, nullptr, 0, 0, 1, 128);   // scb = silu(c)

    for (int i = 0; i < NBLK; ++i) {
        // cross 1: cg += cross(ln(cg), a)
        {
            const unsigned short* Wc;
            if (bigw) Wc = wcrossS + (size_t)(i * 2 + 0) * 4 * WSZ;
            else { tcvt(moe_attn + (size_t)(i * 2 + 0) * 4 * WSZ, wt, D, D, 4, stream); Wc = wt; }
            ln_kernel<<<BATCH * NC, 256, 0, stream>>>(ws + o_cg, lnb, BATCH * NC, 1, nullptr, 0, 0, 0);
            g_bf(0, lnb, Wc, nullptr, c_q, D, BATCH * NC, D, D, 768, stream);
            cvt_bf16<<<(BATCH * NA * D / 8 + 255) / 256, 256, 0, stream>>>(ws + o_a, kvbf, BATCH * NA * D / 8);
            g_bf(0, kvbf, Wc + 1 * WSZ, nullptr, c_kv, 2 * D, BATCH * NA, 2 * D, D, 0, stream);
            attn_mfma<<<dim3((NC + 127) / 128, NH, BATCH), 512, 0, stream>>>(
                c_q, D, 0, c_kv, 2 * D, 0, c_kv, 2 * D, D, attO, D, NC, NA);
            g_res(attO, Wc + 3 * WSZ, nullptr, ws + o_cg, D, BATCH * NC, D, D, nullptr, 0, 0, 1, stream);
        }
        // cross 2: bg += cross(ln(bg), cg)
        {
            const unsigned short* Wc;
            if (bigw) Wc = wcrossS + (size_t)(i * 2 + 1) * 4 * WSZ;
            else { tcvt(moe_attn + (size_t)(i * 2 + 1) * 4 * WSZ, wt, D, D, 4, stream); Wc = wt; }
            ln_kernel<<<BATCH * NB, 256, 0, stream>>>(ws + o_bg, lnb, BATCH * NB, 1, nullptr, 0, 0, 0);
            g_bf(0, lnb, Wc, nullptr, c_q, D, BATCH * NB, D, D, 768, stream);
            cvt_bf16<<<(BATCH * NC * D / 8 + 255) / 256, 256, 0, stream>>>(ws + o_cg, kvbf, BATCH * NC * D / 8);
            g_bf(0, kvbf, Wc + 1 * WSZ, nullptr, c_kv, 2 * D, BATCH * NC, 2 * D, D, 0, stream);
            attn_mfma<<<dim3(1, NH, BATCH), 512, 0, stream>>>(
                c_q, D, 0, c_kv, 2 * D, 0, c_kv, 2 * D, D, attO, D, NB, NC);
            g_res(attO, Wc + 3 * WSZ, nullptr, ws + o_bg, D, BATCH * NB, D, D, nullptr, 0, 0, 1, stream);
        }
        // ---- MoE: all 3 groups batched ----
        ln_kernel<<<MOER, 256, 0, stream>>>(ws + o_a, lnb, MOER, 1, nullptr, 0, 0, 0);
        router_kernel<<<MOER, 64, 0, stream>>>(lnb, moe_rout + (size_t)(i * 3) * D * NEXP, idx_p, gval_p);
        scatter_kernel<<<1, 256, 0, stream>>>(idx_p, cnt_p, list_p, MOER);
        const int RT = 12;
        if (bigw) {
            moe_lds<1><<<dim3(24, 12 * RT), 256, 0, stream>>>(
                lnb, wmoe1S + (size_t)(i * 3) * NEXP * D * FF, nullptr, hbuf,
                cnt_p, list_p, gval_p, RT, 0);
            moe_lds<2><<<dim3(12, 12 * RT), 256, 0, stream>>>(
                hbuf, wmoe2S + (size_t)(i * 3) * NEXP * D * FF, ws + o_a, nullptr,
                cnt_p, list_p, gval_p, RT, 0);
        } else {
            for (int g = 0; g < 3; ++g) {
                tcvt(moe_W1 + (size_t)(i * 3 + g) * NEXP * D * FF, wt, D, FF, NEXP, stream);
                moe_lds<1><<<dim3(24, 4 * RT), 256, 0, stream>>>(
                    lnb, wt, nullptr, hbuf, cnt_p, list_p, gval_p, RT, g * 4);
                tcvt(moe_W2 + (size_t)(i * 3 + g) * NEXP * FF * D, wt, FF, D, NEXP, stream);
                moe_lds<2><<<dim3(12, 4 * RT), 256, 0, stream>>>(
                    hbuf, wt, ws + o_a, nullptr, cnt_p, list_p, gval_p, RT, g * 4);
            }
        }
    }

    // ---- concat into x ----
    concat_kernel<<<(BATCH * NTOK * D + 255) / 256, 256, 0, stream>>>(
        ws + o_traj, ws + o_a, ws + o_bg, ws + o_cg, ws + o_x, BATCH * NTOK * D);

    // ---- adaLN modulations: all 6 layers in ONE launch (z-strided), + head ----
    if (bigw) {
        gemm_lds<0, 0, 128><<<dim3(36, 1, DEPTH), 256, 0, stream>>>(
            scb, wadaS, dit_adab, ws + o_mod, nullptr, 6 * D, D, 0,
            nullptr, 0, 0, 1, 8,
            (size_t)D * 6 * D, (size_t)6 * D, (size_t)8 * 6 * D);
        gemm_lds<0, 0, 128><<<dim3(12, 1), 256, 0, stream>>>(
            scb, wada2S, out_adab, ws + o_mod2, nullptr, 2 * D, D, 0, nullptr, 0, 0, 1, 8);
    } else {
        for (int i = 0; i < DEPTH; ++i) {
            tcvt(dit_ada + (size_t)i * D * 6 * D, wt, D, 6 * D, 1, stream);
            gemm_lds<0, 0, 128><<<dim3(36, 1), 256, 0, stream>>>(
                scb, wt, dit_adab + (size_t)i * 6 * D, ws + o_mod + (size_t)i * 8 * 6 * D,
                nullptr, 6 * D, D, 0, nullptr, 0, 0, 1, 8);
        }
        tcvt(out_adaW, wt, D, 2 * D, 1, stream);
        gemm_lds<0, 0, 128><<<dim3(12, 1), 256, 0, stream>>>(
            scb, wt, out_adab, ws + o_mod2, nullptr, 2 * D, D, 0, nullptr, 0, 0, 1, 8);
    }

    const int R = BATCH * NTOK;   // 4352 = 34*128
    for (int i = 0; i < DEPTH; ++i) {
        const float* mod_l = ws + o_mod + (size_t)i * 8 * 6 * D;
        const unsigned short *Wq = nullptr, *Wp = nullptr, *Wm1 = nullptr, *Wm2 = nullptr;
        if (bigw) {
            Wq  = wqkvS  + (size_t)i * D * 3 * D;
            Wp  = wprojS + (size_t)i * D * D;
            Wm1 = wmlp1S + (size_t)i * D * FF;
            Wm2 = wmlp2S + (size_t)i * D * FF;
        }
        ln_kernel<<<R, 256, 0, stream>>>(ws + o_x, lnb, R, NTOK, mod_l, 6 * D, 0, 1);
        if (!bigw) { tcvt(dit_qkv + (size_t)i * D * 3 * D, wt, D, 3 * D, 1, stream); Wq = wt; }
        g_bf(0, lnb, Wq, dit_qkvb + (size_t)i * 3 * D, qkvb, 3 * D, R, 3 * D, D, 768, stream);
        attn_mfma<<<dim3((NTOK + 127) / 128, NH, BATCH), 512, 0, stream>>>(
            qkvb, 3 * D, 0, qkvb, 3 * D, D, qkvb, 3 * D, 2 * D, attO, D, NTOK, NTOK);
        if (!bigw) { tcvt(dit_proj + (size_t)i * D * D, wt, D, D, 1, stream); Wp = wt; }
        g_res(attO, Wp, dit_projb + (size_t)i * D, ws + o_x, D, R, D, D,
              mod_l, 6 * D, 2, NTOK, stream);
        ln_kernel<<<R, 256, 0, stream>>>(ws + o_x, lnb, R, NTOK, mod_l, 6 * D, 3, 4);
        if (!bigw) { tcvt(dit_mlp1 + (size_t)i * D * FF, wt, D, FF, 1, stream); Wm1 = wt; }
        g_bf(2, lnb, Wm1, dit_mlp1b + (size_t)i * FF, hbuf, FF, R, FF, D, 0, stream);
        if (!bigw) { tcvt(dit_mlp2 + (size_t)i * FF * D, wt, FF, D, 1, stream); Wm2 = wt; }
        g_res(hbuf, Wm2, dit_mlp2b + (size_t)i * D, ws + o_x, D, R, D, FF,
              mod_l, 6 * D, 5, NTOK, stream);
    }

    // ---- output head ----
    ln_kernel<<<R, 256, 0, stream>>>(ws + o_x, lnb, R, NTOK, ws + o_mod2, 2 * D, 0, 1);
    head_kernel<<<BATCH * TTRAJ, 64, 0, stream>>>(lnb, wt14, out_b, out);
}

// Round 11
// 2379.489 us; speedup vs baseline: 12.2676x; 1.0834x over previous
//
#include <hip/hip_runtime.h>
#include <hip/hip_bf16.h>
#include <math.h>

#define D 768
#define NH 12
#define HD 64
#define NEXP 4
#define FF 3072
#define NBLK 2
#define DEPTH 6
#define NA 64
#define NB 32
#define NC 192
#define BATCH 8
#define TTRAJ 256
#define NTOK 544
#define MAXTOK 1536
#define MOER 2304

typedef __attribute__((ext_vector_type(8))) short short8v;
typedef __attribute__((ext_vector_type(4))) float f32x4;

__device__ __forceinline__ float siluf(float v) { return v / (1.f + expf(-v)); }
__device__ __forceinline__ float geluf(float v) {
    float u = 0.7978845608028654f * (v + 0.044715f * v * v * v);
    return 0.5f * v * (1.f + tanhf(u));
}
__device__ __forceinline__ unsigned short f2bf(float f) {
    union { float f; unsigned u; } v; v.f = f;
    unsigned r = v.u + 0x7fffu + ((v.u >> 16) & 1u);
    return (unsigned short)(r >> 16);
}
__device__ __forceinline__ float bf2f(unsigned short u) {
    union { unsigned u; float f; } v; v.u = ((unsigned)u) << 16; return v.f;
}
__device__ __forceinline__ void gl16(const unsigned short* g, unsigned short* l) {
    __builtin_amdgcn_global_load_lds(
        (const __attribute__((address_space(1))) void*)g,
        (__attribute__((address_space(3))) void*)l, 16, 0, 0);
}

// ---------------- timestep embedding ----------------
__global__ void timestep_kernel(const int* __restrict__ t, unsigned short* __restrict__ tembP) {
    int i = blockIdx.x * blockDim.x + threadIdx.x;
    if (i >= 128 * 256) return;
    int b = i >> 8, j = i & 255;
    float v = 0.f;
    if (b < BATCH) {
        int jj = (j & 127);
        float freq = expf(-logf(10000.f) * (float)jj / 128.f);
        float ang = (float)t[b] * freq;
        v = (j < 128) ? cosf(ang) : sinf(ang);
    }
    tembP[i] = f2bf(v);
}

__global__ void add_ftime(float* __restrict__ traj, const float* __restrict__ wf, int total) {
    int i = blockIdx.x * blockDim.x + threadIdx.x;
    if (i >= total) return;
    int col = i % D;
    int n = (i / D) % TTRAJ;
    traj[i] += wf[(n & 7) * D + col];
}

__global__ void cvt_bf16(const float* __restrict__ in, unsigned short* __restrict__ out, int n8) {
    int i = blockIdx.x * blockDim.x + threadIdx.x;
    if (i >= n8) return;
    float4 a = *(const float4*)(in + i * 8);
    float4 b = *(const float4*)(in + i * 8 + 4);
    unsigned short t[8] = {f2bf(a.x), f2bf(a.y), f2bf(a.z), f2bf(a.w),
                           f2bf(b.x), f2bf(b.y), f2bf(b.z), f2bf(b.w)};
    *(short8v*)(out + i * 8) = *(short8v*)t;
}

// ---------------- small f32 GEMM (traj embed, K=7) ----------------
template<int ACT>
__global__ __launch_bounds__(256) void gemm_act(
    const float* __restrict__ A, int lda,
    const float* __restrict__ B, int ldb,
    const float* __restrict__ bias,
    float* __restrict__ C, int ldc,
    int M, int N, int K)
{
    __shared__ float As[16][65];
    __shared__ float Bs[16][65];
    int tid = threadIdx.x;
    int tx = tid & 15, ty = tid >> 4;
    int row0 = blockIdx.y * 64, col0 = blockIdx.x * 64;
    float acc[4][4] = {};
    for (int k0 = 0; k0 < K; k0 += 16) {
        #pragma unroll
        for (int i = 0; i < 4; ++i) {
            int e = tid + 256 * i; int m = e >> 4; int kk = e & 15;
            int gr = row0 + m, gk = k0 + kk;
            As[kk][m] = (gr < M && gk < K) ? A[(size_t)gr * lda + gk] : 0.f;
        }
        #pragma unroll
        for (int i = 0; i < 4; ++i) {
            int e = tid + 256 * i; int kk = e >> 6; int n = e & 63;
            int gk = k0 + kk, gc = col0 + n;
            Bs[kk][n] = (gk < K && gc < N) ? B[(size_t)gk * ldb + gc] : 0.f;
        }
        __syncthreads();
        #pragma unroll
        for (int kk = 0; kk < 16; ++kk) {
            float a[4], bv[4];
            #pragma unroll
            for (int i = 0; i < 4; ++i) a[i] = As[kk][ty * 4 + i];
            #pragma unroll
            for (int j = 0; j < 4; ++j) bv[j] = Bs[kk][tx * 4 + j];
            #pragma unroll
            for (int i = 0; i < 4; ++i)
                #pragma unroll
                for (int j = 0; j < 4; ++j) acc[i][j] += a[i] * bv[j];
        }
        __syncthreads();
    }
    #pragma unroll
    for (int i = 0; i < 4; ++i) {
        int gr = row0 + ty * 4 + i; if (gr >= M) continue;
        #pragma unroll
        for (int j = 0; j < 4; ++j) {
            int gc = col0 + tx * 4 + j; if (gc >= N) continue;
            float v = acc[i][j] + (bias ? bias[gc] : 0.f);
            if (ACT == 1) v = siluf(v);
            if (ACT == 2) v = geluf(v);
            C[(size_t)gr * ldc + gc] = v;
        }
    }
}

// ---------------- weight transpose + cvt ----------------
__global__ __launch_bounds__(256) void transpose_cvt(
    const float* __restrict__ in, unsigned short* __restrict__ out, int K, int N)
{
    __shared__ unsigned short Ls[64][72];
    const float* src = in + (size_t)blockIdx.z * K * N;
    unsigned short* dst = out + (size_t)blockIdx.z * K * N;
    int k0 = blockIdx.y * 64, n0 = blockIdx.x * 64;
    int tid = threadIdx.x;
    int r = tid >> 2, c0 = (tid & 3) * 16;
    {
        const float* sp = src + (size_t)(k0 + r) * N + n0 + c0;
        #pragma unroll
        for (int j = 0; j < 16; j += 4) {
            float4 f = *(const float4*)(sp + j);
            Ls[c0 + j + 0][r] = f2bf(f.x);
            Ls[c0 + j + 1][r] = f2bf(f.y);
            Ls[c0 + j + 2][r] = f2bf(f.z);
            Ls[c0 + j + 3][r] = f2bf(f.w);
        }
    }
    __syncthreads();
    {
        unsigned short tmp[16];
        #pragma unroll
        for (int j = 0; j < 16; ++j) tmp[j] = Ls[r][c0 + j];
        unsigned short* dp = dst + (size_t)(n0 + r) * K + k0 + c0;
        *(short8v*)dp = *(short8v*)tmp;
        *(short8v*)(dp + 8) = *(short8v*)(tmp + 8);
    }
}

// ---------------- MFMA GEMM: BK=32, dbuf, TM=128, TN=128/64, 4 waves ----
template<int ACT, int OUT, int TN>
__global__ __launch_bounds__(256) void gemm_lds(
    const unsigned short* __restrict__ A,
    const unsigned short* __restrict__ BT,
    const float* __restrict__ bias,
    float* __restrict__ Cf, unsigned short* __restrict__ Cb, int ldc,
    int K, int qscale_cols,
    const float* __restrict__ mod, int modstride, int gchunk, int ntok, int mrows,
    size_t bt_zs = 0, size_t bias_zs = 0, size_t c_zs = 0)
{
    constexpr int NCF = TN / 32;
    constexpr int NBS = TN / 64;
    if (bt_zs) BT += (size_t)blockIdx.z * bt_zs;
    if (bias && bias_zs) bias += (size_t)blockIdx.z * bias_zs;
    if (c_zs) { if (Cf) Cf += (size_t)blockIdx.z * c_zs; if (Cb) Cb += (size_t)blockIdx.z * c_zs; }
    __shared__ unsigned short As[2][128 * 32];
    __shared__ unsigned short Bs[2][TN * 32];
    int tid = threadIdx.x, w = tid >> 6, lane = tid & 63;
    int row0 = blockIdx.y * 128, col0 = blockIdx.x * TN;
    int wrow = (w >> 1) * 64, wcol = (w & 1) * (TN / 2);
    int lr = lane & 15, g = lane >> 4;
    f32x4 acc[4][NCF] = {};

    int ra[2], ka[2], la[2];
    #pragma unroll
    for (int i = 0; i < 2; ++i) {
        int off = tid * 16 + i * 4096;
        int row = off >> 6;
        int slot = (off >> 4) & 3;
        ra[i] = row;
        ka[i] = (slot ^ ((row >> 1) & 3)) * 8;
        la[i] = off >> 1;
    }
    int nt = K >> 5, cur = 0;
    #pragma unroll
    for (int i = 0; i < 2; ++i)
        gl16(A + (size_t)(row0 + ra[i]) * K + ka[i], &As[0][la[i]]);
    #pragma unroll
    for (int i = 0; i < NBS; ++i)
        gl16(BT + (size_t)(col0 + ra[i]) * K + ka[i], &Bs[0][la[i]]);

    for (int t = 0; t < nt; ++t) {
        __syncthreads();
        if (t + 1 < nt) {
            int k0 = (t + 1) << 5;
            #pragma unroll
            for (int i = 0; i < 2; ++i)
                gl16(A + (size_t)(row0 + ra[i]) * K + k0 + ka[i], &As[cur ^ 1][la[i]]);
            #pragma unroll
            for (int i = 0; i < NBS; ++i)
                gl16(BT + (size_t)(col0 + ra[i]) * K + k0 + ka[i], &Bs[cur ^ 1][la[i]]);
        }
        short8v av[4], bv[NCF];
        #pragma unroll
        for (int mr = 0; mr < 4; ++mr) {
            int row = wrow + mr * 16 + lr;
            av[mr] = *(const short8v*)&As[cur][row * 32 + (g ^ ((row >> 1) & 3)) * 8];
        }
        #pragma unroll
        for (int nc = 0; nc < NCF; ++nc) {
            int row = wcol + nc * 16 + lr;
            bv[nc] = *(const short8v*)&Bs[cur][row * 32 + (g ^ ((row >> 1) & 3)) * 8];
        }
        #pragma unroll
        for (int mr = 0; mr < 4; ++mr)
            #pragma unroll
            for (int nc = 0; nc < NCF; ++nc)
                acc[mr][nc] = __builtin_amdgcn_mfma_f32_16x16x32_bf16(
                    av[mr], bv[nc], acc[mr][nc], 0, 0, 0);
        cur ^= 1;
    }
    int rbase = g * 4;
    #pragma unroll
    for (int mr = 0; mr < 4; ++mr) {
        #pragma unroll
        for (int nc = 0; nc < NCF; ++nc) {
            int gc = col0 + wcol + nc * 16 + lr;
            float bb = bias ? bias[gc] : 0.f;
            #pragma unroll
            for (int r = 0; r < 4; ++r) {
                int gr = row0 + wrow + mr * 16 + rbase + r;
                if (gr >= mrows) continue;
                float v = acc[mr][nc][r] + bb;
                if (ACT == 1) v = siluf(v);
                if (ACT == 2) v = geluf(v);
                if (OUT == 0) {
                    Cf[(size_t)gr * ldc + gc] = v;
                } else if (OUT == 1) {
                    if (gc < qscale_cols) v *= 0.125f;
                    Cb[(size_t)gr * ldc + gc] = f2bf(v);
                } else {
                    float gg = 1.f;
                    if (mod) gg = mod[(size_t)(gr / ntok) * modstride + gchunk * D + gc];
                    Cf[(size_t)gr * ldc + gc] += gg * v;
                }
            }
        }
    }
}

// ---------------- MFMA GEMM: TM=256 x TN=128, 8 waves, 512 threads ----------
// bf16 out only (qscale for leading cols, optional gelu). M must be %256.
template<int ACT>
__global__ __launch_bounds__(512, 4) void gemm_lds256(
    const unsigned short* __restrict__ A,
    const unsigned short* __restrict__ BT,
    const float* __restrict__ bias,
    unsigned short* __restrict__ Cb, int ldc,
    int K, int qscale_cols)
{
    __shared__ unsigned short As[2][256 * 32];
    __shared__ unsigned short Bs[2][128 * 32];
    int tid = threadIdx.x, w = tid >> 6, lane = tid & 63;
    int row0 = blockIdx.y * 256, col0 = blockIdx.x * 128;
    int wrow = (w >> 1) * 64, wcol = (w & 1) * 64;
    int lr = lane & 15, g = lane >> 4;
    f32x4 acc[4][4] = {};

    int ra[2], ka[2], la[2];
    #pragma unroll
    for (int i = 0; i < 2; ++i) {
        int off = tid * 16 + i * 8192;          // A: 16 KB (256 rows x 64 B)
        int row = off >> 6;
        int slot = (off >> 4) & 3;
        ra[i] = row;
        ka[i] = (slot ^ ((row >> 1) & 3)) * 8;
        la[i] = off >> 1;
    }
    int rb, kb, lb;
    {
        int off = tid * 16;                      // B: 8 KB (128 rows x 64 B)
        int row = off >> 6;
        int slot = (off >> 4) & 3;
        rb = row;
        kb = (slot ^ ((row >> 1) & 3)) * 8;
        lb = off >> 1;
    }
    int nt = K >> 5, cur = 0;
    #pragma unroll
    for (int i = 0; i < 2; ++i)
        gl16(A + (size_t)(row0 + ra[i]) * K + ka[i], &As[0][la[i]]);
    gl16(BT + (size_t)(col0 + rb) * K + kb, &Bs[0][lb]);

    for (int t = 0; t < nt; ++t) {
        __syncthreads();
        if (t + 1 < nt) {
            int k0 = (t + 1) << 5;
            #pragma unroll
            for (int i = 0; i < 2; ++i)
                gl16(A + (size_t)(row0 + ra[i]) * K + k0 + ka[i], &As[cur ^ 1][la[i]]);
            gl16(BT + (size_t)(col0 + rb) * K + k0 + kb, &Bs[cur ^ 1][lb]);
        }
        short8v av[4], bv[4];
        #pragma unroll
        for (int mr = 0; mr < 4; ++mr) {
            int row = wrow + mr * 16 + lr;
            av[mr] = *(const short8v*)&As[cur][row * 32 + (g ^ ((row >> 1) & 3)) * 8];
        }
        #pragma unroll
        for (int nc = 0; nc < 4; ++nc) {
            int row = wcol + nc * 16 + lr;
            bv[nc] = *(const short8v*)&Bs[cur][row * 32 + (g ^ ((row >> 1) & 3)) * 8];
        }
        #pragma unroll
        for (int mr = 0; mr < 4; ++mr)
            #pragma unroll
            for (int nc = 0; nc < 4; ++nc)
                acc[mr][nc] = __builtin_amdgcn_mfma_f32_16x16x32_bf16(
                    av[mr], bv[nc], acc[mr][nc], 0, 0, 0);
        cur ^= 1;
    }
    int rbase = g * 4;
    int wrow2 = (w >> 1) * 64;   // M offset within 256 uses waves 0..7 -> (w>>1)*64 covers 0..192
    (void)wrow2;
    #pragma unroll
    for (int mr = 0; mr < 4; ++mr) {
        #pragma unroll
        for (int nc = 0; nc < 4; ++nc) {
            int gc = col0 + wcol + nc * 16 + lr;
            float bb = bias ? bias[gc] : 0.f;
            #pragma unroll
            for (int r = 0; r < 4; ++r) {
                int gr = row0 + wrow + mr * 16 + rbase + r;
                float v = acc[mr][nc][r] + bb;
                if (ACT == 2) v = geluf(v);
                if (gc < qscale_cols) v *= 0.125f;
                Cb[(size_t)gr * ldc + gc] = f2bf(v);
            }
        }
    }
}

// ---------------- MoE gathered MFMA GEMM ----------
template<int PHASE>
__global__ __launch_bounds__(256) void moe_lds(
    const unsigned short* __restrict__ A,
    const unsigned short* __restrict__ BTconv,
    float* __restrict__ Cf, unsigned short* __restrict__ Cb,
    const int* __restrict__ cnt, const int* __restrict__ list,
    const float* __restrict__ gval, int RT, int egbase)
{
    constexpr int K  = (PHASE == 1) ? 768 : 3072;
    constexpr int TN = (PHASE == 1) ? 128 : 64;
    constexpr int NCF = TN / 32;
    constexpr int NBS = TN / 64;
    int egl = blockIdx.y / RT, rt = blockIdx.y % RT;
    int eg = egbase + egl;
    int c0 = cnt[eg];
    int mbase = rt * 128;
    if (mbase >= c0) return;
    int mcount = min(128, c0 - mbase);
    __shared__ int toks[128];
    int tid = threadIdx.x, w = tid >> 6, lane = tid & 63;
    if (tid < 128) toks[tid] = list[eg * MAXTOK + mbase + min(tid, mcount - 1)];
    __syncthreads();

    __shared__ unsigned short As[2][128 * 32];
    __shared__ unsigned short Bs[2][TN * 32];
    const unsigned short* BT = BTconv + (size_t)egl * (768 * 3072);
    int col0 = blockIdx.x * TN;
    int wrow = (w >> 1) * 64, wcol = (w & 1) * (TN / 2);
    int lr = lane & 15, g = lane >> 4;
    f32x4 acc[4][NCF] = {};

    int ra[2], ka[2], la[2], tok_s[2];
    #pragma unroll
    for (int i = 0; i < 2; ++i) {
        int off = tid * 16 + i * 4096;
        int row = off >> 6;
        int slot = (off >> 4) & 3;
        ra[i] = row;
        ka[i] = (slot ^ ((row >> 1) & 3)) * 8;
        la[i] = off >> 1;
        tok_s[i] = toks[row];
    }
    int nt = K >> 5, cur = 0;
    #pragma unroll
    for (int i = 0; i < 2; ++i)
        gl16(A + (size_t)tok_s[i] * K + ka[i], &As[0][la[i]]);
    #pragma unroll
    for (int i = 0; i < NBS; ++i)
        gl16(BT + (size_t)(col0 + ra[i]) * K + ka[i], &Bs[0][la[i]]);

    for (int t = 0; t < nt; ++t) {
        __syncthreads();
        if (t + 1 < nt) {
            int k0 = (t + 1) << 5;
            #pragma unroll
            for (int i = 0; i < 2; ++i)
                gl16(A + (size_t)tok_s[i] * K + k0 + ka[i], &As[cur ^ 1][la[i]]);
            #pragma unroll
            for (int i = 0; i < NBS; ++i)
                gl16(BT + (size_t)(col0 + ra[i]) * K + k0 + ka[i], &Bs[cur ^ 1][la[i]]);
        }
        short8v av[4], bv[NCF];
        #pragma unroll
        for (int mr = 0; mr < 4; ++mr) {
            int row = wrow + mr * 16 + lr;
            av[mr] = *(const short8v*)&As[cur][row * 32 + (g ^ ((row >> 1) & 3)) * 8];
        }
        #pragma unroll
        for (int nc = 0; nc < NCF; ++nc) {
            int row = wcol + nc * 16 + lr;
            bv[nc] = *(const short8v*)&Bs[cur][row * 32 + (g ^ ((row >> 1) & 3)) * 8];
        }
        #pragma unroll
        for (int mr = 0; mr < 4; ++mr)
            #pragma unroll
            for (int nc = 0; nc < NCF; ++nc)
                acc[mr][nc] = __builtin_amdgcn_mfma_f32_16x16x32_bf16(
                    av[mr], bv[nc], acc[mr][nc], 0, 0, 0);
        cur ^= 1;
    }
    int rbase = g * 4;
    #pragma unroll
    for (int mr = 0; mr < 4; ++mr) {
        #pragma unroll
        for (int r = 0; r < 4; ++r) {
            int m = wrow + mr * 16 + rbase + r;
            if (m >= mcount) continue;
            int tok = toks[m];
            #pragma unroll
            for (int nc = 0; nc < NCF; ++nc) {
                int gc = col0 + wcol + nc * 16 + lr;
                float v = acc[mr][nc][r];
                if (PHASE == 1) Cb[(size_t)tok * 3072 + gc] = f2bf(geluf(v));
                else            Cf[(size_t)tok * 768 + gc] += gval[tok] * v;
            }
        }
    }
}

// ---------------- LayerNorm -> bf16 ----------------
__global__ __launch_bounds__(256) void ln_kernel(
    const float* __restrict__ X, unsigned short* __restrict__ Y, int R, int ntok,
    const float* __restrict__ mod, int modstride, int shift_chunk, int scale_chunk)
{
    int r = blockIdx.x;
    if (r >= R) return;
    const float* xr = X + (size_t)r * D;
    int tid = threadIdx.x;
    int lane = tid & 63, wid = tid >> 6;
    float v0 = xr[tid], v1 = xr[tid + 256], v2 = xr[tid + 512];
    float s = v0 + v1 + v2;
    float s2 = v0 * v0 + v1 * v1 + v2 * v2;
    for (int off = 32; off > 0; off >>= 1) {
        s += __shfl_xor(s, off, 64);
        s2 += __shfl_xor(s2, off, 64);
    }
    __shared__ float shs[4], shs2[4];
    if (lane == 0) { shs[wid] = s; shs2[wid] = s2; }
    __syncthreads();
    float tot = shs[0] + shs[1] + shs[2] + shs[3];
    float tot2 = shs2[0] + shs2[1] + shs2[2] + shs2[3];
    float mu = tot * (1.f / 768.f);
    float var = tot2 * (1.f / 768.f) - mu * mu;
    float rs = rsqrtf(var + 1e-6f);
    int bb = r / ntok;
    float vv[3] = {v0, v1, v2};
    #pragma unroll
    for (int j = 0; j < 3; ++j) {
        int col = tid + j * 256;
        float nrm = (vv[j] - mu) * rs;
        float y = nrm;
        if (mod) {
            float scv = mod[(size_t)bb * modstride + scale_chunk * D + col];
            float shv = mod[(size_t)bb * modstride + shift_chunk * D + col];
            y = nrm * (1.f + scv) + shv;
        }
        Y[(size_t)r * D + col] = f2bf(y);
    }
}

// ---------------- MFMA flash attention (V transposed in-kernel) ----------
__global__ __launch_bounds__(512) void attn_mfma(
    const unsigned short* __restrict__ Qp, int ldq, int qoff,
    const unsigned short* __restrict__ Kp, int ldk, int koff,
    const unsigned short* __restrict__ Vp, int ldv, int voff,
    unsigned short* __restrict__ O, int ldo,
    int Nq, int Nkv)
{
    __shared__ unsigned short Qs[128 * 64];
    __shared__ unsigned short Ks[64 * 64];
    __shared__ unsigned short Vs[64 * 64];
    __shared__ unsigned short Ps[128 * 64];
    int h = blockIdx.y, b = blockIdx.z, q0 = blockIdx.x * 128;
    int tid = threadIdx.x, w = tid >> 6, lane = tid & 63;
    int wrow = w * 16;
    int lr = lane & 15, g = lane >> 4;

    {
        int srow = tid >> 2, sc = (tid & 3) * 16;
        int gr = min(q0 + srow, Nq - 1);
        const unsigned short* qp = Qp + (size_t)(b * Nq + gr) * ldq + qoff + h * 64 + sc;
        short8v v0 = *(const short8v*)qp, v1 = *(const short8v*)(qp + 8);
        int s0 = sc >> 3;
        *(short8v*)&Qs[srow * 64 + (s0 ^ (srow & 7)) * 8] = v0;
        *(short8v*)&Qs[srow * 64 + ((s0 + 1) ^ (srow & 7)) * 8] = v1;
    }
    float m_r[4] = {-1e30f, -1e30f, -1e30f, -1e30f};
    float l_r[4] = {};
    f32x4 acc0 = {}, acc1 = {}, acc2 = {}, acc3 = {};

    for (int kv0 = 0; kv0 < Nkv; kv0 += 64) {
        {
            int t2 = tid & 255;
            int srow = t2 >> 2, sc = (t2 & 3) * 16;
            int gc = min(kv0 + srow, Nkv - 1);
            if (tid < 256) {
                const unsigned short* kp = Kp + (size_t)(b * Nkv + gc) * ldk + koff + h * 64 + sc;
                short8v v0 = *(const short8v*)kp, v1 = *(const short8v*)(kp + 8);
                int s0 = sc >> 3;
                *(short8v*)&Ks[srow * 64 + (s0 ^ (srow & 7)) * 8] = v0;
                *(short8v*)&Ks[srow * 64 + ((s0 + 1) ^ (srow & 7)) * 8] = v1;
            } else {
                const unsigned short* vp = Vp + (size_t)(b * Nkv + gc) * ldv + voff + h * 64 + sc;
                #pragma unroll
                for (int j = 0; j < 16; ++j) {
                    int d = sc + j;
                    Vs[d * 64 + (((srow >> 3) ^ (d & 7)) * 8) + (srow & 7)] = vp[j];
                }
            }
        }
        __syncthreads();
        short8v aq0, aq1;
        {
            int row = wrow + lr;
            aq0 = *(const short8v*)&Qs[row * 64 + ((0 + g) ^ (row & 7)) * 8];
            aq1 = *(const short8v*)&Qs[row * 64 + ((4 + g) ^ (row & 7)) * 8];
        }
        f32x4 sf[4];
        #pragma unroll
        for (int nc = 0; nc < 4; ++nc) {
            int row = nc * 16 + lr;
            short8v bk0 = *(const short8v*)&Ks[row * 64 + ((0 + g) ^ (row & 7)) * 8];
            short8v bk1 = *(const short8v*)&Ks[row * 64 + ((4 + g) ^ (row & 7)) * 8];
            f32x4 z = {};
            z = __builtin_amdgcn_mfma_f32_16x16x32_bf16(aq0, bk0, z, 0, 0, 0);
            sf[nc] = __builtin_amdgcn_mfma_f32_16x16x32_bf16(aq1, bk1, z, 0, 0, 0);
        }
        bool val0 = (kv0 + 0 * 16 + lr) < Nkv;
        bool val1 = (kv0 + 1 * 16 + lr) < Nkv;
        bool val2 = (kv0 + 2 * 16 + lr) < Nkv;
        bool val3 = (kv0 + 3 * 16 + lr) < Nkv;
        float fs[4];
        #pragma unroll
        for (int r = 0; r < 4; ++r) {
            float s0 = val0 ? sf[0][r] : -1e30f;
            float s1 = val1 ? sf[1][r] : -1e30f;
            float s2 = val2 ? sf[2][r] : -1e30f;
            float s3 = val3 ? sf[3][r] : -1e30f;
            float mx = fmaxf(fmaxf(s0, s1), fmaxf(s2, s3));
            mx = fmaxf(mx, __shfl_xor(mx, 1, 64));
            mx = fmaxf(mx, __shfl_xor(mx, 2, 64));
            mx = fmaxf(mx, __shfl_xor(mx, 4, 64));
            mx = fmaxf(mx, __shfl_xor(mx, 8, 64));
            float mn = fmaxf(m_r[r], mx);
            fs[r] = __expf(m_r[r] - mn);
            m_r[r] = mn;
            float p0 = __expf(s0 - mn), p1 = __expf(s1 - mn);
            float p2 = __expf(s2 - mn), p3 = __expf(s3 - mn);
            float rsum = p0 + p1 + p2 + p3;
            rsum += __shfl_xor(rsum, 1, 64);
            rsum += __shfl_xor(rsum, 2, 64);
            rsum += __shfl_xor(rsum, 4, 64);
            rsum += __shfl_xor(rsum, 8, 64);
            l_r[r] = l_r[r] * fs[r] + rsum;
            int ql = wrow + g * 4 + r;
            int base = ql * 64;
            int x7 = ql & 7;
            Ps[base + (((0 * 16 + lr) >> 3) ^ x7) * 8 + (lr & 7)] = f2bf(p0);
            Ps[base + (((1 * 16 + lr) >> 3) ^ x7) * 8 + (lr & 7)] = f2bf(p1);
            Ps[base + (((2 * 16 + lr) >> 3) ^ x7) * 8 + (lr & 7)] = f2bf(p2);
            Ps[base + (((3 * 16 + lr) >> 3) ^ x7) * 8 + (lr & 7)] = f2bf(p3);
            acc0[r] *= fs[r]; acc1[r] *= fs[r]; acc2[r] *= fs[r]; acc3[r] *= fs[r];
        }
        __syncthreads();
        short8v ap0, ap1;
        {
            int row = wrow + lr;
            ap0 = *(const short8v*)&Ps[row * 64 + ((0 + g) ^ (row & 7)) * 8];
            ap1 = *(const short8v*)&Ps[row * 64 + ((4 + g) ^ (row & 7)) * 8];
        }
        {
            int row = 0 * 16 + lr;
            short8v b0 = *(const short8v*)&Vs[row * 64 + ((0 + g) ^ (row & 7)) * 8];
            short8v b1 = *(const short8v*)&Vs[row * 64 + ((4 + g) ^ (row & 7)) * 8];
            acc0 = __builtin_amdgcn_mfma_f32_16x16x32_bf16(ap0, b0, acc0, 0, 0, 0);
            acc0 = __builtin_amdgcn_mfma_f32_16x16x32_bf16(ap1, b1, acc0, 0, 0, 0);
        }
        {
            int row = 1 * 16 + lr;
            short8v b0 = *(const short8v*)&Vs[row * 64 + ((0 + g) ^ (row & 7)) * 8];
            short8v b1 = *(const short8v*)&Vs[row * 64 + ((4 + g) ^ (row & 7)) * 8];
            acc1 = __builtin_amdgcn_mfma_f32_16x16x32_bf16(ap0, b0, acc1, 0, 0, 0);
            acc1 = __builtin_amdgcn_mfma_f32_16x16x32_bf16(ap1, b1, acc1, 0, 0, 0);
        }
        {
            int row = 2 * 16 + lr;
            short8v b0 = *(const short8v*)&Vs[row * 64 + ((0 + g) ^ (row & 7)) * 8];
            short8v b1 = *(const short8v*)&Vs[row * 64 + ((4 + g) ^ (row & 7)) * 8];
            acc2 = __builtin_amdgcn_mfma_f32_16x16x32_bf16(ap0, b0, acc2, 0, 0, 0);
            acc2 = __builtin_amdgcn_mfma_f32_16x16x32_bf16(ap1, b1, acc2, 0, 0, 0);
        }
        {
            int row = 3 * 16 + lr;
            short8v b0 = *(const short8v*)&Vs[row * 64 + ((0 + g) ^ (row & 7)) * 8];
            short8v b1 = *(const short8v*)&Vs[row * 64 + ((4 + g) ^ (row & 7)) * 8];
            acc3 = __builtin_amdgcn_mfma_f32_16x16x32_bf16(ap0, b0, acc3, 0, 0, 0);
            acc3 = __builtin_amdgcn_mfma_f32_16x16x32_bf16(ap1, b1, acc3, 0, 0, 0);
        }
        __syncthreads();
    }
    #pragma unroll
    for (int r = 0; r < 4; ++r) {
        int ql = wrow + g * 4 + r;
        if (q0 + ql >= Nq) continue;
        float rl = 1.f / l_r[r];
        unsigned short* op = O + (size_t)(b * Nq + q0 + ql) * ldo + h * 64 + lr;
        op[0]  = f2bf(acc0[r] * rl);
        op[16] = f2bf(acc1[r] * rl);
        op[32] = f2bf(acc2[r] * rl);
        op[48] = f2bf(acc3[r] * rl);
    }
}

// ---------------- MoE router ----------------
__global__ __launch_bounds__(64) void router_kernel(
    const unsigned short* __restrict__ X, const float* __restrict__ WrBase,
    int* __restrict__ idx, float* __restrict__ gval)
{
    int tkn = blockIdx.x; int lane = threadIdx.x;
    int grp = (tkn >= 768) ? 2 : (tkn >= 512 ? 1 : 0);
    const float* Wr = WrBase + (size_t)grp * D * NEXP;
    const unsigned short* xr = X + (size_t)tkn * D;
    float p0 = 0, p1 = 0, p2 = 0, p3 = 0;
    for (int dd = lane; dd < D; dd += 64) {
        float xv = bf2f(xr[dd]);
        const float* wq = Wr + dd * 4;
        p0 += xv * wq[0]; p1 += xv * wq[1]; p2 += xv * wq[2]; p3 += xv * wq[3];
    }
    for (int off = 32; off > 0; off >>= 1) {
        p0 += __shfl_xor(p0, off, 64); p1 += __shfl_xor(p1, off, 64);
        p2 += __shfl_xor(p2, off, 64); p3 += __shfl_xor(p3, off, 64);
    }
    if (lane == 0) {
        float best = p0; int e = 0;
        if (p1 > best) { best = p1; e = 1; }
        if (p2 > best) { best = p2; e = 2; }
        if (p3 > best) { best = p3; e = 3; }
        float sum = expf(p0 - best) + expf(p1 - best) + expf(p2 - best) + expf(p3 - best);
        idx[tkn] = grp * 4 + e;
        gval[tkn] = 1.f / sum;
    }
}

__global__ __launch_bounds__(256) void scatter_kernel(
    const int* __restrict__ idx, int* __restrict__ cnt,
    int* __restrict__ list, int ntok)
{
    __shared__ int lcnt[12];
    int tid = threadIdx.x;
    if (tid < 12) lcnt[tid] = 0;
    __syncthreads();
    for (int i = tid; i < ntok; i += 256) {
        int e = idx[i];
        int pos = atomicAdd(&lcnt[e], 1);
        list[e * MAXTOK + pos] = i;
    }
    __syncthreads();
    if (tid < 12) cnt[tid] = lcnt[tid];
}

// ---------------- concat ----------------
__global__ void concat_kernel(const float* __restrict__ traj, const float* __restrict__ a,
                              const float* __restrict__ bg, const float* __restrict__ cg,
                              float* __restrict__ x, int total)
{
    int i = blockIdx.x * blockDim.x + threadIdx.x;
    if (i >= total) return;
    int col = i % D;
    int r = i / D;
    int n = r % NTOK, b = r / NTOK;
    float v;
    if (n < 256)      v = traj[((size_t)b * 256 + n) * D + col];
    else if (n < 320) v = a[((size_t)b * 64 + (n - 256)) * D + col];
    else if (n < 352) v = bg[((size_t)b * 32 + (n - 320)) * D + col];
    else              v = cg[((size_t)b * 192 + (n - 352)) * D + col];
    x[i] = v;
}

// ---------------- output head ----------------
__global__ void head_prep(const float* __restrict__ W, unsigned short* __restrict__ WT14) {
    int i = blockIdx.x * blockDim.x + threadIdx.x;
    if (i >= 14 * 768) return;
    int o = i / 768, d = i % 768;
    WT14[i] = f2bf(W[d * 14 + o]);
}

__global__ __launch_bounds__(64) void head_kernel(
    const unsigned short* __restrict__ lnb, const unsigned short* __restrict__ WT14,
    const float* __restrict__ bias, float* __restrict__ out)
{
    int r = blockIdx.x;
    int b = r >> 8, n = r & 255;
    const unsigned short* hrow = lnb + (size_t)(b * NTOK + n) * D;
    int l = threadIdx.x;
    if (l >= 56) return;
    int o = l >> 2, p = l & 3;
    const unsigned short* hp = hrow + p * 192;
    const unsigned short* wp = WT14 + o * 768 + p * 192;
    float acc = 0.f;
    for (int i = 0; i < 192; i += 8) {
        short8v hv = *(const short8v*)(hp + i);
        short8v wv = *(const short8v*)(wp + i);
        #pragma unroll
        for (int j = 0; j < 8; ++j)
            acc += bf2f((unsigned short)hv[j]) * bf2f((unsigned short)wv[j]);
    }
    acc += __shfl_xor(acc, 1, 64);
    acc += __shfl_xor(acc, 2, 64);
    if (p == 0) out[(size_t)r * 14 + o] = acc + bias[o];
}

// ---------------- host helpers ----------------
static inline void tcvt(const float* W, unsigned short* WT, int K, int N, int z, hipStream_t s) {
    transpose_cvt<<<dim3(N / 64, K / 64, z), 256, 0, s>>>(W, WT, K, N);
}
static inline void g_bf(int act, const unsigned short* A, const unsigned short* BT,
                        const float* bias, unsigned short* C, int ldc,
                        int M, int N, int K, int qcols, hipStream_t s)
{
    if (M % 256 == 0 && N % 128 == 0 && N >= 2304) {
        dim3 g(N / 128, M / 256);
        if (act == 2) gemm_lds256<2><<<g, 512, 0, s>>>(A, BT, bias, C, ldc, K, qcols);
        else          gemm_lds256<0><<<g, 512, 0, s>>>(A, BT, bias, C, ldc, K, qcols);
        return;
    }
    if (N != 768) {
        dim3 g(N / 128, M / 128);
        if (act == 2) gemm_lds<2, 1, 128><<<g, 256, 0, s>>>(A, BT, bias, nullptr, C, ldc, K, qcols, nullptr, 0, 0, 1, 1 << 30);
        else          gemm_lds<0, 1, 128><<<g, 256, 0, s>>>(A, BT, bias, nullptr, C, ldc, K, qcols, nullptr, 0, 0, 1, 1 << 30);
    } else {
        dim3 g(N / 64, M / 128);
        if (act == 2) gemm_lds<2, 1, 64><<<g, 256, 0, s>>>(A, BT, bias, nullptr, C, ldc, K, qcols, nullptr, 0, 0, 1, 1 << 30);
        else          gemm_lds<0, 1, 64><<<g, 256, 0, s>>>(A, BT, bias, nullptr, C, ldc, K, qcols, nullptr, 0, 0, 1, 1 << 30);
    }
}
static inline void g_res(const unsigned short* A, const unsigned short* BT,
                         const float* bias, float* C, int ldc, int M, int N, int K,
                         const float* mod, int modstride, int gchunk, int ntok, hipStream_t s)
{
    dim3 g(N / 64, M / 128);
    gemm_lds<0, 2, 64><<<g, 256, 0, s>>>(A, BT, bias, C, nullptr, ldc, K, 0, mod, modstride, gchunk, ntok, 1 << 30);
}

extern "C" void kernel_launch(void* const* d_in, const int* in_sizes, int n_in,
                              void* d_out, int out_size, void* d_ws, size_t ws_size,
                              hipStream_t stream)
{
    const float* x_traj   = (const float*)d_in[0];
    const int*   t_arr    = (const int*)d_in[1];
    const float* tokA     = (const float*)d_in[2];
    const float* tokB     = (const float*)d_in[3];
    const float* tokC     = (const float*)d_in[4];
    const float* W_traj   = (const float*)d_in[5];
    const float* b_traj   = (const float*)d_in[6];
    const float* W_ftime  = (const float*)d_in[7];
    const float* Wt1      = (const float*)d_in[8];
    const float* bt1      = (const float*)d_in[9];
    const float* Wt2      = (const float*)d_in[10];
    const float* bt2      = (const float*)d_in[11];
    const float* moe_attn = (const float*)d_in[12];
    const float* moe_rout = (const float*)d_in[13];
    const float* moe_W1   = (const float*)d_in[14];
    const float* moe_W2   = (const float*)d_in[15];
    const float* dit_qkv  = (const float*)d_in[16];
    const float* dit_qkvb = (const float*)d_in[17];
    const float* dit_proj = (const float*)d_in[18];
    const float* dit_projb= (const float*)d_in[19];
    const float* dit_mlp1 = (const float*)d_in[20];
    const float* dit_mlp1b= (const float*)d_in[21];
    const float* dit_mlp2 = (const float*)d_in[22];
    const float* dit_mlp2b= (const float*)d_in[23];
    const float* dit_ada  = (const float*)d_in[24];
    const float* dit_adab = (const float*)d_in[25];
    const float* out_adaW = (const float*)d_in[26];
    const float* out_adab = (const float*)d_in[27];
    const float* out_W    = (const float*)d_in[28];
    const float* out_b    = (const float*)d_in[29];
    float* out = (float*)d_out;
    float* ws = (float*)d_ws;

    const size_t o_cnt  = 14336;
    const size_t o_idx  = 14400;
    const size_t o_gval = 16704;
    const size_t o_list = 19008;
    const size_t o_traj = 66624;
    const size_t o_a    = 1639488;
    const size_t o_bg   = 2032704;
    const size_t o_cg   = 2229312;
    const size_t o_x    = 3408960;
    const size_t o_lnb  = 6751296;
    const size_t o_qkvb = 8422464;
    const size_t o_attnO= 13435968;
    const size_t o_h    = 15107136;
    const size_t o_kvbf = 23561280;
    const size_t o_wt   = 24151104;
    const size_t o_wt14 = 28869696;
    const size_t o_tembP= 28875072;
    const size_t o_ub   = 28891456;
    const size_t o_scb  = 28940608;
    const size_t o_mod  = o_traj;
    const size_t o_mod2 = o_traj + 221184;

    const size_t o_wqkv  = 29000000;
    const size_t o_wproj = 34308416;
    const size_t o_wmlp1 = 36077888;
    const size_t o_wmlp2 = 43155776;
    const size_t o_wada  = 50233664;
    const size_t o_wada2 = 60850496;
    const size_t o_wcross= 61440320;
    const size_t o_wmoe1 = 66158912;
    const size_t o_wmoe2 = 94470464;
    const bool bigw = ws_size >= (size_t)123000000 * 4;

    int* cnt_p  = (int*)(ws + o_cnt);
    int* idx_p  = (int*)(ws + o_idx);
    int* list_p = (int*)(ws + o_list);
    float* gval_p = ws + o_gval;
    unsigned short* lnb  = (unsigned short*)(ws + o_lnb);
    unsigned short* qkvb = (unsigned short*)(ws + o_qkvb);
    unsigned short* attO = (unsigned short*)(ws + o_attnO);
    unsigned short* hbuf = (unsigned short*)(ws + o_h);
    unsigned short* kvbf = (unsigned short*)(ws + o_kvbf);
    unsigned short* wt   = (unsigned short*)(ws + o_wt);
    unsigned short* wt14 = (unsigned short*)(ws + o_wt14);
    unsigned short* tembP= (unsigned short*)(ws + o_tembP);
    unsigned short* ub   = (unsigned short*)(ws + o_ub);
    unsigned short* scb  = (unsigned short*)(ws + o_scb);
    unsigned short* wqkvS = (unsigned short*)(ws + o_wqkv);
    unsigned short* wprojS= (unsigned short*)(ws + o_wproj);
    unsigned short* wmlp1S= (unsigned short*)(ws + o_wmlp1);
    unsigned short* wmlp2S= (unsigned short*)(ws + o_wmlp2);
    unsigned short* wadaS = (unsigned short*)(ws + o_wada);
    unsigned short* wada2S= (unsigned short*)(ws + o_wada2);
    unsigned short* wcrossS=(unsigned short*)(ws + o_wcross);
    unsigned short* wmoe1S= (unsigned short*)(ws + o_wmoe1);
    unsigned short* wmoe2S= (unsigned short*)(ws + o_wmoe2);
    unsigned short* c_q  = qkvb;
    unsigned short* c_kv = qkvb + 1179648;

    const size_t WSZ = (size_t)D * D;

    gemm_act<0><<<dim3(12, 32), 256, 0, stream>>>(x_traj, 7, W_traj, D, b_traj,
                                                  ws + o_traj, D, BATCH * TTRAJ, D, 7);
    add_ftime<<<(BATCH * TTRAJ * D + 255) / 256, 256, 0, stream>>>(ws + o_traj, W_ftime, BATCH * TTRAJ * D);

    hipError_t e1 = hipMemcpyAsync(ws + o_a, tokA, (size_t)BATCH * NA * D * 4, hipMemcpyDeviceToDevice, stream); (void)e1;
    hipError_t e2 = hipMemcpyAsync(ws + o_bg, tokB, (size_t)BATCH * NB * D * 4, hipMemcpyDeviceToDevice, stream); (void)e2;
    hipError_t e3 = hipMemcpyAsync(ws + o_cg, tokC, (size_t)BATCH * NC * D * 4, hipMemcpyDeviceToDevice, stream); (void)e3;
    head_prep<<<42, 256, 0, stream>>>(out_W, wt14);

    if (bigw) {
        tcvt(dit_qkv,  wqkvS,  D, 3 * D, DEPTH, stream);
        tcvt(dit_proj, wprojS, D, D, DEPTH, stream);
        tcvt(dit_mlp1, wmlp1S, D, FF, DEPTH, stream);
        tcvt(dit_mlp2, wmlp2S, FF, D, DEPTH, stream);
        tcvt(dit_ada,  wadaS,  D, 6 * D, DEPTH, stream);
        tcvt(out_adaW, wada2S, D, 2 * D, 1, stream);
        tcvt(moe_attn, wcrossS, D, D, NBLK * 2 * 4, stream);
        tcvt(moe_W1,   wmoe1S, D, FF, NBLK * 3 * NEXP, stream);
        tcvt(moe_W2,   wmoe2S, FF, D, NBLK * 3 * NEXP, stream);
    }

    timestep_kernel<<<128, 256, 0, stream>>>(t_arr, tembP);
    tcvt(Wt1, wt, 256, D, 1, stream);
    gemm_lds<1, 1, 64><<<dim3(12, 1), 256, 0, stream>>>(
        tembP, wt, bt1, nullptr, ub, D, 256, 0, nullptr, 0, 0, 1, 128);
    tcvt(Wt2, wt, D, D, 1, stream);
    gemm_lds<1, 1, 64><<<dim3(12, 1), 256, 0, stream>>>(
        ub, wt, bt2, nullptr, scb, D, D, 0, nullptr, 0, 0, 1, 128);

    for (int i = 0; i < NBLK; ++i) {
        {
            const unsigned short* Wc;
            if (bigw) Wc = wcrossS + (size_t)(i * 2 + 0) * 4 * WSZ;
            else { tcvt(moe_attn + (size_t)(i * 2 + 0) * 4 * WSZ, wt, D, D, 4, stream); Wc = wt; }
            ln_kernel<<<BATCH * NC, 256, 0, stream>>>(ws + o_cg, lnb, BATCH * NC, 1, nullptr, 0, 0, 0);
            g_bf(0, lnb, Wc, nullptr, c_q, D, BATCH * NC, D, D, 768, stream);
            cvt_bf16<<<(BATCH * NA * D / 8 + 255) / 256, 256, 0, stream>>>(ws + o_a, kvbf, BATCH * NA * D / 8);
            g_bf(0, kvbf, Wc + 1 * WSZ, nullptr, c_kv, 2 * D, BATCH * NA, 2 * D, D, 0, stream);
            attn_mfma<<<dim3((NC + 127) / 128, NH, BATCH), 512, 0, stream>>>(
                c_q, D, 0, c_kv, 2 * D, 0, c_kv, 2 * D, D, attO, D, NC, NA);
            g_res(attO, Wc + 3 * WSZ, nullptr, ws + o_cg, D, BATCH * NC, D, D, nullptr, 0, 0, 1, stream);
        }
        {
            const unsigned short* Wc;
            if (bigw) Wc = wcrossS + (size_t)(i * 2 + 1) * 4 * WSZ;
            else { tcvt(moe_attn + (size_t)(i * 2 + 1) * 4 * WSZ, wt, D, D, 4, stream); Wc = wt; }
            ln_kernel<<<BATCH * NB, 256, 0, stream>>>(ws + o_bg, lnb, BATCH * NB, 1, nullptr, 0, 0, 0);
            g_bf(0, lnb, Wc, nullptr, c_q, D, BATCH * NB, D, D, 768, stream);
            cvt_bf16<<<(BATCH * NC * D / 8 + 255) / 256, 256, 0, stream>>>(ws + o_cg, kvbf, BATCH * NC * D / 8);
            g_bf(0, kvbf, Wc + 1 * WSZ, nullptr, c_kv, 2 * D, BATCH * NC, 2 * D, D, 0, stream);
            attn_mfma<<<dim3(1, NH, BATCH), 512, 0, stream>>>(
                c_q, D, 0, c_kv, 2 * D, 0, c_kv, 2 * D, D, attO, D, NB, NC);
            g_res(attO, Wc + 3 * WSZ, nullptr, ws + o_bg, D, BATCH * NB, D, D, nullptr, 0, 0, 1, stream);
        }
        ln_kernel<<<MOER, 256, 0, stream>>>(ws + o_a, lnb, MOER, 1, nullptr, 0, 0, 0);
        router_kernel<<<MOER, 64, 0, stream>>>(lnb, moe_rout + (size_t)(i * 3) * D * NEXP, idx_p, gval_p);
        scatter_kernel<<<1, 256, 0, stream>>>(idx_p, cnt_p, list_p, MOER);
        const int RT = 12;
        if (bigw) {
            moe_lds<1><<<dim3(24, 12 * RT), 256, 0, stream>>>(
                lnb, wmoe1S + (size_t)(i * 3) * NEXP * D * FF, nullptr, hbuf,
                cnt_p, list_p, gval_p, RT, 0);
            moe_lds<2><<<dim3(12, 12 * RT), 256, 0, stream>>>(
                hbuf, wmoe2S + (size_t)(i * 3) * NEXP * D * FF, ws + o_a, nullptr,
                cnt_p, list_p, gval_p, RT, 0);
        } else {
            for (int g = 0; g < 3; ++g) {
                tcvt(moe_W1 + (size_t)(i * 3 + g) * NEXP * D * FF, wt, D, FF, NEXP, stream);
                moe_lds<1><<<dim3(24, 4 * RT), 256, 0, stream>>>(
                    lnb, wt, nullptr, hbuf, cnt_p, list_p, gval_p, RT, g * 4);
                tcvt(moe_W2 + (size_t)(i * 3 + g) * NEXP * FF * D, wt, FF, D, NEXP, stream);
                moe_lds<2><<<dim3(12, 4 * RT), 256, 0, stream>>>(
                    hbuf, wt, ws + o_a, nullptr, cnt_p, list_p, gval_p, RT, g * 4);
            }
        }
    }

    concat_kernel<<<(BATCH * NTOK * D + 255) / 256, 256, 0, stream>>>(
        ws + o_traj, ws + o_a, ws + o_bg, ws + o_cg, ws + o_x, BATCH * NTOK * D);

    if (bigw) {
        gemm_lds<0, 0, 128><<<dim3(36, 1, DEPTH), 256, 0, stream>>>(
            scb, wadaS, dit_adab, ws + o_mod, nullptr, 6 * D, D, 0,
            nullptr, 0, 0, 1, 8,
            (size_t)D * 6 * D, (size_t)6 * D, (size_t)8 * 6 * D);
        gemm_lds<0, 0, 128><<<dim3(12, 1), 256, 0, stream>>>(
            scb, wada2S, out_adab, ws + o_mod2, nullptr, 2 * D, D, 0, nullptr, 0, 0, 1, 8);
    } else {
        for (int i = 0; i < DEPTH; ++i) {
            tcvt(dit_ada + (size_t)i * D * 6 * D, wt, D, 6 * D, 1, stream);
            gemm_lds<0, 0, 128><<<dim3(36, 1), 256, 0, stream>>>(
                scb, wt, dit_adab + (size_t)i * 6 * D, ws + o_mod + (size_t)i * 8 * 6 * D,
                nullptr, 6 * D, D, 0, nullptr, 0, 0, 1, 8);
        }
        tcvt(out_adaW, wt, D, 2 * D, 1, stream);
        gemm_lds<0, 0, 128><<<dim3(12, 1), 256, 0, stream>>>(
            scb, wt, out_adab, ws + o_mod2, nullptr, 2 * D, D, 0, nullptr, 0, 0, 1, 8);
    }

    const int R = BATCH * NTOK;   // 4352 = 17*256
    for (int i = 0; i < DEPTH; ++i) {
        const float* mod_l = ws + o_mod + (size_t)i * 8 * 6 * D;
        const unsigned short *Wq = nullptr, *Wp = nullptr, *Wm1 = nullptr, *Wm2 = nullptr;
        if (bigw) {
            Wq  = wqkvS  + (size_t)i * D * 3 * D;
            Wp  = wprojS + (size_t)i * D * D;
            Wm1 = wmlp1S + (size_t)i * D * FF;
            Wm2 = wmlp2S + (size_t)i * D * FF;
        }
        ln_kernel<<<R, 256, 0, stream>>>(ws + o_x, lnb, R, NTOK, mod_l, 6 * D, 0, 1);
        if (!bigw) { tcvt(dit_qkv + (size_t)i * D * 3 * D, wt, D, 3 * D, 1, stream); Wq = wt; }
        g_bf(0, lnb, Wq, dit_qkvb + (size_t)i * 3 * D, qkvb, 3 * D, R, 3 * D, D, 768, stream);
        attn_mfma<<<dim3((NTOK + 127) / 128, NH, BATCH), 512, 0, stream>>>(
            qkvb, 3 * D, 0, qkvb, 3 * D, D, qkvb, 3 * D, 2 * D, attO, D, NTOK, NTOK);
        if (!bigw) { tcvt(dit_proj + (size_t)i * D * D, wt, D, D, 1, stream); Wp = wt; }
        g_res(attO, Wp, dit_projb + (size_t)i * D, ws + o_x, D, R, D, D,
              mod_l, 6 * D, 2, NTOK, stream);
        ln_kernel<<<R, 256, 0, stream>>>(ws + o_x, lnb, R, NTOK, mod_l, 6 * D, 3, 4);
        if (!bigw) { tcvt(dit_mlp1 + (size_t)i * D * FF, wt, D, FF, 1, stream); Wm1 = wt; }
        g_bf(2, lnb, Wm1, dit_mlp1b + (size_t)i * FF, hbuf, FF, R, FF, D, 0, stream);
        if (!bigw) { tcvt(dit_mlp2 + (size_t)i * FF * D, wt, FF, D, 1, stream); Wm2 = wt; }
        g_res(hbuf, Wm2, dit_mlp2b + (size_t)i * D, ws + o_x, D, R, D, FF,
              mod_l, 6 * D, 5, NTOK, stream);
    }

    ln_kernel<<<R, 256, 0, stream>>>(ws + o_x, lnb, R, NTOK, ws + o_mod2, 2 * D, 0, 1);
    head_kernel<<<BATCH * TTRAJ, 64, 0, stream>>>(lnb, wt14, out_b, out);
}

// Round 12
// 2355.740 us; speedup vs baseline: 12.3913x; 1.0101x over previous
//
#include <hip/hip_runtime.h>
#include <hip/hip_bf16.h>
#include <math.h>

#define D 768
#define NH 12
#define HD 64
#define NEXP 4
#define FF 3072
#define NBLK 2
#define DEPTH 6
#define NA 64
#define NB 32
#define NC 192
#define BATCH 8
#define TTRAJ 256
#define NTOK 544
#define MAXTOK 1536
#define MOER 2304

typedef __attribute__((ext_vector_type(8))) short short8v;
typedef __attribute__((ext_vector_type(4))) float f32x4;

__device__ __forceinline__ float siluf(float v) { return v / (1.f + expf(-v)); }
__device__ __forceinline__ float geluf(float v) {
    float u = 0.7978845608028654f * (v + 0.044715f * v * v * v);
    return 0.5f * v * (1.f + tanhf(u));
}
__device__ __forceinline__ unsigned short f2bf(float f) {
    union { float f; unsigned u; } v; v.f = f;
    unsigned r = v.u + 0x7fffu + ((v.u >> 16) & 1u);
    return (unsigned short)(r >> 16);
}
__device__ __forceinline__ float bf2f(unsigned short u) {
    union { unsigned u; float f; } v; v.u = ((unsigned)u) << 16; return v.f;
}
__device__ __forceinline__ void gl16(const unsigned short* g, unsigned short* l) {
    __builtin_amdgcn_global_load_lds(
        (const __attribute__((address_space(1))) void*)g,
        (__attribute__((address_space(3))) void*)l, 16, 0, 0);
}

// ---------------- timestep embedding ----------------
__global__ void timestep_kernel(const int* __restrict__ t, unsigned short* __restrict__ tembP) {
    int i = blockIdx.x * blockDim.x + threadIdx.x;
    if (i >= 128 * 256) return;
    int b = i >> 8, j = i & 255;
    float v = 0.f;
    if (b < BATCH) {
        int jj = (j & 127);
        float freq = expf(-logf(10000.f) * (float)jj / 128.f);
        float ang = (float)t[b] * freq;
        v = (j < 128) ? cosf(ang) : sinf(ang);
    }
    tembP[i] = f2bf(v);
}

__global__ void add_ftime(float* __restrict__ traj, const float* __restrict__ wf, int total) {
    int i = blockIdx.x * blockDim.x + threadIdx.x;
    if (i >= total) return;
    int col = i % D;
    int n = (i / D) % TTRAJ;
    traj[i] += wf[(n & 7) * D + col];
}

__global__ void cvt_bf16(const float* __restrict__ in, unsigned short* __restrict__ out, int n8) {
    int i = blockIdx.x * blockDim.x + threadIdx.x;
    if (i >= n8) return;
    float4 a = *(const float4*)(in + i * 8);
    float4 b = *(const float4*)(in + i * 8 + 4);
    unsigned short t[8] = {f2bf(a.x), f2bf(a.y), f2bf(a.z), f2bf(a.w),
                           f2bf(b.x), f2bf(b.y), f2bf(b.z), f2bf(b.w)};
    *(short8v*)(out + i * 8) = *(short8v*)t;
}

// ---------------- small f32 GEMM (traj embed, K=7) ----------------
template<int ACT>
__global__ __launch_bounds__(256) void gemm_act(
    const float* __restrict__ A, int lda,
    const float* __restrict__ B, int ldb,
    const float* __restrict__ bias,
    float* __restrict__ C, int ldc,
    int M, int N, int K)
{
    __shared__ float As[16][65];
    __shared__ float Bs[16][65];
    int tid = threadIdx.x;
    int tx = tid & 15, ty = tid >> 4;
    int row0 = blockIdx.y * 64, col0 = blockIdx.x * 64;
    float acc[4][4] = {};
    for (int k0 = 0; k0 < K; k0 += 16) {
        #pragma unroll
        for (int i = 0; i < 4; ++i) {
            int e = tid + 256 * i; int m = e >> 4; int kk = e & 15;
            int gr = row0 + m, gk = k0 + kk;
            As[kk][m] = (gr < M && gk < K) ? A[(size_t)gr * lda + gk] : 0.f;
        }
        #pragma unroll
        for (int i = 0; i < 4; ++i) {
            int e = tid + 256 * i; int kk = e >> 6; int n = e & 63;
            int gk = k0 + kk, gc = col0 + n;
            Bs[kk][n] = (gk < K && gc < N) ? B[(size_t)gk * ldb + gc] : 0.f;
        }
        __syncthreads();
        #pragma unroll
        for (int kk = 0; kk < 16; ++kk) {
            float a[4], bv[4];
            #pragma unroll
            for (int i = 0; i < 4; ++i) a[i] = As[kk][ty * 4 + i];
            #pragma unroll
            for (int j = 0; j < 4; ++j) bv[j] = Bs[kk][tx * 4 + j];
            #pragma unroll
            for (int i = 0; i < 4; ++i)
                #pragma unroll
                for (int j = 0; j < 4; ++j) acc[i][j] += a[i] * bv[j];
        }
        __syncthreads();
    }
    #pragma unroll
    for (int i = 0; i < 4; ++i) {
        int gr = row0 + ty * 4 + i; if (gr >= M) continue;
        #pragma unroll
        for (int j = 0; j < 4; ++j) {
            int gc = col0 + tx * 4 + j; if (gc >= N) continue;
            float v = acc[i][j] + (bias ? bias[gc] : 0.f);
            if (ACT == 1) v = siluf(v);
            if (ACT == 2) v = geluf(v);
            C[(size_t)gr * ldc + gc] = v;
        }
    }
}

// ---------------- weight transpose + cvt ----------------
__global__ __launch_bounds__(256) void transpose_cvt(
    const float* __restrict__ in, unsigned short* __restrict__ out, int K, int N)
{
    __shared__ unsigned short Ls[64][72];
    const float* src = in + (size_t)blockIdx.z * K * N;
    unsigned short* dst = out + (size_t)blockIdx.z * K * N;
    int k0 = blockIdx.y * 64, n0 = blockIdx.x * 64;
    int tid = threadIdx.x;
    int r = tid >> 2, c0 = (tid & 3) * 16;
    {
        const float* sp = src + (size_t)(k0 + r) * N + n0 + c0;
        #pragma unroll
        for (int j = 0; j < 16; j += 4) {
            float4 f = *(const float4*)(sp + j);
            Ls[c0 + j + 0][r] = f2bf(f.x);
            Ls[c0 + j + 1][r] = f2bf(f.y);
            Ls[c0 + j + 2][r] = f2bf(f.z);
            Ls[c0 + j + 3][r] = f2bf(f.w);
        }
    }
    __syncthreads();
    {
        unsigned short tmp[16];
        #pragma unroll
        for (int j = 0; j < 16; ++j) tmp[j] = Ls[r][c0 + j];
        unsigned short* dp = dst + (size_t)(n0 + r) * K + k0 + c0;
        *(short8v*)dp = *(short8v*)tmp;
        *(short8v*)(dp + 8) = *(short8v*)(tmp + 8);
    }
}

// ---------------- MFMA GEMM: BK=32, dbuf, TM=128, TN=128/64, 4 waves ----
// OUT: 0 f32, 1 bf16 (+qscale), 2 bf16 gated residual (read-modify-write Cb).
template<int ACT, int OUT, int TN>
__global__ __launch_bounds__(256) void gemm_lds(
    const unsigned short* __restrict__ A,
    const unsigned short* __restrict__ BT,
    const float* __restrict__ bias,
    float* __restrict__ Cf, unsigned short* __restrict__ Cb, int ldc,
    int K, int qscale_cols,
    const float* __restrict__ mod, int modstride, int gchunk, int ntok, int mrows,
    size_t bt_zs = 0, size_t bias_zs = 0, size_t c_zs = 0)
{
    constexpr int NCF = TN / 32;
    constexpr int NBS = TN / 64;
    if (bt_zs) BT += (size_t)blockIdx.z * bt_zs;
    if (bias && bias_zs) bias += (size_t)blockIdx.z * bias_zs;
    if (c_zs) { if (Cf) Cf += (size_t)blockIdx.z * c_zs; if (Cb) Cb += (size_t)blockIdx.z * c_zs; }
    __shared__ unsigned short As[2][128 * 32];
    __shared__ unsigned short Bs[2][TN * 32];
    int tid = threadIdx.x, w = tid >> 6, lane = tid & 63;
    int row0 = blockIdx.y * 128, col0 = blockIdx.x * TN;
    int wrow = (w >> 1) * 64, wcol = (w & 1) * (TN / 2);
    int lr = lane & 15, g = lane >> 4;
    f32x4 acc[4][NCF] = {};

    int ra[2], ka[2], la[2];
    #pragma unroll
    for (int i = 0; i < 2; ++i) {
        int off = tid * 16 + i * 4096;
        int row = off >> 6;
        int slot = (off >> 4) & 3;
        ra[i] = row;
        ka[i] = (slot ^ ((row >> 1) & 3)) * 8;
        la[i] = off >> 1;
    }
    int nt = K >> 5, cur = 0;
    #pragma unroll
    for (int i = 0; i < 2; ++i)
        gl16(A + (size_t)(row0 + ra[i]) * K + ka[i], &As[0][la[i]]);
    #pragma unroll
    for (int i = 0; i < NBS; ++i)
        gl16(BT + (size_t)(col0 + ra[i]) * K + ka[i], &Bs[0][la[i]]);

    for (int t = 0; t < nt; ++t) {
        __syncthreads();
        if (t + 1 < nt) {
            int k0 = (t + 1) << 5;
            #pragma unroll
            for (int i = 0; i < 2; ++i)
                gl16(A + (size_t)(row0 + ra[i]) * K + k0 + ka[i], &As[cur ^ 1][la[i]]);
            #pragma unroll
            for (int i = 0; i < NBS; ++i)
                gl16(BT + (size_t)(col0 + ra[i]) * K + k0 + ka[i], &Bs[cur ^ 1][la[i]]);
        }
        short8v av[4], bv[NCF];
        #pragma unroll
        for (int mr = 0; mr < 4; ++mr) {
            int row = wrow + mr * 16 + lr;
            av[mr] = *(const short8v*)&As[cur][row * 32 + (g ^ ((row >> 1) & 3)) * 8];
        }
        #pragma unroll
        for (int nc = 0; nc < NCF; ++nc) {
            int row = wcol + nc * 16 + lr;
            bv[nc] = *(const short8v*)&Bs[cur][row * 32 + (g ^ ((row >> 1) & 3)) * 8];
        }
        #pragma unroll
        for (int mr = 0; mr < 4; ++mr)
            #pragma unroll
            for (int nc = 0; nc < NCF; ++nc)
                acc[mr][nc] = __builtin_amdgcn_mfma_f32_16x16x32_bf16(
                    av[mr], bv[nc], acc[mr][nc], 0, 0, 0);
        cur ^= 1;
    }
    int rbase = g * 4;
    #pragma unroll
    for (int mr = 0; mr < 4; ++mr) {
        #pragma unroll
        for (int nc = 0; nc < NCF; ++nc) {
            int gc = col0 + wcol + nc * 16 + lr;
            float bb = bias ? bias[gc] : 0.f;
            #pragma unroll
            for (int r = 0; r < 4; ++r) {
                int gr = row0 + wrow + mr * 16 + rbase + r;
                if (gr >= mrows) continue;
                float v = acc[mr][nc][r] + bb;
                if (ACT == 1) v = siluf(v);
                if (ACT == 2) v = geluf(v);
                if (OUT == 0) {
                    Cf[(size_t)gr * ldc + gc] = v;
                } else if (OUT == 1) {
                    if (gc < qscale_cols) v *= 0.125f;
                    Cb[(size_t)gr * ldc + gc] = f2bf(v);
                } else {
                    float gg = 1.f;
                    if (mod) gg = mod[(size_t)(gr / ntok) * modstride + gchunk * D + gc];
                    size_t idx = (size_t)gr * ldc + gc;
                    Cb[idx] = f2bf(bf2f(Cb[idx]) + gg * v);
                }
            }
        }
    }
}

// ---------------- MFMA GEMM: TM=256 x TN=128, 8 waves, 512 threads ----------
template<int ACT>
__global__ __launch_bounds__(512, 4) void gemm_lds256(
    const unsigned short* __restrict__ A,
    const unsigned short* __restrict__ BT,
    const float* __restrict__ bias,
    unsigned short* __restrict__ Cb, int ldc,
    int K, int qscale_cols)
{
    __shared__ unsigned short As[2][256 * 32];
    __shared__ unsigned short Bs[2][128 * 32];
    int tid = threadIdx.x, w = tid >> 6, lane = tid & 63;
    int row0 = blockIdx.y * 256, col0 = blockIdx.x * 128;
    int wrow = (w >> 1) * 64, wcol = (w & 1) * 64;
    int lr = lane & 15, g = lane >> 4;
    f32x4 acc[4][4] = {};

    int ra[2], ka[2], la[2];
    #pragma unroll
    for (int i = 0; i < 2; ++i) {
        int off = tid * 16 + i * 8192;
        int row = off >> 6;
        int slot = (off >> 4) & 3;
        ra[i] = row;
        ka[i] = (slot ^ ((row >> 1) & 3)) * 8;
        la[i] = off >> 1;
    }
    int rb, kb, lb;
    {
        int off = tid * 16;
        int row = off >> 6;
        int slot = (off >> 4) & 3;
        rb = row;
        kb = (slot ^ ((row >> 1) & 3)) * 8;
        lb = off >> 1;
    }
    int nt = K >> 5, cur = 0;
    #pragma unroll
    for (int i = 0; i < 2; ++i)
        gl16(A + (size_t)(row0 + ra[i]) * K + ka[i], &As[0][la[i]]);
    gl16(BT + (size_t)(col0 + rb) * K + kb, &Bs[0][lb]);

    for (int t = 0; t < nt; ++t) {
        __syncthreads();
        if (t + 1 < nt) {
            int k0 = (t + 1) << 5;
            #pragma unroll
            for (int i = 0; i < 2; ++i)
                gl16(A + (size_t)(row0 + ra[i]) * K + k0 + ka[i], &As[cur ^ 1][la[i]]);
            gl16(BT + (size_t)(col0 + rb) * K + k0 + kb, &Bs[cur ^ 1][lb]);
        }
        short8v av[4], bv[4];
        #pragma unroll
        for (int mr = 0; mr < 4; ++mr) {
            int row = wrow + mr * 16 + lr;
            av[mr] = *(const short8v*)&As[cur][row * 32 + (g ^ ((row >> 1) & 3)) * 8];
        }
        #pragma unroll
        for (int nc = 0; nc < 4; ++nc) {
            int row = wcol + nc * 16 + lr;
            bv[nc] = *(const short8v*)&Bs[cur][row * 32 + (g ^ ((row >> 1) & 3)) * 8];
        }
        #pragma unroll
        for (int mr = 0; mr < 4; ++mr)
            #pragma unroll
            for (int nc = 0; nc < 4; ++nc)
                acc[mr][nc] = __builtin_amdgcn_mfma_f32_16x16x32_bf16(
                    av[mr], bv[nc], acc[mr][nc], 0, 0, 0);
        cur ^= 1;
    }
    int rbase = g * 4;
    #pragma unroll
    for (int mr = 0; mr < 4; ++mr) {
        #pragma unroll
        for (int nc = 0; nc < 4; ++nc) {
            int gc = col0 + wcol + nc * 16 + lr;
            float bb = bias ? bias[gc] : 0.f;
            #pragma unroll
            for (int r = 0; r < 4; ++r) {
                int gr = row0 + wrow + mr * 16 + rbase + r;
                float v = acc[mr][nc][r] + bb;
                if (ACT == 2) v = geluf(v);
                if (gc < qscale_cols) v *= 0.125f;
                Cb[(size_t)gr * ldc + gc] = f2bf(v);
            }
        }
    }
}

// ---------------- MoE gathered MFMA GEMM ----------
// PHASE 1: lnb -> hbuf (gelu). PHASE 2: hbuf -> residual bf16 (+= gval*v).
template<int PHASE>
__global__ __launch_bounds__(256) void moe_lds(
    const unsigned short* __restrict__ A,
    const unsigned short* __restrict__ BTconv,
    unsigned short* __restrict__ Cb,
    const int* __restrict__ cnt, const int* __restrict__ list,
    const float* __restrict__ gval, int RT, int egbase)
{
    constexpr int K  = (PHASE == 1) ? 768 : 3072;
    constexpr int TN = (PHASE == 1) ? 128 : 64;
    constexpr int NCF = TN / 32;
    constexpr int NBS = TN / 64;
    int egl = blockIdx.y / RT, rt = blockIdx.y % RT;
    int eg = egbase + egl;
    int c0 = cnt[eg];
    int mbase = rt * 128;
    if (mbase >= c0) return;
    int mcount = min(128, c0 - mbase);
    __shared__ int toks[128];
    int tid = threadIdx.x, w = tid >> 6, lane = tid & 63;
    if (tid < 128) toks[tid] = list[eg * MAXTOK + mbase + min(tid, mcount - 1)];
    __syncthreads();

    __shared__ unsigned short As[2][128 * 32];
    __shared__ unsigned short Bs[2][TN * 32];
    const unsigned short* BT = BTconv + (size_t)egl * (768 * 3072);
    int col0 = blockIdx.x * TN;
    int wrow = (w >> 1) * 64, wcol = (w & 1) * (TN / 2);
    int lr = lane & 15, g = lane >> 4;
    f32x4 acc[4][NCF] = {};

    int ra[2], ka[2], la[2], tok_s[2];
    #pragma unroll
    for (int i = 0; i < 2; ++i) {
        int off = tid * 16 + i * 4096;
        int row = off >> 6;
        int slot = (off >> 4) & 3;
        ra[i] = row;
        ka[i] = (slot ^ ((row >> 1) & 3)) * 8;
        la[i] = off >> 1;
        tok_s[i] = toks[row];
    }
    int nt = K >> 5, cur = 0;
    #pragma unroll
    for (int i = 0; i < 2; ++i)
        gl16(A + (size_t)tok_s[i] * K + ka[i], &As[0][la[i]]);
    #pragma unroll
    for (int i = 0; i < NBS; ++i)
        gl16(BT + (size_t)(col0 + ra[i]) * K + ka[i], &Bs[0][la[i]]);

    for (int t = 0; t < nt; ++t) {
        __syncthreads();
        if (t + 1 < nt) {
            int k0 = (t + 1) << 5;
            #pragma unroll
            for (int i = 0; i < 2; ++i)
                gl16(A + (size_t)tok_s[i] * K + k0 + ka[i], &As[cur ^ 1][la[i]]);
            #pragma unroll
            for (int i = 0; i < NBS; ++i)
                gl16(BT + (size_t)(col0 + ra[i]) * K + k0 + ka[i], &Bs[cur ^ 1][la[i]]);
        }
        short8v av[4], bv[NCF];
        #pragma unroll
        for (int mr = 0; mr < 4; ++mr) {
            int row = wrow + mr * 16 + lr;
            av[mr] = *(const short8v*)&As[cur][row * 32 + (g ^ ((row >> 1) & 3)) * 8];
        }
        #pragma unroll
        for (int nc = 0; nc < NCF; ++nc) {
            int row = wcol + nc * 16 + lr;
            bv[nc] = *(const short8v*)&Bs[cur][row * 32 + (g ^ ((row >> 1) & 3)) * 8];
        }
        #pragma unroll
        for (int mr = 0; mr < 4; ++mr)
            #pragma unroll
            for (int nc = 0; nc < NCF; ++nc)
                acc[mr][nc] = __builtin_amdgcn_mfma_f32_16x16x32_bf16(
                    av[mr], bv[nc], acc[mr][nc], 0, 0, 0);
        cur ^= 1;
    }
    int rbase = g * 4;
    #pragma unroll
    for (int mr = 0; mr < 4; ++mr) {
        #pragma unroll
        for (int r = 0; r < 4; ++r) {
            int m = wrow + mr * 16 + rbase + r;
            if (m >= mcount) continue;
            int tok = toks[m];
            #pragma unroll
            for (int nc = 0; nc < NCF; ++nc) {
                int gc = col0 + wcol + nc * 16 + lr;
                float v = acc[mr][nc][r];
                if (PHASE == 1) Cb[(size_t)tok * 3072 + gc] = f2bf(geluf(v));
                else {
                    size_t idx = (size_t)tok * 768 + gc;
                    Cb[idx] = f2bf(bf2f(Cb[idx]) + gval[tok] * v);
                }
            }
        }
    }
}

// ---------------- LayerNorm (bf16 in) -> bf16 ----------------
__global__ __launch_bounds__(256) void ln_kernel(
    const unsigned short* __restrict__ X, unsigned short* __restrict__ Y, int R, int ntok,
    const float* __restrict__ mod, int modstride, int shift_chunk, int scale_chunk)
{
    int r = blockIdx.x;
    if (r >= R) return;
    const unsigned short* xr = X + (size_t)r * D;
    int tid = threadIdx.x;
    int lane = tid & 63, wid = tid >> 6;
    float v0 = bf2f(xr[tid]), v1 = bf2f(xr[tid + 256]), v2 = bf2f(xr[tid + 512]);
    float s = v0 + v1 + v2;
    float s2 = v0 * v0 + v1 * v1 + v2 * v2;
    for (int off = 32; off > 0; off >>= 1) {
        s += __shfl_xor(s, off, 64);
        s2 += __shfl_xor(s2, off, 64);
    }
    __shared__ float shs[4], shs2[4];
    if (lane == 0) { shs[wid] = s; shs2[wid] = s2; }
    __syncthreads();
    float tot = shs[0] + shs[1] + shs[2] + shs[3];
    float tot2 = shs2[0] + shs2[1] + shs2[2] + shs2[3];
    float mu = tot * (1.f / 768.f);
    float var = tot2 * (1.f / 768.f) - mu * mu;
    float rs = rsqrtf(var + 1e-6f);
    int bb = r / ntok;
    float vv[3] = {v0, v1, v2};
    #pragma unroll
    for (int j = 0; j < 3; ++j) {
        int col = tid + j * 256;
        float nrm = (vv[j] - mu) * rs;
        float y = nrm;
        if (mod) {
            float scv = mod[(size_t)bb * modstride + scale_chunk * D + col];
            float shv = mod[(size_t)bb * modstride + shift_chunk * D + col];
            y = nrm * (1.f + scv) + shv;
        }
        Y[(size_t)r * D + col] = f2bf(y);
    }
}

// ---------------- MFMA flash attention (V transposed in-kernel) ----------
__global__ __launch_bounds__(512) void attn_mfma(
    const unsigned short* __restrict__ Qp, int ldq, int qoff,
    const unsigned short* __restrict__ Kp, int ldk, int koff,
    const unsigned short* __restrict__ Vp, int ldv, int voff,
    unsigned short* __restrict__ O, int ldo,
    int Nq, int Nkv)
{
    __shared__ unsigned short Qs[128 * 64];
    __shared__ unsigned short Ks[64 * 64];
    __shared__ unsigned short Vs[64 * 64];
    __shared__ unsigned short Ps[128 * 64];
    int h = blockIdx.y, b = blockIdx.z, q0 = blockIdx.x * 128;
    int tid = threadIdx.x, w = tid >> 6, lane = tid & 63;
    int wrow = w * 16;
    int lr = lane & 15, g = lane >> 4;

    {
        int srow = tid >> 2, sc = (tid & 3) * 16;
        int gr = min(q0 + srow, Nq - 1);
        const unsigned short* qp = Qp + (size_t)(b * Nq + gr) * ldq + qoff + h * 64 + sc;
        short8v v0 = *(const short8v*)qp, v1 = *(const short8v*)(qp + 8);
        int s0 = sc >> 3;
        *(short8v*)&Qs[srow * 64 + (s0 ^ (srow & 7)) * 8] = v0;
        *(short8v*)&Qs[srow * 64 + ((s0 + 1) ^ (srow & 7)) * 8] = v1;
    }
    float m_r[4] = {-1e30f, -1e30f, -1e30f, -1e30f};
    float l_r[4] = {};
    f32x4 acc0 = {}, acc1 = {}, acc2 = {}, acc3 = {};

    for (int kv0 = 0; kv0 < Nkv; kv0 += 64) {
        {
            int t2 = tid & 255;
            int srow = t2 >> 2, sc = (t2 & 3) * 16;
            int gc = min(kv0 + srow, Nkv - 1);
            if (tid < 256) {
                const unsigned short* kp = Kp + (size_t)(b * Nkv + gc) * ldk + koff + h * 64 + sc;
                short8v v0 = *(const short8v*)kp, v1 = *(const short8v*)(kp + 8);
                int s0 = sc >> 3;
                *(short8v*)&Ks[srow * 64 + (s0 ^ (srow & 7)) * 8] = v0;
                *(short8v*)&Ks[srow * 64 + ((s0 + 1) ^ (srow & 7)) * 8] = v1;
            } else {
                const unsigned short* vp = Vp + (size_t)(b * Nkv + gc) * ldv + voff + h * 64 + sc;
                #pragma unroll
                for (int j = 0; j < 16; ++j) {
                    int d = sc + j;
                    Vs[d * 64 + (((srow >> 3) ^ (d & 7)) * 8) + (srow & 7)] = vp[j];
                }
            }
        }
        __syncthreads();
        short8v aq0, aq1;
        {
            int row = wrow + lr;
            aq0 = *(const short8v*)&Qs[row * 64 + ((0 + g) ^ (row & 7)) * 8];
            aq1 = *(const short8v*)&Qs[row * 64 + ((4 + g) ^ (row & 7)) * 8];
        }
        f32x4 sf[4];
        #pragma unroll
        for (int nc = 0; nc < 4; ++nc) {
            int row = nc * 16 + lr;
            short8v bk0 = *(const short8v*)&Ks[row * 64 + ((0 + g) ^ (row & 7)) * 8];
            short8v bk1 = *(const short8v*)&Ks[row * 64 + ((4 + g) ^ (row & 7)) * 8];
            f32x4 z = {};
            z = __builtin_amdgcn_mfma_f32_16x16x32_bf16(aq0, bk0, z, 0, 0, 0);
            sf[nc] = __builtin_amdgcn_mfma_f32_16x16x32_bf16(aq1, bk1, z, 0, 0, 0);
        }
        bool val0 = (kv0 + 0 * 16 + lr) < Nkv;
        bool val1 = (kv0 + 1 * 16 + lr) < Nkv;
        bool val2 = (kv0 + 2 * 16 + lr) < Nkv;
        bool val3 = (kv0 + 3 * 16 + lr) < Nkv;
        float fs[4];
        #pragma unroll
        for (int r = 0; r < 4; ++r) {
            float s0 = val0 ? sf[0][r] : -1e30f;
            float s1 = val1 ? sf[1][r] : -1e30f;
            float s2 = val2 ? sf[2][r] : -1e30f;
            float s3 = val3 ? sf[3][r] : -1e30f;
            float mx = fmaxf(fmaxf(s0, s1), fmaxf(s2, s3));
            mx = fmaxf(mx, __shfl_xor(mx, 1, 64));
            mx = fmaxf(mx, __shfl_xor(mx, 2, 64));
            mx = fmaxf(mx, __shfl_xor(mx, 4, 64));
            mx = fmaxf(mx, __shfl_xor(mx, 8, 64));
            float mn = fmaxf(m_r[r], mx);
            fs[r] = __expf(m_r[r] - mn);
            m_r[r] = mn;
            float p0 = __expf(s0 - mn), p1 = __expf(s1 - mn);
            float p2 = __expf(s2 - mn), p3 = __expf(s3 - mn);
            float rsum = p0 + p1 + p2 + p3;
            rsum += __shfl_xor(rsum, 1, 64);
            rsum += __shfl_xor(rsum, 2, 64);
            rsum += __shfl_xor(rsum, 4, 64);
            rsum += __shfl_xor(rsum, 8, 64);
            l_r[r] = l_r[r] * fs[r] + rsum;
            int ql = wrow + g * 4 + r;
            int base = ql * 64;
            int x7 = ql & 7;
            Ps[base + (((0 * 16 + lr) >> 3) ^ x7) * 8 + (lr & 7)] = f2bf(p0);
            Ps[base + (((1 * 16 + lr) >> 3) ^ x7) * 8 + (lr & 7)] = f2bf(p1);
            Ps[base + (((2 * 16 + lr) >> 3) ^ x7) * 8 + (lr & 7)] = f2bf(p2);
            Ps[base + (((3 * 16 + lr) >> 3) ^ x7) * 8 + (lr & 7)] = f2bf(p3);
            acc0[r] *= fs[r]; acc1[r] *= fs[r]; acc2[r] *= fs[r]; acc3[r] *= fs[r];
        }
        __syncthreads();
        short8v ap0, ap1;
        {
            int row = wrow + lr;
            ap0 = *(const short8v*)&Ps[row * 64 + ((0 + g) ^ (row & 7)) * 8];
            ap1 = *(const short8v*)&Ps[row * 64 + ((4 + g) ^ (row & 7)) * 8];
        }
        {
            int row = 0 * 16 + lr;
            short8v b0 = *(const short8v*)&Vs[row * 64 + ((0 + g) ^ (row & 7)) * 8];
            short8v b1 = *(const short8v*)&Vs[row * 64 + ((4 + g) ^ (row & 7)) * 8];
            acc0 = __builtin_amdgcn_mfma_f32_16x16x32_bf16(ap0, b0, acc0, 0, 0, 0);
            acc0 = __builtin_amdgcn_mfma_f32_16x16x32_bf16(ap1, b1, acc0, 0, 0, 0);
        }
        {
            int row = 1 * 16 + lr;
            short8v b0 = *(const short8v*)&Vs[row * 64 + ((0 + g) ^ (row & 7)) * 8];
            short8v b1 = *(const short8v*)&Vs[row * 64 + ((4 + g) ^ (row & 7)) * 8];
            acc1 = __builtin_amdgcn_mfma_f32_16x16x32_bf16(ap0, b0, acc1, 0, 0, 0);
            acc1 = __builtin_amdgcn_mfma_f32_16x16x32_bf16(ap1, b1, acc1, 0, 0, 0);
        }
        {
            int row = 2 * 16 + lr;
            short8v b0 = *(const short8v*)&Vs[row * 64 + ((0 + g) ^ (row & 7)) * 8];
            short8v b1 = *(const short8v*)&Vs[row * 64 + ((4 + g) ^ (row & 7)) * 8];
            acc2 = __builtin_amdgcn_mfma_f32_16x16x32_bf16(ap0, b0, acc2, 0, 0, 0);
            acc2 = __builtin_amdgcn_mfma_f32_16x16x32_bf16(ap1, b1, acc2, 0, 0, 0);
        }
        {
            int row = 3 * 16 + lr;
            short8v b0 = *(const short8v*)&Vs[row * 64 + ((0 + g) ^ (row & 7)) * 8];
            short8v b1 = *(const short8v*)&Vs[row * 64 + ((4 + g) ^ (row & 7)) * 8];
            acc3 = __builtin_amdgcn_mfma_f32_16x16x32_bf16(ap0, b0, acc3, 0, 0, 0);
            acc3 = __builtin_amdgcn_mfma_f32_16x16x32_bf16(ap1, b1, acc3, 0, 0, 0);
        }
        __syncthreads();
    }
    #pragma unroll
    for (int r = 0; r < 4; ++r) {
        int ql = wrow + g * 4 + r;
        if (q0 + ql >= Nq) continue;
        float rl = 1.f / l_r[r];
        unsigned short* op = O + (size_t)(b * Nq + q0 + ql) * ldo + h * 64 + lr;
        op[0]  = f2bf(acc0[r] * rl);
        op[16] = f2bf(acc1[r] * rl);
        op[32] = f2bf(acc2[r] * rl);
        op[48] = f2bf(acc3[r] * rl);
    }
}

// ---------------- MoE router ----------------
__global__ __launch_bounds__(64) void router_kernel(
    const unsigned short* __restrict__ X, const float* __restrict__ WrBase,
    int* __restrict__ idx, float* __restrict__ gval)
{
    int tkn = blockIdx.x; int lane = threadIdx.x;
    int grp = (tkn >= 768) ? 2 : (tkn >= 512 ? 1 : 0);
    const float* Wr = WrBase + (size_t)grp * D * NEXP;
    const unsigned short* xr = X + (size_t)tkn * D;
    float p0 = 0, p1 = 0, p2 = 0, p3 = 0;
    for (int dd = lane; dd < D; dd += 64) {
        float xv = bf2f(xr[dd]);
        const float* wq = Wr + dd * 4;
        p0 += xv * wq[0]; p1 += xv * wq[1]; p2 += xv * wq[2]; p3 += xv * wq[3];
    }
    for (int off = 32; off > 0; off >>= 1) {
        p0 += __shfl_xor(p0, off, 64); p1 += __shfl_xor(p1, off, 64);
        p2 += __shfl_xor(p2, off, 64); p3 += __shfl_xor(p3, off, 64);
    }
    if (lane == 0) {
        float best = p0; int e = 0;
        if (p1 > best) { best = p1; e = 1; }
        if (p2 > best) { best = p2; e = 2; }
        if (p3 > best) { best = p3; e = 3; }
        float sum = expf(p0 - best) + expf(p1 - best) + expf(p2 - best) + expf(p3 - best);
        idx[tkn] = grp * 4 + e;
        gval[tkn] = 1.f / sum;
    }
}

__global__ __launch_bounds__(256) void scatter_kernel(
    const int* __restrict__ idx, int* __restrict__ cnt,
    int* __restrict__ list, int ntok)
{
    __shared__ int lcnt[12];
    int tid = threadIdx.x;
    if (tid < 12) lcnt[tid] = 0;
    __syncthreads();
    for (int i = tid; i < ntok; i += 256) {
        int e = idx[i];
        int pos = atomicAdd(&lcnt[e], 1);
        list[e * MAXTOK + pos] = i;
    }
    __syncthreads();
    if (tid < 12) cnt[tid] = lcnt[tid];
}

// ---------------- concat (traj f32 + groups bf16 -> x bf16) ----------------
__global__ void concat_kernel(const float* __restrict__ traj, const unsigned short* __restrict__ a,
                              const unsigned short* __restrict__ bg, const unsigned short* __restrict__ cg,
                              unsigned short* __restrict__ x, int total)
{
    int i = blockIdx.x * blockDim.x + threadIdx.x;
    if (i >= total) return;
    int col = i % D;
    int r = i / D;
    int n = r % NTOK, b = r / NTOK;
    unsigned short v;
    if (n < 256)      v = f2bf(traj[((size_t)b * 256 + n) * D + col]);
    else if (n < 320) v = a[((size_t)b * 64 + (n - 256)) * D + col];
    else if (n < 352) v = bg[((size_t)b * 32 + (n - 320)) * D + col];
    else              v = cg[((size_t)b * 192 + (n - 352)) * D + col];
    x[i] = v;
}

// ---------------- output head ----------------
__global__ void head_prep(const float* __restrict__ W, unsigned short* __restrict__ WT14) {
    int i = blockIdx.x * blockDim.x + threadIdx.x;
    if (i >= 14 * 768) return;
    int o = i / 768, d = i % 768;
    WT14[i] = f2bf(W[d * 14 + o]);
}

__global__ __launch_bounds__(64) void head_kernel(
    const unsigned short* __restrict__ lnb, const unsigned short* __restrict__ WT14,
    const float* __restrict__ bias, float* __restrict__ out)
{
    int r = blockIdx.x;
    int b = r >> 8, n = r & 255;
    const unsigned short* hrow = lnb + (size_t)(b * NTOK + n) * D;
    int l = threadIdx.x;
    if (l >= 56) return;
    int o = l >> 2, p = l & 3;
    const unsigned short* hp = hrow + p * 192;
    const unsigned short* wp = WT14 + o * 768 + p * 192;
    float acc = 0.f;
    for (int i = 0; i < 192; i += 8) {
        short8v hv = *(const short8v*)(hp + i);
        short8v wv = *(const short8v*)(wp + i);
        #pragma unroll
        for (int j = 0; j < 8; ++j)
            acc += bf2f((unsigned short)hv[j]) * bf2f((unsigned short)wv[j]);
    }
    acc += __shfl_xor(acc, 1, 64);
    acc += __shfl_xor(acc, 2, 64);
    if (p == 0) out[(size_t)r * 14 + o] = acc + bias[o];
}

// ---------------- host helpers ----------------
static inline void tcvt(const float* W, unsigned short* WT, int K, int N, int z, hipStream_t s) {
    transpose_cvt<<<dim3(N / 64, K / 64, z), 256, 0, s>>>(W, WT, K, N);
}
static inline void g_bf(int act, const unsigned short* A, const unsigned short* BT,
                        const float* bias, unsigned short* C, int ldc,
                        int M, int N, int K, int qcols, hipStream_t s)
{
    if (M % 256 == 0 && N % 128 == 0 && N >= 2304) {
        dim3 g(N / 128, M / 256);
        if (act == 2) gemm_lds256<2><<<g, 512, 0, s>>>(A, BT, bias, C, ldc, K, qcols);
        else          gemm_lds256<0><<<g, 512, 0, s>>>(A, BT, bias, C, ldc, K, qcols);
        return;
    }
    if (N != 768) {
        dim3 g(N / 128, M / 128);
        if (act == 2) gemm_lds<2, 1, 128><<<g, 256, 0, s>>>(A, BT, bias, nullptr, C, ldc, K, qcols, nullptr, 0, 0, 1, 1 << 30);
        else          gemm_lds<0, 1, 128><<<g, 256, 0, s>>>(A, BT, bias, nullptr, C, ldc, K, qcols, nullptr, 0, 0, 1, 1 << 30);
    } else {
        dim3 g(N / 64, M / 128);
        if (act == 2) gemm_lds<2, 1, 64><<<g, 256, 0, s>>>(A, BT, bias, nullptr, C, ldc, K, qcols, nullptr, 0, 0, 1, 1 << 30);
        else          gemm_lds<0, 1, 64><<<g, 256, 0, s>>>(A, BT, bias, nullptr, C, ldc, K, qcols, nullptr, 0, 0, 1, 1 << 30);
    }
}
static inline void g_res(const unsigned short* A, const unsigned short* BT,
                         const float* bias, unsigned short* C, int ldc, int M, int N, int K,
                         const float* mod, int modstride, int gchunk, int ntok, hipStream_t s)
{
    dim3 g(N / 64, M / 128);
    gemm_lds<0, 2, 64><<<g, 256, 0, s>>>(A, BT, bias, nullptr, C, ldc, K, 0, mod, modstride, gchunk, ntok, 1 << 30);
}

extern "C" void kernel_launch(void* const* d_in, const int* in_sizes, int n_in,
                              void* d_out, int out_size, void* d_ws, size_t ws_size,
                              hipStream_t stream)
{
    const float* x_traj   = (const float*)d_in[0];
    const int*   t_arr    = (const int*)d_in[1];
    const float* tokA     = (const float*)d_in[2];
    const float* tokB     = (const float*)d_in[3];
    const float* tokC     = (const float*)d_in[4];
    const float* W_traj   = (const float*)d_in[5];
    const float* b_traj   = (const float*)d_in[6];
    const float* W_ftime  = (const float*)d_in[7];
    const float* Wt1      = (const float*)d_in[8];
    const float* bt1      = (const float*)d_in[9];
    const float* Wt2      = (const float*)d_in[10];
    const float* bt2      = (const float*)d_in[11];
    const float* moe_attn = (const float*)d_in[12];
    const float* moe_rout = (const float*)d_in[13];
    const float* moe_W1   = (const float*)d_in[14];
    const float* moe_W2   = (const float*)d_in[15];
    const float* dit_qkv  = (const float*)d_in[16];
    const float* dit_qkvb = (const float*)d_in[17];
    const float* dit_proj = (const float*)d_in[18];
    const float* dit_projb= (const float*)d_in[19];
    const float* dit_mlp1 = (const float*)d_in[20];
    const float* dit_mlp1b= (const float*)d_in[21];
    const float* dit_mlp2 = (const float*)d_in[22];
    const float* dit_mlp2b= (const float*)d_in[23];
    const float* dit_ada  = (const float*)d_in[24];
    const float* dit_adab = (const float*)d_in[25];
    const float* out_adaW = (const float*)d_in[26];
    const float* out_adab = (const float*)d_in[27];
    const float* out_W    = (const float*)d_in[28];
    const float* out_b    = (const float*)d_in[29];
    float* out = (float*)d_out;
    float* ws = (float*)d_ws;

    const size_t o_cnt  = 14336;
    const size_t o_idx  = 14400;
    const size_t o_gval = 16704;
    const size_t o_list = 19008;
    const size_t o_traj = 66624;             // f32 traj; later mod buffers
    const size_t o_a    = 1639488;           // bf16 a|bg|cg = 2304x768 shorts
    const size_t o_x    = 3408960;           // bf16 x = 4352x768 shorts
    const size_t o_lnb  = 6751296;
    const size_t o_qkvb = 8422464;
    const size_t o_attnO= 13435968;
    const size_t o_h    = 15107136;
    const size_t o_wt   = 24151104;
    const size_t o_wt14 = 28869696;
    const size_t o_tembP= 28875072;
    const size_t o_ub   = 28891456;
    const size_t o_scb  = 28940608;
    const size_t o_mod  = o_traj;
    const size_t o_mod2 = o_traj + 221184;

    const size_t o_wqkv  = 29000000;
    const size_t o_wproj = 34308416;
    const size_t o_wmlp1 = 36077888;
    const size_t o_wmlp2 = 43155776;
    const size_t o_wada  = 50233664;
    const size_t o_wada2 = 60850496;
    const size_t o_wcross= 61440320;
    const size_t o_wmoe1 = 66158912;
    const size_t o_wmoe2 = 94470464;
    const bool bigw = ws_size >= (size_t)123000000 * 4;

    int* cnt_p  = (int*)(ws + o_cnt);
    int* idx_p  = (int*)(ws + o_idx);
    int* list_p = (int*)(ws + o_list);
    float* gval_p = ws + o_gval;
    unsigned short* abf  = (unsigned short*)(ws + o_a);
    unsigned short* bgbf = abf + 512 * 768;
    unsigned short* cgbf = abf + 768 * 768;
    unsigned short* xbf  = (unsigned short*)(ws + o_x);
    unsigned short* lnb  = (unsigned short*)(ws + o_lnb);
    unsigned short* qkvb = (unsigned short*)(ws + o_qkvb);
    unsigned short* attO = (unsigned short*)(ws + o_attnO);
    unsigned short* hbuf = (unsigned short*)(ws + o_h);
    unsigned short* wt   = (unsigned short*)(ws + o_wt);
    unsigned short* wt14 = (unsigned short*)(ws + o_wt14);
    unsigned short* tembP= (unsigned short*)(ws + o_tembP);
    unsigned short* ub   = (unsigned short*)(ws + o_ub);
    unsigned short* scb  = (unsigned short*)(ws + o_scb);
    unsigned short* wqkvS = (unsigned short*)(ws + o_wqkv);
    unsigned short* wprojS= (unsigned short*)(ws + o_wproj);
    unsigned short* wmlp1S= (unsigned short*)(ws + o_wmlp1);
    unsigned short* wmlp2S= (unsigned short*)(ws + o_wmlp2);
    unsigned short* wadaS = (unsigned short*)(ws + o_wada);
    unsigned short* wada2S= (unsigned short*)(ws + o_wada2);
    unsigned short* wcrossS=(unsigned short*)(ws + o_wcross);
    unsigned short* wmoe1S= (unsigned short*)(ws + o_wmoe1);
    unsigned short* wmoe2S= (unsigned short*)(ws + o_wmoe2);
    unsigned short* c_q  = qkvb;
    unsigned short* c_kv = qkvb + 1179648;

    const size_t WSZ = (size_t)D * D;

    gemm_act<0><<<dim3(12, 32), 256, 0, stream>>>(x_traj, 7, W_traj, D, b_traj,
                                                  ws + o_traj, D, BATCH * TTRAJ, D, 7);
    add_ftime<<<(BATCH * TTRAJ * D + 255) / 256, 256, 0, stream>>>(ws + o_traj, W_ftime, BATCH * TTRAJ * D);

    cvt_bf16<<<(512 * 768 / 8 + 255) / 256, 256, 0, stream>>>(tokA, abf, 512 * 768 / 8);
    cvt_bf16<<<(256 * 768 / 8 + 255) / 256, 256, 0, stream>>>(tokB, bgbf, 256 * 768 / 8);
    cvt_bf16<<<(1536 * 768 / 8 + 255) / 256, 256, 0, stream>>>(tokC, cgbf, 1536 * 768 / 8);
    head_prep<<<42, 256, 0, stream>>>(out_W, wt14);

    if (bigw) {
        tcvt(dit_qkv,  wqkvS,  D, 3 * D, DEPTH, stream);
        tcvt(dit_proj, wprojS, D, D, DEPTH, stream);
        tcvt(dit_mlp1, wmlp1S, D, FF, DEPTH, stream);
        tcvt(dit_mlp2, wmlp2S, FF, D, DEPTH, stream);
        tcvt(dit_ada,  wadaS,  D, 6 * D, DEPTH, stream);
        tcvt(out_adaW, wada2S, D, 2 * D, 1, stream);
        tcvt(moe_attn, wcrossS, D, D, NBLK * 2 * 4, stream);
        tcvt(moe_W1,   wmoe1S, D, FF, NBLK * 3 * NEXP, stream);
        tcvt(moe_W2,   wmoe2S, FF, D, NBLK * 3 * NEXP, stream);
    }

    timestep_kernel<<<128, 256, 0, stream>>>(t_arr, tembP);
    tcvt(Wt1, wt, 256, D, 1, stream);
    gemm_lds<1, 1, 64><<<dim3(12, 1), 256, 0, stream>>>(
        tembP, wt, bt1, nullptr, ub, D, 256, 0, nullptr, 0, 0, 1, 128);
    tcvt(Wt2, wt, D, D, 1, stream);
    gemm_lds<1, 1, 64><<<dim3(12, 1), 256, 0, stream>>>(
        ub, wt, bt2, nullptr, scb, D, D, 0, nullptr, 0, 0, 1, 128);

    for (int i = 0; i < NBLK; ++i) {
        {
            const unsigned short* Wc;
            if (bigw) Wc = wcrossS + (size_t)(i * 2 + 0) * 4 * WSZ;
            else { tcvt(moe_attn + (size_t)(i * 2 + 0) * 4 * WSZ, wt, D, D, 4, stream); Wc = wt; }
            ln_kernel<<<BATCH * NC, 256, 0, stream>>>(cgbf, lnb, BATCH * NC, 1, nullptr, 0, 0, 0);
            g_bf(0, lnb, Wc, nullptr, c_q, D, BATCH * NC, D, D, 768, stream);
            g_bf(0, abf, Wc + 1 * WSZ, nullptr, c_kv, 2 * D, BATCH * NA, 2 * D, D, 0, stream);
            attn_mfma<<<dim3((NC + 127) / 128, NH, BATCH), 512, 0, stream>>>(
                c_q, D, 0, c_kv, 2 * D, 0, c_kv, 2 * D, D, attO, D, NC, NA);
            g_res(attO, Wc + 3 * WSZ, nullptr, cgbf, D, BATCH * NC, D, D, nullptr, 0, 0, 1, stream);
        }
        {
            const unsigned short* Wc;
            if (bigw) Wc = wcrossS + (size_t)(i * 2 + 1) * 4 * WSZ;
            else { tcvt(moe_attn + (size_t)(i * 2 + 1) * 4 * WSZ, wt, D, D, 4, stream); Wc = wt; }
            ln_kernel<<<BATCH * NB, 256, 0, stream>>>(bgbf, lnb, BATCH * NB, 1, nullptr, 0, 0, 0);
            g_bf(0, lnb, Wc, nullptr, c_q, D, BATCH * NB, D, D, 768, stream);
            g_bf(0, cgbf, Wc + 1 * WSZ, nullptr, c_kv, 2 * D, BATCH * NC, 2 * D, D, 0, stream);
            attn_mfma<<<dim3(1, NH, BATCH), 512, 0, stream>>>(
                c_q, D, 0, c_kv, 2 * D, 0, c_kv, 2 * D, D, attO, D, NB, NC);
            g_res(attO, Wc + 3 * WSZ, nullptr, bgbf, D, BATCH * NB, D, D, nullptr, 0, 0, 1, stream);
        }
        ln_kernel<<<MOER, 256, 0, stream>>>(abf, lnb, MOER, 1, nullptr, 0, 0, 0);
        router_kernel<<<MOER, 64, 0, stream>>>(lnb, moe_rout + (size_t)(i * 3) * D * NEXP, idx_p, gval_p);
        scatter_kernel<<<1, 256, 0, stream>>>(idx_p, cnt_p, list_p, MOER);
        const int RT = 12;
        if (bigw) {
            moe_lds<1><<<dim3(24, 12 * RT), 256, 0, stream>>>(
                lnb, wmoe1S + (size_t)(i * 3) * NEXP * D * FF, hbuf,
                cnt_p, list_p, gval_p, RT, 0);
            moe_lds<2><<<dim3(12, 12 * RT), 256, 0, stream>>>(
                hbuf, wmoe2S + (size_t)(i * 3) * NEXP * D * FF, abf,
                cnt_p, list_p, gval_p, RT, 0);
        } else {
            for (int g = 0; g < 3; ++g) {
                tcvt(moe_W1 + (size_t)(i * 3 + g) * NEXP * D * FF, wt, D, FF, NEXP, stream);
                moe_lds<1><<<dim3(24, 4 * RT), 256, 0, stream>>>(
                    lnb, wt, hbuf, cnt_p, list_p, gval_p, RT, g * 4);
                tcvt(moe_W2 + (size_t)(i * 3 + g) * NEXP * FF * D, wt, FF, D, NEXP, stream);
                moe_lds<2><<<dim3(12, 4 * RT), 256, 0, stream>>>(
                    hbuf, wt, abf, cnt_p, list_p, gval_p, RT, g * 4);
            }
        }
    }

    concat_kernel<<<(BATCH * NTOK * D + 255) / 256, 256, 0, stream>>>(
        ws + o_traj, abf, bgbf, cgbf, xbf, BATCH * NTOK * D);

    if (bigw) {
        gemm_lds<0, 0, 128><<<dim3(36, 1, DEPTH), 256, 0, stream>>>(
            scb, wadaS, dit_adab, ws + o_mod, nullptr, 6 * D, D, 0,
            nullptr, 0, 0, 1, 8,
            (size_t)D * 6 * D, (size_t)6 * D, (size_t)8 * 6 * D);
        gemm_lds<0, 0, 128><<<dim3(12, 1), 256, 0, stream>>>(
            scb, wada2S, out_adab, ws + o_mod2, nullptr, 2 * D, D, 0, nullptr, 0, 0, 1, 8);
    } else {
        for (int i = 0; i < DEPTH; ++i) {
            tcvt(dit_ada + (size_t)i * D * 6 * D, wt, D, 6 * D, 1, stream);
            gemm_lds<0, 0, 128><<<dim3(36, 1), 256, 0, stream>>>(
                scb, wt, dit_adab + (size_t)i * 6 * D, ws + o_mod + (size_t)i * 8 * 6 * D,
                nullptr, 6 * D, D, 0, nullptr, 0, 0, 1, 8);
        }
        tcvt(out_adaW, wt, D, 2 * D, 1, stream);
        gemm_lds<0, 0, 128><<<dim3(12, 1), 256, 0, stream>>>(
            scb, wt, out_adab, ws + o_mod2, nullptr, 2 * D, D, 0, nullptr, 0, 0, 1, 8);
    }

    const int R = BATCH * NTOK;   // 4352 = 17*256
    for (int i = 0; i < DEPTH; ++i) {
        const float* mod_l = ws + o_mod + (size_t)i * 8 * 6 * D;
        const unsigned short *Wq = nullptr, *Wp = nullptr, *Wm1 = nullptr, *Wm2 = nullptr;
        if (bigw) {
            Wq  = wqkvS  + (size_t)i * D * 3 * D;
            Wp  = wprojS + (size_t)i * D * D;
            Wm1 = wmlp1S + (size_t)i * D * FF;
            Wm2 = wmlp2S + (size_t)i * D * FF;
        }
        ln_kernel<<<R, 256, 0, stream>>>(xbf, lnb, R, NTOK, mod_l, 6 * D, 0, 1);
        if (!bigw) { tcvt(dit_qkv + (size_t)i * D * 3 * D, wt, D, 3 * D, 1, stream); Wq = wt; }
        g_bf(0, lnb, Wq, dit_qkvb + (size_t)i * 3 * D, qkvb, 3 * D, R, 3 * D, D, 768, stream);
        attn_mfma<<<dim3((NTOK + 127) / 128, NH, BATCH), 512, 0, stream>>>(
            qkvb, 3 * D, 0, qkvb, 3 * D, D, qkvb, 3 * D, 2 * D, attO, D, NTOK, NTOK);
        if (!bigw) { tcvt(dit_proj + (size_t)i * D * D, wt, D, D, 1, stream); Wp = wt; }
        g_res(attO, Wp, dit_projb + (size_t)i * D, xbf, D, R, D, D,
              mod_l, 6 * D, 2, NTOK, stream);
        ln_kernel<<<R, 256, 0, stream>>>(xbf, lnb, R, NTOK, mod_l, 6 * D, 3, 4);
        if (!bigw) { tcvt(dit_mlp1 + (size_t)i * D * FF, wt, D, FF, 1, stream); Wm1 = wt; }
        g_bf(2, lnb, Wm1, dit_mlp1b + (size_t)i * FF, hbuf, FF, R, FF, D, 0, stream);
        if (!bigw) { tcvt(dit_mlp2 + (size_t)i * FF * D, wt, FF, D, 1, stream); Wm2 = wt; }
        g_res(hbuf, Wm2, dit_mlp2b + (size_t)i * D, xbf, D, R, D, FF,
              mod_l, 6 * D, 5, NTOK, stream);
    }

    ln_kernel<<<R, 256, 0, stream>>>(xbf, lnb, R, NTOK, ws + o_mod2, 2 * D, 0, 1);
    head_kernel<<<BATCH * TTRAJ, 64, 0, stream>>>(lnb, wt14, out_b, out);
}